// Round 9
// baseline (880.964 us; speedup 1.0000x reference)
//
#include <hip/hip_runtime.h>
#include <hip/hip_bf16.h>
#include <cstddef>

static constexpr int BATCH = 16;   // B

typedef __attribute__((ext_vector_type(8))) short bf16x8;
typedef __attribute__((ext_vector_type(4))) float f32x4;

__device__ __forceinline__ unsigned short f2bf(float f) {
  unsigned u = __float_as_uint(f);
  return (unsigned short)((u + 0x7fffu + ((u >> 16) & 1u)) >> 16);  // RNE
}

__global__ void init_kernel(float* __restrict__ tail, int n) {
  for (int i = threadIdx.x; i < n; i += 256) tail[i] = 0.f;
}

// ---- convert the 12 block-phase weight matrices to bf16 (layout [o][cin]) --
struct WcvtArgs { const float* p[12]; int sz[12]; int off[12]; };
__global__ __launch_bounds__(256)
void wcvt_kernel(WcvtArgs a, unsigned short* __restrict__ dst) {
  const int t = blockIdx.x;
  const float* src = a.p[t];
  unsigned short* d = dst + a.off[t];
  const int sz = a.sz[t];
  for (int i = blockIdx.y * 256 + threadIdx.x; i < sz; i += 16 * 256)
    d[i] = f2bf(src[i]);
}

// ---------------- q/k conv: f32 [b][c][n] -> bf16, dual layouts -------------
template<int TR>
__global__ __launch_bounds__(256)
void conv_qk_kernel(const float* __restrict__ X, const float* __restrict__ W,
                    const float* __restrict__ bias, unsigned short* __restrict__ Y) {
  __shared__ float wsT[64][4];
  const int tid = threadIdx.x;
  const int o0 = blockIdx.x << 2;
  const int b  = blockIdx.z;
  const int px = (blockIdx.y << 9) + (tid << 1);
  {
    int c = tid >> 2, k = tid & 3;
    wsT[c][k] = W[((o0 + k) << 6) + c];
  }
  __syncthreads();
  float acc[4][2] = {};
  const float* xb = X + ((size_t)b << 16) + px;
#pragma unroll 4
  for (int c = 0; c < 64; ++c) {
    float2 xv = *reinterpret_cast<const float2*>(xb + (c << 10));
    float4 w = *reinterpret_cast<const float4*>(wsT[c]);
    acc[0][0] = fmaf(w.x, xv.x, acc[0][0]); acc[0][1] = fmaf(w.x, xv.y, acc[0][1]);
    acc[1][0] = fmaf(w.y, xv.x, acc[1][0]); acc[1][1] = fmaf(w.y, xv.y, acc[1][1]);
    acc[2][0] = fmaf(w.z, xv.x, acc[2][0]); acc[2][1] = fmaf(w.z, xv.y, acc[2][1]);
    acc[3][0] = fmaf(w.w, xv.x, acc[3][0]); acc[3][1] = fmaf(w.w, xv.y, acc[3][1]);
  }
  float b0 = bias[o0], b1 = bias[o0 + 1], b2 = bias[o0 + 2], b3 = bias[o0 + 3];
  if (TR == 0) {
    ushort4 v0, v1;
    v0.x = f2bf(acc[0][0] + b0); v0.y = f2bf(acc[1][0] + b1);
    v0.z = f2bf(acc[2][0] + b2); v0.w = f2bf(acc[3][0] + b3);
    v1.x = f2bf(acc[0][1] + b0); v1.y = f2bf(acc[1][1] + b1);
    v1.z = f2bf(acc[2][1] + b2); v1.w = f2bf(acc[3][1] + b3);
    unsigned short* yt = Y + ((size_t)b << 16) + ((size_t)px << 6) + o0;
    *reinterpret_cast<ushort4*>(yt) = v0;
    *reinterpret_cast<ushort4*>(yt + 64) = v1;
  } else {
    float bv[4] = {b0, b1, b2, b3};
#pragma unroll
    for (int k = 0; k < 4; ++k) {
      ushort2 v;
      v.x = f2bf(acc[k][0] + bv[k]); v.y = f2bf(acc[k][1] + bv[k]);
      *reinterpret_cast<ushort2*>(Y + ((size_t)b << 16) + ((size_t)(o0 + k) << 10) + px) = v;
    }
  }
}

// ---- MFMA fused PV ---------------------------------------------------------
__global__ __launch_bounds__(256)
void pv_mfma_kernel(const unsigned short* __restrict__ QAt,
                    const unsigned short* __restrict__ QBt,
                    const unsigned short* __restrict__ KBc,
                    float* __restrict__ PART, float* __restrict__ bsum) {
  __shared__ __align__(16) unsigned short Ai[4096];
  __shared__ __align__(16) unsigned short Bj[4096];
  __shared__ __align__(16) unsigned short Pl[4096];
  __shared__ float red[256];
  const int tid = threadIdx.x;
  const int lane = tid & 63, w = tid >> 6;
  const int g = lane >> 4, m = lane & 15;
  const int i0 = blockIdx.x << 6;
  const int jbase = blockIdx.y << 8;
  const int b = blockIdx.z;
  const size_t nb = (size_t)b << 16;

  {
    const unsigned short* src = QAt + nb + ((size_t)i0 << 6);
#pragma unroll
    for (int s = 0; s < 2; ++s) {
      int idx = tid + (s << 8);
      int n = idx >> 3, cc = idx & 7;
      bf16x8 v = *reinterpret_cast<const bf16x8*>(src + (n << 6) + ((cc ^ (n & 7)) << 3));
      *reinterpret_cast<bf16x8*>(Ai + (idx << 3)) = v;
    }
  }
  f32x4 accO[4];
#pragma unroll
  for (int n = 0; n < 4; ++n) accO[n] = (f32x4){0.f, 0.f, 0.f, 0.f};
  float psum = 0.f;

  for (int jt = 0; jt < 4; ++jt) {
    const int j0 = jbase + (jt << 6);
    __syncthreads();
    {
      const unsigned short* src = QBt + nb + ((size_t)j0 << 6);
#pragma unroll
      for (int s = 0; s < 2; ++s) {
        int idx = tid + (s << 8);
        int n = idx >> 3, cc = idx & 7;
        bf16x8 v = *reinterpret_cast<const bf16x8*>(src + (n << 6) + ((cc ^ (n & 7)) << 3));
        *reinterpret_cast<bf16x8*>(Bj + (idx << 3)) = v;
      }
    }
    __syncthreads();
    const int jrow = (w << 4) | m;
    bf16x8 a0 = *reinterpret_cast<const bf16x8*>(Bj + (jrow << 6) + ((g ^ (jrow & 7)) << 3));
    bf16x8 a1 = *reinterpret_cast<const bf16x8*>(Bj + (jrow << 6) + (((g + 4) ^ (jrow & 7)) << 3));
    f32x4 e[4];
#pragma unroll
    for (int n = 0; n < 4; ++n) {
      const int irow = (n << 4) | m;
      bf16x8 b0v = *reinterpret_cast<const bf16x8*>(Ai + (irow << 6) + ((g ^ (irow & 7)) << 3));
      bf16x8 b1v = *reinterpret_cast<const bf16x8*>(Ai + (irow << 6) + (((g + 4) ^ (irow & 7)) << 3));
      e[n] = (f32x4){0.f, 0.f, 0.f, 0.f};
      e[n] = __builtin_amdgcn_mfma_f32_16x16x32_bf16(a0, b0v, e[n], 0, 0, 0);
      e[n] = __builtin_amdgcn_mfma_f32_16x16x32_bf16(a1, b1v, e[n], 0, 0, 0);
    }
    const int j = (w << 4) | (g << 2);
#pragma unroll
    for (int n = 0; n < 4; ++n) {
      const int irow = (n << 4) | m;
      float p0 = __expf(-e[n][0]), p1 = __expf(-e[n][1]);
      float p2 = __expf(-e[n][2]), p3 = __expf(-e[n][3]);
      psum += (p0 + p1) + (p2 + p3);
      unsigned pk01 = (unsigned)f2bf(p0) | ((unsigned)f2bf(p1) << 16);
      unsigned pk23 = (unsigned)f2bf(p2) | ((unsigned)f2bf(p3) << 16);
      int base = irow << 6;
      int off0 = base + ((((j) >> 3) ^ (irow & 7)) << 3) + (j & 7);
      int off2 = base + ((((j + 2) >> 3) ^ (irow & 7)) << 3) + ((j + 2) & 7);
      *reinterpret_cast<unsigned*>(Pl + off0) = pk01;
      *reinterpret_cast<unsigned*>(Pl + off2) = pk23;
    }
    const int crow = (w << 4) | m;
    const unsigned short* kbp = KBc + nb + ((size_t)crow << 10) + j0 + (g << 3);
    bf16x8 ka0 = *reinterpret_cast<const bf16x8*>(kbp);
    bf16x8 ka1 = *reinterpret_cast<const bf16x8*>(kbp + 32);
    __syncthreads();
#pragma unroll
    for (int n = 0; n < 4; ++n) {
      const int irow = (n << 4) | m;
      bf16x8 p0 = *reinterpret_cast<const bf16x8*>(Pl + (irow << 6) + ((g ^ (irow & 7)) << 3));
      bf16x8 p1 = *reinterpret_cast<const bf16x8*>(Pl + (irow << 6) + (((g + 4) ^ (irow & 7)) << 3));
      accO[n] = __builtin_amdgcn_mfma_f32_16x16x32_bf16(ka0, p0, accO[n], 0, 0, 0);
      accO[n] = __builtin_amdgcn_mfma_f32_16x16x32_bf16(ka1, p1, accO[n], 0, 0, 0);
    }
  }
  float* OUT = PART + ((size_t)blockIdx.y << 20) + ((size_t)(b * 64) << 10);
#pragma unroll
  for (int n = 0; n < 4; ++n) {
    const int ig = i0 + (n << 4) + m;
    const int c = (w << 4) + (g << 2);
#pragma unroll
    for (int r = 0; r < 4; ++r)
      OUT[((size_t)(c + r) << 10) + ig] = accO[n][r];
  }
  red[tid] = psum; __syncthreads();
  for (int s = 128; s > 0; s >>= 1) {
    if (tid < s) red[tid] += red[tid + s];
    __syncthreads();
  }
  if (tid == 0) atomicAdd(bsum + b, red[0]);
}

// ---- MFMA fused PtV --------------------------------------------------------
__global__ __launch_bounds__(256)
void tpv_mfma_kernel(const unsigned short* __restrict__ QAt,
                     const unsigned short* __restrict__ QBt,
                     const unsigned short* __restrict__ KAc,
                     float* __restrict__ PART) {
  __shared__ __align__(16) unsigned short Bj[4096];
  __shared__ __align__(16) unsigned short Ai[4096];
  __shared__ __align__(16) unsigned short Pl[4096];
  const int tid = threadIdx.x;
  const int lane = tid & 63, w = tid >> 6;
  const int g = lane >> 4, m = lane & 15;
  const int j0 = blockIdx.x << 6;
  const int ibase = blockIdx.y << 8;
  const int b = blockIdx.z;
  const size_t nb = (size_t)b << 16;

  {
    const unsigned short* src = QBt + nb + ((size_t)j0 << 6);
#pragma unroll
    for (int s = 0; s < 2; ++s) {
      int idx = tid + (s << 8);
      int n = idx >> 3, cc = idx & 7;
      bf16x8 v = *reinterpret_cast<const bf16x8*>(src + (n << 6) + ((cc ^ (n & 7)) << 3));
      *reinterpret_cast<bf16x8*>(Bj + (idx << 3)) = v;
    }
  }
  f32x4 accO[4];
#pragma unroll
  for (int n = 0; n < 4; ++n) accO[n] = (f32x4){0.f, 0.f, 0.f, 0.f};

  for (int it = 0; it < 4; ++it) {
    const int i0 = ibase + (it << 6);
    __syncthreads();
    {
      const unsigned short* src = QAt + nb + ((size_t)i0 << 6);
#pragma unroll
      for (int s = 0; s < 2; ++s) {
        int idx = tid + (s << 8);
        int n = idx >> 3, cc = idx & 7;
        bf16x8 v = *reinterpret_cast<const bf16x8*>(src + (n << 6) + ((cc ^ (n & 7)) << 3));
        *reinterpret_cast<bf16x8*>(Ai + (idx << 3)) = v;
      }
    }
    __syncthreads();
    const int irow_a = (w << 4) | m;
    bf16x8 a0 = *reinterpret_cast<const bf16x8*>(Ai + (irow_a << 6) + ((g ^ (irow_a & 7)) << 3));
    bf16x8 a1 = *reinterpret_cast<const bf16x8*>(Ai + (irow_a << 6) + (((g + 4) ^ (irow_a & 7)) << 3));
    f32x4 e[4];
#pragma unroll
    for (int n = 0; n < 4; ++n) {
      const int jrow = (n << 4) | m;
      bf16x8 b0v = *reinterpret_cast<const bf16x8*>(Bj + (jrow << 6) + ((g ^ (jrow & 7)) << 3));
      bf16x8 b1v = *reinterpret_cast<const bf16x8*>(Bj + (jrow << 6) + (((g + 4) ^ (jrow & 7)) << 3));
      e[n] = (f32x4){0.f, 0.f, 0.f, 0.f};
      e[n] = __builtin_amdgcn_mfma_f32_16x16x32_bf16(a0, b0v, e[n], 0, 0, 0);
      e[n] = __builtin_amdgcn_mfma_f32_16x16x32_bf16(a1, b1v, e[n], 0, 0, 0);
    }
    const int i = (w << 4) | (g << 2);
#pragma unroll
    for (int n = 0; n < 4; ++n) {
      const int jrow = (n << 4) | m;
      float p0 = __expf(-e[n][0]), p1 = __expf(-e[n][1]);
      float p2 = __expf(-e[n][2]), p3 = __expf(-e[n][3]);
      unsigned pk01 = (unsigned)f2bf(p0) | ((unsigned)f2bf(p1) << 16);
      unsigned pk23 = (unsigned)f2bf(p2) | ((unsigned)f2bf(p3) << 16);
      int base = jrow << 6;
      int off0 = base + ((((i) >> 3) ^ (jrow & 7)) << 3) + (i & 7);
      int off2 = base + ((((i + 2) >> 3) ^ (jrow & 7)) << 3) + ((i + 2) & 7);
      *reinterpret_cast<unsigned*>(Pl + off0) = pk01;
      *reinterpret_cast<unsigned*>(Pl + off2) = pk23;
    }
    const int crow = (w << 4) | m;
    const unsigned short* kap = KAc + nb + ((size_t)crow << 10) + i0 + (g << 3);
    bf16x8 ka0 = *reinterpret_cast<const bf16x8*>(kap);
    bf16x8 ka1 = *reinterpret_cast<const bf16x8*>(kap + 32);
    __syncthreads();
#pragma unroll
    for (int n = 0; n < 4; ++n) {
      const int jrow = (n << 4) | m;
      bf16x8 p0 = *reinterpret_cast<const bf16x8*>(Pl + (jrow << 6) + ((g ^ (jrow & 7)) << 3));
      bf16x8 p1 = *reinterpret_cast<const bf16x8*>(Pl + (jrow << 6) + (((g + 4) ^ (jrow & 7)) << 3));
      accO[n] = __builtin_amdgcn_mfma_f32_16x16x32_bf16(ka0, p0, accO[n], 0, 0, 0);
      accO[n] = __builtin_amdgcn_mfma_f32_16x16x32_bf16(ka1, p1, accO[n], 0, 0, 0);
    }
  }
  float* OUT = PART + ((size_t)blockIdx.y << 20) + ((size_t)(b * 64) << 10);
#pragma unroll
  for (int n = 0; n < 4; ++n) {
    const int jg = j0 + (n << 4) + m;
    const int c = (w << 4) + (g << 2);
#pragma unroll
    for (int r = 0; r < 4; ++r)
      OUT[((size_t)(c + r) << 10) + jg] = accO[n][r];
  }
}

// ---- merge: Y0[b][n][0:64] = XR, [64:128] = (sum of 4 partials)/bsum, bf16 --
__global__ __launch_bounds__(256)
void merge_kernel(const float* __restrict__ PART, const float* __restrict__ XR,
                  const float* __restrict__ bsum, unsigned short* __restrict__ Y0) {
  __shared__ float ts[128][66];
  const int tid = threadIdx.x;
  const int n0 = blockIdx.x << 6;
  const int b = blockIdx.y;
  const float invS = 1.f / bsum[b];
  const size_t M1 = (size_t)1 << 20;
#pragma unroll
  for (int it = 0; it < 4; ++it) {
    int idx = it * 256 + tid;
    int c = idx >> 4, nq = (idx & 15) << 2;
    float4 v = *reinterpret_cast<const float4*>(XR + ((size_t)(b * 64 + c) << 10) + n0 + nq);
    ts[c][nq] = v.x; ts[c][nq + 1] = v.y; ts[c][nq + 2] = v.z; ts[c][nq + 3] = v.w;
  }
#pragma unroll
  for (int it = 0; it < 4; ++it) {
    int idx = it * 256 + tid;
    int c = idx >> 4, nq = (idx & 15) << 2;
    const float* p = PART + ((size_t)(b * 64 + c) << 10) + n0 + nq;
    float4 a = *reinterpret_cast<const float4*>(p);
    float4 b4 = *reinterpret_cast<const float4*>(p + M1);
    float4 c4 = *reinterpret_cast<const float4*>(p + 2 * M1);
    float4 d4 = *reinterpret_cast<const float4*>(p + 3 * M1);
    ts[64 + c][nq]     = ((a.x + b4.x) + (c4.x + d4.x)) * invS;
    ts[64 + c][nq + 1] = ((a.y + b4.y) + (c4.y + d4.y)) * invS;
    ts[64 + c][nq + 2] = ((a.z + b4.z) + (c4.z + d4.z)) * invS;
    ts[64 + c][nq + 3] = ((a.w + b4.w) + (c4.w + d4.w)) * invS;
  }
  __syncthreads();
  const int n = tid >> 2, c0 = (tid & 3) << 5;
  unsigned short* dst = Y0 + ((size_t)(b * 1024 + n0 + n) << 7) + c0;
#pragma unroll
  for (int q8 = 0; q8 < 4; ++q8) {
    const int cb = c0 + (q8 << 3);
    unsigned w0 = (unsigned)f2bf(ts[cb + 0][n]) | ((unsigned)f2bf(ts[cb + 1][n]) << 16);
    unsigned w1 = (unsigned)f2bf(ts[cb + 2][n]) | ((unsigned)f2bf(ts[cb + 3][n]) << 16);
    unsigned w2 = (unsigned)f2bf(ts[cb + 4][n]) | ((unsigned)f2bf(ts[cb + 5][n]) << 16);
    unsigned w3 = (unsigned)f2bf(ts[cb + 6][n]) | ((unsigned)f2bf(ts[cb + 7][n]) << 16);
    *reinterpret_cast<uint4*>(dst + (q8 << 3)) = make_uint4(w0, w1, w2, w3);
  }
}

// ---- MFMA conv v2: NT n-subtiles/wave, hoisted W frags, optional fused
// pre-BN+relu on the input (PREBN). Y[b][n][o] = sum_c W[o][c] X'[b][n][c].
template<int CIN, int NT, bool PREBN>
__global__ __launch_bounds__(256)
void conv_mfma_kernel(const unsigned short* __restrict__ Xin,
                      const unsigned short* __restrict__ Wb,
                      unsigned short* __restrict__ Yout,
                      const float* __restrict__ prodSums,
                      const float* __restrict__ gamf,
                      const float* __restrict__ betf,
                      float* __restrict__ outSums, int COUT) {
  constexpr int KS = CIN / 32;
  __shared__ float scs[PREBN ? CIN : 1];
  __shared__ float shs[PREBN ? CIN : 1];
  const int tid = threadIdx.x;
  const int lane = tid & 63, w = tid >> 6;
  const int g = lane >> 4, m = lane & 15;
  const int o0 = (blockIdx.x << 6) + (w << 4);
  const int n0 = blockIdx.y * (NT << 4);
  const int b = blockIdx.z;
  if (PREBN) {
    const float invN = 1.f / 16384.f;
    for (int c = tid; c < CIN; c += 256) {
      float mm = prodSums[c] * invN;
      float vv = prodSums[256 + c] * invN - mm * mm;
      float s = gamf[c] * rsqrtf(vv + 1e-5f);
      scs[c] = s; shs[c] = betf[c] - mm * s;
    }
    __syncthreads();
  }
  const unsigned short* Xb = Xin + (size_t)(b * 1024 + n0) * CIN + (g << 3);
  const unsigned short* Wr = Wb + (size_t)(o0 + m) * CIN + (g << 3);
  bf16x8 af[KS];
#pragma unroll
  for (int k = 0; k < KS; ++k)
    af[k] = *reinterpret_cast<const bf16x8*>(Wr + (k << 5));
  f32x4 acc[NT];
#pragma unroll
  for (int nt = 0; nt < NT; ++nt) acc[nt] = (f32x4){0.f, 0.f, 0.f, 0.f};
#pragma unroll
  for (int nt = 0; nt < NT; ++nt) {
    bf16x8 bv[KS];
#pragma unroll
    for (int k = 0; k < KS; ++k)
      bv[k] = *reinterpret_cast<const bf16x8*>(Xb + (size_t)((nt << 4) + m) * CIN + (k << 5));
    if (PREBN) {
#pragma unroll
      for (int k = 0; k < KS; ++k) {
        const int kb = (k << 5) + (g << 3);
#pragma unroll
        for (int j = 0; j < 8; ++j) {
          float x = __uint_as_float((unsigned)(unsigned short)bv[k][j] << 16);
          x = fmaxf(fmaf(x, scs[kb + j], shs[kb + j]), 0.f);
          bv[k][j] = (short)f2bf(x);
        }
      }
    }
#pragma unroll
    for (int k = 0; k < KS; ++k)
      acc[nt] = __builtin_amdgcn_mfma_f32_16x16x32_bf16(af[k], bv[k], acc[nt], 0, 0, 0);
  }
  unsigned short* Yb = Yout + (size_t)(b * 1024 + n0) * COUT + o0 + (g << 2);
#pragma unroll
  for (int nt = 0; nt < NT; ++nt) {
    ushort4 v;
    v.x = f2bf(acc[nt][0]); v.y = f2bf(acc[nt][1]);
    v.z = f2bf(acc[nt][2]); v.w = f2bf(acc[nt][3]);
    *reinterpret_cast<ushort4*>(Yb + (size_t)((nt << 4) + m) * COUT) = v;
  }
  if (outSums) {
    float s[4], q[4];
#pragma unroll
    for (int r = 0; r < 4; ++r) {
      s[r] = 0.f; q[r] = 0.f;
#pragma unroll
      for (int nt = 0; nt < NT; ++nt) {
        s[r] += acc[nt][r];
        q[r] += acc[nt][r] * acc[nt][r];
      }
    }
#pragma unroll
    for (int r = 0; r < 4; ++r) {
      for (int off = 1; off < 16; off <<= 1) {
        s[r] += __shfl_xor(s[r], off);
        q[r] += __shfl_xor(q[r], off);
      }
    }
    if (m == 0) {
#pragma unroll
      for (int r = 0; r < 4; ++r) {
        atomicAdd(&outSums[o0 + (g << 2) + r], s[r]);
        atomicAdd(&outSums[256 + o0 + (g << 2) + r], q[r]);
      }
    }
  }
}

// ---- finish: MODE 1: relu(bn0(T)+S); 2: relu(bn0(T)+bn1(S)) ----------------
template<int C, int MODE>
__global__ __launch_bounds__(256)
void finish_kernel(const unsigned short* __restrict__ T,
                   const float* __restrict__ sums0, const float* __restrict__ g0f,
                   const float* __restrict__ b0f,
                   const unsigned short* __restrict__ S,
                   const float* __restrict__ sums1, const float* __restrict__ g1f,
                   const float* __restrict__ b1f,
                   unsigned short* __restrict__ OUT) {
  __shared__ float sc0[C], sh0[C];
  __shared__ float sc1[(MODE == 2) ? C : 1], sh1[(MODE == 2) ? C : 1];
  const int tid = threadIdx.x;
  const float invN = 1.f / 16384.f;
  for (int c = tid; c < C; c += 256) {
    float mm = sums0[c] * invN;
    float vv = sums0[256 + c] * invN - mm * mm;
    float s = g0f[c] * rsqrtf(vv + 1e-5f);
    sc0[c] = s; sh0[c] = b0f[c] - mm * s;
    if (MODE == 2) {
      float m1 = sums1[c] * invN;
      float v1 = sums1[256 + c] * invN - m1 * m1;
      float s1 = g1f[c] * rsqrtf(v1 + 1e-5f);
      sc1[c] = s1; sh1[c] = b1f[c] - m1 * s1;
    }
  }
  __syncthreads();
  const size_t i8 = ((size_t)blockIdx.x * 256 + tid) << 3;
  const int c0 = (int)(i8 & (size_t)(C - 1));
  uint4 tv = *reinterpret_cast<const uint4*>(T + i8);
  uint4 sv = *reinterpret_cast<const uint4*>(S + i8);
  unsigned tw[4] = {tv.x, tv.y, tv.z, tv.w};
  unsigned sw[4] = {sv.x, sv.y, sv.z, sv.w};
  unsigned ow[4];
#pragma unroll
  for (int jw = 0; jw < 4; ++jw) {
    unsigned r = 0;
#pragma unroll
    for (int h = 0; h < 2; ++h) {
      int c = c0 + jw * 2 + h;
      float x = __uint_as_float(((tw[jw] >> (h * 16)) & 0xffffu) << 16);
      x = fmaf(x, sc0[c], sh0[c]);
      if (MODE == 1) x += __uint_as_float(((sw[jw] >> (h * 16)) & 0xffffu) << 16);
      if (MODE == 2) {
        float y = __uint_as_float(((sw[jw] >> (h * 16)) & 0xffffu) << 16);
        x += fmaf(y, sc1[c], sh1[c]);
      }
      x = fmaxf(x, 0.f);
      r |= ((unsigned)f2bf(x)) << (h * 16);
    }
    ow[jw] = r;
  }
  *reinterpret_cast<uint4*>(OUT + i8) = make_uint4(ow[0], ow[1], ow[2], ow[3]);
}

// ---- writeout: out[b][c][n] f32 = bn(F[b][n][c]) via LDS transpose ---------
__global__ __launch_bounds__(256)
void writeout_t_kernel(const unsigned short* __restrict__ F, const float* __restrict__ sums,
                       const float* __restrict__ gam, const float* __restrict__ bet,
                       float* __restrict__ out) {
  __shared__ float ts[64][66];
  __shared__ float sc[64], sh[64];
  const int tid = threadIdx.x;
  const float invN = 1.f / 16384.f;
  if (tid < 64) {
    float mm = sums[tid] * invN;
    float vv = sums[256 + tid] * invN - mm * mm;
    float s = gam[tid] * rsqrtf(vv + 1e-5f);
    sc[tid] = s; sh[tid] = bet[tid] - mm * s;
  }
  __syncthreads();
  const int n0 = blockIdx.x << 6;
  const int b = blockIdx.y;
  {
    const int n = tid >> 2, c0 = (tid & 3) << 4;
    const unsigned short* Fr = F + ((size_t)(b * 1024 + n0 + n) << 6) + c0;
    uint4 v0 = *reinterpret_cast<const uint4*>(Fr);
    uint4 v1 = *reinterpret_cast<const uint4*>(Fr + 8);
    unsigned vw[8] = {v0.x, v0.y, v0.z, v0.w, v1.x, v1.y, v1.z, v1.w};
#pragma unroll
    for (int jw = 0; jw < 8; ++jw) {
      int c = c0 + jw * 2;
      float x0 = __uint_as_float((vw[jw] & 0xffffu) << 16);
      float x1 = __uint_as_float((vw[jw] >> 16) << 16);
      ts[c][n] = fmaf(x0, sc[c], sh[c]);
      ts[c + 1][n] = fmaf(x1, sc[c + 1], sh[c + 1]);
    }
  }
  __syncthreads();
  const int c = tid >> 2, nq = (tid & 3) << 4;
  float* orow = out + ((size_t)(b * 64 + c) << 10) + n0 + nq;
#pragma unroll
  for (int q = 0; q < 4; ++q) {
    float4 ov;
    ov.x = ts[c][nq + q * 4 + 0]; ov.y = ts[c][nq + q * 4 + 1];
    ov.z = ts[c][nq + q * 4 + 2]; ov.w = ts[c][nq + q * 4 + 3];
    *reinterpret_cast<float4*>(orow + q * 4) = ov;
  }
}

// ============================ host side =====================================
extern "C" void kernel_launch(void* const* d_in, const int* in_sizes, int n_in,
                              void* d_out, int out_size, void* d_ws, size_t ws_size,
                              hipStream_t stream) {
  float* wsf = (float*)d_ws;
  const size_t M1 = (size_t)1 << 20;
  const size_t H1 = (size_t)1 << 19;

  unsigned short* QAt = (unsigned short*)wsf;                 // [0, 0.5M)
  unsigned short* QBt = (unsigned short*)(wsf + H1);          // [0.5M, 1M)
  unsigned short* KAc = (unsigned short*)(wsf + 2 * H1);      // [1M, 1.5M)
  unsigned short* KBc = (unsigned short*)(wsf + 3 * H1);      // [1.5M, 2M)
  float* PART = wsf + 2 * M1;                                 // [2M, 6M)
  unsigned short* Y0A = (unsigned short*)(wsf + 6 * M1);      // [6M, 7M)
  unsigned short* Y0B = (unsigned short*)(wsf + 7 * M1);      // [7M, 8M)
  unsigned short* T1  = (unsigned short*)(wsf + 8 * M1);      // [8M, 9M)
  unsigned short* T2  = (unsigned short*)(wsf + 9 * M1);      // [9M, 10M)
  unsigned short* O1  = (unsigned short*)(wsf + 10 * M1);     // [10M, 11M)
  unsigned short* T3  = (unsigned short*)(wsf + 11 * M1);     // [11M, 13M)
  unsigned short* T4  = (unsigned short*)(wsf + 13 * M1);     // [13M, 15M)
  unsigned short* T5  = (unsigned short*)(wsf + 15 * M1);     // [15M, 17M)
  unsigned short* Fb  = (unsigned short*)(wsf + 17 * M1);     // [17M, 17.5M)
  float* tail = wsf + 17 * M1 + H1;
  float* bsum = tail;
  float* stats = tail + 16;                                   // 12 * 512
  unsigned short* wbf = (unsigned short*)(tail + 16 + 12 * 512);

  const float* pp[46];
  for (int i = 0; i < 46 && i < n_in; ++i) pp[i] = (const float*)d_in[i];
  const float* XAF = pp[0];
  const float* XBF = pp[1];

  init_kernel<<<1, 256, 0, stream>>>(tail, 16 + 12 * 512);

  const int widx[12] = {10, 13, 16, 19, 22, 25, 28, 31, 34, 37, 40, 43};
  WcvtArgs wa;
  int woff[12];
  {
    int run = 0;
    for (int i = 0; i < 12; ++i) {
      wa.p[i] = pp[widx[i]];
      wa.sz[i] = in_sizes[widx[i]];
      wa.off[i] = run; woff[i] = run;
      run += in_sizes[widx[i]];
    }
  }
  wcvt_kernel<<<dim3(12, 16), 256, 0, stream>>>(wa, wbf);

  float* ST[12];
  for (int i = 0; i < 12; ++i) ST[i] = stats + i * 512;

  dim3 gq(16, 2, BATCH);
  conv_qk_kernel<0><<<gq, 256, 0, stream>>>(XAF, pp[2], pp[3], QAt);
  conv_qk_kernel<0><<<gq, 256, 0, stream>>>(XBF, pp[4], pp[5], QBt);
  conv_qk_kernel<1><<<gq, 256, 0, stream>>>(XAF, pp[6], pp[7], KAc);
  conv_qk_kernel<1><<<gq, 256, 0, stream>>>(XBF, pp[8], pp[9], KBc);

  pv_mfma_kernel<<<dim3(16, 4, BATCH), 256, 0, stream>>>(QAt, QBt, KBc, PART, bsum);
  merge_kernel<<<dim3(16, BATCH), 256, 0, stream>>>(PART, XAF, bsum, Y0A);
  tpv_mfma_kernel<<<dim3(16, 4, BATCH), 256, 0, stream>>>(QAt, QBt, KAc, PART);
  merge_kernel<<<dim3(16, BATCH), 256, 0, stream>>>(PART, XBF, bsum, Y0B);

  for (int sbi = 0; sbi < 2; ++sbi) {
    const unsigned short* Y0 = sbi ? Y0B : Y0A;
    const int base1 = sbi ? 16 : 10;
    const int base2 = sbi ? 31 : 22;
    const int baseo = sbi ? 43 : 40;
    const unsigned short* w11 = wbf + woff[sbi ? 2 : 0];
    const unsigned short* w12 = wbf + woff[sbi ? 3 : 1];
    const unsigned short* w21 = wbf + woff[sbi ? 7 : 4];
    const unsigned short* w22 = wbf + woff[sbi ? 8 : 5];
    const unsigned short* w2s = wbf + woff[sbi ? 9 : 6];
    const unsigned short* wo  = wbf + woff[sbi ? 11 : 10];
    float* s1 = ST[sbi * 6 + 0];
    float* s2 = ST[sbi * 6 + 1];
    float* s3 = ST[sbi * 6 + 2];
    float* s4 = ST[sbi * 6 + 3];
    float* s5 = ST[sbi * 6 + 4];
    float* s6 = ST[sbi * 6 + 5];

    // block 1 (128 -> 128): conv1 raw+stats; conv2 fuses bn1+relu on input
    conv_mfma_kernel<128, 2, false><<<dim3(2, 32, BATCH), 256, 0, stream>>>(
        Y0, w11, T1, nullptr, nullptr, nullptr, s1, 128);
    conv_mfma_kernel<128, 2, true><<<dim3(2, 32, BATCH), 256, 0, stream>>>(
        T1, w12, T2, s1, pp[base1 + 1], pp[base1 + 2], s2, 128);
    finish_kernel<128, 1><<<1024, 256, 0, stream>>>(
        T2, s2, pp[base1 + 4], pp[base1 + 5], Y0, nullptr, nullptr, nullptr, O1);

    // block 2 (128 -> 256): conv w21 raw+stats; w22 fuses bn+relu; shortcut w2s
    conv_mfma_kernel<128, 2, false><<<dim3(4, 32, BATCH), 256, 0, stream>>>(
        O1, w21, T3, nullptr, nullptr, nullptr, s3, 256);
    conv_mfma_kernel<256, 2, true><<<dim3(4, 32, BATCH), 256, 0, stream>>>(
        T3, w22, T4, s3, pp[base2 + 1], pp[base2 + 2], s4, 256);
    conv_mfma_kernel<128, 2, false><<<dim3(4, 32, BATCH), 256, 0, stream>>>(
        O1, w2s, T5, nullptr, nullptr, nullptr, s5, 256);
    finish_kernel<256, 2><<<2048, 256, 0, stream>>>(
        T4, s4, pp[base2 + 4], pp[base2 + 5], T5, s5, pp[base2 + 7], pp[base2 + 8], T3);

    // output conv (256 -> 64) + BN + transpose out
    conv_mfma_kernel<256, 1, false><<<dim3(1, 64, BATCH), 256, 0, stream>>>(
        T3, wo, Fb, nullptr, nullptr, nullptr, s6, 64);
    writeout_t_kernel<<<dim3(16, BATCH), 256, 0, stream>>>(
        Fb, s6, pp[baseo + 1], pp[baseo + 2], (float*)d_out + sbi * M1);
  }
}

// Round 10
// 396.631 us; speedup vs baseline: 2.2211x; 2.2211x over previous
//
#include <hip/hip_runtime.h>
#include <hip/hip_bf16.h>
#include <cstddef>

static constexpr int BATCH = 16;   // B
static constexpr int NCOPY = 16;   // stat atomic spread copies

typedef __attribute__((ext_vector_type(8))) short bf16x8;
typedef __attribute__((ext_vector_type(4))) float f32x4;

__device__ __forceinline__ unsigned short f2bf(float f) {
  unsigned u = __float_as_uint(f);
  return (unsigned short)((u + 0x7fffu + ((u >> 16) & 1u)) >> 16);  // RNE
}

__global__ void init_kernel(float* __restrict__ t, int n) {
  int i = blockIdx.x * 256 + threadIdx.x;
  if (i < n) t[i] = 0.f;
}

// ---- convert the 12 block-phase weight matrices to bf16 (layout [o][cin]) --
struct WcvtArgs { const float* p[12]; int sz[12]; int off[12]; };
__global__ __launch_bounds__(256)
void wcvt_kernel(WcvtArgs a, unsigned short* __restrict__ dst) {
  const int t = blockIdx.x;
  const float* src = a.p[t];
  unsigned short* d = dst + a.off[t];
  const int sz = a.sz[t];
  for (int i = blockIdx.y * 256 + threadIdx.x; i < sz; i += 16 * 256)
    d[i] = f2bf(src[i]);
}

// ---------------- q/k conv: f32 [b][c][n] -> bf16, dual layouts -------------
template<int TR>
__global__ __launch_bounds__(256)
void conv_qk_kernel(const float* __restrict__ X, const float* __restrict__ W,
                    const float* __restrict__ bias, unsigned short* __restrict__ Y) {
  __shared__ float wsT[64][4];
  const int tid = threadIdx.x;
  const int o0 = blockIdx.x << 2;
  const int b  = blockIdx.z;
  const int px = (blockIdx.y << 9) + (tid << 1);
  {
    int c = tid >> 2, k = tid & 3;
    wsT[c][k] = W[((o0 + k) << 6) + c];
  }
  __syncthreads();
  float acc[4][2] = {};
  const float* xb = X + ((size_t)b << 16) + px;
#pragma unroll 4
  for (int c = 0; c < 64; ++c) {
    float2 xv = *reinterpret_cast<const float2*>(xb + (c << 10));
    float4 w = *reinterpret_cast<const float4*>(wsT[c]);
    acc[0][0] = fmaf(w.x, xv.x, acc[0][0]); acc[0][1] = fmaf(w.x, xv.y, acc[0][1]);
    acc[1][0] = fmaf(w.y, xv.x, acc[1][0]); acc[1][1] = fmaf(w.y, xv.y, acc[1][1]);
    acc[2][0] = fmaf(w.z, xv.x, acc[2][0]); acc[2][1] = fmaf(w.z, xv.y, acc[2][1]);
    acc[3][0] = fmaf(w.w, xv.x, acc[3][0]); acc[3][1] = fmaf(w.w, xv.y, acc[3][1]);
  }
  float b0 = bias[o0], b1 = bias[o0 + 1], b2 = bias[o0 + 2], b3 = bias[o0 + 3];
  if (TR == 0) {
    ushort4 v0, v1;
    v0.x = f2bf(acc[0][0] + b0); v0.y = f2bf(acc[1][0] + b1);
    v0.z = f2bf(acc[2][0] + b2); v0.w = f2bf(acc[3][0] + b3);
    v1.x = f2bf(acc[0][1] + b0); v1.y = f2bf(acc[1][1] + b1);
    v1.z = f2bf(acc[2][1] + b2); v1.w = f2bf(acc[3][1] + b3);
    unsigned short* yt = Y + ((size_t)b << 16) + ((size_t)px << 6) + o0;
    *reinterpret_cast<ushort4*>(yt) = v0;
    *reinterpret_cast<ushort4*>(yt + 64) = v1;
  } else {
    float bv[4] = {b0, b1, b2, b3};
#pragma unroll
    for (int k = 0; k < 4; ++k) {
      ushort2 v;
      v.x = f2bf(acc[k][0] + bv[k]); v.y = f2bf(acc[k][1] + bv[k]);
      *reinterpret_cast<ushort2*>(Y + ((size_t)b << 16) + ((size_t)(o0 + k) << 10) + px) = v;
    }
  }
}

// ---- MFMA fused PV ---------------------------------------------------------
__global__ __launch_bounds__(256)
void pv_mfma_kernel(const unsigned short* __restrict__ QAt,
                    const unsigned short* __restrict__ QBt,
                    const unsigned short* __restrict__ KBc,
                    float* __restrict__ PART, float* __restrict__ bsum) {
  __shared__ __align__(16) unsigned short Ai[4096];
  __shared__ __align__(16) unsigned short Bj[4096];
  __shared__ __align__(16) unsigned short Pl[4096];
  __shared__ float red[256];
  const int tid = threadIdx.x;
  const int lane = tid & 63, w = tid >> 6;
  const int g = lane >> 4, m = lane & 15;
  const int i0 = blockIdx.x << 6;
  const int jbase = blockIdx.y << 8;
  const int b = blockIdx.z;
  const size_t nb = (size_t)b << 16;

  {
    const unsigned short* src = QAt + nb + ((size_t)i0 << 6);
#pragma unroll
    for (int s = 0; s < 2; ++s) {
      int idx = tid + (s << 8);
      int n = idx >> 3, cc = idx & 7;
      bf16x8 v = *reinterpret_cast<const bf16x8*>(src + (n << 6) + ((cc ^ (n & 7)) << 3));
      *reinterpret_cast<bf16x8*>(Ai + (idx << 3)) = v;
    }
  }
  f32x4 accO[4];
#pragma unroll
  for (int n = 0; n < 4; ++n) accO[n] = (f32x4){0.f, 0.f, 0.f, 0.f};
  float psum = 0.f;

  for (int jt = 0; jt < 4; ++jt) {
    const int j0 = jbase + (jt << 6);
    __syncthreads();
    {
      const unsigned short* src = QBt + nb + ((size_t)j0 << 6);
#pragma unroll
      for (int s = 0; s < 2; ++s) {
        int idx = tid + (s << 8);
        int n = idx >> 3, cc = idx & 7;
        bf16x8 v = *reinterpret_cast<const bf16x8*>(src + (n << 6) + ((cc ^ (n & 7)) << 3));
        *reinterpret_cast<bf16x8*>(Bj + (idx << 3)) = v;
      }
    }
    __syncthreads();
    const int jrow = (w << 4) | m;
    bf16x8 a0 = *reinterpret_cast<const bf16x8*>(Bj + (jrow << 6) + ((g ^ (jrow & 7)) << 3));
    bf16x8 a1 = *reinterpret_cast<const bf16x8*>(Bj + (jrow << 6) + (((g + 4) ^ (jrow & 7)) << 3));
    f32x4 e[4];
#pragma unroll
    for (int n = 0; n < 4; ++n) {
      const int irow = (n << 4) | m;
      bf16x8 b0v = *reinterpret_cast<const bf16x8*>(Ai + (irow << 6) + ((g ^ (irow & 7)) << 3));
      bf16x8 b1v = *reinterpret_cast<const bf16x8*>(Ai + (irow << 6) + (((g + 4) ^ (irow & 7)) << 3));
      e[n] = (f32x4){0.f, 0.f, 0.f, 0.f};
      e[n] = __builtin_amdgcn_mfma_f32_16x16x32_bf16(a0, b0v, e[n], 0, 0, 0);
      e[n] = __builtin_amdgcn_mfma_f32_16x16x32_bf16(a1, b1v, e[n], 0, 0, 0);
    }
    const int j = (w << 4) | (g << 2);
#pragma unroll
    for (int n = 0; n < 4; ++n) {
      const int irow = (n << 4) | m;
      float p0 = __expf(-e[n][0]), p1 = __expf(-e[n][1]);
      float p2 = __expf(-e[n][2]), p3 = __expf(-e[n][3]);
      psum += (p0 + p1) + (p2 + p3);
      unsigned pk01 = (unsigned)f2bf(p0) | ((unsigned)f2bf(p1) << 16);
      unsigned pk23 = (unsigned)f2bf(p2) | ((unsigned)f2bf(p3) << 16);
      int base = irow << 6;
      int off0 = base + ((((j) >> 3) ^ (irow & 7)) << 3) + (j & 7);
      int off2 = base + ((((j + 2) >> 3) ^ (irow & 7)) << 3) + ((j + 2) & 7);
      *reinterpret_cast<unsigned*>(Pl + off0) = pk01;
      *reinterpret_cast<unsigned*>(Pl + off2) = pk23;
    }
    const int crow = (w << 4) | m;
    const unsigned short* kbp = KBc + nb + ((size_t)crow << 10) + j0 + (g << 3);
    bf16x8 ka0 = *reinterpret_cast<const bf16x8*>(kbp);
    bf16x8 ka1 = *reinterpret_cast<const bf16x8*>(kbp + 32);
    __syncthreads();
#pragma unroll
    for (int n = 0; n < 4; ++n) {
      const int irow = (n << 4) | m;
      bf16x8 p0 = *reinterpret_cast<const bf16x8*>(Pl + (irow << 6) + ((g ^ (irow & 7)) << 3));
      bf16x8 p1 = *reinterpret_cast<const bf16x8*>(Pl + (irow << 6) + (((g + 4) ^ (irow & 7)) << 3));
      accO[n] = __builtin_amdgcn_mfma_f32_16x16x32_bf16(ka0, p0, accO[n], 0, 0, 0);
      accO[n] = __builtin_amdgcn_mfma_f32_16x16x32_bf16(ka1, p1, accO[n], 0, 0, 0);
    }
  }
  float* OUT = PART + ((size_t)blockIdx.y << 20) + ((size_t)(b * 64) << 10);
#pragma unroll
  for (int n = 0; n < 4; ++n) {
    const int ig = i0 + (n << 4) + m;
    const int c = (w << 4) + (g << 2);
#pragma unroll
    for (int r = 0; r < 4; ++r)
      OUT[((size_t)(c + r) << 10) + ig] = accO[n][r];
  }
  red[tid] = psum; __syncthreads();
  for (int s = 128; s > 0; s >>= 1) {
    if (tid < s) red[tid] += red[tid + s];
    __syncthreads();
  }
  if (tid == 0) atomicAdd(bsum + b, red[0]);
}

// ---- MFMA fused PtV --------------------------------------------------------
__global__ __launch_bounds__(256)
void tpv_mfma_kernel(const unsigned short* __restrict__ QAt,
                     const unsigned short* __restrict__ QBt,
                     const unsigned short* __restrict__ KAc,
                     float* __restrict__ PART) {
  __shared__ __align__(16) unsigned short Bj[4096];
  __shared__ __align__(16) unsigned short Ai[4096];
  __shared__ __align__(16) unsigned short Pl[4096];
  const int tid = threadIdx.x;
  const int lane = tid & 63, w = tid >> 6;
  const int g = lane >> 4, m = lane & 15;
  const int j0 = blockIdx.x << 6;
  const int ibase = blockIdx.y << 8;
  const int b = blockIdx.z;
  const size_t nb = (size_t)b << 16;

  {
    const unsigned short* src = QBt + nb + ((size_t)j0 << 6);
#pragma unroll
    for (int s = 0; s < 2; ++s) {
      int idx = tid + (s << 8);
      int n = idx >> 3, cc = idx & 7;
      bf16x8 v = *reinterpret_cast<const bf16x8*>(src + (n << 6) + ((cc ^ (n & 7)) << 3));
      *reinterpret_cast<bf16x8*>(Bj + (idx << 3)) = v;
    }
  }
  f32x4 accO[4];
#pragma unroll
  for (int n = 0; n < 4; ++n) accO[n] = (f32x4){0.f, 0.f, 0.f, 0.f};

  for (int it = 0; it < 4; ++it) {
    const int i0 = ibase + (it << 6);
    __syncthreads();
    {
      const unsigned short* src = QAt + nb + ((size_t)i0 << 6);
#pragma unroll
      for (int s = 0; s < 2; ++s) {
        int idx = tid + (s << 8);
        int n = idx >> 3, cc = idx & 7;
        bf16x8 v = *reinterpret_cast<const bf16x8*>(src + (n << 6) + ((cc ^ (n & 7)) << 3));
        *reinterpret_cast<bf16x8*>(Ai + (idx << 3)) = v;
      }
    }
    __syncthreads();
    const int irow_a = (w << 4) | m;
    bf16x8 a0 = *reinterpret_cast<const bf16x8*>(Ai + (irow_a << 6) + ((g ^ (irow_a & 7)) << 3));
    bf16x8 a1 = *reinterpret_cast<const bf16x8*>(Ai + (irow_a << 6) + (((g + 4) ^ (irow_a & 7)) << 3));
    f32x4 e[4];
#pragma unroll
    for (int n = 0; n < 4; ++n) {
      const int jrow = (n << 4) | m;
      bf16x8 b0v = *reinterpret_cast<const bf16x8*>(Bj + (jrow << 6) + ((g ^ (jrow & 7)) << 3));
      bf16x8 b1v = *reinterpret_cast<const bf16x8*>(Bj + (jrow << 6) + (((g + 4) ^ (jrow & 7)) << 3));
      e[n] = (f32x4){0.f, 0.f, 0.f, 0.f};
      e[n] = __builtin_amdgcn_mfma_f32_16x16x32_bf16(a0, b0v, e[n], 0, 0, 0);
      e[n] = __builtin_amdgcn_mfma_f32_16x16x32_bf16(a1, b1v, e[n], 0, 0, 0);
    }
    const int i = (w << 4) | (g << 2);
#pragma unroll
    for (int n = 0; n < 4; ++n) {
      const int jrow = (n << 4) | m;
      float p0 = __expf(-e[n][0]), p1 = __expf(-e[n][1]);
      float p2 = __expf(-e[n][2]), p3 = __expf(-e[n][3]);
      unsigned pk01 = (unsigned)f2bf(p0) | ((unsigned)f2bf(p1) << 16);
      unsigned pk23 = (unsigned)f2bf(p2) | ((unsigned)f2bf(p3) << 16);
      int base = jrow << 6;
      int off0 = base + ((((i) >> 3) ^ (jrow & 7)) << 3) + (i & 7);
      int off2 = base + ((((i + 2) >> 3) ^ (jrow & 7)) << 3) + ((i + 2) & 7);
      *reinterpret_cast<unsigned*>(Pl + off0) = pk01;
      *reinterpret_cast<unsigned*>(Pl + off2) = pk23;
    }
    const int crow = (w << 4) | m;
    const unsigned short* kap = KAc + nb + ((size_t)crow << 10) + i0 + (g << 3);
    bf16x8 ka0 = *reinterpret_cast<const bf16x8*>(kap);
    bf16x8 ka1 = *reinterpret_cast<const bf16x8*>(kap + 32);
    __syncthreads();
#pragma unroll
    for (int n = 0; n < 4; ++n) {
      const int jrow = (n << 4) | m;
      bf16x8 p0 = *reinterpret_cast<const bf16x8*>(Pl + (jrow << 6) + ((g ^ (jrow & 7)) << 3));
      bf16x8 p1 = *reinterpret_cast<const bf16x8*>(Pl + (jrow << 6) + (((g + 4) ^ (jrow & 7)) << 3));
      accO[n] = __builtin_amdgcn_mfma_f32_16x16x32_bf16(ka0, p0, accO[n], 0, 0, 0);
      accO[n] = __builtin_amdgcn_mfma_f32_16x16x32_bf16(ka1, p1, accO[n], 0, 0, 0);
    }
  }
  float* OUT = PART + ((size_t)blockIdx.y << 20) + ((size_t)(b * 64) << 10);
#pragma unroll
  for (int n = 0; n < 4; ++n) {
    const int jg = j0 + (n << 4) + m;
    const int c = (w << 4) + (g << 2);
#pragma unroll
    for (int r = 0; r < 4; ++r)
      OUT[((size_t)(c + r) << 10) + jg] = accO[n][r];
  }
}

// ---- merge: Y0[b][n][0:64] = XR, [64:128] = (sum of 4 partials)/bsum, bf16 --
__global__ __launch_bounds__(256)
void merge_kernel(const float* __restrict__ PART, const float* __restrict__ XR,
                  const float* __restrict__ bsum, unsigned short* __restrict__ Y0) {
  __shared__ float ts[128][66];
  const int tid = threadIdx.x;
  const int n0 = blockIdx.x << 6;
  const int b = blockIdx.y;
  const float invS = 1.f / bsum[b];
  const size_t M1 = (size_t)1 << 20;
#pragma unroll
  for (int it = 0; it < 4; ++it) {
    int idx = it * 256 + tid;
    int c = idx >> 4, nq = (idx & 15) << 2;
    float4 v = *reinterpret_cast<const float4*>(XR + ((size_t)(b * 64 + c) << 10) + n0 + nq);
    ts[c][nq] = v.x; ts[c][nq + 1] = v.y; ts[c][nq + 2] = v.z; ts[c][nq + 3] = v.w;
  }
#pragma unroll
  for (int it = 0; it < 4; ++it) {
    int idx = it * 256 + tid;
    int c = idx >> 4, nq = (idx & 15) << 2;
    const float* p = PART + ((size_t)(b * 64 + c) << 10) + n0 + nq;
    float4 a = *reinterpret_cast<const float4*>(p);
    float4 b4 = *reinterpret_cast<const float4*>(p + M1);
    float4 c4 = *reinterpret_cast<const float4*>(p + 2 * M1);
    float4 d4 = *reinterpret_cast<const float4*>(p + 3 * M1);
    ts[64 + c][nq]     = ((a.x + b4.x) + (c4.x + d4.x)) * invS;
    ts[64 + c][nq + 1] = ((a.y + b4.y) + (c4.y + d4.y)) * invS;
    ts[64 + c][nq + 2] = ((a.z + b4.z) + (c4.z + d4.z)) * invS;
    ts[64 + c][nq + 3] = ((a.w + b4.w) + (c4.w + d4.w)) * invS;
  }
  __syncthreads();
  const int n = tid >> 2, c0 = (tid & 3) << 5;
  unsigned short* dst = Y0 + ((size_t)(b * 1024 + n0 + n) << 7) + c0;
#pragma unroll
  for (int q8 = 0; q8 < 4; ++q8) {
    const int cb = c0 + (q8 << 3);
    unsigned w0 = (unsigned)f2bf(ts[cb + 0][n]) | ((unsigned)f2bf(ts[cb + 1][n]) << 16);
    unsigned w1 = (unsigned)f2bf(ts[cb + 2][n]) | ((unsigned)f2bf(ts[cb + 3][n]) << 16);
    unsigned w2 = (unsigned)f2bf(ts[cb + 4][n]) | ((unsigned)f2bf(ts[cb + 5][n]) << 16);
    unsigned w3 = (unsigned)f2bf(ts[cb + 6][n]) | ((unsigned)f2bf(ts[cb + 7][n]) << 16);
    *reinterpret_cast<uint4*>(dst + (q8 << 3)) = make_uint4(w0, w1, w2, w3);
  }
}

// ---- MFMA conv v3: 1 tile/wave, max wave count, 16-copy stats --------------
// grid (COUT/64, 64*BATCH). Wave: 16 n-rows x 16 outputs, full K.
template<int CIN, bool PREBN>
__global__ __launch_bounds__(256)
void conv_mfma_kernel(const unsigned short* __restrict__ Xin,
                      const unsigned short* __restrict__ Wb,
                      unsigned short* __restrict__ Yout,
                      const float* __restrict__ prodSums,
                      const float* __restrict__ gamf,
                      const float* __restrict__ betf,
                      float* __restrict__ outSums, int COUT) {
  constexpr int KS = CIN / 32;
  __shared__ float scs[PREBN ? CIN : 1];
  __shared__ float shs[PREBN ? CIN : 1];
  const int tid = threadIdx.x;
  const int lane = tid & 63, w = tid >> 6;
  const int g = lane >> 4, m = lane & 15;
  const int o0 = (blockIdx.x << 6) + (w << 4);
  const int nsub = blockIdx.y;
  const int b = nsub >> 6;
  const int n0 = (nsub & 63) << 4;
  if (PREBN) {
    const float invN = 1.f / 16384.f;
    for (int c = tid; c < CIN; c += 256) {
      float s0 = 0.f, q0 = 0.f;
#pragma unroll
      for (int p = 0; p < NCOPY; ++p) {
        s0 += prodSums[p * 512 + c];
        q0 += prodSums[p * 512 + 256 + c];
      }
      float mm = s0 * invN;
      float vv = q0 * invN - mm * mm;
      float s = gamf[c] * rsqrtf(vv + 1e-5f);
      scs[c] = s; shs[c] = betf[c] - mm * s;
    }
    __syncthreads();
  }
  const unsigned short* Xr = Xin + (size_t)(b * 1024 + n0 + m) * CIN + (g << 3);
  const unsigned short* Wr = Wb + (size_t)(o0 + m) * CIN + (g << 3);
  bf16x8 af[KS], bv[KS];
#pragma unroll
  for (int k = 0; k < KS; ++k) af[k] = *reinterpret_cast<const bf16x8*>(Wr + (k << 5));
#pragma unroll
  for (int k = 0; k < KS; ++k) bv[k] = *reinterpret_cast<const bf16x8*>(Xr + (k << 5));
  if (PREBN) {
#pragma unroll
    for (int k = 0; k < KS; ++k) {
      const int kb = (k << 5) + (g << 3);
#pragma unroll
      for (int j = 0; j < 8; ++j) {
        float x = __uint_as_float((unsigned)(unsigned short)bv[k][j] << 16);
        x = fmaxf(fmaf(x, scs[kb + j], shs[kb + j]), 0.f);
        bv[k][j] = (short)f2bf(x);
      }
    }
  }
  f32x4 acc = (f32x4){0.f, 0.f, 0.f, 0.f};
#pragma unroll
  for (int k = 0; k < KS; ++k)
    acc = __builtin_amdgcn_mfma_f32_16x16x32_bf16(af[k], bv[k], acc, 0, 0, 0);
  {
    ushort4 v;
    v.x = f2bf(acc[0]); v.y = f2bf(acc[1]);
    v.z = f2bf(acc[2]); v.w = f2bf(acc[3]);
    *reinterpret_cast<ushort4*>(Yout + (size_t)(b * 1024 + n0 + m) * COUT + o0 + (g << 2)) = v;
  }
  if (outSums) {
    float s[4], q[4];
#pragma unroll
    for (int r = 0; r < 4; ++r) { s[r] = acc[r]; q[r] = acc[r] * acc[r]; }
#pragma unroll
    for (int r = 0; r < 4; ++r) {
      for (int off = 1; off < 16; off <<= 1) {
        s[r] += __shfl_xor(s[r], off);
        q[r] += __shfl_xor(q[r], off);
      }
    }
    if (m == 0) {
      float* dst = outSums + (nsub & (NCOPY - 1)) * 512;
#pragma unroll
      for (int r = 0; r < 4; ++r) {
        atomicAdd(&dst[o0 + (g << 2) + r], s[r]);
        atomicAdd(&dst[256 + o0 + (g << 2) + r], q[r]);
      }
    }
  }
}

// ---- finish: MODE 1: relu(bn0(T)+S); 2: relu(bn0(T)+bn1(S)) ----------------
template<int C, int MODE>
__global__ __launch_bounds__(256)
void finish_kernel(const unsigned short* __restrict__ T,
                   const float* __restrict__ sums0, const float* __restrict__ g0f,
                   const float* __restrict__ b0f,
                   const unsigned short* __restrict__ S,
                   const float* __restrict__ sums1, const float* __restrict__ g1f,
                   const float* __restrict__ b1f,
                   unsigned short* __restrict__ OUT) {
  __shared__ float sc0[C], sh0[C];
  __shared__ float sc1[(MODE == 2) ? C : 1], sh1[(MODE == 2) ? C : 1];
  const int tid = threadIdx.x;
  const float invN = 1.f / 16384.f;
  for (int c = tid; c < C; c += 256) {
    float s0 = 0.f, q0 = 0.f;
#pragma unroll
    for (int p = 0; p < NCOPY; ++p) {
      s0 += sums0[p * 512 + c];
      q0 += sums0[p * 512 + 256 + c];
    }
    float mm = s0 * invN;
    float vv = q0 * invN - mm * mm;
    float s = g0f[c] * rsqrtf(vv + 1e-5f);
    sc0[c] = s; sh0[c] = b0f[c] - mm * s;
    if (MODE == 2) {
      float s1v = 0.f, q1v = 0.f;
#pragma unroll
      for (int p = 0; p < NCOPY; ++p) {
        s1v += sums1[p * 512 + c];
        q1v += sums1[p * 512 + 256 + c];
      }
      float m1 = s1v * invN;
      float v1 = q1v * invN - m1 * m1;
      float ss = g1f[c] * rsqrtf(v1 + 1e-5f);
      sc1[c] = ss; sh1[c] = b1f[c] - m1 * ss;
    }
  }
  __syncthreads();
  const size_t i8 = ((size_t)blockIdx.x * 256 + tid) << 3;
  const int c0 = (int)(i8 & (size_t)(C - 1));
  uint4 tv = *reinterpret_cast<const uint4*>(T + i8);
  uint4 sv = *reinterpret_cast<const uint4*>(S + i8);
  unsigned tw[4] = {tv.x, tv.y, tv.z, tv.w};
  unsigned sw[4] = {sv.x, sv.y, sv.z, sv.w};
  unsigned ow[4];
#pragma unroll
  for (int jw = 0; jw < 4; ++jw) {
    unsigned r = 0;
#pragma unroll
    for (int h = 0; h < 2; ++h) {
      int c = c0 + jw * 2 + h;
      float x = __uint_as_float(((tw[jw] >> (h * 16)) & 0xffffu) << 16);
      x = fmaf(x, sc0[c], sh0[c]);
      if (MODE == 1) x += __uint_as_float(((sw[jw] >> (h * 16)) & 0xffffu) << 16);
      if (MODE == 2) {
        float y = __uint_as_float(((sw[jw] >> (h * 16)) & 0xffffu) << 16);
        x += fmaf(y, sc1[c], sh1[c]);
      }
      x = fmaxf(x, 0.f);
      r |= ((unsigned)f2bf(x)) << (h * 16);
    }
    ow[jw] = r;
  }
  *reinterpret_cast<uint4*>(OUT + i8) = make_uint4(ow[0], ow[1], ow[2], ow[3]);
}

// ---- writeout: out[b][c][n] f32 = bn(F[b][n][c]) via LDS transpose ---------
__global__ __launch_bounds__(256)
void writeout_t_kernel(const unsigned short* __restrict__ F, const float* __restrict__ sums,
                       const float* __restrict__ gam, const float* __restrict__ bet,
                       float* __restrict__ out) {
  __shared__ float ts[64][66];
  __shared__ float sc[64], sh[64];
  const int tid = threadIdx.x;
  const float invN = 1.f / 16384.f;
  if (tid < 64) {
    float s0 = 0.f, q0 = 0.f;
#pragma unroll
    for (int p = 0; p < NCOPY; ++p) {
      s0 += sums[p * 512 + tid];
      q0 += sums[p * 512 + 256 + tid];
    }
    float mm = s0 * invN;
    float vv = q0 * invN - mm * mm;
    float s = gam[tid] * rsqrtf(vv + 1e-5f);
    sc[tid] = s; sh[tid] = bet[tid] - mm * s;
  }
  __syncthreads();
  const int n0 = blockIdx.x << 6;
  const int b = blockIdx.y;
  {
    const int n = tid >> 2, c0 = (tid & 3) << 4;
    const unsigned short* Fr = F + ((size_t)(b * 1024 + n0 + n) << 6) + c0;
    uint4 v0 = *reinterpret_cast<const uint4*>(Fr);
    uint4 v1 = *reinterpret_cast<const uint4*>(Fr + 8);
    unsigned vw[8] = {v0.x, v0.y, v0.z, v0.w, v1.x, v1.y, v1.z, v1.w};
#pragma unroll
    for (int jw = 0; jw < 8; ++jw) {
      int c = c0 + jw * 2;
      float x0 = __uint_as_float((vw[jw] & 0xffffu) << 16);
      float x1 = __uint_as_float((vw[jw] >> 16) << 16);
      ts[c][n] = fmaf(x0, sc[c], sh[c]);
      ts[c + 1][n] = fmaf(x1, sc[c + 1], sh[c + 1]);
    }
  }
  __syncthreads();
  const int c = tid >> 2, nq = (tid & 3) << 4;
  float* orow = out + ((size_t)(b * 64 + c) << 10) + n0 + nq;
#pragma unroll
  for (int q = 0; q < 4; ++q) {
    float4 ov;
    ov.x = ts[c][nq + q * 4 + 0]; ov.y = ts[c][nq + q * 4 + 1];
    ov.z = ts[c][nq + q * 4 + 2]; ov.w = ts[c][nq + q * 4 + 3];
    *reinterpret_cast<float4*>(orow + q * 4) = ov;
  }
}

// ============================ host side =====================================
extern "C" void kernel_launch(void* const* d_in, const int* in_sizes, int n_in,
                              void* d_out, int out_size, void* d_ws, size_t ws_size,
                              hipStream_t stream) {
  float* wsf = (float*)d_ws;
  const size_t M1 = (size_t)1 << 20;
  const size_t H1 = (size_t)1 << 19;
  const int SSTR = NCOPY * 512;  // floats per stat set

  unsigned short* QAt = (unsigned short*)wsf;                 // [0, 0.5M)
  unsigned short* QBt = (unsigned short*)(wsf + H1);          // [0.5M, 1M)
  unsigned short* KAc = (unsigned short*)(wsf + 2 * H1);      // [1M, 1.5M)
  unsigned short* KBc = (unsigned short*)(wsf + 3 * H1);      // [1.5M, 2M)
  float* PART = wsf + 2 * M1;                                 // [2M, 6M)
  unsigned short* Y0A = (unsigned short*)(wsf + 6 * M1);      // [6M, 7M)
  unsigned short* Y0B = (unsigned short*)(wsf + 7 * M1);      // [7M, 8M)
  unsigned short* T1  = (unsigned short*)(wsf + 8 * M1);      // [8M, 9M)
  unsigned short* T2  = (unsigned short*)(wsf + 9 * M1);      // [9M, 10M)
  unsigned short* O1  = (unsigned short*)(wsf + 10 * M1);     // [10M, 11M)
  unsigned short* T3  = (unsigned short*)(wsf + 11 * M1);     // [11M, 13M)
  unsigned short* T4  = (unsigned short*)(wsf + 13 * M1);     // [13M, 15M)
  unsigned short* T5  = (unsigned short*)(wsf + 15 * M1);     // [15M, 17M)
  unsigned short* Fb  = (unsigned short*)(wsf + 17 * M1);     // [17M, 17.5M)
  float* tail = wsf + 17 * M1 + H1;
  float* bsum = tail;
  float* stats = tail + 16;                                   // 12 * SSTR
  unsigned short* wbf = (unsigned short*)(stats + 12 * SSTR);

  const float* pp[46];
  for (int i = 0; i < 46 && i < n_in; ++i) pp[i] = (const float*)d_in[i];
  const float* XAF = pp[0];
  const float* XBF = pp[1];

  const int initN = 16 + 12 * SSTR;
  init_kernel<<<(initN + 255) / 256, 256, 0, stream>>>(tail, initN);

  const int widx[12] = {10, 13, 16, 19, 22, 25, 28, 31, 34, 37, 40, 43};
  WcvtArgs wa;
  int woff[12];
  {
    int run = 0;
    for (int i = 0; i < 12; ++i) {
      wa.p[i] = pp[widx[i]];
      wa.sz[i] = in_sizes[widx[i]];
      wa.off[i] = run; woff[i] = run;
      run += in_sizes[widx[i]];
    }
  }
  wcvt_kernel<<<dim3(12, 16), 256, 0, stream>>>(wa, wbf);

  float* ST[12];
  for (int i = 0; i < 12; ++i) ST[i] = stats + i * SSTR;

  dim3 gq(16, 2, BATCH);
  conv_qk_kernel<0><<<gq, 256, 0, stream>>>(XAF, pp[2], pp[3], QAt);
  conv_qk_kernel<0><<<gq, 256, 0, stream>>>(XBF, pp[4], pp[5], QBt);
  conv_qk_kernel<1><<<gq, 256, 0, stream>>>(XAF, pp[6], pp[7], KAc);
  conv_qk_kernel<1><<<gq, 256, 0, stream>>>(XBF, pp[8], pp[9], KBc);

  pv_mfma_kernel<<<dim3(16, 4, BATCH), 256, 0, stream>>>(QAt, QBt, KBc, PART, bsum);
  merge_kernel<<<dim3(16, BATCH), 256, 0, stream>>>(PART, XAF, bsum, Y0A);
  tpv_mfma_kernel<<<dim3(16, 4, BATCH), 256, 0, stream>>>(QAt, QBt, KAc, PART);
  merge_kernel<<<dim3(16, BATCH), 256, 0, stream>>>(PART, XBF, bsum, Y0B);

  const int NSUB = 64 * BATCH;  // 1024 n-subtiles
  for (int sbi = 0; sbi < 2; ++sbi) {
    const unsigned short* Y0 = sbi ? Y0B : Y0A;
    const int base1 = sbi ? 16 : 10;
    const int base2 = sbi ? 31 : 22;
    const int baseo = sbi ? 43 : 40;
    const unsigned short* w11 = wbf + woff[sbi ? 2 : 0];
    const unsigned short* w12 = wbf + woff[sbi ? 3 : 1];
    const unsigned short* w21 = wbf + woff[sbi ? 7 : 4];
    const unsigned short* w22 = wbf + woff[sbi ? 8 : 5];
    const unsigned short* w2s = wbf + woff[sbi ? 9 : 6];
    const unsigned short* wo  = wbf + woff[sbi ? 11 : 10];
    float* s1 = ST[sbi * 6 + 0];
    float* s2 = ST[sbi * 6 + 1];
    float* s3 = ST[sbi * 6 + 2];
    float* s4 = ST[sbi * 6 + 3];
    float* s5 = ST[sbi * 6 + 4];
    float* s6 = ST[sbi * 6 + 5];

    // block 1 (128 -> 128)
    conv_mfma_kernel<128, false><<<dim3(2, NSUB), 256, 0, stream>>>(
        Y0, w11, T1, nullptr, nullptr, nullptr, s1, 128);
    conv_mfma_kernel<128, true><<<dim3(2, NSUB), 256, 0, stream>>>(
        T1, w12, T2, s1, pp[base1 + 1], pp[base1 + 2], s2, 128);
    finish_kernel<128, 1><<<1024, 256, 0, stream>>>(
        T2, s2, pp[base1 + 4], pp[base1 + 5], Y0, nullptr, nullptr, nullptr, O1);

    // block 2 (128 -> 256, with shortcut)
    conv_mfma_kernel<128, false><<<dim3(4, NSUB), 256, 0, stream>>>(
        O1, w21, T3, nullptr, nullptr, nullptr, s3, 256);
    conv_mfma_kernel<256, true><<<dim3(4, NSUB), 256, 0, stream>>>(
        T3, w22, T4, s3, pp[base2 + 1], pp[base2 + 2], s4, 256);
    conv_mfma_kernel<128, false><<<dim3(4, NSUB), 256, 0, stream>>>(
        O1, w2s, T5, nullptr, nullptr, nullptr, s5, 256);
    finish_kernel<256, 2><<<2048, 256, 0, stream>>>(
        T4, s4, pp[base2 + 4], pp[base2 + 5], T5, s5, pp[base2 + 7], pp[base2 + 8], T3);

    // output conv (256 -> 64) + BN + transpose out
    conv_mfma_kernel<256, false><<<dim3(1, NSUB), 256, 0, stream>>>(
        T3, wo, Fb, nullptr, nullptr, nullptr, s6, 64);
    writeout_t_kernel<<<dim3(16, BATCH), 256, 0, stream>>>(
        Fb, s6, pp[baseo + 1], pp[baseo + 2], (float*)d_out + sbi * M1);
  }
}

// Round 11
// 333.067 us; speedup vs baseline: 2.6450x; 1.1908x over previous
//
#include <hip/hip_runtime.h>
#include <hip/hip_bf16.h>
#include <cstddef>

static constexpr int BATCH = 16;   // B
static constexpr int NCOPY = 16;   // stat atomic spread copies

typedef __attribute__((ext_vector_type(8))) short bf16x8;
typedef __attribute__((ext_vector_type(4))) float f32x4;

__device__ __forceinline__ unsigned short f2bf(float f) {
  unsigned u = __float_as_uint(f);
  return (unsigned short)((u + 0x7fffu + ((u >> 16) & 1u)) >> 16);  // RNE
}

__global__ void init_kernel(float* __restrict__ t, int n) {
  int i = blockIdx.x * 256 + threadIdx.x;
  if (i < n) t[i] = 0.f;
}

// ---- convert the 12 block-phase weight matrices to bf16 (layout [o][cin]) --
struct WcvtArgs { const float* p[12]; int sz[12]; int off[12]; };
__global__ __launch_bounds__(256)
void wcvt_kernel(WcvtArgs a, unsigned short* __restrict__ dst) {
  const int t = blockIdx.x;
  const float* src = a.p[t];
  unsigned short* d = dst + a.off[t];
  const int sz = a.sz[t];
  for (int i = blockIdx.y * 256 + threadIdx.x; i < sz; i += 16 * 256)
    d[i] = f2bf(src[i]);
}

// ---- bnprep: fold 16-copy sums + gamma/beta into scale/shift table ---------
__global__ void bnprep_kernel(const float* __restrict__ sums,
                              const float* __restrict__ gam,
                              const float* __restrict__ bet,
                              float* __restrict__ dst, int C) {
  const int c = threadIdx.x;
  if (c < C) {
    float s0 = 0.f, q0 = 0.f;
#pragma unroll
    for (int p = 0; p < NCOPY; ++p) {
      s0 += sums[p * 512 + c];
      q0 += sums[p * 512 + 256 + c];
    }
    const float invN = 1.f / 16384.f;
    float mm = s0 * invN;
    float vv = q0 * invN - mm * mm;
    float s = gam[c] * rsqrtf(vv + 1e-5f);
    dst[c] = s;
    dst[256 + c] = bet[c] - mm * s;
  }
}

// ---------------- q/k conv: f32 [b][c][n] -> bf16, dual layouts -------------
template<int TR>
__global__ __launch_bounds__(256)
void conv_qk_kernel(const float* __restrict__ X, const float* __restrict__ W,
                    const float* __restrict__ bias, unsigned short* __restrict__ Y) {
  __shared__ float wsT[64][4];
  const int tid = threadIdx.x;
  const int o0 = blockIdx.x << 2;
  const int b  = blockIdx.z;
  const int px = (blockIdx.y << 9) + (tid << 1);
  {
    int c = tid >> 2, k = tid & 3;
    wsT[c][k] = W[((o0 + k) << 6) + c];
  }
  __syncthreads();
  float acc[4][2] = {};
  const float* xb = X + ((size_t)b << 16) + px;
#pragma unroll 4
  for (int c = 0; c < 64; ++c) {
    float2 xv = *reinterpret_cast<const float2*>(xb + (c << 10));
    float4 w = *reinterpret_cast<const float4*>(wsT[c]);
    acc[0][0] = fmaf(w.x, xv.x, acc[0][0]); acc[0][1] = fmaf(w.x, xv.y, acc[0][1]);
    acc[1][0] = fmaf(w.y, xv.x, acc[1][0]); acc[1][1] = fmaf(w.y, xv.y, acc[1][1]);
    acc[2][0] = fmaf(w.z, xv.x, acc[2][0]); acc[2][1] = fmaf(w.z, xv.y, acc[2][1]);
    acc[3][0] = fmaf(w.w, xv.x, acc[3][0]); acc[3][1] = fmaf(w.w, xv.y, acc[3][1]);
  }
  float b0 = bias[o0], b1 = bias[o0 + 1], b2 = bias[o0 + 2], b3 = bias[o0 + 3];
  if (TR == 0) {
    ushort4 v0, v1;
    v0.x = f2bf(acc[0][0] + b0); v0.y = f2bf(acc[1][0] + b1);
    v0.z = f2bf(acc[2][0] + b2); v0.w = f2bf(acc[3][0] + b3);
    v1.x = f2bf(acc[0][1] + b0); v1.y = f2bf(acc[1][1] + b1);
    v1.z = f2bf(acc[2][1] + b2); v1.w = f2bf(acc[3][1] + b3);
    unsigned short* yt = Y + ((size_t)b << 16) + ((size_t)px << 6) + o0;
    *reinterpret_cast<ushort4*>(yt) = v0;
    *reinterpret_cast<ushort4*>(yt + 64) = v1;
  } else {
    float bv[4] = {b0, b1, b2, b3};
#pragma unroll
    for (int k = 0; k < 4; ++k) {
      ushort2 v;
      v.x = f2bf(acc[k][0] + bv[k]); v.y = f2bf(acc[k][1] + bv[k]);
      *reinterpret_cast<ushort2*>(Y + ((size_t)b << 16) + ((size_t)(o0 + k) << 10) + px) = v;
    }
  }
}

// ---- MFMA fused PV ---------------------------------------------------------
__global__ __launch_bounds__(256)
void pv_mfma_kernel(const unsigned short* __restrict__ QAt,
                    const unsigned short* __restrict__ QBt,
                    const unsigned short* __restrict__ KBc,
                    float* __restrict__ PART, float* __restrict__ bsum) {
  __shared__ __align__(16) unsigned short Ai[4096];
  __shared__ __align__(16) unsigned short Bj[4096];
  __shared__ __align__(16) unsigned short Pl[4096];
  __shared__ float red[256];
  const int tid = threadIdx.x;
  const int lane = tid & 63, w = tid >> 6;
  const int g = lane >> 4, m = lane & 15;
  const int i0 = blockIdx.x << 6;
  const int jbase = blockIdx.y << 8;
  const int b = blockIdx.z;
  const size_t nb = (size_t)b << 16;

  {
    const unsigned short* src = QAt + nb + ((size_t)i0 << 6);
#pragma unroll
    for (int s = 0; s < 2; ++s) {
      int idx = tid + (s << 8);
      int n = idx >> 3, cc = idx & 7;
      bf16x8 v = *reinterpret_cast<const bf16x8*>(src + (n << 6) + ((cc ^ (n & 7)) << 3));
      *reinterpret_cast<bf16x8*>(Ai + (idx << 3)) = v;
    }
  }
  f32x4 accO[4];
#pragma unroll
  for (int n = 0; n < 4; ++n) accO[n] = (f32x4){0.f, 0.f, 0.f, 0.f};
  float psum = 0.f;

  for (int jt = 0; jt < 4; ++jt) {
    const int j0 = jbase + (jt << 6);
    __syncthreads();
    {
      const unsigned short* src = QBt + nb + ((size_t)j0 << 6);
#pragma unroll
      for (int s = 0; s < 2; ++s) {
        int idx = tid + (s << 8);
        int n = idx >> 3, cc = idx & 7;
        bf16x8 v = *reinterpret_cast<const bf16x8*>(src + (n << 6) + ((cc ^ (n & 7)) << 3));
        *reinterpret_cast<bf16x8*>(Bj + (idx << 3)) = v;
      }
    }
    __syncthreads();
    const int jrow = (w << 4) | m;
    bf16x8 a0 = *reinterpret_cast<const bf16x8*>(Bj + (jrow << 6) + ((g ^ (jrow & 7)) << 3));
    bf16x8 a1 = *reinterpret_cast<const bf16x8*>(Bj + (jrow << 6) + (((g + 4) ^ (jrow & 7)) << 3));
    f32x4 e[4];
#pragma unroll
    for (int n = 0; n < 4; ++n) {
      const int irow = (n << 4) | m;
      bf16x8 b0v = *reinterpret_cast<const bf16x8*>(Ai + (irow << 6) + ((g ^ (irow & 7)) << 3));
      bf16x8 b1v = *reinterpret_cast<const bf16x8*>(Ai + (irow << 6) + (((g + 4) ^ (irow & 7)) << 3));
      e[n] = (f32x4){0.f, 0.f, 0.f, 0.f};
      e[n] = __builtin_amdgcn_mfma_f32_16x16x32_bf16(a0, b0v, e[n], 0, 0, 0);
      e[n] = __builtin_amdgcn_mfma_f32_16x16x32_bf16(a1, b1v, e[n], 0, 0, 0);
    }
    const int j = (w << 4) | (g << 2);
#pragma unroll
    for (int n = 0; n < 4; ++n) {
      const int irow = (n << 4) | m;
      float p0 = __expf(-e[n][0]), p1 = __expf(-e[n][1]);
      float p2 = __expf(-e[n][2]), p3 = __expf(-e[n][3]);
      psum += (p0 + p1) + (p2 + p3);
      unsigned pk01 = (unsigned)f2bf(p0) | ((unsigned)f2bf(p1) << 16);
      unsigned pk23 = (unsigned)f2bf(p2) | ((unsigned)f2bf(p3) << 16);
      int base = irow << 6;
      int off0 = base + ((((j) >> 3) ^ (irow & 7)) << 3) + (j & 7);
      int off2 = base + ((((j + 2) >> 3) ^ (irow & 7)) << 3) + ((j + 2) & 7);
      *reinterpret_cast<unsigned*>(Pl + off0) = pk01;
      *reinterpret_cast<unsigned*>(Pl + off2) = pk23;
    }
    const int crow = (w << 4) | m;
    const unsigned short* kbp = KBc + nb + ((size_t)crow << 10) + j0 + (g << 3);
    bf16x8 ka0 = *reinterpret_cast<const bf16x8*>(kbp);
    bf16x8 ka1 = *reinterpret_cast<const bf16x8*>(kbp + 32);
    __syncthreads();
#pragma unroll
    for (int n = 0; n < 4; ++n) {
      const int irow = (n << 4) | m;
      bf16x8 p0 = *reinterpret_cast<const bf16x8*>(Pl + (irow << 6) + ((g ^ (irow & 7)) << 3));
      bf16x8 p1 = *reinterpret_cast<const bf16x8*>(Pl + (irow << 6) + (((g + 4) ^ (irow & 7)) << 3));
      accO[n] = __builtin_amdgcn_mfma_f32_16x16x32_bf16(ka0, p0, accO[n], 0, 0, 0);
      accO[n] = __builtin_amdgcn_mfma_f32_16x16x32_bf16(ka1, p1, accO[n], 0, 0, 0);
    }
  }
  float* OUT = PART + ((size_t)blockIdx.y << 20) + ((size_t)(b * 64) << 10);
#pragma unroll
  for (int n = 0; n < 4; ++n) {
    const int ig = i0 + (n << 4) + m;
    const int c = (w << 4) + (g << 2);
#pragma unroll
    for (int r = 0; r < 4; ++r)
      OUT[((size_t)(c + r) << 10) + ig] = accO[n][r];
  }
  red[tid] = psum; __syncthreads();
  for (int s = 128; s > 0; s >>= 1) {
    if (tid < s) red[tid] += red[tid + s];
    __syncthreads();
  }
  if (tid == 0) atomicAdd(bsum + b, red[0]);
}

// ---- MFMA fused PtV --------------------------------------------------------
__global__ __launch_bounds__(256)
void tpv_mfma_kernel(const unsigned short* __restrict__ QAt,
                     const unsigned short* __restrict__ QBt,
                     const unsigned short* __restrict__ KAc,
                     float* __restrict__ PART) {
  __shared__ __align__(16) unsigned short Bj[4096];
  __shared__ __align__(16) unsigned short Ai[4096];
  __shared__ __align__(16) unsigned short Pl[4096];
  const int tid = threadIdx.x;
  const int lane = tid & 63, w = tid >> 6;
  const int g = lane >> 4, m = lane & 15;
  const int j0 = blockIdx.x << 6;
  const int ibase = blockIdx.y << 8;
  const int b = blockIdx.z;
  const size_t nb = (size_t)b << 16;

  {
    const unsigned short* src = QBt + nb + ((size_t)j0 << 6);
#pragma unroll
    for (int s = 0; s < 2; ++s) {
      int idx = tid + (s << 8);
      int n = idx >> 3, cc = idx & 7;
      bf16x8 v = *reinterpret_cast<const bf16x8*>(src + (n << 6) + ((cc ^ (n & 7)) << 3));
      *reinterpret_cast<bf16x8*>(Bj + (idx << 3)) = v;
    }
  }
  f32x4 accO[4];
#pragma unroll
  for (int n = 0; n < 4; ++n) accO[n] = (f32x4){0.f, 0.f, 0.f, 0.f};

  for (int it = 0; it < 4; ++it) {
    const int i0 = ibase + (it << 6);
    __syncthreads();
    {
      const unsigned short* src = QAt + nb + ((size_t)i0 << 6);
#pragma unroll
      for (int s = 0; s < 2; ++s) {
        int idx = tid + (s << 8);
        int n = idx >> 3, cc = idx & 7;
        bf16x8 v = *reinterpret_cast<const bf16x8*>(src + (n << 6) + ((cc ^ (n & 7)) << 3));
        *reinterpret_cast<bf16x8*>(Ai + (idx << 3)) = v;
      }
    }
    __syncthreads();
    const int irow_a = (w << 4) | m;
    bf16x8 a0 = *reinterpret_cast<const bf16x8*>(Ai + (irow_a << 6) + ((g ^ (irow_a & 7)) << 3));
    bf16x8 a1 = *reinterpret_cast<const bf16x8*>(Ai + (irow_a << 6) + (((g + 4) ^ (irow_a & 7)) << 3));
    f32x4 e[4];
#pragma unroll
    for (int n = 0; n < 4; ++n) {
      const int jrow = (n << 4) | m;
      bf16x8 b0v = *reinterpret_cast<const bf16x8*>(Bj + (jrow << 6) + ((g ^ (jrow & 7)) << 3));
      bf16x8 b1v = *reinterpret_cast<const bf16x8*>(Bj + (jrow << 6) + (((g + 4) ^ (jrow & 7)) << 3));
      e[n] = (f32x4){0.f, 0.f, 0.f, 0.f};
      e[n] = __builtin_amdgcn_mfma_f32_16x16x32_bf16(a0, b0v, e[n], 0, 0, 0);
      e[n] = __builtin_amdgcn_mfma_f32_16x16x32_bf16(a1, b1v, e[n], 0, 0, 0);
    }
    const int i = (w << 4) | (g << 2);
#pragma unroll
    for (int n = 0; n < 4; ++n) {
      const int jrow = (n << 4) | m;
      float p0 = __expf(-e[n][0]), p1 = __expf(-e[n][1]);
      float p2 = __expf(-e[n][2]), p3 = __expf(-e[n][3]);
      unsigned pk01 = (unsigned)f2bf(p0) | ((unsigned)f2bf(p1) << 16);
      unsigned pk23 = (unsigned)f2bf(p2) | ((unsigned)f2bf(p3) << 16);
      int base = jrow << 6;
      int off0 = base + ((((i) >> 3) ^ (jrow & 7)) << 3) + (i & 7);
      int off2 = base + ((((i + 2) >> 3) ^ (jrow & 7)) << 3) + ((i + 2) & 7);
      *reinterpret_cast<unsigned*>(Pl + off0) = pk01;
      *reinterpret_cast<unsigned*>(Pl + off2) = pk23;
    }
    const int crow = (w << 4) | m;
    const unsigned short* kap = KAc + nb + ((size_t)crow << 10) + i0 + (g << 3);
    bf16x8 ka0 = *reinterpret_cast<const bf16x8*>(kap);
    bf16x8 ka1 = *reinterpret_cast<const bf16x8*>(kap + 32);
    __syncthreads();
#pragma unroll
    for (int n = 0; n < 4; ++n) {
      const int jrow = (n << 4) | m;
      bf16x8 p0 = *reinterpret_cast<const bf16x8*>(Pl + (jrow << 6) + ((g ^ (jrow & 7)) << 3));
      bf16x8 p1 = *reinterpret_cast<const bf16x8*>(Pl + (jrow << 6) + (((g + 4) ^ (jrow & 7)) << 3));
      accO[n] = __builtin_amdgcn_mfma_f32_16x16x32_bf16(ka0, p0, accO[n], 0, 0, 0);
      accO[n] = __builtin_amdgcn_mfma_f32_16x16x32_bf16(ka1, p1, accO[n], 0, 0, 0);
    }
  }
  float* OUT = PART + ((size_t)blockIdx.y << 20) + ((size_t)(b * 64) << 10);
#pragma unroll
  for (int n = 0; n < 4; ++n) {
    const int jg = j0 + (n << 4) + m;
    const int c = (w << 4) + (g << 2);
#pragma unroll
    for (int r = 0; r < 4; ++r)
      OUT[((size_t)(c + r) << 10) + jg] = accO[n][r];
  }
}

// ---- merge: Y0[b][n][0:64] = XR, [64:128] = (sum of 4 partials)/bsum, bf16 --
__global__ __launch_bounds__(256)
void merge_kernel(const float* __restrict__ PART, const float* __restrict__ XR,
                  const float* __restrict__ bsum, unsigned short* __restrict__ Y0) {
  __shared__ float ts[128][66];
  const int tid = threadIdx.x;
  const int n0 = blockIdx.x << 6;
  const int b = blockIdx.y;
  const float invS = 1.f / bsum[b];
  const size_t M1 = (size_t)1 << 20;
#pragma unroll
  for (int it = 0; it < 4; ++it) {
    int idx = it * 256 + tid;
    int c = idx >> 4, nq = (idx & 15) << 2;
    float4 v = *reinterpret_cast<const float4*>(XR + ((size_t)(b * 64 + c) << 10) + n0 + nq);
    ts[c][nq] = v.x; ts[c][nq + 1] = v.y; ts[c][nq + 2] = v.z; ts[c][nq + 3] = v.w;
  }
#pragma unroll
  for (int it = 0; it < 4; ++it) {
    int idx = it * 256 + tid;
    int c = idx >> 4, nq = (idx & 15) << 2;
    const float* p = PART + ((size_t)(b * 64 + c) << 10) + n0 + nq;
    float4 a = *reinterpret_cast<const float4*>(p);
    float4 b4 = *reinterpret_cast<const float4*>(p + M1);
    float4 c4 = *reinterpret_cast<const float4*>(p + 2 * M1);
    float4 d4 = *reinterpret_cast<const float4*>(p + 3 * M1);
    ts[64 + c][nq]     = ((a.x + b4.x) + (c4.x + d4.x)) * invS;
    ts[64 + c][nq + 1] = ((a.y + b4.y) + (c4.y + d4.y)) * invS;
    ts[64 + c][nq + 2] = ((a.z + b4.z) + (c4.z + d4.z)) * invS;
    ts[64 + c][nq + 3] = ((a.w + b4.w) + (c4.w + d4.w)) * invS;
  }
  __syncthreads();
  const int n = tid >> 2, c0 = (tid & 3) << 5;
  unsigned short* dst = Y0 + ((size_t)(b * 1024 + n0 + n) << 7) + c0;
#pragma unroll
  for (int q8 = 0; q8 < 4; ++q8) {
    const int cb = c0 + (q8 << 3);
    unsigned w0 = (unsigned)f2bf(ts[cb + 0][n]) | ((unsigned)f2bf(ts[cb + 1][n]) << 16);
    unsigned w1 = (unsigned)f2bf(ts[cb + 2][n]) | ((unsigned)f2bf(ts[cb + 3][n]) << 16);
    unsigned w2 = (unsigned)f2bf(ts[cb + 4][n]) | ((unsigned)f2bf(ts[cb + 5][n]) << 16);
    unsigned w3 = (unsigned)f2bf(ts[cb + 6][n]) | ((unsigned)f2bf(ts[cb + 7][n]) << 16);
    *reinterpret_cast<uint4*>(dst + (q8 << 3)) = make_uint4(w0, w1, w2, w3);
  }
}

// ---- MFMA conv v5: NT n-tiles/wave, W frags loaded once, prep-table PREBN --
// grid (COUT/64, 16384/(NT*16)). Wave: NT x (16 n-rows x 16 outputs).
template<int CIN, int NT, bool PREBN>
__global__ __launch_bounds__(256)
void conv_mfma_kernel(const unsigned short* __restrict__ Xin,
                      const unsigned short* __restrict__ Wb,
                      unsigned short* __restrict__ Yout,
                      const float* __restrict__ pre,
                      float* __restrict__ outSums, int COUT) {
  constexpr int KS = CIN / 32;
  __shared__ float scs[PREBN ? CIN : 1];
  __shared__ float shs[PREBN ? CIN : 1];
  const int tid = threadIdx.x;
  const int lane = tid & 63, w = tid >> 6;
  const int g = lane >> 4, m = lane & 15;
  const int o0 = (blockIdx.x << 6) + (w << 4);
  const int nbase = blockIdx.y * (NT << 4);
  if (PREBN) {
    for (int c = tid; c < CIN; c += 256) {
      scs[c] = pre[c];
      shs[c] = pre[256 + c];
    }
    __syncthreads();
  }
  const unsigned short* Wr = Wb + (size_t)(o0 + m) * CIN + (g << 3);
  bf16x8 af[KS];
#pragma unroll
  for (int k = 0; k < KS; ++k) af[k] = *reinterpret_cast<const bf16x8*>(Wr + (k << 5));
  float sr[4] = {0.f, 0.f, 0.f, 0.f}, qr[4] = {0.f, 0.f, 0.f, 0.f};
#pragma unroll
  for (int nt = 0; nt < NT; ++nt) {
    const int row = nbase + (nt << 4) + m;
    const unsigned short* Xr = Xin + (size_t)row * CIN + (g << 3);
    bf16x8 bv[KS];
#pragma unroll
    for (int k = 0; k < KS; ++k) bv[k] = *reinterpret_cast<const bf16x8*>(Xr + (k << 5));
    if (PREBN) {
#pragma unroll
      for (int k = 0; k < KS; ++k) {
        const int kb = (k << 5) + (g << 3);
#pragma unroll
        for (int j = 0; j < 8; ++j) {
          float x = __uint_as_float((unsigned)(unsigned short)bv[k][j] << 16);
          x = fmaxf(fmaf(x, scs[kb + j], shs[kb + j]), 0.f);
          bv[k][j] = (short)f2bf(x);
        }
      }
    }
    f32x4 acc = (f32x4){0.f, 0.f, 0.f, 0.f};
#pragma unroll
    for (int k = 0; k < KS; ++k)
      acc = __builtin_amdgcn_mfma_f32_16x16x32_bf16(af[k], bv[k], acc, 0, 0, 0);
    ushort4 v;
    v.x = f2bf(acc[0]); v.y = f2bf(acc[1]);
    v.z = f2bf(acc[2]); v.w = f2bf(acc[3]);
    *reinterpret_cast<ushort4*>(Yout + (size_t)row * COUT + o0 + (g << 2)) = v;
    if (outSums) {
#pragma unroll
      for (int r = 0; r < 4; ++r) {
        sr[r] += acc[r];
        qr[r] = fmaf(acc[r], acc[r], qr[r]);
      }
    }
  }
  if (outSums) {
#pragma unroll
    for (int r = 0; r < 4; ++r) {
      for (int off = 1; off < 16; off <<= 1) {
        sr[r] += __shfl_xor(sr[r], off);
        qr[r] += __shfl_xor(qr[r], off);
      }
    }
    if (m == 0) {
      float* dst = outSums + (blockIdx.y & (NCOPY - 1)) * 512;
#pragma unroll
      for (int r = 0; r < 4; ++r) {
        atomicAdd(&dst[o0 + (g << 2) + r], sr[r]);
        atomicAdd(&dst[256 + o0 + (g << 2) + r], qr[r]);
      }
    }
  }
}

// ---- finish: MODE 1: relu(bn0(T)+S); 2: relu(bn0(T)+bn1(S)) ----------------
// bn scale/shift come from precomputed prep tables (512 floats each).
template<int C, int MODE>
__global__ __launch_bounds__(256)
void finish_kernel(const unsigned short* __restrict__ T,
                   const float* __restrict__ p0,
                   const unsigned short* __restrict__ S,
                   const float* __restrict__ p1,
                   unsigned short* __restrict__ OUT) {
  __shared__ float sc0[C], sh0[C];
  __shared__ float sc1[(MODE == 2) ? C : 1], sh1[(MODE == 2) ? C : 1];
  const int tid = threadIdx.x;
  for (int c = tid; c < C; c += 256) {
    sc0[c] = p0[c]; sh0[c] = p0[256 + c];
    if (MODE == 2) { sc1[c] = p1[c]; sh1[c] = p1[256 + c]; }
  }
  __syncthreads();
  const size_t i8 = ((size_t)blockIdx.x * 256 + tid) << 3;
  const int c0 = (int)(i8 & (size_t)(C - 1));
  uint4 tv = *reinterpret_cast<const uint4*>(T + i8);
  uint4 sv = *reinterpret_cast<const uint4*>(S + i8);
  unsigned tw[4] = {tv.x, tv.y, tv.z, tv.w};
  unsigned sw[4] = {sv.x, sv.y, sv.z, sv.w};
  unsigned ow[4];
#pragma unroll
  for (int jw = 0; jw < 4; ++jw) {
    unsigned r = 0;
#pragma unroll
    for (int h = 0; h < 2; ++h) {
      int c = c0 + jw * 2 + h;
      float x = __uint_as_float(((tw[jw] >> (h * 16)) & 0xffffu) << 16);
      x = fmaf(x, sc0[c], sh0[c]);
      if (MODE == 1) x += __uint_as_float(((sw[jw] >> (h * 16)) & 0xffffu) << 16);
      if (MODE == 2) {
        float y = __uint_as_float(((sw[jw] >> (h * 16)) & 0xffffu) << 16);
        x += fmaf(y, sc1[c], sh1[c]);
      }
      x = fmaxf(x, 0.f);
      r |= ((unsigned)f2bf(x)) << (h * 16);
    }
    ow[jw] = r;
  }
  *reinterpret_cast<uint4*>(OUT + i8) = make_uint4(ow[0], ow[1], ow[2], ow[3]);
}

// ---- writeout: out[b][c][n] f32 = bn(F[b][n][c]) via LDS transpose ---------
__global__ __launch_bounds__(256)
void writeout_t_kernel(const unsigned short* __restrict__ F,
                       const float* __restrict__ pre,
                       float* __restrict__ out) {
  __shared__ float ts[64][66];
  __shared__ float sc[64], sh[64];
  const int tid = threadIdx.x;
  if (tid < 64) {
    sc[tid] = pre[tid];
    sh[tid] = pre[256 + tid];
  }
  __syncthreads();
  const int n0 = blockIdx.x << 6;
  const int b = blockIdx.y;
  {
    const int n = tid >> 2, c0 = (tid & 3) << 4;
    const unsigned short* Fr = F + ((size_t)(b * 1024 + n0 + n) << 6) + c0;
    uint4 v0 = *reinterpret_cast<const uint4*>(Fr);
    uint4 v1 = *reinterpret_cast<const uint4*>(Fr + 8);
    unsigned vw[8] = {v0.x, v0.y, v0.z, v0.w, v1.x, v1.y, v1.z, v1.w};
#pragma unroll
    for (int jw = 0; jw < 8; ++jw) {
      int c = c0 + jw * 2;
      float x0 = __uint_as_float((vw[jw] & 0xffffu) << 16);
      float x1 = __uint_as_float((vw[jw] >> 16) << 16);
      ts[c][n] = fmaf(x0, sc[c], sh[c]);
      ts[c + 1][n] = fmaf(x1, sc[c + 1], sh[c + 1]);
    }
  }
  __syncthreads();
  const int c = tid >> 2, nq = (tid & 3) << 4;
  float* orow = out + ((size_t)(b * 64 + c) << 10) + n0 + nq;
#pragma unroll
  for (int q = 0; q < 4; ++q) {
    float4 ov;
    ov.x = ts[c][nq + q * 4 + 0]; ov.y = ts[c][nq + q * 4 + 1];
    ov.z = ts[c][nq + q * 4 + 2]; ov.w = ts[c][nq + q * 4 + 3];
    *reinterpret_cast<float4*>(orow + q * 4) = ov;
  }
}

// ============================ host side =====================================
extern "C" void kernel_launch(void* const* d_in, const int* in_sizes, int n_in,
                              void* d_out, int out_size, void* d_ws, size_t ws_size,
                              hipStream_t stream) {
  float* wsf = (float*)d_ws;
  const size_t M1 = (size_t)1 << 20;
  const size_t H1 = (size_t)1 << 19;
  const int SSTR = NCOPY * 512;  // floats per stat set

  unsigned short* QAt = (unsigned short*)wsf;                 // [0, 0.5M)
  unsigned short* QBt = (unsigned short*)(wsf + H1);          // [0.5M, 1M)
  unsigned short* KAc = (unsigned short*)(wsf + 2 * H1);      // [1M, 1.5M)
  unsigned short* KBc = (unsigned short*)(wsf + 3 * H1);      // [1.5M, 2M)
  float* PART = wsf + 2 * M1;                                 // [2M, 6M)
  unsigned short* Y0A = (unsigned short*)(wsf + 6 * M1);      // [6M, 7M)
  unsigned short* Y0B = (unsigned short*)(wsf + 7 * M1);      // [7M, 8M)
  unsigned short* T1  = (unsigned short*)(wsf + 8 * M1);      // [8M, 9M)
  unsigned short* T2  = (unsigned short*)(wsf + 9 * M1);      // [9M, 10M)
  unsigned short* O1  = (unsigned short*)(wsf + 10 * M1);     // [10M, 11M)
  unsigned short* T3  = (unsigned short*)(wsf + 11 * M1);     // [11M, 13M)
  unsigned short* T4  = (unsigned short*)(wsf + 13 * M1);     // [13M, 15M)
  unsigned short* T5  = (unsigned short*)(wsf + 15 * M1);     // [15M, 17M)
  unsigned short* Fb  = (unsigned short*)(wsf + 17 * M1);     // [17M, 17.5M)
  float* tail = wsf + 17 * M1 + H1;
  float* bsum = tail;
  float* stats = tail + 16;                                   // 12 * SSTR
  float* prep  = stats + 12 * SSTR;                           // 12 * 512
  unsigned short* wbf = (unsigned short*)(prep + 12 * 512);

  const float* pp[46];
  for (int i = 0; i < 46 && i < n_in; ++i) pp[i] = (const float*)d_in[i];
  const float* XAF = pp[0];
  const float* XBF = pp[1];

  const int initN = 16 + 12 * SSTR;
  init_kernel<<<(initN + 255) / 256, 256, 0, stream>>>(tail, initN);

  const int widx[12] = {10, 13, 16, 19, 22, 25, 28, 31, 34, 37, 40, 43};
  WcvtArgs wa;
  int woff[12];
  {
    int run = 0;
    for (int i = 0; i < 12; ++i) {
      wa.p[i] = pp[widx[i]];
      wa.sz[i] = in_sizes[widx[i]];
      wa.off[i] = run; woff[i] = run;
      run += in_sizes[widx[i]];
    }
  }
  wcvt_kernel<<<dim3(12, 16), 256, 0, stream>>>(wa, wbf);

  float* ST[12];
  float* PR[12];
  for (int i = 0; i < 12; ++i) { ST[i] = stats + i * SSTR; PR[i] = prep + i * 512; }

  dim3 gq(16, 2, BATCH);
  conv_qk_kernel<0><<<gq, 256, 0, stream>>>(XAF, pp[2], pp[3], QAt);
  conv_qk_kernel<0><<<gq, 256, 0, stream>>>(XBF, pp[4], pp[5], QBt);
  conv_qk_kernel<1><<<gq, 256, 0, stream>>>(XAF, pp[6], pp[7], KAc);
  conv_qk_kernel<1><<<gq, 256, 0, stream>>>(XBF, pp[8], pp[9], KBc);

  pv_mfma_kernel<<<dim3(16, 4, BATCH), 256, 0, stream>>>(QAt, QBt, KBc, PART, bsum);
  merge_kernel<<<dim3(16, BATCH), 256, 0, stream>>>(PART, XAF, bsum, Y0A);
  tpv_mfma_kernel<<<dim3(16, 4, BATCH), 256, 0, stream>>>(QAt, QBt, KAc, PART);
  merge_kernel<<<dim3(16, BATCH), 256, 0, stream>>>(PART, XBF, bsum, Y0B);

  for (int sbi = 0; sbi < 2; ++sbi) {
    const unsigned short* Y0 = sbi ? Y0B : Y0A;
    const int base1 = sbi ? 16 : 10;
    const int base2 = sbi ? 31 : 22;
    const int baseo = sbi ? 43 : 40;
    const unsigned short* w11 = wbf + woff[sbi ? 2 : 0];
    const unsigned short* w12 = wbf + woff[sbi ? 3 : 1];
    const unsigned short* w21 = wbf + woff[sbi ? 7 : 4];
    const unsigned short* w22 = wbf + woff[sbi ? 8 : 5];
    const unsigned short* w2s = wbf + woff[sbi ? 9 : 6];
    const unsigned short* wo  = wbf + woff[sbi ? 11 : 10];
    float* s1 = ST[sbi * 6 + 0];  float* p1 = PR[sbi * 6 + 0];
    float* s2 = ST[sbi * 6 + 1];  float* p2 = PR[sbi * 6 + 1];
    float* s3 = ST[sbi * 6 + 2];  float* p3 = PR[sbi * 6 + 2];
    float* s4 = ST[sbi * 6 + 3];  float* p4 = PR[sbi * 6 + 3];
    float* s5 = ST[sbi * 6 + 4];  float* p5 = PR[sbi * 6 + 4];
    float* s6 = ST[sbi * 6 + 5];  float* p6 = PR[sbi * 6 + 5];

    // block 1 (128 -> 128)
    conv_mfma_kernel<128, 2, false><<<dim3(2, 512), 256, 0, stream>>>(
        Y0, w11, T1, nullptr, s1, 128);
    bnprep_kernel<<<1, 256, 0, stream>>>(s1, pp[base1 + 1], pp[base1 + 2], p1, 128);
    conv_mfma_kernel<128, 2, true><<<dim3(2, 512), 256, 0, stream>>>(
        T1, w12, T2, p1, s2, 128);
    bnprep_kernel<<<1, 256, 0, stream>>>(s2, pp[base1 + 4], pp[base1 + 5], p2, 128);
    finish_kernel<128, 1><<<1024, 256, 0, stream>>>(T2, p2, Y0, nullptr, O1);

    // block 2 (128 -> 256, with shortcut)
    conv_mfma_kernel<128, 2, false><<<dim3(4, 512), 256, 0, stream>>>(
        O1, w21, T3, nullptr, s3, 256);
    conv_mfma_kernel<128, 2, false><<<dim3(4, 512), 256, 0, stream>>>(
        O1, w2s, T5, nullptr, s5, 256);
    bnprep_kernel<<<1, 256, 0, stream>>>(s3, pp[base2 + 1], pp[base2 + 2], p3, 256);
    conv_mfma_kernel<256, 4, true><<<dim3(4, 256), 256, 0, stream>>>(
        T3, w22, T4, p3, s4, 256);
    bnprep_kernel<<<1, 256, 0, stream>>>(s4, pp[base2 + 4], pp[base2 + 5], p4, 256);
    bnprep_kernel<<<1, 256, 0, stream>>>(s5, pp[base2 + 7], pp[base2 + 8], p5, 256);
    finish_kernel<256, 2><<<2048, 256, 0, stream>>>(T4, p4, T5, p5, T3);

    // output conv (256 -> 64) + BN + transpose out
    conv_mfma_kernel<256, 2, false><<<dim3(1, 512), 256, 0, stream>>>(
        T3, wo, Fb, nullptr, s6, 64);
    bnprep_kernel<<<1, 256, 0, stream>>>(s6, pp[baseo + 1], pp[baseo + 2], p6, 64);
    writeout_t_kernel<<<dim3(16, BATCH), 256, 0, stream>>>(
        Fb, p6, (float*)d_out + sbi * M1);
  }
}

// Round 12
// 319.681 us; speedup vs baseline: 2.7558x; 1.0419x over previous
//
#include <hip/hip_runtime.h>
#include <hip/hip_bf16.h>
#include <cstddef>

static constexpr int BATCH = 16;   // B
static constexpr int NCOPY = 16;   // stat atomic spread copies

typedef __attribute__((ext_vector_type(8))) short bf16x8;
typedef __attribute__((ext_vector_type(4))) float f32x4;

__device__ __forceinline__ unsigned short f2bf(float f) {
  unsigned u = __float_as_uint(f);
  return (unsigned short)((u + 0x7fffu + ((u >> 16) & 1u)) >> 16);  // RNE
}

__global__ void init_kernel(float* __restrict__ t, int n) {
  int i = blockIdx.x * 256 + threadIdx.x;
  if (i < n) t[i] = 0.f;
}

// ---- convert the 12 block-phase weight matrices to bf16 (layout [o][cin]) --
struct WcvtArgs { const float* p[12]; int sz[12]; int off[12]; };
__global__ __launch_bounds__(256)
void wcvt_kernel(WcvtArgs a, unsigned short* __restrict__ dst) {
  const int t = blockIdx.x;
  const float* src = a.p[t];
  unsigned short* d = dst + a.off[t];
  const int sz = a.sz[t];
  for (int i = blockIdx.y * 256 + threadIdx.x; i < sz; i += 16 * 256)
    d[i] = f2bf(src[i]);
}

// ---- bnprep: fold 16-copy sums + gamma/beta into scale/shift tables --------
struct BnArgs { const float* sums[4]; const float* gam[4]; const float* bet[4];
                float* dst[4]; };
__global__ void bnprep_kernel(BnArgs a, int C) {
  const int t = blockIdx.x;
  const int c = threadIdx.x;
  if (c < C) {
    const float* sums = a.sums[t];
    float s0 = 0.f, q0 = 0.f;
#pragma unroll
    for (int p = 0; p < NCOPY; ++p) {
      s0 += sums[p * 512 + c];
      q0 += sums[p * 512 + 256 + c];
    }
    const float invN = 1.f / 16384.f;
    float mm = s0 * invN;
    float vv = q0 * invN - mm * mm;
    float s = a.gam[t][c] * rsqrtf(vv + 1e-5f);
    a.dst[t][c] = s;
    a.dst[t][256 + c] = a.bet[t][c] - mm * s;
  }
}

// ---------------- q/k convs (all 4 in one launch) ---------------------------
struct QKArgs { const float* X[4]; const float* W[4]; const float* B[4];
                unsigned short* Y[4]; int tr[4]; };
__global__ __launch_bounds__(256)
void conv_qk_all_kernel(QKArgs a) {
  __shared__ float wsT[64][4];
  const int tid = threadIdx.x;
  const int z = blockIdx.z;
  const int which = z >> 4;
  const int b = z & 15;
  const int o0 = blockIdx.x << 2;
  const int px = (blockIdx.y << 9) + (tid << 1);
  const float* W = a.W[which];
  {
    int c = tid >> 2, k = tid & 3;
    wsT[c][k] = W[((o0 + k) << 6) + c];
  }
  __syncthreads();
  float acc[4][2] = {};
  const float* xb = a.X[which] + ((size_t)b << 16) + px;
#pragma unroll 4
  for (int c = 0; c < 64; ++c) {
    float2 xv = *reinterpret_cast<const float2*>(xb + (c << 10));
    float4 w = *reinterpret_cast<const float4*>(wsT[c]);
    acc[0][0] = fmaf(w.x, xv.x, acc[0][0]); acc[0][1] = fmaf(w.x, xv.y, acc[0][1]);
    acc[1][0] = fmaf(w.y, xv.x, acc[1][0]); acc[1][1] = fmaf(w.y, xv.y, acc[1][1]);
    acc[2][0] = fmaf(w.z, xv.x, acc[2][0]); acc[2][1] = fmaf(w.z, xv.y, acc[2][1]);
    acc[3][0] = fmaf(w.w, xv.x, acc[3][0]); acc[3][1] = fmaf(w.w, xv.y, acc[3][1]);
  }
  const float* bias = a.B[which];
  unsigned short* Y = a.Y[which];
  float b0 = bias[o0], b1 = bias[o0 + 1], b2 = bias[o0 + 2], b3 = bias[o0 + 3];
  if (a.tr[which] == 0) {
    ushort4 v0, v1;
    v0.x = f2bf(acc[0][0] + b0); v0.y = f2bf(acc[1][0] + b1);
    v0.z = f2bf(acc[2][0] + b2); v0.w = f2bf(acc[3][0] + b3);
    v1.x = f2bf(acc[0][1] + b0); v1.y = f2bf(acc[1][1] + b1);
    v1.z = f2bf(acc[2][1] + b2); v1.w = f2bf(acc[3][1] + b3);
    unsigned short* yt = Y + ((size_t)b << 16) + ((size_t)px << 6) + o0;
    *reinterpret_cast<ushort4*>(yt) = v0;
    *reinterpret_cast<ushort4*>(yt + 64) = v1;
  } else {
    float bv[4] = {b0, b1, b2, b3};
#pragma unroll
    for (int k = 0; k < 4; ++k) {
      ushort2 v;
      v.x = f2bf(acc[k][0] + bv[k]); v.y = f2bf(acc[k][1] + bv[k]);
      *reinterpret_cast<ushort2*>(Y + ((size_t)b << 16) + ((size_t)(o0 + k) << 10) + px) = v;
    }
  }
}

// ---- MFMA fused PV ---------------------------------------------------------
__global__ __launch_bounds__(256)
void pv_mfma_kernel(const unsigned short* __restrict__ QAt,
                    const unsigned short* __restrict__ QBt,
                    const unsigned short* __restrict__ KBc,
                    float* __restrict__ PART, float* __restrict__ bsum) {
  __shared__ __align__(16) unsigned short Ai[4096];
  __shared__ __align__(16) unsigned short Bj[4096];
  __shared__ __align__(16) unsigned short Pl[4096];
  __shared__ float red[256];
  const int tid = threadIdx.x;
  const int lane = tid & 63, w = tid >> 6;
  const int g = lane >> 4, m = lane & 15;
  const int i0 = blockIdx.x << 6;
  const int jbase = blockIdx.y << 8;
  const int b = blockIdx.z;
  const size_t nb = (size_t)b << 16;

  {
    const unsigned short* src = QAt + nb + ((size_t)i0 << 6);
#pragma unroll
    for (int s = 0; s < 2; ++s) {
      int idx = tid + (s << 8);
      int n = idx >> 3, cc = idx & 7;
      bf16x8 v = *reinterpret_cast<const bf16x8*>(src + (n << 6) + ((cc ^ (n & 7)) << 3));
      *reinterpret_cast<bf16x8*>(Ai + (idx << 3)) = v;
    }
  }
  f32x4 accO[4];
#pragma unroll
  for (int n = 0; n < 4; ++n) accO[n] = (f32x4){0.f, 0.f, 0.f, 0.f};
  float psum = 0.f;

  for (int jt = 0; jt < 4; ++jt) {
    const int j0 = jbase + (jt << 6);
    __syncthreads();
    {
      const unsigned short* src = QBt + nb + ((size_t)j0 << 6);
#pragma unroll
      for (int s = 0; s < 2; ++s) {
        int idx = tid + (s << 8);
        int n = idx >> 3, cc = idx & 7;
        bf16x8 v = *reinterpret_cast<const bf16x8*>(src + (n << 6) + ((cc ^ (n & 7)) << 3));
        *reinterpret_cast<bf16x8*>(Bj + (idx << 3)) = v;
      }
    }
    __syncthreads();
    const int jrow = (w << 4) | m;
    bf16x8 a0 = *reinterpret_cast<const bf16x8*>(Bj + (jrow << 6) + ((g ^ (jrow & 7)) << 3));
    bf16x8 a1 = *reinterpret_cast<const bf16x8*>(Bj + (jrow << 6) + (((g + 4) ^ (jrow & 7)) << 3));
    f32x4 e[4];
#pragma unroll
    for (int n = 0; n < 4; ++n) {
      const int irow = (n << 4) | m;
      bf16x8 b0v = *reinterpret_cast<const bf16x8*>(Ai + (irow << 6) + ((g ^ (irow & 7)) << 3));
      bf16x8 b1v = *reinterpret_cast<const bf16x8*>(Ai + (irow << 6) + (((g + 4) ^ (irow & 7)) << 3));
      e[n] = (f32x4){0.f, 0.f, 0.f, 0.f};
      e[n] = __builtin_amdgcn_mfma_f32_16x16x32_bf16(a0, b0v, e[n], 0, 0, 0);
      e[n] = __builtin_amdgcn_mfma_f32_16x16x32_bf16(a1, b1v, e[n], 0, 0, 0);
    }
    const int j = (w << 4) | (g << 2);
#pragma unroll
    for (int n = 0; n < 4; ++n) {
      const int irow = (n << 4) | m;
      float p0 = __expf(-e[n][0]), p1 = __expf(-e[n][1]);
      float p2 = __expf(-e[n][2]), p3 = __expf(-e[n][3]);
      psum += (p0 + p1) + (p2 + p3);
      unsigned pk01 = (unsigned)f2bf(p0) | ((unsigned)f2bf(p1) << 16);
      unsigned pk23 = (unsigned)f2bf(p2) | ((unsigned)f2bf(p3) << 16);
      int base = irow << 6;
      int off0 = base + ((((j) >> 3) ^ (irow & 7)) << 3) + (j & 7);
      int off2 = base + ((((j + 2) >> 3) ^ (irow & 7)) << 3) + ((j + 2) & 7);
      *reinterpret_cast<unsigned*>(Pl + off0) = pk01;
      *reinterpret_cast<unsigned*>(Pl + off2) = pk23;
    }
    const int crow = (w << 4) | m;
    const unsigned short* kbp = KBc + nb + ((size_t)crow << 10) + j0 + (g << 3);
    bf16x8 ka0 = *reinterpret_cast<const bf16x8*>(kbp);
    bf16x8 ka1 = *reinterpret_cast<const bf16x8*>(kbp + 32);
    __syncthreads();
#pragma unroll
    for (int n = 0; n < 4; ++n) {
      const int irow = (n << 4) | m;
      bf16x8 p0 = *reinterpret_cast<const bf16x8*>(Pl + (irow << 6) + ((g ^ (irow & 7)) << 3));
      bf16x8 p1 = *reinterpret_cast<const bf16x8*>(Pl + (irow << 6) + (((g + 4) ^ (irow & 7)) << 3));
      accO[n] = __builtin_amdgcn_mfma_f32_16x16x32_bf16(ka0, p0, accO[n], 0, 0, 0);
      accO[n] = __builtin_amdgcn_mfma_f32_16x16x32_bf16(ka1, p1, accO[n], 0, 0, 0);
    }
  }
  float* OUT = PART + ((size_t)blockIdx.y << 20) + ((size_t)(b * 64) << 10);
#pragma unroll
  for (int n = 0; n < 4; ++n) {
    const int ig = i0 + (n << 4) + m;
    const int c = (w << 4) + (g << 2);
#pragma unroll
    for (int r = 0; r < 4; ++r)
      OUT[((size_t)(c + r) << 10) + ig] = accO[n][r];
  }
  red[tid] = psum; __syncthreads();
  for (int s = 128; s > 0; s >>= 1) {
    if (tid < s) red[tid] += red[tid + s];
    __syncthreads();
  }
  if (tid == 0) atomicAdd(bsum + b, red[0]);
}

// ---- MFMA fused PtV --------------------------------------------------------
__global__ __launch_bounds__(256)
void tpv_mfma_kernel(const unsigned short* __restrict__ QAt,
                     const unsigned short* __restrict__ QBt,
                     const unsigned short* __restrict__ KAc,
                     float* __restrict__ PART) {
  __shared__ __align__(16) unsigned short Bj[4096];
  __shared__ __align__(16) unsigned short Ai[4096];
  __shared__ __align__(16) unsigned short Pl[4096];
  const int tid = threadIdx.x;
  const int lane = tid & 63, w = tid >> 6;
  const int g = lane >> 4, m = lane & 15;
  const int j0 = blockIdx.x << 6;
  const int ibase = blockIdx.y << 8;
  const int b = blockIdx.z;
  const size_t nb = (size_t)b << 16;

  {
    const unsigned short* src = QBt + nb + ((size_t)j0 << 6);
#pragma unroll
    for (int s = 0; s < 2; ++s) {
      int idx = tid + (s << 8);
      int n = idx >> 3, cc = idx & 7;
      bf16x8 v = *reinterpret_cast<const bf16x8*>(src + (n << 6) + ((cc ^ (n & 7)) << 3));
      *reinterpret_cast<bf16x8*>(Bj + (idx << 3)) = v;
    }
  }
  f32x4 accO[4];
#pragma unroll
  for (int n = 0; n < 4; ++n) accO[n] = (f32x4){0.f, 0.f, 0.f, 0.f};

  for (int it = 0; it < 4; ++it) {
    const int i0 = ibase + (it << 6);
    __syncthreads();
    {
      const unsigned short* src = QAt + nb + ((size_t)i0 << 6);
#pragma unroll
      for (int s = 0; s < 2; ++s) {
        int idx = tid + (s << 8);
        int n = idx >> 3, cc = idx & 7;
        bf16x8 v = *reinterpret_cast<const bf16x8*>(src + (n << 6) + ((cc ^ (n & 7)) << 3));
        *reinterpret_cast<bf16x8*>(Ai + (idx << 3)) = v;
      }
    }
    __syncthreads();
    const int irow_a = (w << 4) | m;
    bf16x8 a0 = *reinterpret_cast<const bf16x8*>(Ai + (irow_a << 6) + ((g ^ (irow_a & 7)) << 3));
    bf16x8 a1 = *reinterpret_cast<const bf16x8*>(Ai + (irow_a << 6) + (((g + 4) ^ (irow_a & 7)) << 3));
    f32x4 e[4];
#pragma unroll
    for (int n = 0; n < 4; ++n) {
      const int jrow = (n << 4) | m;
      bf16x8 b0v = *reinterpret_cast<const bf16x8*>(Bj + (jrow << 6) + ((g ^ (jrow & 7)) << 3));
      bf16x8 b1v = *reinterpret_cast<const bf16x8*>(Bj + (jrow << 6) + (((g + 4) ^ (jrow & 7)) << 3));
      e[n] = (f32x4){0.f, 0.f, 0.f, 0.f};
      e[n] = __builtin_amdgcn_mfma_f32_16x16x32_bf16(a0, b0v, e[n], 0, 0, 0);
      e[n] = __builtin_amdgcn_mfma_f32_16x16x32_bf16(a1, b1v, e[n], 0, 0, 0);
    }
    const int i = (w << 4) | (g << 2);
#pragma unroll
    for (int n = 0; n < 4; ++n) {
      const int jrow = (n << 4) | m;
      float p0 = __expf(-e[n][0]), p1 = __expf(-e[n][1]);
      float p2 = __expf(-e[n][2]), p3 = __expf(-e[n][3]);
      unsigned pk01 = (unsigned)f2bf(p0) | ((unsigned)f2bf(p1) << 16);
      unsigned pk23 = (unsigned)f2bf(p2) | ((unsigned)f2bf(p3) << 16);
      int base = jrow << 6;
      int off0 = base + ((((i) >> 3) ^ (jrow & 7)) << 3) + (i & 7);
      int off2 = base + ((((i + 2) >> 3) ^ (jrow & 7)) << 3) + ((i + 2) & 7);
      *reinterpret_cast<unsigned*>(Pl + off0) = pk01;
      *reinterpret_cast<unsigned*>(Pl + off2) = pk23;
    }
    const int crow = (w << 4) | m;
    const unsigned short* kap = KAc + nb + ((size_t)crow << 10) + i0 + (g << 3);
    bf16x8 ka0 = *reinterpret_cast<const bf16x8*>(kap);
    bf16x8 ka1 = *reinterpret_cast<const bf16x8*>(kap + 32);
    __syncthreads();
#pragma unroll
    for (int n = 0; n < 4; ++n) {
      const int jrow = (n << 4) | m;
      bf16x8 p0 = *reinterpret_cast<const bf16x8*>(Pl + (jrow << 6) + ((g ^ (jrow & 7)) << 3));
      bf16x8 p1 = *reinterpret_cast<const bf16x8*>(Pl + (jrow << 6) + (((g + 4) ^ (jrow & 7)) << 3));
      accO[n] = __builtin_amdgcn_mfma_f32_16x16x32_bf16(ka0, p0, accO[n], 0, 0, 0);
      accO[n] = __builtin_amdgcn_mfma_f32_16x16x32_bf16(ka1, p1, accO[n], 0, 0, 0);
    }
  }
  float* OUT = PART + ((size_t)blockIdx.y << 20) + ((size_t)(b * 64) << 10);
#pragma unroll
  for (int n = 0; n < 4; ++n) {
    const int jg = j0 + (n << 4) + m;
    const int c = (w << 4) + (g << 2);
#pragma unroll
    for (int r = 0; r < 4; ++r)
      OUT[((size_t)(c + r) << 10) + jg] = accO[n][r];
  }
}

// ---- merge both streams: Y0[z][b][n][0:64]=XR, [64:128]=sum(PART)/bsum -----
struct MergeArgs { const float* PART[2]; const float* XR[2]; unsigned short* Y0[2]; };
__global__ __launch_bounds__(256)
void merge_kernel(MergeArgs a, const float* __restrict__ bsum) {
  __shared__ float ts[128][66];
  const int tid = threadIdx.x;
  const int n0 = blockIdx.x << 6;
  const int b = blockIdx.y;
  const int z = blockIdx.z;
  const float invS = 1.f / bsum[b];
  const size_t M1 = (size_t)1 << 20;
  const float* XR = a.XR[z];
  const float* PART = a.PART[z];
#pragma unroll
  for (int it = 0; it < 4; ++it) {
    int idx = it * 256 + tid;
    int c = idx >> 4, nq = (idx & 15) << 2;
    float4 v = *reinterpret_cast<const float4*>(XR + ((size_t)(b * 64 + c) << 10) + n0 + nq);
    ts[c][nq] = v.x; ts[c][nq + 1] = v.y; ts[c][nq + 2] = v.z; ts[c][nq + 3] = v.w;
  }
#pragma unroll
  for (int it = 0; it < 4; ++it) {
    int idx = it * 256 + tid;
    int c = idx >> 4, nq = (idx & 15) << 2;
    const float* p = PART + ((size_t)(b * 64 + c) << 10) + n0 + nq;
    float4 av = *reinterpret_cast<const float4*>(p);
    float4 b4 = *reinterpret_cast<const float4*>(p + M1);
    float4 c4 = *reinterpret_cast<const float4*>(p + 2 * M1);
    float4 d4 = *reinterpret_cast<const float4*>(p + 3 * M1);
    ts[64 + c][nq]     = ((av.x + b4.x) + (c4.x + d4.x)) * invS;
    ts[64 + c][nq + 1] = ((av.y + b4.y) + (c4.y + d4.y)) * invS;
    ts[64 + c][nq + 2] = ((av.z + b4.z) + (c4.z + d4.z)) * invS;
    ts[64 + c][nq + 3] = ((av.w + b4.w) + (c4.w + d4.w)) * invS;
  }
  __syncthreads();
  const int n = tid >> 2, c0 = (tid & 3) << 5;
  unsigned short* dst = a.Y0[z] + ((size_t)(b * 1024 + n0 + n) << 7) + c0;
#pragma unroll
  for (int q8 = 0; q8 < 4; ++q8) {
    const int cb = c0 + (q8 << 3);
    unsigned w0 = (unsigned)f2bf(ts[cb + 0][n]) | ((unsigned)f2bf(ts[cb + 1][n]) << 16);
    unsigned w1 = (unsigned)f2bf(ts[cb + 2][n]) | ((unsigned)f2bf(ts[cb + 3][n]) << 16);
    unsigned w2 = (unsigned)f2bf(ts[cb + 4][n]) | ((unsigned)f2bf(ts[cb + 5][n]) << 16);
    unsigned w3 = (unsigned)f2bf(ts[cb + 6][n]) | ((unsigned)f2bf(ts[cb + 7][n]) << 16);
    *reinterpret_cast<uint4*>(dst + (q8 << 3)) = make_uint4(w0, w1, w2, w3);
  }
}

// ---- MFMA conv v6: z-indexed multi-instance, NT n-tiles/wave ---------------
struct ConvArgs {
  const unsigned short* X[4];
  const unsigned short* W[4];
  unsigned short* Y[4];
  const float* pre[4];
  float* sums[4];
};
template<int CIN, int NT, bool PREBN>
__global__ __launch_bounds__(256)
void conv_mfma_kernel(ConvArgs a, int COUT) {
  constexpr int KS = CIN / 32;
  __shared__ float scs[PREBN ? CIN : 1];
  __shared__ float shs[PREBN ? CIN : 1];
  const int tid = threadIdx.x;
  const int lane = tid & 63, w = tid >> 6;
  const int g = lane >> 4, m = lane & 15;
  const int z = blockIdx.z;
  const int o0 = (blockIdx.x << 6) + (w << 4);
  const int nbase = blockIdx.y * (NT << 4);
  if (PREBN) {
    const float* pre = a.pre[z];
    for (int c = tid; c < CIN; c += 256) {
      scs[c] = pre[c];
      shs[c] = pre[256 + c];
    }
    __syncthreads();
  }
  const unsigned short* Wr = a.W[z] + (size_t)(o0 + m) * CIN + (g << 3);
  bf16x8 af[KS];
#pragma unroll
  for (int k = 0; k < KS; ++k) af[k] = *reinterpret_cast<const bf16x8*>(Wr + (k << 5));
  const unsigned short* Xin = a.X[z];
  unsigned short* Yout = a.Y[z];
  float sr[4] = {0.f, 0.f, 0.f, 0.f}, qr[4] = {0.f, 0.f, 0.f, 0.f};
#pragma unroll
  for (int nt = 0; nt < NT; ++nt) {
    const int row = nbase + (nt << 4) + m;
    const unsigned short* Xr = Xin + (size_t)row * CIN + (g << 3);
    bf16x8 bv[KS];
#pragma unroll
    for (int k = 0; k < KS; ++k) bv[k] = *reinterpret_cast<const bf16x8*>(Xr + (k << 5));
    if (PREBN) {
#pragma unroll
      for (int k = 0; k < KS; ++k) {
        const int kb = (k << 5) + (g << 3);
#pragma unroll
        for (int j = 0; j < 8; ++j) {
          float x = __uint_as_float((unsigned)(unsigned short)bv[k][j] << 16);
          x = fmaxf(fmaf(x, scs[kb + j], shs[kb + j]), 0.f);
          bv[k][j] = (short)f2bf(x);
        }
      }
    }
    f32x4 acc = (f32x4){0.f, 0.f, 0.f, 0.f};
#pragma unroll
    for (int k = 0; k < KS; ++k)
      acc = __builtin_amdgcn_mfma_f32_16x16x32_bf16(af[k], bv[k], acc, 0, 0, 0);
    ushort4 v;
    v.x = f2bf(acc[0]); v.y = f2bf(acc[1]);
    v.z = f2bf(acc[2]); v.w = f2bf(acc[3]);
    *reinterpret_cast<ushort4*>(Yout + (size_t)row * COUT + o0 + (g << 2)) = v;
#pragma unroll
    for (int r = 0; r < 4; ++r) {
      sr[r] += acc[r];
      qr[r] = fmaf(acc[r], acc[r], qr[r]);
    }
  }
#pragma unroll
  for (int r = 0; r < 4; ++r) {
    for (int off = 1; off < 16; off <<= 1) {
      sr[r] += __shfl_xor(sr[r], off);
      qr[r] += __shfl_xor(qr[r], off);
    }
  }
  if (m == 0) {
    float* dst = a.sums[z] + (blockIdx.y & (NCOPY - 1)) * 512;
#pragma unroll
    for (int r = 0; r < 4; ++r) {
      atomicAdd(&dst[o0 + (g << 2) + r], sr[r]);
      atomicAdd(&dst[256 + o0 + (g << 2) + r], qr[r]);
    }
  }
}

// ---- finish: MODE 1: relu(bn0(T)+S); 2: relu(bn0(T)+bn1(S)); z-indexed -----
struct FinArgs { const unsigned short* T[2]; const float* P0[2];
                 const unsigned short* S[2]; const float* P1[2];
                 unsigned short* O[2]; };
template<int C, int MODE>
__global__ __launch_bounds__(256)
void finish_kernel(FinArgs a) {
  __shared__ float sc0[C], sh0[C];
  __shared__ float sc1[(MODE == 2) ? C : 1], sh1[(MODE == 2) ? C : 1];
  const int tid = threadIdx.x;
  const int z = blockIdx.y;
  for (int c = tid; c < C; c += 256) {
    sc0[c] = a.P0[z][c]; sh0[c] = a.P0[z][256 + c];
    if (MODE == 2) { sc1[c] = a.P1[z][c]; sh1[c] = a.P1[z][256 + c]; }
  }
  __syncthreads();
  const size_t i8 = ((size_t)blockIdx.x * 256 + tid) << 3;
  const int c0 = (int)(i8 & (size_t)(C - 1));
  uint4 tv = *reinterpret_cast<const uint4*>(a.T[z] + i8);
  uint4 sv = *reinterpret_cast<const uint4*>(a.S[z] + i8);
  unsigned tw[4] = {tv.x, tv.y, tv.z, tv.w};
  unsigned sw[4] = {sv.x, sv.y, sv.z, sv.w};
  unsigned ow[4];
#pragma unroll
  for (int jw = 0; jw < 4; ++jw) {
    unsigned r = 0;
#pragma unroll
    for (int h = 0; h < 2; ++h) {
      int c = c0 + jw * 2 + h;
      float x = __uint_as_float(((tw[jw] >> (h * 16)) & 0xffffu) << 16);
      x = fmaf(x, sc0[c], sh0[c]);
      if (MODE == 1) x += __uint_as_float(((sw[jw] >> (h * 16)) & 0xffffu) << 16);
      if (MODE == 2) {
        float y = __uint_as_float(((sw[jw] >> (h * 16)) & 0xffffu) << 16);
        x += fmaf(y, sc1[c], sh1[c]);
      }
      x = fmaxf(x, 0.f);
      r |= ((unsigned)f2bf(x)) << (h * 16);
    }
    ow[jw] = r;
  }
  *reinterpret_cast<uint4*>(a.O[z] + i8) = make_uint4(ow[0], ow[1], ow[2], ow[3]);
}

// ---- writeout: out[b][c][n] f32 = bn(F[b][n][c]) via LDS transpose ---------
struct WoArgs { const unsigned short* F[2]; const float* pre[2]; float* out[2]; };
__global__ __launch_bounds__(256)
void writeout_t_kernel(WoArgs a) {
  __shared__ float ts[64][66];
  __shared__ float sc[64], sh[64];
  const int tid = threadIdx.x;
  const int z = blockIdx.z;
  if (tid < 64) {
    sc[tid] = a.pre[z][tid];
    sh[tid] = a.pre[z][256 + tid];
  }
  __syncthreads();
  const int n0 = blockIdx.x << 6;
  const int b = blockIdx.y;
  {
    const int n = tid >> 2, c0 = (tid & 3) << 4;
    const unsigned short* Fr = a.F[z] + ((size_t)(b * 1024 + n0 + n) << 6) + c0;
    uint4 v0 = *reinterpret_cast<const uint4*>(Fr);
    uint4 v1 = *reinterpret_cast<const uint4*>(Fr + 8);
    unsigned vw[8] = {v0.x, v0.y, v0.z, v0.w, v1.x, v1.y, v1.z, v1.w};
#pragma unroll
    for (int jw = 0; jw < 8; ++jw) {
      int c = c0 + jw * 2;
      float x0 = __uint_as_float((vw[jw] & 0xffffu) << 16);
      float x1 = __uint_as_float((vw[jw] >> 16) << 16);
      ts[c][n] = fmaf(x0, sc[c], sh[c]);
      ts[c + 1][n] = fmaf(x1, sc[c + 1], sh[c + 1]);
    }
  }
  __syncthreads();
  const int c = tid >> 2, nq = (tid & 3) << 4;
  float* orow = a.out[z] + ((size_t)(b * 64 + c) << 10) + n0 + nq;
#pragma unroll
  for (int q = 0; q < 4; ++q) {
    float4 ov;
    ov.x = ts[c][nq + q * 4 + 0]; ov.y = ts[c][nq + q * 4 + 1];
    ov.z = ts[c][nq + q * 4 + 2]; ov.w = ts[c][nq + q * 4 + 3];
    *reinterpret_cast<float4*>(orow + q * 4) = ov;
  }
}

// ============================ host side =====================================
extern "C" void kernel_launch(void* const* d_in, const int* in_sizes, int n_in,
                              void* d_out, int out_size, void* d_ws, size_t ws_size,
                              hipStream_t stream) {
  float* wsf = (float*)d_ws;
  const size_t M1 = (size_t)1 << 20;
  const size_t H1 = (size_t)1 << 19;
  const int SSTR = NCOPY * 512;

  // ws layout (floats): attention [0,8M); both-stream block phase [8,23M)
  unsigned short* QAt = (unsigned short*)wsf;                 // [0, 0.5M)
  unsigned short* QBt = (unsigned short*)(wsf + H1);          // [0.5M, 1M)
  unsigned short* KAc = (unsigned short*)(wsf + 2 * H1);      // [1M, 1.5M)
  unsigned short* KBc = (unsigned short*)(wsf + 3 * H1);      // [1.5M, 2M)
  float* PART1 = wsf + 2 * M1;                                // [2M, 6M)
  float* PART2 = wsf + 14 * M1;                               // [14M,18M) dead in phase B? no — see T4
  unsigned short* Y0A = (unsigned short*)(wsf + 6 * M1);      // [6M, 7M)
  unsigned short* Y0B = (unsigned short*)(wsf + 7 * M1);      // [7M, 8M)
  unsigned short* T1a = (unsigned short*)(wsf + 8 * M1);
  unsigned short* T1b = (unsigned short*)(wsf + 9 * M1);
  unsigned short* T2a = (unsigned short*)(wsf + 10 * M1);
  unsigned short* T2b = (unsigned short*)(wsf + 11 * M1);
  unsigned short* O1a = (unsigned short*)(wsf + 12 * M1);
  unsigned short* O1b = (unsigned short*)(wsf + 13 * M1);
  unsigned short* T3a = (unsigned short*)(wsf + 2 * M1);      // over PART1 (dead)
  unsigned short* T3b = (unsigned short*)(wsf + 4 * M1);
  unsigned short* T4a = (unsigned short*)(wsf + 14 * M1);     // over PART2 (dead)
  unsigned short* T4b = (unsigned short*)(wsf + 16 * M1);
  unsigned short* T5a = (unsigned short*)(wsf + 18 * M1);
  unsigned short* T5b = (unsigned short*)(wsf + 20 * M1);
  unsigned short* Fba = (unsigned short*)(wsf + 22 * M1);
  unsigned short* Fbb = (unsigned short*)(wsf + 22 * M1 + H1);
  float* tail = wsf + 23 * M1;
  float* bsum = tail;
  float* stats = tail + 16;                                   // 12 * SSTR
  float* prep  = stats + 12 * SSTR;                           // 12 * 512
  unsigned short* wbf = (unsigned short*)(prep + 12 * 512);

  const float* pp[46];
  for (int i = 0; i < 46 && i < n_in; ++i) pp[i] = (const float*)d_in[i];

  const int initN = 16 + 12 * SSTR;
  init_kernel<<<(initN + 255) / 256, 256, 0, stream>>>(tail, initN);

  const int widx[12] = {10, 13, 16, 19, 22, 25, 28, 31, 34, 37, 40, 43};
  WcvtArgs wa;
  int woff[12];
  {
    int run = 0;
    for (int i = 0; i < 12; ++i) {
      wa.p[i] = pp[widx[i]];
      wa.sz[i] = in_sizes[widx[i]];
      wa.off[i] = run; woff[i] = run;
      run += in_sizes[widx[i]];
    }
  }
  wcvt_kernel<<<dim3(12, 16), 256, 0, stream>>>(wa, wbf);

  float* ST[12];
  float* PR[12];
  for (int i = 0; i < 12; ++i) { ST[i] = stats + i * SSTR; PR[i] = prep + i * 512; }

  // ---- all 4 q/k convs in one launch ----
  QKArgs qk;
  qk.X[0] = pp[0]; qk.W[0] = pp[2]; qk.B[0] = pp[3]; qk.Y[0] = QAt; qk.tr[0] = 0;
  qk.X[1] = pp[1]; qk.W[1] = pp[4]; qk.B[1] = pp[5]; qk.Y[1] = QBt; qk.tr[1] = 0;
  qk.X[2] = pp[0]; qk.W[2] = pp[6]; qk.B[2] = pp[7]; qk.Y[2] = KAc; qk.tr[2] = 1;
  qk.X[3] = pp[1]; qk.W[3] = pp[8]; qk.B[3] = pp[9]; qk.Y[3] = KBc; qk.tr[3] = 1;
  conv_qk_all_kernel<<<dim3(16, 2, 64), 256, 0, stream>>>(qk);

  // ---- attention: pv->PART1, tpv->PART2 (concurrent), merged merge ----
  pv_mfma_kernel<<<dim3(16, 4, BATCH), 256, 0, stream>>>(QAt, QBt, KBc, PART1, bsum);
  tpv_mfma_kernel<<<dim3(16, 4, BATCH), 256, 0, stream>>>(QAt, QBt, KAc, PART2);
  MergeArgs ma;
  ma.PART[0] = PART1; ma.XR[0] = pp[0]; ma.Y0[0] = Y0A;
  ma.PART[1] = PART2; ma.XR[1] = pp[1]; ma.Y0[1] = Y0B;
  merge_kernel<<<dim3(16, BATCH, 2), 256, 0, stream>>>(ma, bsum);

  // ---- block phase, both streams fused per launch ----
  const unsigned short* w11[2] = {wbf + woff[0], wbf + woff[2]};
  const unsigned short* w12[2] = {wbf + woff[1], wbf + woff[3]};
  const unsigned short* w21[2] = {wbf + woff[4], wbf + woff[7]};
  const unsigned short* w22[2] = {wbf + woff[5], wbf + woff[8]};
  const unsigned short* w2s[2] = {wbf + woff[6], wbf + woff[9]};
  const unsigned short* wo[2]  = {wbf + woff[10], wbf + woff[11]};
  const unsigned short* Y0[2] = {Y0A, Y0B};
  unsigned short* T1z[2] = {T1a, T1b};
  unsigned short* T2z[2] = {T2a, T2b};
  unsigned short* O1z[2] = {O1a, O1b};
  unsigned short* T3z[2] = {T3a, T3b};
  unsigned short* T4z[2] = {T4a, T4b};
  unsigned short* T5z[2] = {T5a, T5b};
  unsigned short* Fbz[2] = {Fba, Fbb};
  const int g1[2] = {10, 16}, g2[2] = {22, 31}, go[2] = {40, 43};

  ConvArgs ca;
  BnArgs ba;
  FinArgs fa;

  // conv1 both: Y0 -> T1 (stats s1)
  for (int z = 0; z < 2; ++z) {
    ca.X[z] = Y0[z]; ca.W[z] = w11[z]; ca.Y[z] = T1z[z];
    ca.pre[z] = nullptr; ca.sums[z] = ST[z * 6 + 0];
  }
  conv_mfma_kernel<128, 2, false><<<dim3(2, 512, 2), 256, 0, stream>>>(ca, 128);
  for (int z = 0; z < 2; ++z) {
    ba.sums[z] = ST[z * 6 + 0]; ba.gam[z] = pp[g1[z] + 1];
    ba.bet[z] = pp[g1[z] + 2]; ba.dst[z] = PR[z * 6 + 0];
  }
  bnprep_kernel<<<2, 256, 0, stream>>>(ba, 128);

  // conv2 both (PREBN p1): T1 -> T2 (stats s2)
  for (int z = 0; z < 2; ++z) {
    ca.X[z] = T1z[z]; ca.W[z] = w12[z]; ca.Y[z] = T2z[z];
    ca.pre[z] = PR[z * 6 + 0]; ca.sums[z] = ST[z * 6 + 1];
  }
  conv_mfma_kernel<128, 2, true><<<dim3(2, 512, 2), 256, 0, stream>>>(ca, 128);
  for (int z = 0; z < 2; ++z) {
    ba.sums[z] = ST[z * 6 + 1]; ba.gam[z] = pp[g1[z] + 4];
    ba.bet[z] = pp[g1[z] + 5]; ba.dst[z] = PR[z * 6 + 1];
  }
  bnprep_kernel<<<2, 256, 0, stream>>>(ba, 128);

  // finish1 both: O1 = relu(bn(T2) + Y0)
  for (int z = 0; z < 2; ++z) {
    fa.T[z] = T2z[z]; fa.P0[z] = PR[z * 6 + 1];
    fa.S[z] = Y0[z]; fa.P1[z] = nullptr; fa.O[z] = O1z[z];
  }
  finish_kernel<128, 1><<<dim3(1024, 2), 256, 0, stream>>>(fa);

  // conv3 quad: O1 -> T3 (w21, s3) and O1 -> T5 (w2s, s5), both streams
  {
    ConvArgs cq;
    cq.X[0] = O1a; cq.W[0] = w21[0]; cq.Y[0] = T3a; cq.pre[0] = nullptr; cq.sums[0] = ST[2];
    cq.X[1] = O1a; cq.W[1] = w2s[0]; cq.Y[1] = T5a; cq.pre[1] = nullptr; cq.sums[1] = ST[4];
    cq.X[2] = O1b; cq.W[2] = w21[1]; cq.Y[2] = T3b; cq.pre[2] = nullptr; cq.sums[2] = ST[8];
    cq.X[3] = O1b; cq.W[3] = w2s[1]; cq.Y[3] = T5b; cq.pre[3] = nullptr; cq.sums[3] = ST[10];
    conv_mfma_kernel<128, 2, false><<<dim3(4, 512, 4), 256, 0, stream>>>(cq, 256);
  }
  {
    BnArgs bq;
    bq.sums[0] = ST[2];  bq.gam[0] = pp[g2[0] + 1]; bq.bet[0] = pp[g2[0] + 2]; bq.dst[0] = PR[2];
    bq.sums[1] = ST[4];  bq.gam[1] = pp[g2[0] + 7]; bq.bet[1] = pp[g2[0] + 8]; bq.dst[1] = PR[4];
    bq.sums[2] = ST[8];  bq.gam[2] = pp[g2[1] + 1]; bq.bet[2] = pp[g2[1] + 2]; bq.dst[2] = PR[8];
    bq.sums[3] = ST[10]; bq.gam[3] = pp[g2[1] + 7]; bq.bet[3] = pp[g2[1] + 8]; bq.dst[3] = PR[10];
    bnprep_kernel<<<4, 256, 0, stream>>>(bq, 256);
  }

  // conv4 both (PREBN p3): T3 -> T4 (stats s4)
  for (int z = 0; z < 2; ++z) {
    ca.X[z] = T3z[z]; ca.W[z] = w22[z]; ca.Y[z] = T4z[z];
    ca.pre[z] = PR[z * 6 + 2]; ca.sums[z] = ST[z * 6 + 3];
  }
  conv_mfma_kernel<256, 4, true><<<dim3(4, 256, 2), 256, 0, stream>>>(ca, 256);
  for (int z = 0; z < 2; ++z) {
    ba.sums[z] = ST[z * 6 + 3]; ba.gam[z] = pp[g2[z] + 4];
    ba.bet[z] = pp[g2[z] + 5]; ba.dst[z] = PR[z * 6 + 3];
  }
  bnprep_kernel<<<2, 256, 0, stream>>>(ba, 256);

  // finish2 both: T3 = relu(bn(T4) + bn(T5))
  for (int z = 0; z < 2; ++z) {
    fa.T[z] = T4z[z]; fa.P0[z] = PR[z * 6 + 3];
    fa.S[z] = T5z[z]; fa.P1[z] = PR[z * 6 + 4]; fa.O[z] = T3z[z];
  }
  finish_kernel<256, 2><<<dim3(2048, 2), 256, 0, stream>>>(fa);

  // conv6 both: T3 -> Fb (stats s6)
  for (int z = 0; z < 2; ++z) {
    ca.X[z] = T3z[z]; ca.W[z] = wo[z]; ca.Y[z] = Fbz[z];
    ca.pre[z] = nullptr; ca.sums[z] = ST[z * 6 + 5];
  }
  conv_mfma_kernel<256, 2, false><<<dim3(1, 512, 2), 256, 0, stream>>>(ca, 64);
  for (int z = 0; z < 2; ++z) {
    ba.sums[z] = ST[z * 6 + 5]; ba.gam[z] = pp[go[z] + 1];
    ba.bet[z] = pp[go[z] + 2]; ba.dst[z] = PR[z * 6 + 5];
  }
  bnprep_kernel<<<2, 256, 0, stream>>>(ba, 64);

  // writeout both
  WoArgs wo2;
  for (int z = 0; z < 2; ++z) {
    wo2.F[z] = Fbz[z]; wo2.pre[z] = PR[z * 6 + 5];
    wo2.out[z] = (float*)d_out + z * M1;
  }
  writeout_t_kernel<<<dim3(16, BATCH, 2), 256, 0, stream>>>(wo2);
}

// Round 13
// 318.059 us; speedup vs baseline: 2.7698x; 1.0051x over previous
//
#include <hip/hip_runtime.h>
#include <hip/hip_bf16.h>
#include <cstddef>

static constexpr int BATCH = 16;   // B
static constexpr int NCOPY = 16;   // stat atomic spread copies

typedef __attribute__((ext_vector_type(8))) short bf16x8;
typedef __attribute__((ext_vector_type(4))) float f32x4;

__device__ __forceinline__ unsigned short f2bf(float f) {
  unsigned u = __float_as_uint(f);
  return (unsigned short)((u + 0x7fffu + ((u >> 16) & 1u)) >> 16);  // RNE
}

// uniform 4-way select with compile-time indices (keeps pointers in SGPRs)
#define SEL4(dst, arr, idx)                                   \
  do {                                                        \
    if ((idx) == 0) dst = arr[0];                             \
    else if ((idx) == 1) dst = arr[1];                        \
    else if ((idx) == 2) dst = arr[2];                        \
    else dst = arr[3];                                        \
  } while (0)

__global__ void init_kernel(float* __restrict__ t, int n) {
  int i = blockIdx.x * 256 + threadIdx.x;
  if (i < n) t[i] = 0.f;
}

// ---- convert the 12 block-phase weight matrices to bf16 (layout [o][cin]) --
struct WcvtArgs { const float* p[12]; int sz[12]; int off[12]; };
__global__ __launch_bounds__(256)
void wcvt_kernel(WcvtArgs a, unsigned short* __restrict__ dst) {
  const int t = blockIdx.x;
  const float* src = a.p[t];
  unsigned short* d = dst + a.off[t];
  const int sz = a.sz[t];
  for (int i = blockIdx.y * 256 + threadIdx.x; i < sz; i += 16 * 256)
    d[i] = f2bf(src[i]);
}

// ---- bnprep: fold 16-copy sums + gamma/beta into scale/shift tables --------
struct BnArgs { const float* sums[4]; const float* gam[4]; const float* bet[4];
                float* dst[4]; };
__global__ void bnprep_kernel(BnArgs a, int C) {
  const int t = blockIdx.x;
  const float* sums; const float* gam; const float* bet; float* dst;
  SEL4(sums, a.sums, t); SEL4(gam, a.gam, t); SEL4(bet, a.bet, t); SEL4(dst, a.dst, t);
  const int c = threadIdx.x;
  if (c < C) {
    float s0 = 0.f, q0 = 0.f;
#pragma unroll
    for (int p = 0; p < NCOPY; ++p) {
      s0 += sums[p * 512 + c];
      q0 += sums[p * 512 + 256 + c];
    }
    const float invN = 1.f / 16384.f;
    float mm = s0 * invN;
    float vv = q0 * invN - mm * mm;
    float s = gam[c] * rsqrtf(vv + 1e-5f);
    dst[c] = s;
    dst[256 + c] = bet[c] - mm * s;
  }
}

// ---------------- q/k convs (all 4 in one launch) ---------------------------
struct QKArgs { const float* X[4]; const float* W[4]; const float* B[4];
                unsigned short* Y[4]; };
__global__ __launch_bounds__(256)
void conv_qk_all_kernel(QKArgs a) {
  __shared__ float wsT[64][4];
  const int tid = threadIdx.x;
  const int z = blockIdx.z;
  const int which = z >> 4;
  const int b = z & 15;
  const int o0 = blockIdx.x << 2;
  const int px = (blockIdx.y << 9) + (tid << 1);
  const float* W; const float* X; const float* bias; unsigned short* Y;
  SEL4(W, a.W, which); SEL4(X, a.X, which); SEL4(bias, a.B, which); SEL4(Y, a.Y, which);
  {
    int c = tid >> 2, k = tid & 3;
    wsT[c][k] = W[((o0 + k) << 6) + c];
  }
  __syncthreads();
  float acc[4][2] = {};
  const float* xb = X + ((size_t)b << 16) + px;
#pragma unroll 4
  for (int c = 0; c < 64; ++c) {
    float2 xv = *reinterpret_cast<const float2*>(xb + (c << 10));
    float4 w = *reinterpret_cast<const float4*>(wsT[c]);
    acc[0][0] = fmaf(w.x, xv.x, acc[0][0]); acc[0][1] = fmaf(w.x, xv.y, acc[0][1]);
    acc[1][0] = fmaf(w.y, xv.x, acc[1][0]); acc[1][1] = fmaf(w.y, xv.y, acc[1][1]);
    acc[2][0] = fmaf(w.z, xv.x, acc[2][0]); acc[2][1] = fmaf(w.z, xv.y, acc[2][1]);
    acc[3][0] = fmaf(w.w, xv.x, acc[3][0]); acc[3][1] = fmaf(w.w, xv.y, acc[3][1]);
  }
  float b0 = bias[o0], b1 = bias[o0 + 1], b2 = bias[o0 + 2], b3 = bias[o0 + 3];
  if (which < 2) {  // Q layout [b][n][c]
    ushort4 v0, v1;
    v0.x = f2bf(acc[0][0] + b0); v0.y = f2bf(acc[1][0] + b1);
    v0.z = f2bf(acc[2][0] + b2); v0.w = f2bf(acc[3][0] + b3);
    v1.x = f2bf(acc[0][1] + b0); v1.y = f2bf(acc[1][1] + b1);
    v1.z = f2bf(acc[2][1] + b2); v1.w = f2bf(acc[3][1] + b3);
    unsigned short* yt = Y + ((size_t)b << 16) + ((size_t)px << 6) + o0;
    *reinterpret_cast<ushort4*>(yt) = v0;
    *reinterpret_cast<ushort4*>(yt + 64) = v1;
  } else {          // K layout [b][c][n]
    float bv[4] = {b0, b1, b2, b3};
#pragma unroll
    for (int k = 0; k < 4; ++k) {
      ushort2 v;
      v.x = f2bf(acc[k][0] + bv[k]); v.y = f2bf(acc[k][1] + bv[k]);
      *reinterpret_cast<ushort2*>(Y + ((size_t)b << 16) + ((size_t)(o0 + k) << 10) + px) = v;
    }
  }
}

// ---- MFMA fused PV ---------------------------------------------------------
__global__ __launch_bounds__(256)
void pv_mfma_kernel(const unsigned short* __restrict__ QAt,
                    const unsigned short* __restrict__ QBt,
                    const unsigned short* __restrict__ KBc,
                    float* __restrict__ PART, float* __restrict__ bsum) {
  __shared__ __align__(16) unsigned short Ai[4096];
  __shared__ __align__(16) unsigned short Bj[4096];
  __shared__ __align__(16) unsigned short Pl[4096];
  __shared__ float red[256];
  const int tid = threadIdx.x;
  const int lane = tid & 63, w = tid >> 6;
  const int g = lane >> 4, m = lane & 15;
  const int i0 = blockIdx.x << 6;
  const int jbase = blockIdx.y << 8;
  const int b = blockIdx.z;
  const size_t nb = (size_t)b << 16;

  {
    const unsigned short* src = QAt + nb + ((size_t)i0 << 6);
#pragma unroll
    for (int s = 0; s < 2; ++s) {
      int idx = tid + (s << 8);
      int n = idx >> 3, cc = idx & 7;
      bf16x8 v = *reinterpret_cast<const bf16x8*>(src + (n << 6) + ((cc ^ (n & 7)) << 3));
      *reinterpret_cast<bf16x8*>(Ai + (idx << 3)) = v;
    }
  }
  f32x4 accO[4];
#pragma unroll
  for (int n = 0; n < 4; ++n) accO[n] = (f32x4){0.f, 0.f, 0.f, 0.f};
  float psum = 0.f;

  for (int jt = 0; jt < 4; ++jt) {
    const int j0 = jbase + (jt << 6);
    __syncthreads();
    {
      const unsigned short* src = QBt + nb + ((size_t)j0 << 6);
#pragma unroll
      for (int s = 0; s < 2; ++s) {
        int idx = tid + (s << 8);
        int n = idx >> 3, cc = idx & 7;
        bf16x8 v = *reinterpret_cast<const bf16x8*>(src + (n << 6) + ((cc ^ (n & 7)) << 3));
        *reinterpret_cast<bf16x8*>(Bj + (idx << 3)) = v;
      }
    }
    __syncthreads();
    const int jrow = (w << 4) | m;
    bf16x8 a0 = *reinterpret_cast<const bf16x8*>(Bj + (jrow << 6) + ((g ^ (jrow & 7)) << 3));
    bf16x8 a1 = *reinterpret_cast<const bf16x8*>(Bj + (jrow << 6) + (((g + 4) ^ (jrow & 7)) << 3));
    f32x4 e[4];
#pragma unroll
    for (int n = 0; n < 4; ++n) {
      const int irow = (n << 4) | m;
      bf16x8 b0v = *reinterpret_cast<const bf16x8*>(Ai + (irow << 6) + ((g ^ (irow & 7)) << 3));
      bf16x8 b1v = *reinterpret_cast<const bf16x8*>(Ai + (irow << 6) + (((g + 4) ^ (irow & 7)) << 3));
      e[n] = (f32x4){0.f, 0.f, 0.f, 0.f};
      e[n] = __builtin_amdgcn_mfma_f32_16x16x32_bf16(a0, b0v, e[n], 0, 0, 0);
      e[n] = __builtin_amdgcn_mfma_f32_16x16x32_bf16(a1, b1v, e[n], 0, 0, 0);
    }
    const int j = (w << 4) | (g << 2);
#pragma unroll
    for (int n = 0; n < 4; ++n) {
      const int irow = (n << 4) | m;
      float p0 = __expf(-e[n][0]), p1 = __expf(-e[n][1]);
      float p2 = __expf(-e[n][2]), p3 = __expf(-e[n][3]);
      psum += (p0 + p1) + (p2 + p3);
      unsigned pk01 = (unsigned)f2bf(p0) | ((unsigned)f2bf(p1) << 16);
      unsigned pk23 = (unsigned)f2bf(p2) | ((unsigned)f2bf(p3) << 16);
      int base = irow << 6;
      int off0 = base + ((((j) >> 3) ^ (irow & 7)) << 3) + (j & 7);
      int off2 = base + ((((j + 2) >> 3) ^ (irow & 7)) << 3) + ((j + 2) & 7);
      *reinterpret_cast<unsigned*>(Pl + off0) = pk01;
      *reinterpret_cast<unsigned*>(Pl + off2) = pk23;
    }
    const int crow = (w << 4) | m;
    const unsigned short* kbp = KBc + nb + ((size_t)crow << 10) + j0 + (g << 3);
    bf16x8 ka0 = *reinterpret_cast<const bf16x8*>(kbp);
    bf16x8 ka1 = *reinterpret_cast<const bf16x8*>(kbp + 32);
    __syncthreads();
#pragma unroll
    for (int n = 0; n < 4; ++n) {
      const int irow = (n << 4) | m;
      bf16x8 p0 = *reinterpret_cast<const bf16x8*>(Pl + (irow << 6) + ((g ^ (irow & 7)) << 3));
      bf16x8 p1 = *reinterpret_cast<const bf16x8*>(Pl + (irow << 6) + (((g + 4) ^ (irow & 7)) << 3));
      accO[n] = __builtin_amdgcn_mfma_f32_16x16x32_bf16(ka0, p0, accO[n], 0, 0, 0);
      accO[n] = __builtin_amdgcn_mfma_f32_16x16x32_bf16(ka1, p1, accO[n], 0, 0, 0);
    }
  }
  float* OUT = PART + ((size_t)blockIdx.y << 20) + ((size_t)(b * 64) << 10);
#pragma unroll
  for (int n = 0; n < 4; ++n) {
    const int ig = i0 + (n << 4) + m;
    const int c = (w << 4) + (g << 2);
#pragma unroll
    for (int r = 0; r < 4; ++r)
      OUT[((size_t)(c + r) << 10) + ig] = accO[n][r];
  }
  red[tid] = psum; __syncthreads();
  for (int s = 128; s > 0; s >>= 1) {
    if (tid < s) red[tid] += red[tid + s];
    __syncthreads();
  }
  if (tid == 0) atomicAdd(bsum + b, red[0]);
}

// ---- MFMA fused PtV --------------------------------------------------------
__global__ __launch_bounds__(256)
void tpv_mfma_kernel(const unsigned short* __restrict__ QAt,
                     const unsigned short* __restrict__ QBt,
                     const unsigned short* __restrict__ KAc,
                     float* __restrict__ PART) {
  __shared__ __align__(16) unsigned short Bj[4096];
  __shared__ __align__(16) unsigned short Ai[4096];
  __shared__ __align__(16) unsigned short Pl[4096];
  const int tid = threadIdx.x;
  const int lane = tid & 63, w = tid >> 6;
  const int g = lane >> 4, m = lane & 15;
  const int j0 = blockIdx.x << 6;
  const int ibase = blockIdx.y << 8;
  const int b = blockIdx.z;
  const size_t nb = (size_t)b << 16;

  {
    const unsigned short* src = QBt + nb + ((size_t)j0 << 6);
#pragma unroll
    for (int s = 0; s < 2; ++s) {
      int idx = tid + (s << 8);
      int n = idx >> 3, cc = idx & 7;
      bf16x8 v = *reinterpret_cast<const bf16x8*>(src + (n << 6) + ((cc ^ (n & 7)) << 3));
      *reinterpret_cast<bf16x8*>(Bj + (idx << 3)) = v;
    }
  }
  f32x4 accO[4];
#pragma unroll
  for (int n = 0; n < 4; ++n) accO[n] = (f32x4){0.f, 0.f, 0.f, 0.f};

  for (int it = 0; it < 4; ++it) {
    const int i0 = ibase + (it << 6);
    __syncthreads();
    {
      const unsigned short* src = QAt + nb + ((size_t)i0 << 6);
#pragma unroll
      for (int s = 0; s < 2; ++s) {
        int idx = tid + (s << 8);
        int n = idx >> 3, cc = idx & 7;
        bf16x8 v = *reinterpret_cast<const bf16x8*>(src + (n << 6) + ((cc ^ (n & 7)) << 3));
        *reinterpret_cast<bf16x8*>(Ai + (idx << 3)) = v;
      }
    }
    __syncthreads();
    const int irow_a = (w << 4) | m;
    bf16x8 a0 = *reinterpret_cast<const bf16x8*>(Ai + (irow_a << 6) + ((g ^ (irow_a & 7)) << 3));
    bf16x8 a1 = *reinterpret_cast<const bf16x8*>(Ai + (irow_a << 6) + (((g + 4) ^ (irow_a & 7)) << 3));
    f32x4 e[4];
#pragma unroll
    for (int n = 0; n < 4; ++n) {
      const int jrow = (n << 4) | m;
      bf16x8 b0v = *reinterpret_cast<const bf16x8*>(Bj + (jrow << 6) + ((g ^ (jrow & 7)) << 3));
      bf16x8 b1v = *reinterpret_cast<const bf16x8*>(Bj + (jrow << 6) + (((g + 4) ^ (jrow & 7)) << 3));
      e[n] = (f32x4){0.f, 0.f, 0.f, 0.f};
      e[n] = __builtin_amdgcn_mfma_f32_16x16x32_bf16(a0, b0v, e[n], 0, 0, 0);
      e[n] = __builtin_amdgcn_mfma_f32_16x16x32_bf16(a1, b1v, e[n], 0, 0, 0);
    }
    const int i = (w << 4) | (g << 2);
#pragma unroll
    for (int n = 0; n < 4; ++n) {
      const int jrow = (n << 4) | m;
      float p0 = __expf(-e[n][0]), p1 = __expf(-e[n][1]);
      float p2 = __expf(-e[n][2]), p3 = __expf(-e[n][3]);
      unsigned pk01 = (unsigned)f2bf(p0) | ((unsigned)f2bf(p1) << 16);
      unsigned pk23 = (unsigned)f2bf(p2) | ((unsigned)f2bf(p3) << 16);
      int base = jrow << 6;
      int off0 = base + ((((i) >> 3) ^ (jrow & 7)) << 3) + (i & 7);
      int off2 = base + ((((i + 2) >> 3) ^ (jrow & 7)) << 3) + ((i + 2) & 7);
      *reinterpret_cast<unsigned*>(Pl + off0) = pk01;
      *reinterpret_cast<unsigned*>(Pl + off2) = pk23;
    }
    const int crow = (w << 4) | m;
    const unsigned short* kap = KAc + nb + ((size_t)crow << 10) + i0 + (g << 3);
    bf16x8 ka0 = *reinterpret_cast<const bf16x8*>(kap);
    bf16x8 ka1 = *reinterpret_cast<const bf16x8*>(kap + 32);
    __syncthreads();
#pragma unroll
    for (int n = 0; n < 4; ++n) {
      const int jrow = (n << 4) | m;
      bf16x8 p0 = *reinterpret_cast<const bf16x8*>(Pl + (jrow << 6) + ((g ^ (jrow & 7)) << 3));
      bf16x8 p1 = *reinterpret_cast<const bf16x8*>(Pl + (jrow << 6) + (((g + 4) ^ (jrow & 7)) << 3));
      accO[n] = __builtin_amdgcn_mfma_f32_16x16x32_bf16(ka0, p0, accO[n], 0, 0, 0);
      accO[n] = __builtin_amdgcn_mfma_f32_16x16x32_bf16(ka1, p1, accO[n], 0, 0, 0);
    }
  }
  float* OUT = PART + ((size_t)blockIdx.y << 20) + ((size_t)(b * 64) << 10);
#pragma unroll
  for (int n = 0; n < 4; ++n) {
    const int jg = j0 + (n << 4) + m;
    const int c = (w << 4) + (g << 2);
#pragma unroll
    for (int r = 0; r < 4; ++r)
      OUT[((size_t)(c + r) << 10) + jg] = accO[n][r];
  }
}

// ---- merge both streams ----------------------------------------------------
struct MergeArgs { const float* PART[2]; const float* XR[2]; unsigned short* Y0[2]; };
__global__ __launch_bounds__(256)
void merge_kernel(MergeArgs a, const float* __restrict__ bsum) {
  __shared__ float ts[128][66];
  const int tid = threadIdx.x;
  const int n0 = blockIdx.x << 6;
  const int b = blockIdx.y;
  const int z = blockIdx.z;
  const float invS = 1.f / bsum[b];
  const size_t M1 = (size_t)1 << 20;
  const float* XR = z ? a.XR[1] : a.XR[0];
  const float* PART = z ? a.PART[1] : a.PART[0];
  unsigned short* Y0 = z ? a.Y0[1] : a.Y0[0];
#pragma unroll
  for (int it = 0; it < 4; ++it) {
    int idx = it * 256 + tid;
    int c = idx >> 4, nq = (idx & 15) << 2;
    float4 v = *reinterpret_cast<const float4*>(XR + ((size_t)(b * 64 + c) << 10) + n0 + nq);
    ts[c][nq] = v.x; ts[c][nq + 1] = v.y; ts[c][nq + 2] = v.z; ts[c][nq + 3] = v.w;
  }
#pragma unroll
  for (int it = 0; it < 4; ++it) {
    int idx = it * 256 + tid;
    int c = idx >> 4, nq = (idx & 15) << 2;
    const float* p = PART + ((size_t)(b * 64 + c) << 10) + n0 + nq;
    float4 av = *reinterpret_cast<const float4*>(p);
    float4 b4 = *reinterpret_cast<const float4*>(p + M1);
    float4 c4 = *reinterpret_cast<const float4*>(p + 2 * M1);
    float4 d4 = *reinterpret_cast<const float4*>(p + 3 * M1);
    ts[64 + c][nq]     = ((av.x + b4.x) + (c4.x + d4.x)) * invS;
    ts[64 + c][nq + 1] = ((av.y + b4.y) + (c4.y + d4.y)) * invS;
    ts[64 + c][nq + 2] = ((av.z + b4.z) + (c4.z + d4.z)) * invS;
    ts[64 + c][nq + 3] = ((av.w + b4.w) + (c4.w + d4.w)) * invS;
  }
  __syncthreads();
  const int n = tid >> 2, c0 = (tid & 3) << 5;
  unsigned short* dst = Y0 + ((size_t)(b * 1024 + n0 + n) << 7) + c0;
#pragma unroll
  for (int q8 = 0; q8 < 4; ++q8) {
    const int cb = c0 + (q8 << 3);
    unsigned w0 = (unsigned)f2bf(ts[cb + 0][n]) | ((unsigned)f2bf(ts[cb + 1][n]) << 16);
    unsigned w1 = (unsigned)f2bf(ts[cb + 2][n]) | ((unsigned)f2bf(ts[cb + 3][n]) << 16);
    unsigned w2 = (unsigned)f2bf(ts[cb + 4][n]) | ((unsigned)f2bf(ts[cb + 5][n]) << 16);
    unsigned w3 = (unsigned)f2bf(ts[cb + 6][n]) | ((unsigned)f2bf(ts[cb + 7][n]) << 16);
    *reinterpret_cast<uint4*>(dst + (q8 << 3)) = make_uint4(w0, w1, w2, w3);
  }
}

// ---- MFMA conv v7: z-indexed with scalar-safe pointer select ---------------
struct ConvArgs {
  const unsigned short* X[4];
  const unsigned short* W[4];
  unsigned short* Y[4];
  const float* pre[4];
  float* sums[4];
};
template<int CIN, int NT, bool PREBN>
__global__ __launch_bounds__(256)
void conv_mfma_kernel(ConvArgs a, int COUT) {
  constexpr int KS = CIN / 32;
  __shared__ float scs[PREBN ? CIN : 1];
  __shared__ float shs[PREBN ? CIN : 1];
  const int tid = threadIdx.x;
  const int lane = tid & 63, w = tid >> 6;
  const int g = lane >> 4, m = lane & 15;
  const int z = blockIdx.z;
  const int o0 = (blockIdx.x << 6) + (w << 4);
  const int nbase = blockIdx.y * (NT << 4);
  const unsigned short* Xin; const unsigned short* Wb; unsigned short* Yout;
  const float* pre; float* sums;
  SEL4(Xin, a.X, z); SEL4(Wb, a.W, z); SEL4(Yout, a.Y, z);
  SEL4(pre, a.pre, z); SEL4(sums, a.sums, z);
  if (PREBN) {
    for (int c = tid; c < CIN; c += 256) {
      scs[c] = pre[c];
      shs[c] = pre[256 + c];
    }
    __syncthreads();
  }
  const unsigned short* Wr = Wb + (size_t)(o0 + m) * CIN + (g << 3);
  bf16x8 af[KS];
#pragma unroll
  for (int k = 0; k < KS; ++k) af[k] = *reinterpret_cast<const bf16x8*>(Wr + (k << 5));
  float sr[4] = {0.f, 0.f, 0.f, 0.f}, qr[4] = {0.f, 0.f, 0.f, 0.f};
#pragma unroll
  for (int nt = 0; nt < NT; ++nt) {
    const int row = nbase + (nt << 4) + m;
    const unsigned short* Xr = Xin + (size_t)row * CIN + (g << 3);
    bf16x8 bv[KS];
#pragma unroll
    for (int k = 0; k < KS; ++k) bv[k] = *reinterpret_cast<const bf16x8*>(Xr + (k << 5));
    if (PREBN) {
#pragma unroll
      for (int k = 0; k < KS; ++k) {
        const int kb = (k << 5) + (g << 3);
#pragma unroll
        for (int j = 0; j < 8; ++j) {
          float x = __uint_as_float((unsigned)(unsigned short)bv[k][j] << 16);
          x = fmaxf(fmaf(x, scs[kb + j], shs[kb + j]), 0.f);
          bv[k][j] = (short)f2bf(x);
        }
      }
    }
    f32x4 acc = (f32x4){0.f, 0.f, 0.f, 0.f};
#pragma unroll
    for (int k = 0; k < KS; ++k)
      acc = __builtin_amdgcn_mfma_f32_16x16x32_bf16(af[k], bv[k], acc, 0, 0, 0);
    ushort4 v;
    v.x = f2bf(acc[0]); v.y = f2bf(acc[1]);
    v.z = f2bf(acc[2]); v.w = f2bf(acc[3]);
    *reinterpret_cast<ushort4*>(Yout + (size_t)row * COUT + o0 + (g << 2)) = v;
#pragma unroll
    for (int r = 0; r < 4; ++r) {
      sr[r] += acc[r];
      qr[r] = fmaf(acc[r], acc[r], qr[r]);
    }
  }
#pragma unroll
  for (int r = 0; r < 4; ++r) {
    for (int off = 1; off < 16; off <<= 1) {
      sr[r] += __shfl_xor(sr[r], off);
      qr[r] += __shfl_xor(qr[r], off);
    }
  }
  if (m == 0) {
    float* dst = sums + (blockIdx.y & (NCOPY - 1)) * 512;
#pragma unroll
    for (int r = 0; r < 4; ++r) {
      atomicAdd(&dst[o0 + (g << 2) + r], sr[r]);
      atomicAdd(&dst[256 + o0 + (g << 2) + r], qr[r]);
    }
  }
}

// ---- finish: MODE 1: relu(bn0(T)+S); 2: relu(bn0(T)+bn1(S)); z-indexed -----
struct FinArgs { const unsigned short* T[2]; const float* P0[2];
                 const unsigned short* S[2]; const float* P1[2];
                 unsigned short* O[2]; };
template<int C, int MODE>
__global__ __launch_bounds__(256)
void finish_kernel(FinArgs a) {
  __shared__ float sc0[C], sh0[C];
  __shared__ float sc1[(MODE == 2) ? C : 1], sh1[(MODE == 2) ? C : 1];
  const int tid = threadIdx.x;
  const int z = blockIdx.y;
  const unsigned short* T = z ? a.T[1] : a.T[0];
  const float* P0 = z ? a.P0[1] : a.P0[0];
  const unsigned short* S = z ? a.S[1] : a.S[0];
  const float* P1 = z ? a.P1[1] : a.P1[0];
  unsigned short* O = z ? a.O[1] : a.O[0];
  for (int c = tid; c < C; c += 256) {
    sc0[c] = P0[c]; sh0[c] = P0[256 + c];
    if (MODE == 2) { sc1[c] = P1[c]; sh1[c] = P1[256 + c]; }
  }
  __syncthreads();
  const size_t i8 = ((size_t)blockIdx.x * 256 + tid) << 3;
  const int c0 = (int)(i8 & (size_t)(C - 1));
  uint4 tv = *reinterpret_cast<const uint4*>(T + i8);
  uint4 sv = *reinterpret_cast<const uint4*>(S + i8);
  unsigned tw[4] = {tv.x, tv.y, tv.z, tv.w};
  unsigned sw[4] = {sv.x, sv.y, sv.z, sv.w};
  unsigned ow[4];
#pragma unroll
  for (int jw = 0; jw < 4; ++jw) {
    unsigned r = 0;
#pragma unroll
    for (int h = 0; h < 2; ++h) {
      int c = c0 + jw * 2 + h;
      float x = __uint_as_float(((tw[jw] >> (h * 16)) & 0xffffu) << 16);
      x = fmaf(x, sc0[c], sh0[c]);
      if (MODE == 1) x += __uint_as_float(((sw[jw] >> (h * 16)) & 0xffffu) << 16);
      if (MODE == 2) {
        float y = __uint_as_float(((sw[jw] >> (h * 16)) & 0xffffu) << 16);
        x += fmaf(y, sc1[c], sh1[c]);
      }
      x = fmaxf(x, 0.f);
      r |= ((unsigned)f2bf(x)) << (h * 16);
    }
    ow[jw] = r;
  }
  *reinterpret_cast<uint4*>(O + i8) = make_uint4(ow[0], ow[1], ow[2], ow[3]);
}

// ---- writeout: out[b][c][n] f32 = bn(F[b][n][c]) via LDS transpose ---------
struct WoArgs { const unsigned short* F[2]; const float* pre[2]; float* out[2]; };
__global__ __launch_bounds__(256)
void writeout_t_kernel(WoArgs a) {
  __shared__ float ts[64][66];
  __shared__ float sc[64], sh[64];
  const int tid = threadIdx.x;
  const int z = blockIdx.z;
  const unsigned short* F = z ? a.F[1] : a.F[0];
  const float* pre = z ? a.pre[1] : a.pre[0];
  float* outp = z ? a.out[1] : a.out[0];
  if (tid < 64) {
    sc[tid] = pre[tid];
    sh[tid] = pre[256 + tid];
  }
  __syncthreads();
  const int n0 = blockIdx.x << 6;
  const int b = blockIdx.y;
  {
    const int n = tid >> 2, c0 = (tid & 3) << 4;
    const unsigned short* Fr = F + ((size_t)(b * 1024 + n0 + n) << 6) + c0;
    uint4 v0 = *reinterpret_cast<const uint4*>(Fr);
    uint4 v1 = *reinterpret_cast<const uint4*>(Fr + 8);
    unsigned vw[8] = {v0.x, v0.y, v0.z, v0.w, v1.x, v1.y, v1.z, v1.w};
#pragma unroll
    for (int jw = 0; jw < 8; ++jw) {
      int c = c0 + jw * 2;
      float x0 = __uint_as_float((vw[jw] & 0xffffu) << 16);
      float x1 = __uint_as_float((vw[jw] >> 16) << 16);
      ts[c][n] = fmaf(x0, sc[c], sh[c]);
      ts[c + 1][n] = fmaf(x1, sc[c + 1], sh[c + 1]);
    }
  }
  __syncthreads();
  const int c = tid >> 2, nq = (tid & 3) << 4;
  float* orow = outp + ((size_t)(b * 64 + c) << 10) + n0 + nq;
#pragma unroll
  for (int q = 0; q < 4; ++q) {
    float4 ov;
    ov.x = ts[c][nq + q * 4 + 0]; ov.y = ts[c][nq + q * 4 + 1];
    ov.z = ts[c][nq + q * 4 + 2]; ov.w = ts[c][nq + q * 4 + 3];
    *reinterpret_cast<float4*>(orow + q * 4) = ov;
  }
}

// ============================ host side =====================================
extern "C" void kernel_launch(void* const* d_in, const int* in_sizes, int n_in,
                              void* d_out, int out_size, void* d_ws, size_t ws_size,
                              hipStream_t stream) {
  float* wsf = (float*)d_ws;
  const size_t M1 = (size_t)1 << 20;
  const size_t H1 = (size_t)1 << 19;
  const int SSTR = NCOPY * 512;

  unsigned short* QAt = (unsigned short*)wsf;
  unsigned short* QBt = (unsigned short*)(wsf + H1);
  unsigned short* KAc = (unsigned short*)(wsf + 2 * H1);
  unsigned short* KBc = (unsigned short*)(wsf + 3 * H1);
  float* PART1 = wsf + 2 * M1;                                // [2M, 6M)
  float* PART2 = wsf + 14 * M1;                               // [14M,18M)
  unsigned short* Y0A = (unsigned short*)(wsf + 6 * M1);
  unsigned short* Y0B = (unsigned short*)(wsf + 7 * M1);
  unsigned short* T1a = (unsigned short*)(wsf + 8 * M1);
  unsigned short* T1b = (unsigned short*)(wsf + 9 * M1);
  unsigned short* T2a = (unsigned short*)(wsf + 10 * M1);
  unsigned short* T2b = (unsigned short*)(wsf + 11 * M1);
  unsigned short* O1a = (unsigned short*)(wsf + 12 * M1);
  unsigned short* O1b = (unsigned short*)(wsf + 13 * M1);
  unsigned short* T3a = (unsigned short*)(wsf + 2 * M1);      // over PART1 (dead)
  unsigned short* T3b = (unsigned short*)(wsf + 4 * M1);
  unsigned short* T4a = (unsigned short*)(wsf + 14 * M1);     // over PART2 (dead)
  unsigned short* T4b = (unsigned short*)(wsf + 16 * M1);
  unsigned short* T5a = (unsigned short*)(wsf + 18 * M1);
  unsigned short* T5b = (unsigned short*)(wsf + 20 * M1);
  unsigned short* Fba = (unsigned short*)(wsf + 22 * M1);
  unsigned short* Fbb = (unsigned short*)(wsf + 22 * M1 + H1);
  float* tail = wsf + 23 * M1;
  float* bsum = tail;
  float* stats = tail + 16;
  float* prep  = stats + 12 * SSTR;
  unsigned short* wbf = (unsigned short*)(prep + 12 * 512);

  const float* pp[46];
  for (int i = 0; i < 46 && i < n_in; ++i) pp[i] = (const float*)d_in[i];

  const int initN = 16 + 12 * SSTR;
  init_kernel<<<(initN + 255) / 256, 256, 0, stream>>>(tail, initN);

  const int widx[12] = {10, 13, 16, 19, 22, 25, 28, 31, 34, 37, 40, 43};
  WcvtArgs wa;
  int woff[12];
  {
    int run = 0;
    for (int i = 0; i < 12; ++i) {
      wa.p[i] = pp[widx[i]];
      wa.sz[i] = in_sizes[widx[i]];
      wa.off[i] = run; woff[i] = run;
      run += in_sizes[widx[i]];
    }
  }
  wcvt_kernel<<<dim3(12, 16), 256, 0, stream>>>(wa, wbf);

  float* ST[12];
  float* PR[12];
  for (int i = 0; i < 12; ++i) { ST[i] = stats + i * SSTR; PR[i] = prep + i * 512; }

  QKArgs qk;
  qk.X[0] = pp[0]; qk.W[0] = pp[2]; qk.B[0] = pp[3]; qk.Y[0] = QAt;
  qk.X[1] = pp[1]; qk.W[1] = pp[4]; qk.B[1] = pp[5]; qk.Y[1] = QBt;
  qk.X[2] = pp[0]; qk.W[2] = pp[6]; qk.B[2] = pp[7]; qk.Y[2] = KAc;
  qk.X[3] = pp[1]; qk.W[3] = pp[8]; qk.B[3] = pp[9]; qk.Y[3] = KBc;
  conv_qk_all_kernel<<<dim3(16, 2, 64), 256, 0, stream>>>(qk);

  pv_mfma_kernel<<<dim3(16, 4, BATCH), 256, 0, stream>>>(QAt, QBt, KBc, PART1, bsum);
  tpv_mfma_kernel<<<dim3(16, 4, BATCH), 256, 0, stream>>>(QAt, QBt, KAc, PART2);
  MergeArgs ma;
  ma.PART[0] = PART1; ma.XR[0] = pp[0]; ma.Y0[0] = Y0A;
  ma.PART[1] = PART2; ma.XR[1] = pp[1]; ma.Y0[1] = Y0B;
  merge_kernel<<<dim3(16, BATCH, 2), 256, 0, stream>>>(ma, bsum);

  const unsigned short* w11[2] = {wbf + woff[0], wbf + woff[2]};
  const unsigned short* w12[2] = {wbf + woff[1], wbf + woff[3]};
  const unsigned short* w21[2] = {wbf + woff[4], wbf + woff[7]};
  const unsigned short* w22[2] = {wbf + woff[5], wbf + woff[8]};
  const unsigned short* w2s[2] = {wbf + woff[6], wbf + woff[9]};
  const unsigned short* wo[2]  = {wbf + woff[10], wbf + woff[11]};
  const unsigned short* Y0[2] = {Y0A, Y0B};
  unsigned short* T1z[2] = {T1a, T1b};
  unsigned short* T2z[2] = {T2a, T2b};
  unsigned short* O1z[2] = {O1a, O1b};
  unsigned short* T3z[2] = {T3a, T3b};
  unsigned short* T4z[2] = {T4a, T4b};
  unsigned short* T5z[2] = {T5a, T5b};
  unsigned short* Fbz[2] = {Fba, Fbb};
  const int g1[2] = {10, 16}, g2[2] = {22, 31}, go[2] = {40, 43};

  ConvArgs ca;
  BnArgs ba;
  FinArgs fa;

  // conv1 both: Y0 -> T1 (stats s1)
  for (int z = 0; z < 2; ++z) {
    ca.X[z] = Y0[z]; ca.W[z] = w11[z]; ca.Y[z] = T1z[z];
    ca.pre[z] = nullptr; ca.sums[z] = ST[z * 6 + 0];
    ca.X[2 + z] = nullptr; ca.W[2 + z] = nullptr; ca.Y[2 + z] = nullptr;
    ca.pre[2 + z] = nullptr; ca.sums[2 + z] = nullptr;
  }
  conv_mfma_kernel<128, 2, false><<<dim3(2, 512, 2), 256, 0, stream>>>(ca, 128);
  for (int z = 0; z < 2; ++z) {
    ba.sums[z] = ST[z * 6 + 0]; ba.gam[z] = pp[g1[z] + 1];
    ba.bet[z] = pp[g1[z] + 2]; ba.dst[z] = PR[z * 6 + 0];
    ba.sums[2 + z] = nullptr; ba.gam[2 + z] = nullptr;
    ba.bet[2 + z] = nullptr; ba.dst[2 + z] = nullptr;
  }
  bnprep_kernel<<<2, 256, 0, stream>>>(ba, 128);

  // conv2 both (PREBN p1): T1 -> T2 (stats s2)
  for (int z = 0; z < 2; ++z) {
    ca.X[z] = T1z[z]; ca.W[z] = w12[z]; ca.Y[z] = T2z[z];
    ca.pre[z] = PR[z * 6 + 0]; ca.sums[z] = ST[z * 6 + 1];
  }
  conv_mfma_kernel<128, 2, true><<<dim3(2, 512, 2), 256, 0, stream>>>(ca, 128);
  for (int z = 0; z < 2; ++z) {
    ba.sums[z] = ST[z * 6 + 1]; ba.gam[z] = pp[g1[z] + 4];
    ba.bet[z] = pp[g1[z] + 5]; ba.dst[z] = PR[z * 6 + 1];
  }
  bnprep_kernel<<<2, 256, 0, stream>>>(ba, 128);

  // finish1 both: O1 = relu(bn(T2) + Y0)
  for (int z = 0; z < 2; ++z) {
    fa.T[z] = T2z[z]; fa.P0[z] = PR[z * 6 + 1];
    fa.S[z] = Y0[z]; fa.P1[z] = nullptr; fa.O[z] = O1z[z];
  }
  finish_kernel<128, 1><<<dim3(1024, 2), 256, 0, stream>>>(fa);

  // conv3 quad: O1 -> T3 (w21) and O1 -> T5 (w2s), both streams
  {
    ConvArgs cq;
    cq.X[0] = O1a; cq.W[0] = w21[0]; cq.Y[0] = T3a; cq.pre[0] = nullptr; cq.sums[0] = ST[2];
    cq.X[1] = O1a; cq.W[1] = w2s[0]; cq.Y[1] = T5a; cq.pre[1] = nullptr; cq.sums[1] = ST[4];
    cq.X[2] = O1b; cq.W[2] = w21[1]; cq.Y[2] = T3b; cq.pre[2] = nullptr; cq.sums[2] = ST[8];
    cq.X[3] = O1b; cq.W[3] = w2s[1]; cq.Y[3] = T5b; cq.pre[3] = nullptr; cq.sums[3] = ST[10];
    conv_mfma_kernel<128, 2, false><<<dim3(4, 512, 4), 256, 0, stream>>>(cq, 256);
  }
  {
    BnArgs bq;
    bq.sums[0] = ST[2];  bq.gam[0] = pp[g2[0] + 1]; bq.bet[0] = pp[g2[0] + 2]; bq.dst[0] = PR[2];
    bq.sums[1] = ST[4];  bq.gam[1] = pp[g2[0] + 7]; bq.bet[1] = pp[g2[0] + 8]; bq.dst[1] = PR[4];
    bq.sums[2] = ST[8];  bq.gam[2] = pp[g2[1] + 1]; bq.bet[2] = pp[g2[1] + 2]; bq.dst[2] = PR[8];
    bq.sums[3] = ST[10]; bq.gam[3] = pp[g2[1] + 7]; bq.bet[3] = pp[g2[1] + 8]; bq.dst[3] = PR[10];
    bnprep_kernel<<<4, 256, 0, stream>>>(bq, 256);
  }

  // conv4 both (PREBN p3): T3 -> T4 (stats s4)
  for (int z = 0; z < 2; ++z) {
    ca.X[z] = T3z[z]; ca.W[z] = w22[z]; ca.Y[z] = T4z[z];
    ca.pre[z] = PR[z * 6 + 2]; ca.sums[z] = ST[z * 6 + 3];
  }
  conv_mfma_kernel<256, 4, true><<<dim3(4, 256, 2), 256, 0, stream>>>(ca, 256);
  for (int z = 0; z < 2; ++z) {
    ba.sums[z] = ST[z * 6 + 3]; ba.gam[z] = pp[g2[z] + 4];
    ba.bet[z] = pp[g2[z] + 5]; ba.dst[z] = PR[z * 6 + 3];
  }
  bnprep_kernel<<<2, 256, 0, stream>>>(ba, 256);

  // finish2 both: T3 = relu(bn(T4) + bn(T5))
  for (int z = 0; z < 2; ++z) {
    fa.T[z] = T4z[z]; fa.P0[z] = PR[z * 6 + 3];
    fa.S[z] = T5z[z]; fa.P1[z] = PR[z * 6 + 4]; fa.O[z] = T3z[z];
  }
  finish_kernel<256, 2><<<dim3(2048, 2), 256, 0, stream>>>(fa);

  // conv6 both: T3 -> Fb (stats s6)
  for (int z = 0; z < 2; ++z) {
    ca.X[z] = T3z[z]; ca.W[z] = wo[z]; ca.Y[z] = Fbz[z];
    ca.pre[z] = nullptr; ca.sums[z] = ST[z * 6 + 5];
  }
  conv_mfma_kernel<256, 2, false><<<dim3(1, 512, 2), 256, 0, stream>>>(ca, 64);
  for (int z = 0; z < 2; ++z) {
    ba.sums[z] = ST[z * 6 + 5]; ba.gam[z] = pp[go[z] + 1];
    ba.bet[z] = pp[go[z] + 2]; ba.dst[z] = PR[z * 6 + 5];
  }
  bnprep_kernel<<<2, 256, 0, stream>>>(ba, 64);

  WoArgs wo2;
  for (int z = 0; z < 2; ++z) {
    wo2.F[z] = Fbz[z]; wo2.pre[z] = PR[z * 6 + 5];
    wo2.out[z] = (float*)d_out + z * M1;
  }
  writeout_t_kernel<<<dim3(16, BATCH, 2), 256, 0, stream>>>(wo2);
}

// Round 14
// 267.725 us; speedup vs baseline: 3.2906x; 1.1880x over previous
//
#include <hip/hip_runtime.h>
#include <hip/hip_bf16.h>
#include <cstddef>

static constexpr int BATCH = 16;
static constexpr int NCOPY = 16;
static constexpr int SSTR  = NCOPY * 512;   // floats per stat set

typedef __attribute__((ext_vector_type(8))) short bf16x8;
typedef __attribute__((ext_vector_type(4))) float f32x4;

__device__ __forceinline__ unsigned short f2bf(float f) {
  unsigned u = __float_as_uint(f);
  return (unsigned short)((u + 0x7fffu + ((u >> 16) & 1u)) >> 16);  // RNE
}

#define SEL4(dst, arr, idx)                                   \
  do {                                                        \
    if ((idx) == 0) dst = arr[0];                             \
    else if ((idx) == 1) dst = arr[1];                        \
    else if ((idx) == 2) dst = arr[2];                        \
    else dst = arr[3];                                        \
  } while (0)

__global__ void init_kernel(float* __restrict__ t, int n) {
  int i = blockIdx.x * 256 + threadIdx.x;
  if (i < n) t[i] = 0.f;
}

// ---- convert the 12 block-phase weight matrices to bf16 (layout [o][cin]) --
struct WcvtArgs { const float* p[12]; int sz[12]; int off[12]; };
__global__ __launch_bounds__(256)
void wcvt_kernel(WcvtArgs a, unsigned short* __restrict__ dst) {
  const int t = blockIdx.x;
  const float* src = a.p[t];
  unsigned short* d = dst + a.off[t];
  const int sz = a.sz[t];
  for (int i = blockIdx.y * 256 + threadIdx.x; i < sz; i += 16 * 256)
    d[i] = f2bf(src[i]);
}

// ---- bnprep (tiny; struct + SEL4 is fine here) -----------------------------
struct BnArgs { const float* sums[4]; const float* gam[4]; const float* bet[4];
                float* dst[4]; };
__global__ void bnprep_kernel(BnArgs a, int C) {
  const int t = blockIdx.x;
  const float* sums; const float* gam; const float* bet; float* dst;
  SEL4(sums, a.sums, t); SEL4(gam, a.gam, t); SEL4(bet, a.bet, t); SEL4(dst, a.dst, t);
  const int c = threadIdx.x;
  if (c < C) {
    float s0 = 0.f, q0 = 0.f;
#pragma unroll
    for (int p = 0; p < NCOPY; ++p) {
      s0 += sums[p * 512 + c];
      q0 += sums[p * 512 + 256 + c];
    }
    const float invN = 1.f / 16384.f;
    float mm = s0 * invN;
    float vv = q0 * invN - mm * mm;
    float s = gam[c] * rsqrtf(vv + 1e-5f);
    dst[c] = s;
    dst[256 + c] = bet[c] - mm * s;
  }
}

// ---------------- q/k convs (all 4 in one launch) ---------------------------
struct QKArgs { const float* X[4]; const float* W[4]; const float* B[4];
                unsigned short* Y[4]; };
__global__ __launch_bounds__(256)
void conv_qk_all_kernel(QKArgs a) {
  __shared__ float wsT[64][4];
  const int tid = threadIdx.x;
  const int z = blockIdx.z;
  const int which = z >> 4;
  const int b = z & 15;
  const int o0 = blockIdx.x << 2;
  const int px = (blockIdx.y << 9) + (tid << 1);
  const float* W; const float* X; const float* bias; unsigned short* Y;
  SEL4(W, a.W, which); SEL4(X, a.X, which); SEL4(bias, a.B, which); SEL4(Y, a.Y, which);
  {
    int c = tid >> 2, k = tid & 3;
    wsT[c][k] = W[((o0 + k) << 6) + c];
  }
  __syncthreads();
  float acc[4][2] = {};
  const float* xb = X + ((size_t)b << 16) + px;
#pragma unroll 4
  for (int c = 0; c < 64; ++c) {
    float2 xv = *reinterpret_cast<const float2*>(xb + (c << 10));
    float4 w = *reinterpret_cast<const float4*>(wsT[c]);
    acc[0][0] = fmaf(w.x, xv.x, acc[0][0]); acc[0][1] = fmaf(w.x, xv.y, acc[0][1]);
    acc[1][0] = fmaf(w.y, xv.x, acc[1][0]); acc[1][1] = fmaf(w.y, xv.y, acc[1][1]);
    acc[2][0] = fmaf(w.z, xv.x, acc[2][0]); acc[2][1] = fmaf(w.z, xv.y, acc[2][1]);
    acc[3][0] = fmaf(w.w, xv.x, acc[3][0]); acc[3][1] = fmaf(w.w, xv.y, acc[3][1]);
  }
  float b0 = bias[o0], b1 = bias[o0 + 1], b2 = bias[o0 + 2], b3 = bias[o0 + 3];
  if (which < 2) {
    ushort4 v0, v1;
    v0.x = f2bf(acc[0][0] + b0); v0.y = f2bf(acc[1][0] + b1);
    v0.z = f2bf(acc[2][0] + b2); v0.w = f2bf(acc[3][0] + b3);
    v1.x = f2bf(acc[0][1] + b0); v1.y = f2bf(acc[1][1] + b1);
    v1.z = f2bf(acc[2][1] + b2); v1.w = f2bf(acc[3][1] + b3);
    unsigned short* yt = Y + ((size_t)b << 16) + ((size_t)px << 6) + o0;
    *reinterpret_cast<ushort4*>(yt) = v0;
    *reinterpret_cast<ushort4*>(yt + 64) = v1;
  } else {
    float bv[4] = {b0, b1, b2, b3};
#pragma unroll
    for (int k = 0; k < 4; ++k) {
      ushort2 v;
      v.x = f2bf(acc[k][0] + bv[k]); v.y = f2bf(acc[k][1] + bv[k]);
      *reinterpret_cast<ushort2*>(Y + ((size_t)b << 16) + ((size_t)(o0 + k) << 10) + px) = v;
    }
  }
}

// ---- MFMA fused PV ---------------------------------------------------------
__global__ __launch_bounds__(256)
void pv_mfma_kernel(const unsigned short* __restrict__ QAt,
                    const unsigned short* __restrict__ QBt,
                    const unsigned short* __restrict__ KBc,
                    float* __restrict__ PART, float* __restrict__ bsum) {
  __shared__ __align__(16) unsigned short Ai[4096];
  __shared__ __align__(16) unsigned short Bj[4096];
  __shared__ __align__(16) unsigned short Pl[4096];
  __shared__ float red[256];
  const int tid = threadIdx.x;
  const int lane = tid & 63, w = tid >> 6;
  const int g = lane >> 4, m = lane & 15;
  const int i0 = blockIdx.x << 6;
  const int jbase = blockIdx.y << 8;
  const int b = blockIdx.z;
  const size_t nb = (size_t)b << 16;

  {
    const unsigned short* src = QAt + nb + ((size_t)i0 << 6);
#pragma unroll
    for (int s = 0; s < 2; ++s) {
      int idx = tid + (s << 8);
      int n = idx >> 3, cc = idx & 7;
      bf16x8 v = *reinterpret_cast<const bf16x8*>(src + (n << 6) + ((cc ^ (n & 7)) << 3));
      *reinterpret_cast<bf16x8*>(Ai + (idx << 3)) = v;
    }
  }
  f32x4 accO[4];
#pragma unroll
  for (int n = 0; n < 4; ++n) accO[n] = (f32x4){0.f, 0.f, 0.f, 0.f};
  float psum = 0.f;

  for (int jt = 0; jt < 4; ++jt) {
    const int j0 = jbase + (jt << 6);
    __syncthreads();
    {
      const unsigned short* src = QBt + nb + ((size_t)j0 << 6);
#pragma unroll
      for (int s = 0; s < 2; ++s) {
        int idx = tid + (s << 8);
        int n = idx >> 3, cc = idx & 7;
        bf16x8 v = *reinterpret_cast<const bf16x8*>(src + (n << 6) + ((cc ^ (n & 7)) << 3));
        *reinterpret_cast<bf16x8*>(Bj + (idx << 3)) = v;
      }
    }
    __syncthreads();
    const int jrow = (w << 4) | m;
    bf16x8 a0 = *reinterpret_cast<const bf16x8*>(Bj + (jrow << 6) + ((g ^ (jrow & 7)) << 3));
    bf16x8 a1 = *reinterpret_cast<const bf16x8*>(Bj + (jrow << 6) + (((g + 4) ^ (jrow & 7)) << 3));
    f32x4 e[4];
#pragma unroll
    for (int n = 0; n < 4; ++n) {
      const int irow = (n << 4) | m;
      bf16x8 b0v = *reinterpret_cast<const bf16x8*>(Ai + (irow << 6) + ((g ^ (irow & 7)) << 3));
      bf16x8 b1v = *reinterpret_cast<const bf16x8*>(Ai + (irow << 6) + (((g + 4) ^ (irow & 7)) << 3));
      e[n] = (f32x4){0.f, 0.f, 0.f, 0.f};
      e[n] = __builtin_amdgcn_mfma_f32_16x16x32_bf16(a0, b0v, e[n], 0, 0, 0);
      e[n] = __builtin_amdgcn_mfma_f32_16x16x32_bf16(a1, b1v, e[n], 0, 0, 0);
    }
    const int j = (w << 4) | (g << 2);
#pragma unroll
    for (int n = 0; n < 4; ++n) {
      const int irow = (n << 4) | m;
      float p0 = __expf(-e[n][0]), p1 = __expf(-e[n][1]);
      float p2 = __expf(-e[n][2]), p3 = __expf(-e[n][3]);
      psum += (p0 + p1) + (p2 + p3);
      unsigned pk01 = (unsigned)f2bf(p0) | ((unsigned)f2bf(p1) << 16);
      unsigned pk23 = (unsigned)f2bf(p2) | ((unsigned)f2bf(p3) << 16);
      int base = irow << 6;
      int off0 = base + ((((j) >> 3) ^ (irow & 7)) << 3) + (j & 7);
      int off2 = base + ((((j + 2) >> 3) ^ (irow & 7)) << 3) + ((j + 2) & 7);
      *reinterpret_cast<unsigned*>(Pl + off0) = pk01;
      *reinterpret_cast<unsigned*>(Pl + off2) = pk23;
    }
    const int crow = (w << 4) | m;
    const unsigned short* kbp = KBc + nb + ((size_t)crow << 10) + j0 + (g << 3);
    bf16x8 ka0 = *reinterpret_cast<const bf16x8*>(kbp);
    bf16x8 ka1 = *reinterpret_cast<const bf16x8*>(kbp + 32);
    __syncthreads();
#pragma unroll
    for (int n = 0; n < 4; ++n) {
      const int irow = (n << 4) | m;
      bf16x8 p0 = *reinterpret_cast<const bf16x8*>(Pl + (irow << 6) + ((g ^ (irow & 7)) << 3));
      bf16x8 p1 = *reinterpret_cast<const bf16x8*>(Pl + (irow << 6) + (((g + 4) ^ (irow & 7)) << 3));
      accO[n] = __builtin_amdgcn_mfma_f32_16x16x32_bf16(ka0, p0, accO[n], 0, 0, 0);
      accO[n] = __builtin_amdgcn_mfma_f32_16x16x32_bf16(ka1, p1, accO[n], 0, 0, 0);
    }
  }
  float* OUT = PART + ((size_t)blockIdx.y << 20) + ((size_t)(b * 64) << 10);
#pragma unroll
  for (int n = 0; n < 4; ++n) {
    const int ig = i0 + (n << 4) + m;
    const int c = (w << 4) + (g << 2);
#pragma unroll
    for (int r = 0; r < 4; ++r)
      OUT[((size_t)(c + r) << 10) + ig] = accO[n][r];
  }
  red[tid] = psum; __syncthreads();
  for (int s = 128; s > 0; s >>= 1) {
    if (tid < s) red[tid] += red[tid + s];
    __syncthreads();
  }
  if (tid == 0) atomicAdd(bsum + b, red[0]);
}

// ---- MFMA fused PtV --------------------------------------------------------
__global__ __launch_bounds__(256)
void tpv_mfma_kernel(const unsigned short* __restrict__ QAt,
                     const unsigned short* __restrict__ QBt,
                     const unsigned short* __restrict__ KAc,
                     float* __restrict__ PART) {
  __shared__ __align__(16) unsigned short Bj[4096];
  __shared__ __align__(16) unsigned short Ai[4096];
  __shared__ __align__(16) unsigned short Pl[4096];
  const int tid = threadIdx.x;
  const int lane = tid & 63, w = tid >> 6;
  const int g = lane >> 4, m = lane & 15;
  const int j0 = blockIdx.x << 6;
  const int ibase = blockIdx.y << 8;
  const int b = blockIdx.z;
  const size_t nb = (size_t)b << 16;

  {
    const unsigned short* src = QBt + nb + ((size_t)j0 << 6);
#pragma unroll
    for (int s = 0; s < 2; ++s) {
      int idx = tid + (s << 8);
      int n = idx >> 3, cc = idx & 7;
      bf16x8 v = *reinterpret_cast<const bf16x8*>(src + (n << 6) + ((cc ^ (n & 7)) << 3));
      *reinterpret_cast<bf16x8*>(Bj + (idx << 3)) = v;
    }
  }
  f32x4 accO[4];
#pragma unroll
  for (int n = 0; n < 4; ++n) accO[n] = (f32x4){0.f, 0.f, 0.f, 0.f};

  for (int it = 0; it < 4; ++it) {
    const int i0 = ibase + (it << 6);
    __syncthreads();
    {
      const unsigned short* src = QAt + nb + ((size_t)i0 << 6);
#pragma unroll
      for (int s = 0; s < 2; ++s) {
        int idx = tid + (s << 8);
        int n = idx >> 3, cc = idx & 7;
        bf16x8 v = *reinterpret_cast<const bf16x8*>(src + (n << 6) + ((cc ^ (n & 7)) << 3));
        *reinterpret_cast<bf16x8*>(Ai + (idx << 3)) = v;
      }
    }
    __syncthreads();
    const int irow_a = (w << 4) | m;
    bf16x8 a0 = *reinterpret_cast<const bf16x8*>(Ai + (irow_a << 6) + ((g ^ (irow_a & 7)) << 3));
    bf16x8 a1 = *reinterpret_cast<const bf16x8*>(Ai + (irow_a << 6) + (((g + 4) ^ (irow_a & 7)) << 3));
    f32x4 e[4];
#pragma unroll
    for (int n = 0; n < 4; ++n) {
      const int jrow = (n << 4) | m;
      bf16x8 b0v = *reinterpret_cast<const bf16x8*>(Bj + (jrow << 6) + ((g ^ (jrow & 7)) << 3));
      bf16x8 b1v = *reinterpret_cast<const bf16x8*>(Bj + (jrow << 6) + (((g + 4) ^ (jrow & 7)) << 3));
      e[n] = (f32x4){0.f, 0.f, 0.f, 0.f};
      e[n] = __builtin_amdgcn_mfma_f32_16x16x32_bf16(a0, b0v, e[n], 0, 0, 0);
      e[n] = __builtin_amdgcn_mfma_f32_16x16x32_bf16(a1, b1v, e[n], 0, 0, 0);
    }
    const int i = (w << 4) | (g << 2);
#pragma unroll
    for (int n = 0; n < 4; ++n) {
      const int jrow = (n << 4) | m;
      float p0 = __expf(-e[n][0]), p1 = __expf(-e[n][1]);
      float p2 = __expf(-e[n][2]), p3 = __expf(-e[n][3]);
      unsigned pk01 = (unsigned)f2bf(p0) | ((unsigned)f2bf(p1) << 16);
      unsigned pk23 = (unsigned)f2bf(p2) | ((unsigned)f2bf(p3) << 16);
      int base = jrow << 6;
      int off0 = base + ((((i) >> 3) ^ (jrow & 7)) << 3) + (i & 7);
      int off2 = base + ((((i + 2) >> 3) ^ (jrow & 7)) << 3) + ((i + 2) & 7);
      *reinterpret_cast<unsigned*>(Pl + off0) = pk01;
      *reinterpret_cast<unsigned*>(Pl + off2) = pk23;
    }
    const int crow = (w << 4) | m;
    const unsigned short* kap = KAc + nb + ((size_t)crow << 10) + i0 + (g << 3);
    bf16x8 ka0 = *reinterpret_cast<const bf16x8*>(kap);
    bf16x8 ka1 = *reinterpret_cast<const bf16x8*>(kap + 32);
    __syncthreads();
#pragma unroll
    for (int n = 0; n < 4; ++n) {
      const int jrow = (n << 4) | m;
      bf16x8 p0 = *reinterpret_cast<const bf16x8*>(Pl + (jrow << 6) + ((g ^ (jrow & 7)) << 3));
      bf16x8 p1 = *reinterpret_cast<const bf16x8*>(Pl + (jrow << 6) + (((g + 4) ^ (jrow & 7)) << 3));
      accO[n] = __builtin_amdgcn_mfma_f32_16x16x32_bf16(ka0, p0, accO[n], 0, 0, 0);
      accO[n] = __builtin_amdgcn_mfma_f32_16x16x32_bf16(ka1, p1, accO[n], 0, 0, 0);
    }
  }
  float* OUT = PART + ((size_t)blockIdx.y << 20) + ((size_t)(b * 64) << 10);
#pragma unroll
  for (int n = 0; n < 4; ++n) {
    const int jg = j0 + (n << 4) + m;
    const int c = (w << 4) + (g << 2);
#pragma unroll
    for (int r = 0; r < 4; ++r)
      OUT[((size_t)(c + r) << 10) + jg] = accO[n][r];
  }
}

// ---- merge both streams (PART stride 4M floats; Y0 stride 1M floats) -------
__global__ __launch_bounds__(256)
void merge_kernel(const float* __restrict__ PARTb, const float* __restrict__ XA,
                  const float* __restrict__ XB, unsigned short* __restrict__ Y0b,
                  const float* __restrict__ bsum) {
  __shared__ float ts[128][66];
  const int tid = threadIdx.x;
  const int n0 = blockIdx.x << 6;
  const int b = blockIdx.y;
  const int z = blockIdx.z;
  const float invS = 1.f / bsum[b];
  const size_t M1 = (size_t)1 << 20;
  const float* XR = z ? XB : XA;
  const float* PART = PARTb + (size_t)z * 4 * M1;
  unsigned short* Y0 = Y0b + (size_t)z * 2 * M1;
#pragma unroll
  for (int it = 0; it < 4; ++it) {
    int idx = it * 256 + tid;
    int c = idx >> 4, nq = (idx & 15) << 2;
    float4 v = *reinterpret_cast<const float4*>(XR + ((size_t)(b * 64 + c) << 10) + n0 + nq);
    ts[c][nq] = v.x; ts[c][nq + 1] = v.y; ts[c][nq + 2] = v.z; ts[c][nq + 3] = v.w;
  }
#pragma unroll
  for (int it = 0; it < 4; ++it) {
    int idx = it * 256 + tid;
    int c = idx >> 4, nq = (idx & 15) << 2;
    const float* p = PART + ((size_t)(b * 64 + c) << 10) + n0 + nq;
    float4 av = *reinterpret_cast<const float4*>(p);
    float4 b4 = *reinterpret_cast<const float4*>(p + M1);
    float4 c4 = *reinterpret_cast<const float4*>(p + 2 * M1);
    float4 d4 = *reinterpret_cast<const float4*>(p + 3 * M1);
    ts[64 + c][nq]     = ((av.x + b4.x) + (c4.x + d4.x)) * invS;
    ts[64 + c][nq + 1] = ((av.y + b4.y) + (c4.y + d4.y)) * invS;
    ts[64 + c][nq + 2] = ((av.z + b4.z) + (c4.z + d4.z)) * invS;
    ts[64 + c][nq + 3] = ((av.w + b4.w) + (c4.w + d4.w)) * invS;
  }
  __syncthreads();
  const int n = tid >> 2, c0 = (tid & 3) << 5;
  unsigned short* dst = Y0 + ((size_t)(b * 1024 + n0 + n) << 7) + c0;
#pragma unroll
  for (int q8 = 0; q8 < 4; ++q8) {
    const int cb = c0 + (q8 << 3);
    unsigned w0 = (unsigned)f2bf(ts[cb + 0][n]) | ((unsigned)f2bf(ts[cb + 1][n]) << 16);
    unsigned w1 = (unsigned)f2bf(ts[cb + 2][n]) | ((unsigned)f2bf(ts[cb + 3][n]) << 16);
    unsigned w2 = (unsigned)f2bf(ts[cb + 4][n]) | ((unsigned)f2bf(ts[cb + 5][n]) << 16);
    unsigned w3 = (unsigned)f2bf(ts[cb + 6][n]) | ((unsigned)f2bf(ts[cb + 7][n]) << 16);
    *reinterpret_cast<uint4*>(dst + (q8 << 3)) = make_uint4(w0, w1, w2, w3);
  }
}

// ---- MFMA conv v8: stride-batched z, capped VGPR, per-k load/convert/MFMA --
template<int CIN, int NT, bool PREBN, int XDIV>
__global__ __launch_bounds__(256, 4)
void conv_mfma_kernel(const unsigned short* __restrict__ X0,
                      const unsigned short* __restrict__ W0,
                      unsigned short* __restrict__ Y0,
                      const float* __restrict__ pre0,
                      float* __restrict__ sums0,
                      int COUT, long xstr, long wstr, long ystr) {
  constexpr int KS = CIN / 32;
  __shared__ float scs[PREBN ? CIN : 1];
  __shared__ float shs[PREBN ? CIN : 1];
  const int tid = threadIdx.x;
  const int lane = tid & 63, w = tid >> 6;
  const int g = lane >> 4, m = lane & 15;
  const int z = blockIdx.z;
  const int o0 = (blockIdx.x << 6) + (w << 4);
  const int nbase = blockIdx.y * (NT << 4);
  const unsigned short* Xin = X0 + (size_t)(z >> XDIV) * xstr;
  const unsigned short* Wb  = W0 + (size_t)z * wstr;
  unsigned short* Yout      = Y0 + (size_t)z * ystr;
  float* sums               = sums0 + (size_t)z * SSTR;
  if (PREBN) {
    const float* pre = pre0 + (size_t)z * 512;
    for (int c = tid; c < CIN; c += 256) {
      scs[c] = pre[c];
      shs[c] = pre[256 + c];
    }
    __syncthreads();
  }
  const unsigned short* Wr = Wb + (size_t)(o0 + m) * CIN + (g << 3);
  bf16x8 af[KS];
#pragma unroll
  for (int k = 0; k < KS; ++k) af[k] = *reinterpret_cast<const bf16x8*>(Wr + (k << 5));
  float sr[4] = {0.f, 0.f, 0.f, 0.f}, qr[4] = {0.f, 0.f, 0.f, 0.f};
#pragma unroll
  for (int nt = 0; nt < NT; ++nt) {
    const int row = nbase + (nt << 4) + m;
    const unsigned short* Xr = Xin + (size_t)row * CIN + (g << 3);
    f32x4 acc = (f32x4){0.f, 0.f, 0.f, 0.f};
#pragma unroll
    for (int k = 0; k < KS; ++k) {
      bf16x8 bv = *reinterpret_cast<const bf16x8*>(Xr + (k << 5));
      if (PREBN) {
        const int kb = (k << 5) + (g << 3);
#pragma unroll
        for (int j = 0; j < 8; ++j) {
          float x = __uint_as_float((unsigned)(unsigned short)bv[j] << 16);
          x = fmaxf(fmaf(x, scs[kb + j], shs[kb + j]), 0.f);
          bv[j] = (short)f2bf(x);
        }
      }
      acc = __builtin_amdgcn_mfma_f32_16x16x32_bf16(af[k], bv, acc, 0, 0, 0);
    }
    ushort4 v;
    v.x = f2bf(acc[0]); v.y = f2bf(acc[1]);
    v.z = f2bf(acc[2]); v.w = f2bf(acc[3]);
    *reinterpret_cast<ushort4*>(Yout + (size_t)row * COUT + o0 + (g << 2)) = v;
#pragma unroll
    for (int r = 0; r < 4; ++r) {
      sr[r] += acc[r];
      qr[r] = fmaf(acc[r], acc[r], qr[r]);
    }
  }
#pragma unroll
  for (int r = 0; r < 4; ++r) {
    for (int off = 1; off < 16; off <<= 1) {
      sr[r] += __shfl_xor(sr[r], off);
      qr[r] += __shfl_xor(qr[r], off);
    }
  }
  if (m == 0) {
    float* dst = sums + (blockIdx.y & (NCOPY - 1)) * 512;
#pragma unroll
    for (int r = 0; r < 4; ++r) {
      atomicAdd(&dst[o0 + (g << 2) + r], sr[r]);
      atomicAdd(&dst[256 + o0 + (g << 2) + r], qr[r]);
    }
  }
}

// ---- finish (stride-batched): MODE 1: relu(bn0(T)+S); 2: relu(bn0(T)+bn1(S))
template<int C, int MODE>
__global__ __launch_bounds__(256)
void finish_kernel(const unsigned short* __restrict__ T0, const float* __restrict__ P0b,
                   const unsigned short* __restrict__ S0, const float* __restrict__ P1b,
                   unsigned short* __restrict__ O0,
                   long tstr, long sstr, long ostr) {
  __shared__ float sc0[C], sh0[C];
  __shared__ float sc1[(MODE == 2) ? C : 1], sh1[(MODE == 2) ? C : 1];
  const int tid = threadIdx.x;
  const int z = blockIdx.y;
  const unsigned short* T = T0 + (size_t)z * tstr;
  const unsigned short* S = S0 + (size_t)z * sstr;
  unsigned short* O = O0 + (size_t)z * ostr;
  const float* P0 = P0b + (size_t)z * 512;
  const float* P1 = (MODE == 2) ? (P1b + (size_t)z * 512) : nullptr;
  for (int c = tid; c < C; c += 256) {
    sc0[c] = P0[c]; sh0[c] = P0[256 + c];
    if (MODE == 2) { sc1[c] = P1[c]; sh1[c] = P1[256 + c]; }
  }
  __syncthreads();
  const size_t i8 = ((size_t)blockIdx.x * 256 + tid) << 3;
  const int c0 = (int)(i8 & (size_t)(C - 1));
  uint4 tv = *reinterpret_cast<const uint4*>(T + i8);
  uint4 sv = *reinterpret_cast<const uint4*>(S + i8);
  unsigned tw[4] = {tv.x, tv.y, tv.z, tv.w};
  unsigned sw[4] = {sv.x, sv.y, sv.z, sv.w};
  unsigned ow[4];
#pragma unroll
  for (int jw = 0; jw < 4; ++jw) {
    unsigned r = 0;
#pragma unroll
    for (int h = 0; h < 2; ++h) {
      int c = c0 + jw * 2 + h;
      float x = __uint_as_float(((tw[jw] >> (h * 16)) & 0xffffu) << 16);
      x = fmaf(x, sc0[c], sh0[c]);
      if (MODE == 1) x += __uint_as_float(((sw[jw] >> (h * 16)) & 0xffffu) << 16);
      if (MODE == 2) {
        float y = __uint_as_float(((sw[jw] >> (h * 16)) & 0xffffu) << 16);
        x += fmaf(y, sc1[c], sh1[c]);
      }
      x = fmaxf(x, 0.f);
      r |= ((unsigned)f2bf(x)) << (h * 16);
    }
    ow[jw] = r;
  }
  *reinterpret_cast<uint4*>(O + i8) = make_uint4(ow[0], ow[1], ow[2], ow[3]);
}

// ---- writeout (stride-batched) ---------------------------------------------
__global__ __launch_bounds__(256)
void writeout_t_kernel(const unsigned short* __restrict__ F0,
                       const float* __restrict__ pre0,
                       float* __restrict__ out0) {
  __shared__ float ts[64][66];
  __shared__ float sc[64], sh[64];
  const int tid = threadIdx.x;
  const int z = blockIdx.z;
  const size_t M1 = (size_t)1 << 20;
  const unsigned short* F = F0 + (size_t)z * M1;     // 0.5M floats = 1M shorts
  const float* pre = pre0 + (size_t)z * 512;
  float* outp = out0 + (size_t)z * M1;
  if (tid < 64) {
    sc[tid] = pre[tid];
    sh[tid] = pre[256 + tid];
  }
  __syncthreads();
  const int n0 = blockIdx.x << 6;
  const int b = blockIdx.y;
  {
    const int n = tid >> 2, c0 = (tid & 3) << 4;
    const unsigned short* Fr = F + ((size_t)(b * 1024 + n0 + n) << 6) + c0;
    uint4 v0 = *reinterpret_cast<const uint4*>(Fr);
    uint4 v1 = *reinterpret_cast<const uint4*>(Fr + 8);
    unsigned vw[8] = {v0.x, v0.y, v0.z, v0.w, v1.x, v1.y, v1.z, v1.w};
#pragma unroll
    for (int jw = 0; jw < 8; ++jw) {
      int c = c0 + jw * 2;
      float x0 = __uint_as_float((vw[jw] & 0xffffu) << 16);
      float x1 = __uint_as_float((vw[jw] >> 16) << 16);
      ts[c][n] = fmaf(x0, sc[c], sh[c]);
      ts[c + 1][n] = fmaf(x1, sc[c + 1], sh[c + 1]);
    }
  }
  __syncthreads();
  const int c = tid >> 2, nq = (tid & 3) << 4;
  float* orow = outp + ((size_t)(b * 64 + c) << 10) + n0 + nq;
#pragma unroll
  for (int q = 0; q < 4; ++q) {
    float4 ov;
    ov.x = ts[c][nq + q * 4 + 0]; ov.y = ts[c][nq + q * 4 + 1];
    ov.z = ts[c][nq + q * 4 + 2]; ov.w = ts[c][nq + q * 4 + 3];
    *reinterpret_cast<float4*>(orow + q * 4) = ov;
  }
}

// ============================ host side =====================================
extern "C" void kernel_launch(void* const* d_in, const int* in_sizes, int n_in,
                              void* d_out, int out_size, void* d_ws, size_t ws_size,
                              hipStream_t stream) {
  float* wsf = (float*)d_ws;
  const size_t M1 = (size_t)1 << 20;
  const size_t H1 = (size_t)1 << 19;

  // flat layout (floats) — ws is 256 MB, total use ~31.3M floats
  unsigned short* QAt = (unsigned short*)wsf;
  unsigned short* QBt = (unsigned short*)(wsf + H1);
  unsigned short* KAc = (unsigned short*)(wsf + 2 * H1);
  unsigned short* KBc = (unsigned short*)(wsf + 3 * H1);
  float* PART1 = wsf + 2 * M1;                    // [2M,6M); PART2 [6M,10M)
  unsigned short* Y0A = (unsigned short*)(wsf + 10 * M1);  // stride 1M floats
  unsigned short* T1a = (unsigned short*)(wsf + 12 * M1);
  unsigned short* T2a = (unsigned short*)(wsf + 14 * M1);
  unsigned short* O1a = (unsigned short*)(wsf + 16 * M1);
  unsigned short* T3a = (unsigned short*)(wsf + 18 * M1);  // T3a,T5a,T3b,T5b @2M stride
  unsigned short* T4a = (unsigned short*)(wsf + 26 * M1);  // T4a,T4b @2M stride
  unsigned short* Fba = (unsigned short*)(wsf + 30 * M1);  // Fba,Fbb @0.5M stride
  float* tail = wsf + 31 * M1;
  float* bsum = tail;
  float* stats = tail + 16;                       // 12 * SSTR
  float* prep  = stats + 12 * SSTR;               // 12 * 512
  unsigned short* wbf = (unsigned short*)(prep + 12 * 512);

  const float* pp[46];
  for (int i = 0; i < 46 && i < n_in; ++i) pp[i] = (const float*)d_in[i];

  const int initN = 16 + 12 * SSTR;
  init_kernel<<<(initN + 255) / 256, 256, 0, stream>>>(tail, initN);

  // weight slot order: w11a,w11b,w12a,w12b,w21a,w2sa,w21b,w2sb,w22a,w22b,woa,wob
  const int widx[12] = {10, 16, 13, 19, 22, 28, 31, 37, 25, 34, 40, 43};
  WcvtArgs wa;
  int woff[12];
  {
    int run = 0;
    for (int i = 0; i < 12; ++i) {
      wa.p[i] = pp[widx[i]];
      wa.sz[i] = in_sizes[widx[i]];
      wa.off[i] = run; woff[i] = run;
      run += in_sizes[widx[i]];
    }
  }
  wcvt_kernel<<<dim3(12, 16), 256, 0, stream>>>(wa, wbf);

  QKArgs qk;
  qk.X[0] = pp[0]; qk.W[0] = pp[2]; qk.B[0] = pp[3]; qk.Y[0] = QAt;
  qk.X[1] = pp[1]; qk.W[1] = pp[4]; qk.B[1] = pp[5]; qk.Y[1] = QBt;
  qk.X[2] = pp[0]; qk.W[2] = pp[6]; qk.B[2] = pp[7]; qk.Y[2] = KAc;
  qk.X[3] = pp[1]; qk.W[3] = pp[8]; qk.B[3] = pp[9]; qk.Y[3] = KBc;
  conv_qk_all_kernel<<<dim3(16, 2, 64), 256, 0, stream>>>(qk);

  pv_mfma_kernel<<<dim3(16, 4, BATCH), 256, 0, stream>>>(QAt, QBt, KBc, PART1, bsum);
  tpv_mfma_kernel<<<dim3(16, 4, BATCH), 256, 0, stream>>>(QAt, QBt, KAc, PART1 + 4 * M1);
  merge_kernel<<<dim3(16, BATCH, 2), 256, 0, stream>>>(PART1, pp[0], pp[1], Y0A, bsum);

  // stat bases (stride SSTR per z): conv1@0, conv2@2, quad@4..7, conv4@8, conv6@10
  float* S_c1 = stats;
  float* S_c2 = stats + 2 * SSTR;
  float* S_q  = stats + 4 * SSTR;
  float* S_c4 = stats + 8 * SSTR;
  float* S_c6 = stats + 10 * SSTR;
  // prep slots (stride 512 per z within a pair)
  float* P_c1 = prep;              // conv1 stats -> conv2 PREBN
  float* P_c2 = prep + 2 * 512;    // conv2 stats -> finish1
  float* P_c3 = prep + 4 * 512;    // w21 stats -> conv4 PREBN
  float* P_sc = prep + 6 * 512;    // shortcut stats -> finish2
  float* P_c4 = prep + 8 * 512;    // conv4 stats -> finish2
  float* P_c6 = prep + 10 * 512;   // conv6 stats -> writeout

  const long SH1 = (long)2 * M1;   // 1M-float buffer stride in shorts
  const long SH2 = (long)4 * M1;   // 2M-float buffer stride in shorts
  BnArgs ba;

  // conv1: Y0 -> T1
  conv_mfma_kernel<128, 2, false, 0><<<dim3(2, 512, 2), 256, 0, stream>>>(
      Y0A, wbf + woff[0], T1a, nullptr, S_c1, 128, SH1, 16384, SH1);
  ba.sums[0] = S_c1; ba.gam[0] = pp[11]; ba.bet[0] = pp[12]; ba.dst[0] = P_c1;
  ba.sums[1] = S_c1 + SSTR; ba.gam[1] = pp[17]; ba.bet[1] = pp[18]; ba.dst[1] = P_c1 + 512;
  ba.sums[2] = nullptr; ba.gam[2] = nullptr; ba.bet[2] = nullptr; ba.dst[2] = nullptr;
  ba.sums[3] = nullptr; ba.gam[3] = nullptr; ba.bet[3] = nullptr; ba.dst[3] = nullptr;
  bnprep_kernel<<<2, 256, 0, stream>>>(ba, 128);

  // conv2 (PREBN): T1 -> T2
  conv_mfma_kernel<128, 2, true, 0><<<dim3(2, 512, 2), 256, 0, stream>>>(
      T1a, wbf + woff[2], T2a, P_c1, S_c2, 128, SH1, 16384, SH1);
  ba.sums[0] = S_c2; ba.gam[0] = pp[14]; ba.bet[0] = pp[15]; ba.dst[0] = P_c2;
  ba.sums[1] = S_c2 + SSTR; ba.gam[1] = pp[20]; ba.bet[1] = pp[21]; ba.dst[1] = P_c2 + 512;
  bnprep_kernel<<<2, 256, 0, stream>>>(ba, 128);

  // finish1: O1 = relu(bn(T2) + Y0)
  finish_kernel<128, 1><<<dim3(1024, 2), 256, 0, stream>>>(
      T2a, P_c2, Y0A, nullptr, O1a, SH1, SH1, SH1);

  // conv3 quad: O1 -> {T3a,T5a,T3b,T5b}
  conv_mfma_kernel<128, 2, false, 1><<<dim3(4, 512, 4), 256, 0, stream>>>(
      O1a, wbf + woff[4], T3a, nullptr, S_q, 256, SH1, 32768, SH2);
  ba.sums[0] = S_q;            ba.gam[0] = pp[23]; ba.bet[0] = pp[24]; ba.dst[0] = P_c3;
  ba.sums[1] = S_q + SSTR;     ba.gam[1] = pp[29]; ba.bet[1] = pp[30]; ba.dst[1] = P_sc;
  ba.sums[2] = S_q + 2 * SSTR; ba.gam[2] = pp[32]; ba.bet[2] = pp[33]; ba.dst[2] = P_c3 + 512;
  ba.sums[3] = S_q + 3 * SSTR; ba.gam[3] = pp[38]; ba.bet[3] = pp[39]; ba.dst[3] = P_sc + 512;
  bnprep_kernel<<<4, 256, 0, stream>>>(ba, 256);

  // conv4 (PREBN): T3 -> T4   (T3 stride 4M floats = 8M shorts)
  conv_mfma_kernel<256, 4, true, 0><<<dim3(4, 256, 2), 256, 0, stream>>>(
      T3a, wbf + woff[8], T4a, P_c3, S_c4, 256, (long)8 * M1, 65536, SH2);
  ba.sums[0] = S_c4; ba.gam[0] = pp[26]; ba.bet[0] = pp[27]; ba.dst[0] = P_c4;
  ba.sums[1] = S_c4 + SSTR; ba.gam[1] = pp[35]; ba.bet[1] = pp[36]; ba.dst[1] = P_c4 + 512;
  bnprep_kernel<<<2, 256, 0, stream>>>(ba, 256);

  // finish2: T3 = relu(bn(T4) + bn(T5));  T5 stride 8M shorts, O stride 8M shorts
  finish_kernel<256, 2><<<dim3(2048, 2), 256, 0, stream>>>(
      T4a, P_c4, T3a + SH2, P_sc, T3a, SH2, (long)8 * M1, (long)8 * M1);

  // conv6: T3 -> Fb
  conv_mfma_kernel<256, 2, false, 0><<<dim3(1, 512, 2), 256, 0, stream>>>(
      T3a, wbf + woff[10], Fba, nullptr, S_c6, 64, (long)8 * M1, 16384, (long)M1);
  ba.sums[0] = S_c6; ba.gam[0] = pp[41]; ba.bet[0] = pp[42]; ba.dst[0] = P_c6;
  ba.sums[1] = S_c6 + SSTR; ba.gam[1] = pp[44]; ba.bet[1] = pp[45]; ba.dst[1] = P_c6 + 512;
  bnprep_kernel<<<2, 256, 0, stream>>>(ba, 64);

  // writeout both
  writeout_t_kernel<<<dim3(16, BATCH, 2), 256, 0, stream>>>(
      Fba, P_c6, (float*)d_out);
}

// Round 15
// 243.358 us; speedup vs baseline: 3.6200x; 1.1001x over previous
//
#include <hip/hip_runtime.h>
#include <hip/hip_bf16.h>
#include <cstddef>

static constexpr int BATCH = 16;
static constexpr int NCOPY = 16;
static constexpr int SSTR  = NCOPY * 512;   // floats per stat set

typedef __attribute__((ext_vector_type(8))) short bf16x8;
typedef __attribute__((ext_vector_type(4))) float f32x4;

__device__ __forceinline__ unsigned short f2bf(float f) {
  unsigned u = __float_as_uint(f);
  return (unsigned short)((u + 0x7fffu + ((u >> 16) & 1u)) >> 16);  // RNE
}

#define SEL4(dst, arr, idx)                                   \
  do {                                                        \
    if ((idx) == 0) dst = arr[0];                             \
    else if ((idx) == 1) dst = arr[1];                        \
    else if ((idx) == 2) dst = arr[2];                        \
    else dst = arr[3];                                        \
  } while (0)

__global__ void init_kernel(float* __restrict__ t, int n) {
  int i = blockIdx.x * 256 + threadIdx.x;
  if (i < n) t[i] = 0.f;
}

// ---- convert the 12 block-phase weight matrices to bf16 (layout [o][cin]) --
struct WcvtArgs { const float* p[12]; int sz[12]; int off[12]; };
__global__ __launch_bounds__(256)
void wcvt_kernel(WcvtArgs a, unsigned short* __restrict__ dst) {
  const int t = blockIdx.x;
  const float* src = a.p[t];
  unsigned short* d = dst + a.off[t];
  const int sz = a.sz[t];
  for (int i = blockIdx.y * 256 + threadIdx.x; i < sz; i += 16 * 256)
    d[i] = f2bf(src[i]);
}

// ---- bnprep ----------------------------------------------------------------
struct BnArgs { const float* sums[4]; const float* gam[4]; const float* bet[4];
                float* dst[4]; };
__global__ void bnprep_kernel(BnArgs a, int C) {
  const int t = blockIdx.x;
  const float* sums; const float* gam; const float* bet; float* dst;
  SEL4(sums, a.sums, t); SEL4(gam, a.gam, t); SEL4(bet, a.bet, t); SEL4(dst, a.dst, t);
  const int c = threadIdx.x;
  if (c < C) {
    float s0 = 0.f, q0 = 0.f;
#pragma unroll
    for (int p = 0; p < NCOPY; ++p) {
      s0 += sums[p * 512 + c];
      q0 += sums[p * 512 + 256 + c];
    }
    const float invN = 1.f / 16384.f;
    float mm = s0 * invN;
    float vv = q0 * invN - mm * mm;
    float s = gam[c] * rsqrtf(vv + 1e-5f);
    dst[c] = s;
    dst[256 + c] = bet[c] - mm * s;
  }
}

// ---------------- q/k convs (all 4 in one launch) ---------------------------
struct QKArgs { const float* X[4]; const float* W[4]; const float* B[4];
                unsigned short* Y[4]; };
__global__ __launch_bounds__(256)
void conv_qk_all_kernel(QKArgs a) {
  __shared__ float wsT[64][4];
  const int tid = threadIdx.x;
  const int z = blockIdx.z;
  const int which = z >> 4;
  const int b = z & 15;
  const int o0 = blockIdx.x << 2;
  const int px = (blockIdx.y << 9) + (tid << 1);
  const float* W; const float* X; const float* bias; unsigned short* Y;
  SEL4(W, a.W, which); SEL4(X, a.X, which); SEL4(bias, a.B, which); SEL4(Y, a.Y, which);
  {
    int c = tid >> 2, k = tid & 3;
    wsT[c][k] = W[((o0 + k) << 6) + c];
  }
  __syncthreads();
  float acc[4][2] = {};
  const float* xb = X + ((size_t)b << 16) + px;
#pragma unroll 4
  for (int c = 0; c < 64; ++c) {
    float2 xv = *reinterpret_cast<const float2*>(xb + (c << 10));
    float4 w = *reinterpret_cast<const float4*>(wsT[c]);
    acc[0][0] = fmaf(w.x, xv.x, acc[0][0]); acc[0][1] = fmaf(w.x, xv.y, acc[0][1]);
    acc[1][0] = fmaf(w.y, xv.x, acc[1][0]); acc[1][1] = fmaf(w.y, xv.y, acc[1][1]);
    acc[2][0] = fmaf(w.z, xv.x, acc[2][0]); acc[2][1] = fmaf(w.z, xv.y, acc[2][1]);
    acc[3][0] = fmaf(w.w, xv.x, acc[3][0]); acc[3][1] = fmaf(w.w, xv.y, acc[3][1]);
  }
  float b0 = bias[o0], b1 = bias[o0 + 1], b2 = bias[o0 + 2], b3 = bias[o0 + 3];
  if (which < 2) {
    ushort4 v0, v1;
    v0.x = f2bf(acc[0][0] + b0); v0.y = f2bf(acc[1][0] + b1);
    v0.z = f2bf(acc[2][0] + b2); v0.w = f2bf(acc[3][0] + b3);
    v1.x = f2bf(acc[0][1] + b0); v1.y = f2bf(acc[1][1] + b1);
    v1.z = f2bf(acc[2][1] + b2); v1.w = f2bf(acc[3][1] + b3);
    unsigned short* yt = Y + ((size_t)b << 16) + ((size_t)px << 6) + o0;
    *reinterpret_cast<ushort4*>(yt) = v0;
    *reinterpret_cast<ushort4*>(yt + 64) = v1;
  } else {
    float bv[4] = {b0, b1, b2, b3};
#pragma unroll
    for (int k = 0; k < 4; ++k) {
      ushort2 v;
      v.x = f2bf(acc[k][0] + bv[k]); v.y = f2bf(acc[k][1] + bv[k]);
      *reinterpret_cast<ushort2*>(Y + ((size_t)b << 16) + ((size_t)(o0 + k) << 10) + px) = v;
    }
  }
}

// ---- MFMA fused PV ---------------------------------------------------------
__global__ __launch_bounds__(256)
void pv_mfma_kernel(const unsigned short* __restrict__ QAt,
                    const unsigned short* __restrict__ QBt,
                    const unsigned short* __restrict__ KBc,
                    float* __restrict__ PART, float* __restrict__ bsum) {
  __shared__ __align__(16) unsigned short Ai[4096];
  __shared__ __align__(16) unsigned short Bj[4096];
  __shared__ __align__(16) unsigned short Pl[4096];
  __shared__ float red[256];
  const int tid = threadIdx.x;
  const int lane = tid & 63, w = tid >> 6;
  const int g = lane >> 4, m = lane & 15;
  const int i0 = blockIdx.x << 6;
  const int jbase = blockIdx.y << 8;
  const int b = blockIdx.z;
  const size_t nb = (size_t)b << 16;

  {
    const unsigned short* src = QAt + nb + ((size_t)i0 << 6);
#pragma unroll
    for (int s = 0; s < 2; ++s) {
      int idx = tid + (s << 8);
      int n = idx >> 3, cc = idx & 7;
      bf16x8 v = *reinterpret_cast<const bf16x8*>(src + (n << 6) + ((cc ^ (n & 7)) << 3));
      *reinterpret_cast<bf16x8*>(Ai + (idx << 3)) = v;
    }
  }
  f32x4 accO[4];
#pragma unroll
  for (int n = 0; n < 4; ++n) accO[n] = (f32x4){0.f, 0.f, 0.f, 0.f};
  float psum = 0.f;

  for (int jt = 0; jt < 4; ++jt) {
    const int j0 = jbase + (jt << 6);
    __syncthreads();
    {
      const unsigned short* src = QBt + nb + ((size_t)j0 << 6);
#pragma unroll
      for (int s = 0; s < 2; ++s) {
        int idx = tid + (s << 8);
        int n = idx >> 3, cc = idx & 7;
        bf16x8 v = *reinterpret_cast<const bf16x8*>(src + (n << 6) + ((cc ^ (n & 7)) << 3));
        *reinterpret_cast<bf16x8*>(Bj + (idx << 3)) = v;
      }
    }
    __syncthreads();
    const int jrow = (w << 4) | m;
    bf16x8 a0 = *reinterpret_cast<const bf16x8*>(Bj + (jrow << 6) + ((g ^ (jrow & 7)) << 3));
    bf16x8 a1 = *reinterpret_cast<const bf16x8*>(Bj + (jrow << 6) + (((g + 4) ^ (jrow & 7)) << 3));
    f32x4 e[4];
#pragma unroll
    for (int n = 0; n < 4; ++n) {
      const int irow = (n << 4) | m;
      bf16x8 b0v = *reinterpret_cast<const bf16x8*>(Ai + (irow << 6) + ((g ^ (irow & 7)) << 3));
      bf16x8 b1v = *reinterpret_cast<const bf16x8*>(Ai + (irow << 6) + (((g + 4) ^ (irow & 7)) << 3));
      e[n] = (f32x4){0.f, 0.f, 0.f, 0.f};
      e[n] = __builtin_amdgcn_mfma_f32_16x16x32_bf16(a0, b0v, e[n], 0, 0, 0);
      e[n] = __builtin_amdgcn_mfma_f32_16x16x32_bf16(a1, b1v, e[n], 0, 0, 0);
    }
    const int j = (w << 4) | (g << 2);
#pragma unroll
    for (int n = 0; n < 4; ++n) {
      const int irow = (n << 4) | m;
      float p0 = __expf(-e[n][0]), p1 = __expf(-e[n][1]);
      float p2 = __expf(-e[n][2]), p3 = __expf(-e[n][3]);
      psum += (p0 + p1) + (p2 + p3);
      unsigned pk01 = (unsigned)f2bf(p0) | ((unsigned)f2bf(p1) << 16);
      unsigned pk23 = (unsigned)f2bf(p2) | ((unsigned)f2bf(p3) << 16);
      int base = irow << 6;
      int off0 = base + ((((j) >> 3) ^ (irow & 7)) << 3) + (j & 7);
      int off2 = base + ((((j + 2) >> 3) ^ (irow & 7)) << 3) + ((j + 2) & 7);
      *reinterpret_cast<unsigned*>(Pl + off0) = pk01;
      *reinterpret_cast<unsigned*>(Pl + off2) = pk23;
    }
    const int crow = (w << 4) | m;
    const unsigned short* kbp = KBc + nb + ((size_t)crow << 10) + j0 + (g << 3);
    bf16x8 ka0 = *reinterpret_cast<const bf16x8*>(kbp);
    bf16x8 ka1 = *reinterpret_cast<const bf16x8*>(kbp + 32);
    __syncthreads();
#pragma unroll
    for (int n = 0; n < 4; ++n) {
      const int irow = (n << 4) | m;
      bf16x8 p0 = *reinterpret_cast<const bf16x8*>(Pl + (irow << 6) + ((g ^ (irow & 7)) << 3));
      bf16x8 p1 = *reinterpret_cast<const bf16x8*>(Pl + (irow << 6) + (((g + 4) ^ (irow & 7)) << 3));
      accO[n] = __builtin_amdgcn_mfma_f32_16x16x32_bf16(ka0, p0, accO[n], 0, 0, 0);
      accO[n] = __builtin_amdgcn_mfma_f32_16x16x32_bf16(ka1, p1, accO[n], 0, 0, 0);
    }
  }
  float* OUT = PART + ((size_t)blockIdx.y << 20) + ((size_t)(b * 64) << 10);
#pragma unroll
  for (int n = 0; n < 4; ++n) {
    const int ig = i0 + (n << 4) + m;
    const int c = (w << 4) + (g << 2);
#pragma unroll
    for (int r = 0; r < 4; ++r)
      OUT[((size_t)(c + r) << 10) + ig] = accO[n][r];
  }
  red[tid] = psum; __syncthreads();
  for (int s = 128; s > 0; s >>= 1) {
    if (tid < s) red[tid] += red[tid + s];
    __syncthreads();
  }
  if (tid == 0) atomicAdd(bsum + b, red[0]);
}

// ---- MFMA fused PtV --------------------------------------------------------
__global__ __launch_bounds__(256)
void tpv_mfma_kernel(const unsigned short* __restrict__ QAt,
                     const unsigned short* __restrict__ QBt,
                     const unsigned short* __restrict__ KAc,
                     float* __restrict__ PART) {
  __shared__ __align__(16) unsigned short Bj[4096];
  __shared__ __align__(16) unsigned short Ai[4096];
  __shared__ __align__(16) unsigned short Pl[4096];
  const int tid = threadIdx.x;
  const int lane = tid & 63, w = tid >> 6;
  const int g = lane >> 4, m = lane & 15;
  const int j0 = blockIdx.x << 6;
  const int ibase = blockIdx.y << 8;
  const int b = blockIdx.z;
  const size_t nb = (size_t)b << 16;

  {
    const unsigned short* src = QBt + nb + ((size_t)j0 << 6);
#pragma unroll
    for (int s = 0; s < 2; ++s) {
      int idx = tid + (s << 8);
      int n = idx >> 3, cc = idx & 7;
      bf16x8 v = *reinterpret_cast<const bf16x8*>(src + (n << 6) + ((cc ^ (n & 7)) << 3));
      *reinterpret_cast<bf16x8*>(Bj + (idx << 3)) = v;
    }
  }
  f32x4 accO[4];
#pragma unroll
  for (int n = 0; n < 4; ++n) accO[n] = (f32x4){0.f, 0.f, 0.f, 0.f};

  for (int it = 0; it < 4; ++it) {
    const int i0 = ibase + (it << 6);
    __syncthreads();
    {
      const unsigned short* src = QAt + nb + ((size_t)i0 << 6);
#pragma unroll
      for (int s = 0; s < 2; ++s) {
        int idx = tid + (s << 8);
        int n = idx >> 3, cc = idx & 7;
        bf16x8 v = *reinterpret_cast<const bf16x8*>(src + (n << 6) + ((cc ^ (n & 7)) << 3));
        *reinterpret_cast<bf16x8*>(Ai + (idx << 3)) = v;
      }
    }
    __syncthreads();
    const int irow_a = (w << 4) | m;
    bf16x8 a0 = *reinterpret_cast<const bf16x8*>(Ai + (irow_a << 6) + ((g ^ (irow_a & 7)) << 3));
    bf16x8 a1 = *reinterpret_cast<const bf16x8*>(Ai + (irow_a << 6) + (((g + 4) ^ (irow_a & 7)) << 3));
    f32x4 e[4];
#pragma unroll
    for (int n = 0; n < 4; ++n) {
      const int jrow = (n << 4) | m;
      bf16x8 b0v = *reinterpret_cast<const bf16x8*>(Bj + (jrow << 6) + ((g ^ (jrow & 7)) << 3));
      bf16x8 b1v = *reinterpret_cast<const bf16x8*>(Bj + (jrow << 6) + (((g + 4) ^ (jrow & 7)) << 3));
      e[n] = (f32x4){0.f, 0.f, 0.f, 0.f};
      e[n] = __builtin_amdgcn_mfma_f32_16x16x32_bf16(a0, b0v, e[n], 0, 0, 0);
      e[n] = __builtin_amdgcn_mfma_f32_16x16x32_bf16(a1, b1v, e[n], 0, 0, 0);
    }
    const int i = (w << 4) | (g << 2);
#pragma unroll
    for (int n = 0; n < 4; ++n) {
      const int jrow = (n << 4) | m;
      float p0 = __expf(-e[n][0]), p1 = __expf(-e[n][1]);
      float p2 = __expf(-e[n][2]), p3 = __expf(-e[n][3]);
      unsigned pk01 = (unsigned)f2bf(p0) | ((unsigned)f2bf(p1) << 16);
      unsigned pk23 = (unsigned)f2bf(p2) | ((unsigned)f2bf(p3) << 16);
      int base = jrow << 6;
      int off0 = base + ((((i) >> 3) ^ (jrow & 7)) << 3) + (i & 7);
      int off2 = base + ((((i + 2) >> 3) ^ (jrow & 7)) << 3) + ((i + 2) & 7);
      *reinterpret_cast<unsigned*>(Pl + off0) = pk01;
      *reinterpret_cast<unsigned*>(Pl + off2) = pk23;
    }
    const int crow = (w << 4) | m;
    const unsigned short* kap = KAc + nb + ((size_t)crow << 10) + i0 + (g << 3);
    bf16x8 ka0 = *reinterpret_cast<const bf16x8*>(kap);
    bf16x8 ka1 = *reinterpret_cast<const bf16x8*>(kap + 32);
    __syncthreads();
#pragma unroll
    for (int n = 0; n < 4; ++n) {
      const int jrow = (n << 4) | m;
      bf16x8 p0 = *reinterpret_cast<const bf16x8*>(Pl + (jrow << 6) + ((g ^ (jrow & 7)) << 3));
      bf16x8 p1 = *reinterpret_cast<const bf16x8*>(Pl + (jrow << 6) + (((g + 4) ^ (jrow & 7)) << 3));
      accO[n] = __builtin_amdgcn_mfma_f32_16x16x32_bf16(ka0, p0, accO[n], 0, 0, 0);
      accO[n] = __builtin_amdgcn_mfma_f32_16x16x32_bf16(ka1, p1, accO[n], 0, 0, 0);
    }
  }
  float* OUT = PART + ((size_t)blockIdx.y << 20) + ((size_t)(b * 64) << 10);
#pragma unroll
  for (int n = 0; n < 4; ++n) {
    const int jg = j0 + (n << 4) + m;
    const int c = (w << 4) + (g << 2);
#pragma unroll
    for (int r = 0; r < 4; ++r)
      OUT[((size_t)(c + r) << 10) + jg] = accO[n][r];
  }
}

// ---- merge both streams ----------------------------------------------------
__global__ __launch_bounds__(256)
void merge_kernel(const float* __restrict__ PARTb, const float* __restrict__ XA,
                  const float* __restrict__ XB, unsigned short* __restrict__ Y0b,
                  const float* __restrict__ bsum) {
  __shared__ float ts[128][66];
  const int tid = threadIdx.x;
  const int n0 = blockIdx.x << 6;
  const int b = blockIdx.y;
  const int z = blockIdx.z;
  const float invS = 1.f / bsum[b];
  const size_t M1 = (size_t)1 << 20;
  const float* XR = z ? XB : XA;
  const float* PART = PARTb + (size_t)z * 4 * M1;
  unsigned short* Y0 = Y0b + (size_t)z * 2 * M1;
#pragma unroll
  for (int it = 0; it < 4; ++it) {
    int idx = it * 256 + tid;
    int c = idx >> 4, nq = (idx & 15) << 2;
    float4 v = *reinterpret_cast<const float4*>(XR + ((size_t)(b * 64 + c) << 10) + n0 + nq);
    ts[c][nq] = v.x; ts[c][nq + 1] = v.y; ts[c][nq + 2] = v.z; ts[c][nq + 3] = v.w;
  }
#pragma unroll
  for (int it = 0; it < 4; ++it) {
    int idx = it * 256 + tid;
    int c = idx >> 4, nq = (idx & 15) << 2;
    const float* p = PART + ((size_t)(b * 64 + c) << 10) + n0 + nq;
    float4 av = *reinterpret_cast<const float4*>(p);
    float4 b4 = *reinterpret_cast<const float4*>(p + M1);
    float4 c4 = *reinterpret_cast<const float4*>(p + 2 * M1);
    float4 d4 = *reinterpret_cast<const float4*>(p + 3 * M1);
    ts[64 + c][nq]     = ((av.x + b4.x) + (c4.x + d4.x)) * invS;
    ts[64 + c][nq + 1] = ((av.y + b4.y) + (c4.y + d4.y)) * invS;
    ts[64 + c][nq + 2] = ((av.z + b4.z) + (c4.z + d4.z)) * invS;
    ts[64 + c][nq + 3] = ((av.w + b4.w) + (c4.w + d4.w)) * invS;
  }
  __syncthreads();
  const int n = tid >> 2, c0 = (tid & 3) << 5;
  unsigned short* dst = Y0 + ((size_t)(b * 1024 + n0 + n) << 7) + c0;
#pragma unroll
  for (int q8 = 0; q8 < 4; ++q8) {
    const int cb = c0 + (q8 << 3);
    unsigned w0 = (unsigned)f2bf(ts[cb + 0][n]) | ((unsigned)f2bf(ts[cb + 1][n]) << 16);
    unsigned w1 = (unsigned)f2bf(ts[cb + 2][n]) | ((unsigned)f2bf(ts[cb + 3][n]) << 16);
    unsigned w2 = (unsigned)f2bf(ts[cb + 4][n]) | ((unsigned)f2bf(ts[cb + 5][n]) << 16);
    unsigned w3 = (unsigned)f2bf(ts[cb + 6][n]) | ((unsigned)f2bf(ts[cb + 7][n]) << 16);
    *reinterpret_cast<uint4*>(dst + (q8 << 3)) = make_uint4(w0, w1, w2, w3);
  }
}

// ---- MFMA conv v9: OC output-subtiles per wave (B-load reuse), NT n-tiles --
// Block: 4 waves cover 4*OC*16 outputs. grid.x = COUT/(OC*64).
template<int CIN, int OC, int NT, bool PREBN, int XDIV>
__global__ __launch_bounds__(256, 4)
void conv_mfma_kernel(const unsigned short* __restrict__ X0,
                      const unsigned short* __restrict__ W0,
                      unsigned short* __restrict__ Y0,
                      const float* __restrict__ pre0,
                      float* __restrict__ sums0,
                      int COUT, long xstr, long wstr, long ystr) {
  constexpr int KS = CIN / 32;
  __shared__ float scs[PREBN ? CIN : 1];
  __shared__ float shs[PREBN ? CIN : 1];
  const int tid = threadIdx.x;
  const int lane = tid & 63, w = tid >> 6;
  const int g = lane >> 4, m = lane & 15;
  const int z = blockIdx.z;
  const int o0 = blockIdx.x * (OC << 6) + w * (OC << 4);
  const int nbase = blockIdx.y * (NT << 4);
  const unsigned short* Xin = X0 + (size_t)(z >> XDIV) * xstr;
  const unsigned short* Wb  = W0 + (size_t)z * wstr;
  unsigned short* Yout      = Y0 + (size_t)z * ystr;
  float* sums               = sums0 + (size_t)z * SSTR;
  if (PREBN) {
    const float* pre = pre0 + (size_t)z * 512;
    for (int c = tid; c < CIN; c += 256) {
      scs[c] = pre[c];
      shs[c] = pre[256 + c];
    }
    __syncthreads();
  }
  bf16x8 af[KS][OC];
#pragma unroll
  for (int oc = 0; oc < OC; ++oc) {
    const unsigned short* Wr = Wb + (size_t)(o0 + (oc << 4) + m) * CIN + (g << 3);
#pragma unroll
    for (int k = 0; k < KS; ++k)
      af[k][oc] = *reinterpret_cast<const bf16x8*>(Wr + (k << 5));
  }
  float sr[OC][4], qr[OC][4];
#pragma unroll
  for (int oc = 0; oc < OC; ++oc)
#pragma unroll
    for (int r = 0; r < 4; ++r) { sr[oc][r] = 0.f; qr[oc][r] = 0.f; }
#pragma unroll
  for (int nt = 0; nt < NT; ++nt) {
    const int row = nbase + (nt << 4) + m;
    const unsigned short* Xr = Xin + (size_t)row * CIN + (g << 3);
    f32x4 acc[OC];
#pragma unroll
    for (int oc = 0; oc < OC; ++oc) acc[oc] = (f32x4){0.f, 0.f, 0.f, 0.f};
#pragma unroll
    for (int k = 0; k < KS; ++k) {
      bf16x8 bv = *reinterpret_cast<const bf16x8*>(Xr + (k << 5));
      if (PREBN) {
        const int kb = (k << 5) + (g << 3);
#pragma unroll
        for (int j = 0; j < 8; ++j) {
          float x = __uint_as_float((unsigned)(unsigned short)bv[j] << 16);
          x = fmaxf(fmaf(x, scs[kb + j], shs[kb + j]), 0.f);
          bv[j] = (short)f2bf(x);
        }
      }
#pragma unroll
      for (int oc = 0; oc < OC; ++oc)
        acc[oc] = __builtin_amdgcn_mfma_f32_16x16x32_bf16(af[k][oc], bv, acc[oc], 0, 0, 0);
    }
#pragma unroll
    for (int oc = 0; oc < OC; ++oc) {
      ushort4 v;
      v.x = f2bf(acc[oc][0]); v.y = f2bf(acc[oc][1]);
      v.z = f2bf(acc[oc][2]); v.w = f2bf(acc[oc][3]);
      *reinterpret_cast<ushort4*>(Yout + (size_t)row * COUT + o0 + (oc << 4) + (g << 2)) = v;
#pragma unroll
      for (int r = 0; r < 4; ++r) {
        sr[oc][r] += acc[oc][r];
        qr[oc][r] = fmaf(acc[oc][r], acc[oc][r], qr[oc][r]);
      }
    }
  }
#pragma unroll
  for (int oc = 0; oc < OC; ++oc)
#pragma unroll
    for (int r = 0; r < 4; ++r) {
      for (int off = 1; off < 16; off <<= 1) {
        sr[oc][r] += __shfl_xor(sr[oc][r], off);
        qr[oc][r] += __shfl_xor(qr[oc][r], off);
      }
    }
  if (m == 0) {
    float* dst = sums + (blockIdx.y & (NCOPY - 1)) * 512;
#pragma unroll
    for (int oc = 0; oc < OC; ++oc)
#pragma unroll
      for (int r = 0; r < 4; ++r) {
        atomicAdd(&dst[o0 + (oc << 4) + (g << 2) + r], sr[oc][r]);
        atomicAdd(&dst[256 + o0 + (oc << 4) + (g << 2) + r], qr[oc][r]);
      }
  }
}

// ---- finish (stride-batched) -----------------------------------------------
template<int C, int MODE>
__global__ __launch_bounds__(256)
void finish_kernel(const unsigned short* __restrict__ T0, const float* __restrict__ P0b,
                   const unsigned short* __restrict__ S0, const float* __restrict__ P1b,
                   unsigned short* __restrict__ O0,
                   long tstr, long sstr, long ostr) {
  __shared__ float sc0[C], sh0[C];
  __shared__ float sc1[(MODE == 2) ? C : 1], sh1[(MODE == 2) ? C : 1];
  const int tid = threadIdx.x;
  const int z = blockIdx.y;
  const unsigned short* T = T0 + (size_t)z * tstr;
  const unsigned short* S = S0 + (size_t)z * sstr;
  unsigned short* O = O0 + (size_t)z * ostr;
  const float* P0 = P0b + (size_t)z * 512;
  const float* P1 = (MODE == 2) ? (P1b + (size_t)z * 512) : nullptr;
  for (int c = tid; c < C; c += 256) {
    sc0[c] = P0[c]; sh0[c] = P0[256 + c];
    if (MODE == 2) { sc1[c] = P1[c]; sh1[c] = P1[256 + c]; }
  }
  __syncthreads();
  const size_t i8 = ((size_t)blockIdx.x * 256 + tid) << 3;
  const int c0 = (int)(i8 & (size_t)(C - 1));
  uint4 tv = *reinterpret_cast<const uint4*>(T + i8);
  uint4 sv = *reinterpret_cast<const uint4*>(S + i8);
  unsigned tw[4] = {tv.x, tv.y, tv.z, tv.w};
  unsigned sw[4] = {sv.x, sv.y, sv.z, sv.w};
  unsigned ow[4];
#pragma unroll
  for (int jw = 0; jw < 4; ++jw) {
    unsigned r = 0;
#pragma unroll
    for (int h = 0; h < 2; ++h) {
      int c = c0 + jw * 2 + h;
      float x = __uint_as_float(((tw[jw] >> (h * 16)) & 0xffffu) << 16);
      x = fmaf(x, sc0[c], sh0[c]);
      if (MODE == 1) x += __uint_as_float(((sw[jw] >> (h * 16)) & 0xffffu) << 16);
      if (MODE == 2) {
        float y = __uint_as_float(((sw[jw] >> (h * 16)) & 0xffffu) << 16);
        x += fmaf(y, sc1[c], sh1[c]);
      }
      x = fmaxf(x, 0.f);
      r |= ((unsigned)f2bf(x)) << (h * 16);
    }
    ow[jw] = r;
  }
  *reinterpret_cast<uint4*>(O + i8) = make_uint4(ow[0], ow[1], ow[2], ow[3]);
}

// ---- writeout (stride-batched) ---------------------------------------------
__global__ __launch_bounds__(256)
void writeout_t_kernel(const unsigned short* __restrict__ F0,
                       const float* __restrict__ pre0,
                       float* __restrict__ out0) {
  __shared__ float ts[64][66];
  __shared__ float sc[64], sh[64];
  const int tid = threadIdx.x;
  const int z = blockIdx.z;
  const size_t M1 = (size_t)1 << 20;
  const unsigned short* F = F0 + (size_t)z * M1;
  const float* pre = pre0 + (size_t)z * 512;
  float* outp = out0 + (size_t)z * M1;
  if (tid < 64) {
    sc[tid] = pre[tid];
    sh[tid] = pre[256 + tid];
  }
  __syncthreads();
  const int n0 = blockIdx.x << 6;
  const int b = blockIdx.y;
  {
    const int n = tid >> 2, c0 = (tid & 3) << 4;
    const unsigned short* Fr = F + ((size_t)(b * 1024 + n0 + n) << 6) + c0;
    uint4 v0 = *reinterpret_cast<const uint4*>(Fr);
    uint4 v1 = *reinterpret_cast<const uint4*>(Fr + 8);
    unsigned vw[8] = {v0.x, v0.y, v0.z, v0.w, v1.x, v1.y, v1.z, v1.w};
#pragma unroll
    for (int jw = 0; jw < 8; ++jw) {
      int c = c0 + jw * 2;
      float x0 = __uint_as_float((vw[jw] & 0xffffu) << 16);
      float x1 = __uint_as_float((vw[jw] >> 16) << 16);
      ts[c][n] = fmaf(x0, sc[c], sh[c]);
      ts[c + 1][n] = fmaf(x1, sc[c + 1], sh[c + 1]);
    }
  }
  __syncthreads();
  const int c = tid >> 2, nq = (tid & 3) << 4;
  float* orow = outp + ((size_t)(b * 64 + c) << 10) + n0 + nq;
#pragma unroll
  for (int q = 0; q < 4; ++q) {
    float4 ov;
    ov.x = ts[c][nq + q * 4 + 0]; ov.y = ts[c][nq + q * 4 + 1];
    ov.z = ts[c][nq + q * 4 + 2]; ov.w = ts[c][nq + q * 4 + 3];
    *reinterpret_cast<float4*>(orow + q * 4) = ov;
  }
}

// ============================ host side =====================================
extern "C" void kernel_launch(void* const* d_in, const int* in_sizes, int n_in,
                              void* d_out, int out_size, void* d_ws, size_t ws_size,
                              hipStream_t stream) {
  float* wsf = (float*)d_ws;
  const size_t M1 = (size_t)1 << 20;
  const size_t H1 = (size_t)1 << 19;

  unsigned short* QAt = (unsigned short*)wsf;
  unsigned short* QBt = (unsigned short*)(wsf + H1);
  unsigned short* KAc = (unsigned short*)(wsf + 2 * H1);
  unsigned short* KBc = (unsigned short*)(wsf + 3 * H1);
  float* PART1 = wsf + 2 * M1;
  unsigned short* Y0A = (unsigned short*)(wsf + 10 * M1);
  unsigned short* T1a = (unsigned short*)(wsf + 12 * M1);
  unsigned short* T2a = (unsigned short*)(wsf + 14 * M1);
  unsigned short* O1a = (unsigned short*)(wsf + 16 * M1);
  unsigned short* T3a = (unsigned short*)(wsf + 18 * M1);  // T3a,T5a,T3b,T5b @2M stride
  unsigned short* T4a = (unsigned short*)(wsf + 26 * M1);  // T4a,T4b @2M stride
  unsigned short* Fba = (unsigned short*)(wsf + 30 * M1);  // Fba,Fbb @0.5M stride
  float* tail = wsf + 31 * M1;
  float* bsum = tail;
  float* stats = tail + 16;
  float* prep  = stats + 12 * SSTR;
  unsigned short* wbf = (unsigned short*)(prep + 12 * 512);

  const float* pp[46];
  for (int i = 0; i < 46 && i < n_in; ++i) pp[i] = (const float*)d_in[i];

  const int initN = 16 + 12 * SSTR;
  init_kernel<<<(initN + 255) / 256, 256, 0, stream>>>(tail, initN);

  const int widx[12] = {10, 16, 13, 19, 22, 28, 31, 37, 25, 34, 40, 43};
  WcvtArgs wa;
  int woff[12];
  {
    int run = 0;
    for (int i = 0; i < 12; ++i) {
      wa.p[i] = pp[widx[i]];
      wa.sz[i] = in_sizes[widx[i]];
      wa.off[i] = run; woff[i] = run;
      run += in_sizes[widx[i]];
    }
  }
  wcvt_kernel<<<dim3(12, 16), 256, 0, stream>>>(wa, wbf);

  QKArgs qk;
  qk.X[0] = pp[0]; qk.W[0] = pp[2]; qk.B[0] = pp[3]; qk.Y[0] = QAt;
  qk.X[1] = pp[1]; qk.W[1] = pp[4]; qk.B[1] = pp[5]; qk.Y[1] = QBt;
  qk.X[2] = pp[0]; qk.W[2] = pp[6]; qk.B[2] = pp[7]; qk.Y[2] = KAc;
  qk.X[3] = pp[1]; qk.W[3] = pp[8]; qk.B[3] = pp[9]; qk.Y[3] = KBc;
  conv_qk_all_kernel<<<dim3(16, 2, 64), 256, 0, stream>>>(qk);

  pv_mfma_kernel<<<dim3(16, 4, BATCH), 256, 0, stream>>>(QAt, QBt, KBc, PART1, bsum);
  tpv_mfma_kernel<<<dim3(16, 4, BATCH), 256, 0, stream>>>(QAt, QBt, KAc, PART1 + 4 * M1);
  merge_kernel<<<dim3(16, BATCH, 2), 256, 0, stream>>>(PART1, pp[0], pp[1], Y0A, bsum);

  float* S_c1 = stats;
  float* S_c2 = stats + 2 * SSTR;
  float* S_q  = stats + 4 * SSTR;
  float* S_c4 = stats + 8 * SSTR;
  float* S_c6 = stats + 10 * SSTR;
  float* P_c1 = prep;
  float* P_c2 = prep + 2 * 512;
  float* P_c3 = prep + 4 * 512;
  float* P_sc = prep + 6 * 512;
  float* P_c4 = prep + 8 * 512;
  float* P_c6 = prep + 10 * 512;

  const long SH1 = (long)2 * M1;
  const long SH2 = (long)4 * M1;
  BnArgs ba;

  // conv1: Y0 -> T1  (128->128, OC=2, grid.x = 128/128 = 1)
  conv_mfma_kernel<128, 2, 2, false, 0><<<dim3(1, 512, 2), 256, 0, stream>>>(
      Y0A, wbf + woff[0], T1a, nullptr, S_c1, 128, SH1, 16384, SH1);
  ba.sums[0] = S_c1; ba.gam[0] = pp[11]; ba.bet[0] = pp[12]; ba.dst[0] = P_c1;
  ba.sums[1] = S_c1 + SSTR; ba.gam[1] = pp[17]; ba.bet[1] = pp[18]; ba.dst[1] = P_c1 + 512;
  ba.sums[2] = nullptr; ba.gam[2] = nullptr; ba.bet[2] = nullptr; ba.dst[2] = nullptr;
  ba.sums[3] = nullptr; ba.gam[3] = nullptr; ba.bet[3] = nullptr; ba.dst[3] = nullptr;
  bnprep_kernel<<<2, 256, 0, stream>>>(ba, 128);

  // conv2 (PREBN): T1 -> T2
  conv_mfma_kernel<128, 2, 2, true, 0><<<dim3(1, 512, 2), 256, 0, stream>>>(
      T1a, wbf + woff[2], T2a, P_c1, S_c2, 128, SH1, 16384, SH1);
  ba.sums[0] = S_c2; ba.gam[0] = pp[14]; ba.bet[0] = pp[15]; ba.dst[0] = P_c2;
  ba.sums[1] = S_c2 + SSTR; ba.gam[1] = pp[20]; ba.bet[1] = pp[21]; ba.dst[1] = P_c2 + 512;
  bnprep_kernel<<<2, 256, 0, stream>>>(ba, 128);

  // finish1: O1 = relu(bn(T2) + Y0)
  finish_kernel<128, 1><<<dim3(1024, 2), 256, 0, stream>>>(
      T2a, P_c2, Y0A, nullptr, O1a, SH1, SH1, SH1);

  // conv3 quad: O1 -> {T3a,T5a,T3b,T5b}  (128->256, OC=4, grid.x = 256/256 = 1)
  conv_mfma_kernel<128, 4, 2, false, 1><<<dim3(1, 512, 4), 256, 0, stream>>>(
      O1a, wbf + woff[4], T3a, nullptr, S_q, 256, SH1, 32768, SH2);
  ba.sums[0] = S_q;            ba.gam[0] = pp[23]; ba.bet[0] = pp[24]; ba.dst[0] = P_c3;
  ba.sums[1] = S_q + SSTR;     ba.gam[1] = pp[29]; ba.bet[1] = pp[30]; ba.dst[1] = P_sc;
  ba.sums[2] = S_q + 2 * SSTR; ba.gam[2] = pp[32]; ba.bet[2] = pp[33]; ba.dst[2] = P_c3 + 512;
  ba.sums[3] = S_q + 3 * SSTR; ba.gam[3] = pp[38]; ba.bet[3] = pp[39]; ba.dst[3] = P_sc + 512;
  bnprep_kernel<<<4, 256, 0, stream>>>(ba, 256);

  // conv4 (PREBN): T3 -> T4  (256->256, OC=2, grid.x = 256/128 = 2)
  conv_mfma_kernel<256, 2, 2, true, 0><<<dim3(2, 512, 2), 256, 0, stream>>>(
      T3a, wbf + woff[8], T4a, P_c3, S_c4, 256, (long)8 * M1, 65536, SH2);
  ba.sums[0] = S_c4; ba.gam[0] = pp[26]; ba.bet[0] = pp[27]; ba.dst[0] = P_c4;
  ba.sums[1] = S_c4 + SSTR; ba.gam[1] = pp[35]; ba.bet[1] = pp[36]; ba.dst[1] = P_c4 + 512;
  bnprep_kernel<<<2, 256, 0, stream>>>(ba, 256);

  // finish2: T3 = relu(bn(T4) + bn(T5))
  finish_kernel<256, 2><<<dim3(2048, 2), 256, 0, stream>>>(
      T4a, P_c4, T3a + SH2, P_sc, T3a, SH2, (long)8 * M1, (long)8 * M1);

  // conv6: T3 -> Fb  (256->64, OC=1, grid.x = 64/64 = 1)
  conv_mfma_kernel<256, 1, 2, false, 0><<<dim3(1, 512, 2), 256, 0, stream>>>(
      T3a, wbf + woff[10], Fba, nullptr, S_c6, 64, (long)8 * M1, 16384, (long)M1);
  ba.sums[0] = S_c6; ba.gam[0] = pp[41]; ba.bet[0] = pp[42]; ba.dst[0] = P_c6;
  ba.sums[1] = S_c6 + SSTR; ba.gam[1] = pp[44]; ba.bet[1] = pp[45]; ba.dst[1] = P_c6 + 512;
  bnprep_kernel<<<2, 256, 0, stream>>>(ba, 64);

  writeout_t_kernel<<<dim3(16, BATCH, 2), 256, 0, stream>>>(
      Fba, P_c6, (float*)d_out);
}

// Round 16
// 201.798 us; speedup vs baseline: 4.3656x; 1.2060x over previous
//
#include <hip/hip_runtime.h>
#include <hip/hip_bf16.h>
#include <cstddef>

static constexpr int BATCH = 16;
static constexpr int NCOPY = 16;
static constexpr int SSTR  = NCOPY * 512;   // floats per stat set

typedef __attribute__((ext_vector_type(8))) short bf16x8;
typedef __attribute__((ext_vector_type(4))) float f32x4;

__device__ __forceinline__ unsigned short f2bf(float f) {
  unsigned u = __float_as_uint(f);
  return (unsigned short)((u + 0x7fffu + ((u >> 16) & 1u)) >> 16);  // RNE
}

#define SEL4(dst, arr, idx)                                   \
  do {                                                        \
    if ((idx) == 0) dst = arr[0];                             \
    else if ((idx) == 1) dst = arr[1];                        \
    else if ((idx) == 2) dst = arr[2];                        \
    else dst = arr[3];                                        \
  } while (0)

__global__ void init_kernel(float* __restrict__ t, int n) {
  int i = blockIdx.x * 256 + threadIdx.x;
  if (i < n) t[i] = 0.f;
}

// ---- convert the 12 block-phase weight matrices to bf16 (layout [o][cin]) --
struct WcvtArgs { const float* p[12]; int sz[12]; int off[12]; };
__global__ __launch_bounds__(256)
void wcvt_kernel(WcvtArgs a, unsigned short* __restrict__ dst) {
  const int t = blockIdx.x;
  const float* src = a.p[t];
  unsigned short* d = dst + a.off[t];
  const int sz = a.sz[t];
  for (int i = blockIdx.y * 256 + threadIdx.x; i < sz; i += 16 * 256)
    d[i] = f2bf(src[i]);
}

// ---- bnprep ----------------------------------------------------------------
struct BnArgs { const float* sums[4]; const float* gam[4]; const float* bet[4];
                float* dst[4]; };
__global__ void bnprep_kernel(BnArgs a, int C) {
  const int t = blockIdx.x;
  const float* sums; const float* gam; const float* bet; float* dst;
  SEL4(sums, a.sums, t); SEL4(gam, a.gam, t); SEL4(bet, a.bet, t); SEL4(dst, a.dst, t);
  const int c = threadIdx.x;
  if (c < C) {
    float s0 = 0.f, q0 = 0.f;
#pragma unroll
    for (int p = 0; p < NCOPY; ++p) {
      s0 += sums[p * 512 + c];
      q0 += sums[p * 512 + 256 + c];
    }
    const float invN = 1.f / 16384.f;
    float mm = s0 * invN;
    float vv = q0 * invN - mm * mm;
    float s = gam[c] * rsqrtf(vv + 1e-5f);
    dst[c] = s;
    dst[256 + c] = bet[c] - mm * s;
  }
}

// ---------------- q/k convs (all 4 in one launch) ---------------------------
struct QKArgs { const float* X[4]; const float* W[4]; const float* B[4];
                unsigned short* Y[4]; };
__global__ __launch_bounds__(256)
void conv_qk_all_kernel(QKArgs a) {
  __shared__ float wsT[64][4];
  const int tid = threadIdx.x;
  const int z = blockIdx.z;
  const int which = z >> 4;
  const int b = z & 15;
  const int o0 = blockIdx.x << 2;
  const int px = (blockIdx.y << 9) + (tid << 1);
  const float* W; const float* X; const float* bias; unsigned short* Y;
  SEL4(W, a.W, which); SEL4(X, a.X, which); SEL4(bias, a.B, which); SEL4(Y, a.Y, which);
  {
    int c = tid >> 2, k = tid & 3;
    wsT[c][k] = W[((o0 + k) << 6) + c];
  }
  __syncthreads();
  float acc[4][2] = {};
  const float* xb = X + ((size_t)b << 16) + px;
#pragma unroll 4
  for (int c = 0; c < 64; ++c) {
    float2 xv = *reinterpret_cast<const float2*>(xb + (c << 10));
    float4 w = *reinterpret_cast<const float4*>(wsT[c]);
    acc[0][0] = fmaf(w.x, xv.x, acc[0][0]); acc[0][1] = fmaf(w.x, xv.y, acc[0][1]);
    acc[1][0] = fmaf(w.y, xv.x, acc[1][0]); acc[1][1] = fmaf(w.y, xv.y, acc[1][1]);
    acc[2][0] = fmaf(w.z, xv.x, acc[2][0]); acc[2][1] = fmaf(w.z, xv.y, acc[2][1]);
    acc[3][0] = fmaf(w.w, xv.x, acc[3][0]); acc[3][1] = fmaf(w.w, xv.y, acc[3][1]);
  }
  float b0 = bias[o0], b1 = bias[o0 + 1], b2 = bias[o0 + 2], b3 = bias[o0 + 3];
  if (which < 2) {
    ushort4 v0, v1;
    v0.x = f2bf(acc[0][0] + b0); v0.y = f2bf(acc[1][0] + b1);
    v0.z = f2bf(acc[2][0] + b2); v0.w = f2bf(acc[3][0] + b3);
    v1.x = f2bf(acc[0][1] + b0); v1.y = f2bf(acc[1][1] + b1);
    v1.z = f2bf(acc[2][1] + b2); v1.w = f2bf(acc[3][1] + b3);
    unsigned short* yt = Y + ((size_t)b << 16) + ((size_t)px << 6) + o0;
    *reinterpret_cast<ushort4*>(yt) = v0;
    *reinterpret_cast<ushort4*>(yt + 64) = v1;
  } else {
    float bv[4] = {b0, b1, b2, b3};
#pragma unroll
    for (int k = 0; k < 4; ++k) {
      ushort2 v;
      v.x = f2bf(acc[k][0] + bv[k]); v.y = f2bf(acc[k][1] + bv[k]);
      *reinterpret_cast<ushort2*>(Y + ((size_t)b << 16) + ((size_t)(o0 + k) << 10) + px) = v;
    }
  }
}

// ---- MFMA fused PV ---------------------------------------------------------
__global__ __launch_bounds__(256)
void pv_mfma_kernel(const unsigned short* __restrict__ QAt,
                    const unsigned short* __restrict__ QBt,
                    const unsigned short* __restrict__ KBc,
                    float* __restrict__ PART, float* __restrict__ bsum) {
  __shared__ __align__(16) unsigned short Ai[4096];
  __shared__ __align__(16) unsigned short Bj[4096];
  __shared__ __align__(16) unsigned short Pl[4096];
  __shared__ float red[256];
  const int tid = threadIdx.x;
  const int lane = tid & 63, w = tid >> 6;
  const int g = lane >> 4, m = lane & 15;
  const int i0 = blockIdx.x << 6;
  const int jbase = blockIdx.y << 8;
  const int b = blockIdx.z;
  const size_t nb = (size_t)b << 16;

  {
    const unsigned short* src = QAt + nb + ((size_t)i0 << 6);
#pragma unroll
    for (int s = 0; s < 2; ++s) {
      int idx = tid + (s << 8);
      int n = idx >> 3, cc = idx & 7;
      bf16x8 v = *reinterpret_cast<const bf16x8*>(src + (n << 6) + ((cc ^ (n & 7)) << 3));
      *reinterpret_cast<bf16x8*>(Ai + (idx << 3)) = v;
    }
  }
  f32x4 accO[4];
#pragma unroll
  for (int n = 0; n < 4; ++n) accO[n] = (f32x4){0.f, 0.f, 0.f, 0.f};
  float psum = 0.f;

  for (int jt = 0; jt < 4; ++jt) {
    const int j0 = jbase + (jt << 6);
    __syncthreads();
    {
      const unsigned short* src = QBt + nb + ((size_t)j0 << 6);
#pragma unroll
      for (int s = 0; s < 2; ++s) {
        int idx = tid + (s << 8);
        int n = idx >> 3, cc = idx & 7;
        bf16x8 v = *reinterpret_cast<const bf16x8*>(src + (n << 6) + ((cc ^ (n & 7)) << 3));
        *reinterpret_cast<bf16x8*>(Bj + (idx << 3)) = v;
      }
    }
    __syncthreads();
    const int jrow = (w << 4) | m;
    bf16x8 a0 = *reinterpret_cast<const bf16x8*>(Bj + (jrow << 6) + ((g ^ (jrow & 7)) << 3));
    bf16x8 a1 = *reinterpret_cast<const bf16x8*>(Bj + (jrow << 6) + (((g + 4) ^ (jrow & 7)) << 3));
    f32x4 e[4];
#pragma unroll
    for (int n = 0; n < 4; ++n) {
      const int irow = (n << 4) | m;
      bf16x8 b0v = *reinterpret_cast<const bf16x8*>(Ai + (irow << 6) + ((g ^ (irow & 7)) << 3));
      bf16x8 b1v = *reinterpret_cast<const bf16x8*>(Ai + (irow << 6) + (((g + 4) ^ (irow & 7)) << 3));
      e[n] = (f32x4){0.f, 0.f, 0.f, 0.f};
      e[n] = __builtin_amdgcn_mfma_f32_16x16x32_bf16(a0, b0v, e[n], 0, 0, 0);
      e[n] = __builtin_amdgcn_mfma_f32_16x16x32_bf16(a1, b1v, e[n], 0, 0, 0);
    }
    const int j = (w << 4) | (g << 2);
#pragma unroll
    for (int n = 0; n < 4; ++n) {
      const int irow = (n << 4) | m;
      float p0 = __expf(-e[n][0]), p1 = __expf(-e[n][1]);
      float p2 = __expf(-e[n][2]), p3 = __expf(-e[n][3]);
      psum += (p0 + p1) + (p2 + p3);
      unsigned pk01 = (unsigned)f2bf(p0) | ((unsigned)f2bf(p1) << 16);
      unsigned pk23 = (unsigned)f2bf(p2) | ((unsigned)f2bf(p3) << 16);
      int base = irow << 6;
      int off0 = base + ((((j) >> 3) ^ (irow & 7)) << 3) + (j & 7);
      int off2 = base + ((((j + 2) >> 3) ^ (irow & 7)) << 3) + ((j + 2) & 7);
      *reinterpret_cast<unsigned*>(Pl + off0) = pk01;
      *reinterpret_cast<unsigned*>(Pl + off2) = pk23;
    }
    const int crow = (w << 4) | m;
    const unsigned short* kbp = KBc + nb + ((size_t)crow << 10) + j0 + (g << 3);
    bf16x8 ka0 = *reinterpret_cast<const bf16x8*>(kbp);
    bf16x8 ka1 = *reinterpret_cast<const bf16x8*>(kbp + 32);
    __syncthreads();
#pragma unroll
    for (int n = 0; n < 4; ++n) {
      const int irow = (n << 4) | m;
      bf16x8 p0 = *reinterpret_cast<const bf16x8*>(Pl + (irow << 6) + ((g ^ (irow & 7)) << 3));
      bf16x8 p1 = *reinterpret_cast<const bf16x8*>(Pl + (irow << 6) + (((g + 4) ^ (irow & 7)) << 3));
      accO[n] = __builtin_amdgcn_mfma_f32_16x16x32_bf16(ka0, p0, accO[n], 0, 0, 0);
      accO[n] = __builtin_amdgcn_mfma_f32_16x16x32_bf16(ka1, p1, accO[n], 0, 0, 0);
    }
  }
  float* OUT = PART + ((size_t)blockIdx.y << 20) + ((size_t)(b * 64) << 10);
#pragma unroll
  for (int n = 0; n < 4; ++n) {
    const int ig = i0 + (n << 4) + m;
    const int c = (w << 4) + (g << 2);
#pragma unroll
    for (int r = 0; r < 4; ++r)
      OUT[((size_t)(c + r) << 10) + ig] = accO[n][r];
  }
  red[tid] = psum; __syncthreads();
  for (int s = 128; s > 0; s >>= 1) {
    if (tid < s) red[tid] += red[tid + s];
    __syncthreads();
  }
  if (tid == 0) atomicAdd(bsum + b, red[0]);
}

// ---- MFMA fused PtV --------------------------------------------------------
__global__ __launch_bounds__(256)
void tpv_mfma_kernel(const unsigned short* __restrict__ QAt,
                     const unsigned short* __restrict__ QBt,
                     const unsigned short* __restrict__ KAc,
                     float* __restrict__ PART) {
  __shared__ __align__(16) unsigned short Bj[4096];
  __shared__ __align__(16) unsigned short Ai[4096];
  __shared__ __align__(16) unsigned short Pl[4096];
  const int tid = threadIdx.x;
  const int lane = tid & 63, w = tid >> 6;
  const int g = lane >> 4, m = lane & 15;
  const int j0 = blockIdx.x << 6;
  const int ibase = blockIdx.y << 8;
  const int b = blockIdx.z;
  const size_t nb = (size_t)b << 16;

  {
    const unsigned short* src = QBt + nb + ((size_t)j0 << 6);
#pragma unroll
    for (int s = 0; s < 2; ++s) {
      int idx = tid + (s << 8);
      int n = idx >> 3, cc = idx & 7;
      bf16x8 v = *reinterpret_cast<const bf16x8*>(src + (n << 6) + ((cc ^ (n & 7)) << 3));
      *reinterpret_cast<bf16x8*>(Bj + (idx << 3)) = v;
    }
  }
  f32x4 accO[4];
#pragma unroll
  for (int n = 0; n < 4; ++n) accO[n] = (f32x4){0.f, 0.f, 0.f, 0.f};

  for (int it = 0; it < 4; ++it) {
    const int i0 = ibase + (it << 6);
    __syncthreads();
    {
      const unsigned short* src = QAt + nb + ((size_t)i0 << 6);
#pragma unroll
      for (int s = 0; s < 2; ++s) {
        int idx = tid + (s << 8);
        int n = idx >> 3, cc = idx & 7;
        bf16x8 v = *reinterpret_cast<const bf16x8*>(src + (n << 6) + ((cc ^ (n & 7)) << 3));
        *reinterpret_cast<bf16x8*>(Ai + (idx << 3)) = v;
      }
    }
    __syncthreads();
    const int irow_a = (w << 4) | m;
    bf16x8 a0 = *reinterpret_cast<const bf16x8*>(Ai + (irow_a << 6) + ((g ^ (irow_a & 7)) << 3));
    bf16x8 a1 = *reinterpret_cast<const bf16x8*>(Ai + (irow_a << 6) + (((g + 4) ^ (irow_a & 7)) << 3));
    f32x4 e[4];
#pragma unroll
    for (int n = 0; n < 4; ++n) {
      const int jrow = (n << 4) | m;
      bf16x8 b0v = *reinterpret_cast<const bf16x8*>(Bj + (jrow << 6) + ((g ^ (jrow & 7)) << 3));
      bf16x8 b1v = *reinterpret_cast<const bf16x8*>(Bj + (jrow << 6) + (((g + 4) ^ (jrow & 7)) << 3));
      e[n] = (f32x4){0.f, 0.f, 0.f, 0.f};
      e[n] = __builtin_amdgcn_mfma_f32_16x16x32_bf16(a0, b0v, e[n], 0, 0, 0);
      e[n] = __builtin_amdgcn_mfma_f32_16x16x32_bf16(a1, b1v, e[n], 0, 0, 0);
    }
    const int i = (w << 4) | (g << 2);
#pragma unroll
    for (int n = 0; n < 4; ++n) {
      const int jrow = (n << 4) | m;
      float p0 = __expf(-e[n][0]), p1 = __expf(-e[n][1]);
      float p2 = __expf(-e[n][2]), p3 = __expf(-e[n][3]);
      unsigned pk01 = (unsigned)f2bf(p0) | ((unsigned)f2bf(p1) << 16);
      unsigned pk23 = (unsigned)f2bf(p2) | ((unsigned)f2bf(p3) << 16);
      int base = jrow << 6;
      int off0 = base + ((((i) >> 3) ^ (jrow & 7)) << 3) + (i & 7);
      int off2 = base + ((((i + 2) >> 3) ^ (jrow & 7)) << 3) + ((i + 2) & 7);
      *reinterpret_cast<unsigned*>(Pl + off0) = pk01;
      *reinterpret_cast<unsigned*>(Pl + off2) = pk23;
    }
    const int crow = (w << 4) | m;
    const unsigned short* kap = KAc + nb + ((size_t)crow << 10) + i0 + (g << 3);
    bf16x8 ka0 = *reinterpret_cast<const bf16x8*>(kap);
    bf16x8 ka1 = *reinterpret_cast<const bf16x8*>(kap + 32);
    __syncthreads();
#pragma unroll
    for (int n = 0; n < 4; ++n) {
      const int jrow = (n << 4) | m;
      bf16x8 p0 = *reinterpret_cast<const bf16x8*>(Pl + (jrow << 6) + ((g ^ (jrow & 7)) << 3));
      bf16x8 p1 = *reinterpret_cast<const bf16x8*>(Pl + (jrow << 6) + (((g + 4) ^ (jrow & 7)) << 3));
      accO[n] = __builtin_amdgcn_mfma_f32_16x16x32_bf16(ka0, p0, accO[n], 0, 0, 0);
      accO[n] = __builtin_amdgcn_mfma_f32_16x16x32_bf16(ka1, p1, accO[n], 0, 0, 0);
    }
  }
  float* OUT = PART + ((size_t)blockIdx.y << 20) + ((size_t)(b * 64) << 10);
#pragma unroll
  for (int n = 0; n < 4; ++n) {
    const int jg = j0 + (n << 4) + m;
    const int c = (w << 4) + (g << 2);
#pragma unroll
    for (int r = 0; r < 4; ++r)
      OUT[((size_t)(c + r) << 10) + jg] = accO[n][r];
  }
}

// ---- merge both streams ----------------------------------------------------
__global__ __launch_bounds__(256)
void merge_kernel(const float* __restrict__ PARTb, const float* __restrict__ XA,
                  const float* __restrict__ XB, unsigned short* __restrict__ Y0b,
                  const float* __restrict__ bsum) {
  __shared__ float ts[128][66];
  const int tid = threadIdx.x;
  const int n0 = blockIdx.x << 6;
  const int b = blockIdx.y;
  const int z = blockIdx.z;
  const float invS = 1.f / bsum[b];
  const size_t M1 = (size_t)1 << 20;
  const float* XR = z ? XB : XA;
  const float* PART = PARTb + (size_t)z * 4 * M1;
  unsigned short* Y0 = Y0b + (size_t)z * 2 * M1;
#pragma unroll
  for (int it = 0; it < 4; ++it) {
    int idx = it * 256 + tid;
    int c = idx >> 4, nq = (idx & 15) << 2;
    float4 v = *reinterpret_cast<const float4*>(XR + ((size_t)(b * 64 + c) << 10) + n0 + nq);
    ts[c][nq] = v.x; ts[c][nq + 1] = v.y; ts[c][nq + 2] = v.z; ts[c][nq + 3] = v.w;
  }
#pragma unroll
  for (int it = 0; it < 4; ++it) {
    int idx = it * 256 + tid;
    int c = idx >> 4, nq = (idx & 15) << 2;
    const float* p = PART + ((size_t)(b * 64 + c) << 10) + n0 + nq;
    float4 av = *reinterpret_cast<const float4*>(p);
    float4 b4 = *reinterpret_cast<const float4*>(p + M1);
    float4 c4 = *reinterpret_cast<const float4*>(p + 2 * M1);
    float4 d4 = *reinterpret_cast<const float4*>(p + 3 * M1);
    ts[64 + c][nq]     = ((av.x + b4.x) + (c4.x + d4.x)) * invS;
    ts[64 + c][nq + 1] = ((av.y + b4.y) + (c4.y + d4.y)) * invS;
    ts[64 + c][nq + 2] = ((av.z + b4.z) + (c4.z + d4.z)) * invS;
    ts[64 + c][nq + 3] = ((av.w + b4.w) + (c4.w + d4.w)) * invS;
  }
  __syncthreads();
  const int n = tid >> 2, c0 = (tid & 3) << 5;
  unsigned short* dst = Y0 + ((size_t)(b * 1024 + n0 + n) << 7) + c0;
#pragma unroll
  for (int q8 = 0; q8 < 4; ++q8) {
    const int cb = c0 + (q8 << 3);
    unsigned w0 = (unsigned)f2bf(ts[cb + 0][n]) | ((unsigned)f2bf(ts[cb + 1][n]) << 16);
    unsigned w1 = (unsigned)f2bf(ts[cb + 2][n]) | ((unsigned)f2bf(ts[cb + 3][n]) << 16);
    unsigned w2 = (unsigned)f2bf(ts[cb + 4][n]) | ((unsigned)f2bf(ts[cb + 5][n]) << 16);
    unsigned w3 = (unsigned)f2bf(ts[cb + 6][n]) | ((unsigned)f2bf(ts[cb + 7][n]) << 16);
    *reinterpret_cast<uint4*>(dst + (q8 << 3)) = make_uint4(w0, w1, w2, w3);
  }
}

// ---- MFMA conv v10: LDS-staged X tile (BN applied once at staging) ---------
// Block: 64 n-rows x 64 outputs; 4 waves each own 16 outputs, iterate 4 n-subtiles.
// LDS X layout: [64][CIN] bf16, byte XOR-swizzle ((row&7)<<4).
template<int CIN, bool PREBN, int XDIV>
__global__ __launch_bounds__(256, 4)
void conv_mfma_kernel(const unsigned short* __restrict__ X0,
                      const unsigned short* __restrict__ W0,
                      unsigned short* __restrict__ Y0,
                      const float* __restrict__ pre0,
                      float* __restrict__ sums0,
                      int COUT, long xstr, long wstr, long ystr) {
  constexpr int KS = CIN / 32;
  constexpr int ROWB = CIN * 2;            // LDS bytes per row
  constexpr int CPR = CIN / 8;             // 16B chunks per row
  __shared__ __align__(16) unsigned char Xs[64 * ROWB];
  __shared__ float scs[PREBN ? CIN : 1];
  __shared__ float shs[PREBN ? CIN : 1];
  const int tid = threadIdx.x;
  const int lane = tid & 63, w = tid >> 6;
  const int g = lane >> 4, m = lane & 15;
  const int z = blockIdx.z;
  const int o0 = (blockIdx.x << 6) + (w << 4);
  const int nbase = blockIdx.y << 6;       // 64 rows per block
  const unsigned short* Xin = X0 + (size_t)(z >> XDIV) * xstr;
  const unsigned short* Wb  = W0 + (size_t)z * wstr;
  unsigned short* Yout      = Y0 + (size_t)z * ystr;
  float* sums               = sums0 + (size_t)z * SSTR;
  if (PREBN) {
    const float* pre = pre0 + (size_t)z * 512;
    for (int c = tid; c < CIN; c += 256) {
      scs[c] = pre[c];
      shs[c] = pre[256 + c];
    }
    __syncthreads();
  }
  // ---- stage X tile (coalesced 16B chunks), BN+relu once, swizzled write ---
#pragma unroll
  for (int it = 0; it < (64 * CPR) / 256; ++it) {
    const int idx = it * 256 + tid;
    const int row = idx / CPR;
    const int cc = idx % CPR;
    bf16x8 v = *reinterpret_cast<const bf16x8*>(
        Xin + (size_t)(nbase + row) * CIN + cc * 8);
    if (PREBN) {
      const int c0 = cc * 8;
#pragma unroll
      for (int j = 0; j < 8; ++j) {
        float x = __uint_as_float((unsigned)(unsigned short)v[j] << 16);
        x = fmaxf(fmaf(x, scs[c0 + j], shs[c0 + j]), 0.f);
        v[j] = (short)f2bf(x);
      }
    }
    const int byte = (cc << 4) ^ ((row & 7) << 4);
    *reinterpret_cast<bf16x8*>(Xs + row * ROWB + byte) = v;
  }
  __syncthreads();
  // ---- W fragments in registers ----
  const unsigned short* Wr = Wb + (size_t)(o0 + m) * CIN + (g << 3);
  bf16x8 af[KS];
#pragma unroll
  for (int k = 0; k < KS; ++k) af[k] = *reinterpret_cast<const bf16x8*>(Wr + (k << 5));
  float sr[4] = {0.f, 0.f, 0.f, 0.f}, qr[4] = {0.f, 0.f, 0.f, 0.f};
#pragma unroll
  for (int nt = 0; nt < 4; ++nt) {
    const int row = (nt << 4) + m;
    const unsigned char* lrow = Xs + row * ROWB;
    const int swz = (row & 7) << 4;
    f32x4 acc = (f32x4){0.f, 0.f, 0.f, 0.f};
#pragma unroll
    for (int k = 0; k < KS; ++k) {
      const int byte = ((k << 6) + (g << 4)) ^ swz;
      bf16x8 bv = *reinterpret_cast<const bf16x8*>(lrow + byte);
      acc = __builtin_amdgcn_mfma_f32_16x16x32_bf16(af[k], bv, acc, 0, 0, 0);
    }
    ushort4 v;
    v.x = f2bf(acc[0]); v.y = f2bf(acc[1]);
    v.z = f2bf(acc[2]); v.w = f2bf(acc[3]);
    *reinterpret_cast<ushort4*>(Yout + (size_t)(nbase + row) * COUT + o0 + (g << 2)) = v;
#pragma unroll
    for (int r = 0; r < 4; ++r) {
      sr[r] += acc[r];
      qr[r] = fmaf(acc[r], acc[r], qr[r]);
    }
  }
#pragma unroll
  for (int r = 0; r < 4; ++r) {
    for (int off = 1; off < 16; off <<= 1) {
      sr[r] += __shfl_xor(sr[r], off);
      qr[r] += __shfl_xor(qr[r], off);
    }
  }
  if (m == 0) {
    float* dst = sums + (blockIdx.y & (NCOPY - 1)) * 512;
#pragma unroll
    for (int r = 0; r < 4; ++r) {
      atomicAdd(&dst[o0 + (g << 2) + r], sr[r]);
      atomicAdd(&dst[256 + o0 + (g << 2) + r], qr[r]);
    }
  }
}

// ---- finish (stride-batched) -----------------------------------------------
template<int C, int MODE>
__global__ __launch_bounds__(256)
void finish_kernel(const unsigned short* __restrict__ T0, const float* __restrict__ P0b,
                   const unsigned short* __restrict__ S0, const float* __restrict__ P1b,
                   unsigned short* __restrict__ O0,
                   long tstr, long sstr, long ostr) {
  __shared__ float sc0[C], sh0[C];
  __shared__ float sc1[(MODE == 2) ? C : 1], sh1[(MODE == 2) ? C : 1];
  const int tid = threadIdx.x;
  const int z = blockIdx.y;
  const unsigned short* T = T0 + (size_t)z * tstr;
  const unsigned short* S = S0 + (size_t)z * sstr;
  unsigned short* O = O0 + (size_t)z * ostr;
  const float* P0 = P0b + (size_t)z * 512;
  const float* P1 = (MODE == 2) ? (P1b + (size_t)z * 512) : nullptr;
  for (int c = tid; c < C; c += 256) {
    sc0[c] = P0[c]; sh0[c] = P0[256 + c];
    if (MODE == 2) { sc1[c] = P1[c]; sh1[c] = P1[256 + c]; }
  }
  __syncthreads();
  const size_t i8 = ((size_t)blockIdx.x * 256 + tid) << 3;
  const int c0 = (int)(i8 & (size_t)(C - 1));
  uint4 tv = *reinterpret_cast<const uint4*>(T + i8);
  uint4 sv = *reinterpret_cast<const uint4*>(S + i8);
  unsigned tw[4] = {tv.x, tv.y, tv.z, tv.w};
  unsigned sw[4] = {sv.x, sv.y, sv.z, sv.w};
  unsigned ow[4];
#pragma unroll
  for (int jw = 0; jw < 4; ++jw) {
    unsigned r = 0;
#pragma unroll
    for (int h = 0; h < 2; ++h) {
      int c = c0 + jw * 2 + h;
      float x = __uint_as_float(((tw[jw] >> (h * 16)) & 0xffffu) << 16);
      x = fmaf(x, sc0[c], sh0[c]);
      if (MODE == 1) x += __uint_as_float(((sw[jw] >> (h * 16)) & 0xffffu) << 16);
      if (MODE == 2) {
        float y = __uint_as_float(((sw[jw] >> (h * 16)) & 0xffffu) << 16);
        x += fmaf(y, sc1[c], sh1[c]);
      }
      x = fmaxf(x, 0.f);
      r |= ((unsigned)f2bf(x)) << (h * 16);
    }
    ow[jw] = r;
  }
  *reinterpret_cast<uint4*>(O + i8) = make_uint4(ow[0], ow[1], ow[2], ow[3]);
}

// ---- writeout (stride-batched) ---------------------------------------------
__global__ __launch_bounds__(256)
void writeout_t_kernel(const unsigned short* __restrict__ F0,
                       const float* __restrict__ pre0,
                       float* __restrict__ out0) {
  __shared__ float ts[64][66];
  __shared__ float sc[64], sh[64];
  const int tid = threadIdx.x;
  const int z = blockIdx.z;
  const size_t M1 = (size_t)1 << 20;
  const unsigned short* F = F0 + (size_t)z * M1;
  const float* pre = pre0 + (size_t)z * 512;
  float* outp = out0 + (size_t)z * M1;
  if (tid < 64) {
    sc[tid] = pre[tid];
    sh[tid] = pre[256 + tid];
  }
  __syncthreads();
  const int n0 = blockIdx.x << 6;
  const int b = blockIdx.y;
  {
    const int n = tid >> 2, c0 = (tid & 3) << 4;
    const unsigned short* Fr = F + ((size_t)(b * 1024 + n0 + n) << 6) + c0;
    uint4 v0 = *reinterpret_cast<const uint4*>(Fr);
    uint4 v1 = *reinterpret_cast<const uint4*>(Fr + 8);
    unsigned vw[8] = {v0.x, v0.y, v0.z, v0.w, v1.x, v1.y, v1.z, v1.w};
#pragma unroll
    for (int jw = 0; jw < 8; ++jw) {
      int c = c0 + jw * 2;
      float x0 = __uint_as_float((vw[jw] & 0xffffu) << 16);
      float x1 = __uint_as_float((vw[jw] >> 16) << 16);
      ts[c][n] = fmaf(x0, sc[c], sh[c]);
      ts[c + 1][n] = fmaf(x1, sc[c + 1], sh[c + 1]);
    }
  }
  __syncthreads();
  const int c = tid >> 2, nq = (tid & 3) << 4;
  float* orow = outp + ((size_t)(b * 64 + c) << 10) + n0 + nq;
#pragma unroll
  for (int q = 0; q < 4; ++q) {
    float4 ov;
    ov.x = ts[c][nq + q * 4 + 0]; ov.y = ts[c][nq + q * 4 + 1];
    ov.z = ts[c][nq + q * 4 + 2]; ov.w = ts[c][nq + q * 4 + 3];
    *reinterpret_cast<float4*>(orow + q * 4) = ov;
  }
}

// ============================ host side =====================================
extern "C" void kernel_launch(void* const* d_in, const int* in_sizes, int n_in,
                              void* d_out, int out_size, void* d_ws, size_t ws_size,
                              hipStream_t stream) {
  float* wsf = (float*)d_ws;
  const size_t M1 = (size_t)1 << 20;
  const size_t H1 = (size_t)1 << 19;

  unsigned short* QAt = (unsigned short*)wsf;
  unsigned short* QBt = (unsigned short*)(wsf + H1);
  unsigned short* KAc = (unsigned short*)(wsf + 2 * H1);
  unsigned short* KBc = (unsigned short*)(wsf + 3 * H1);
  float* PART1 = wsf + 2 * M1;
  unsigned short* Y0A = (unsigned short*)(wsf + 10 * M1);
  unsigned short* T1a = (unsigned short*)(wsf + 12 * M1);
  unsigned short* T2a = (unsigned short*)(wsf + 14 * M1);
  unsigned short* O1a = (unsigned short*)(wsf + 16 * M1);
  unsigned short* T3a = (unsigned short*)(wsf + 18 * M1);  // T3a,T5a,T3b,T5b @2M-float stride
  unsigned short* T4a = (unsigned short*)(wsf + 26 * M1);  // T4a,T4b @2M-float stride
  unsigned short* Fba = (unsigned short*)(wsf + 30 * M1);  // Fba,Fbb @0.5M-float stride
  float* tail = wsf + 31 * M1;
  float* bsum = tail;
  float* stats = tail + 16;
  float* prep  = stats + 12 * SSTR;
  unsigned short* wbf = (unsigned short*)(prep + 12 * 512);

  const float* pp[46];
  for (int i = 0; i < 46 && i < n_in; ++i) pp[i] = (const float*)d_in[i];

  const int initN = 16 + 12 * SSTR;
  init_kernel<<<(initN + 255) / 256, 256, 0, stream>>>(tail, initN);

  // weight order: w11a,w11b,w12a,w12b,w21a,w2sa,w21b,w2sb,w22a,w22b,woa,wob
  const int widx[12] = {10, 16, 13, 19, 22, 28, 31, 37, 25, 34, 40, 43};
  WcvtArgs wa;
  int woff[12];
  {
    int run = 0;
    for (int i = 0; i < 12; ++i) {
      wa.p[i] = pp[widx[i]];
      wa.sz[i] = in_sizes[widx[i]];
      wa.off[i] = run; woff[i] = run;
      run += in_sizes[widx[i]];
    }
  }
  wcvt_kernel<<<dim3(12, 16), 256, 0, stream>>>(wa, wbf);

  QKArgs qk;
  qk.X[0] = pp[0]; qk.W[0] = pp[2]; qk.B[0] = pp[3]; qk.Y[0] = QAt;
  qk.X[1] = pp[1]; qk.W[1] = pp[4]; qk.B[1] = pp[5]; qk.Y[1] = QBt;
  qk.X[2] = pp[0]; qk.W[2] = pp[6]; qk.B[2] = pp[7]; qk.Y[2] = KAc;
  qk.X[3] = pp[1]; qk.W[3] = pp[8]; qk.B[3] = pp[9]; qk.Y[3] = KBc;
  conv_qk_all_kernel<<<dim3(16, 2, 64), 256, 0, stream>>>(qk);

  pv_mfma_kernel<<<dim3(16, 4, BATCH), 256, 0, stream>>>(QAt, QBt, KBc, PART1, bsum);
  tpv_mfma_kernel<<<dim3(16, 4, BATCH), 256, 0, stream>>>(QAt, QBt, KAc, PART1 + 4 * M1);
  merge_kernel<<<dim3(16, BATCH, 2), 256, 0, stream>>>(PART1, pp[0], pp[1], Y0A, bsum);

  float* S_c1 = stats;
  float* S_c2 = stats + 2 * SSTR;
  float* S_q  = stats + 4 * SSTR;
  float* S_c4 = stats + 8 * SSTR;
  float* S_c6 = stats + 10 * SSTR;
  float* P_c1 = prep;
  float* P_c2 = prep + 2 * 512;
  float* P_c3 = prep + 4 * 512;
  float* P_sc = prep + 6 * 512;
  float* P_c4 = prep + 8 * 512;
  float* P_c6 = prep + 10 * 512;

  const long SH1 = (long)2 * M1;   // 1M-float buffer stride in shorts
  const long SH2 = (long)4 * M1;   // 2M-float buffer stride in shorts
  BnArgs ba;

  // conv1: Y0 -> T1 (128->128)
  conv_mfma_kernel<128, false, 0><<<dim3(2, 256, 2), 256, 0, stream>>>(
      Y0A, wbf + woff[0], T1a, nullptr, S_c1, 128, SH1, 16384, SH1);
  ba.sums[0] = S_c1; ba.gam[0] = pp[11]; ba.bet[0] = pp[12]; ba.dst[0] = P_c1;
  ba.sums[1] = S_c1 + SSTR; ba.gam[1] = pp[17]; ba.bet[1] = pp[18]; ba.dst[1] = P_c1 + 512;
  ba.sums[2] = nullptr; ba.gam[2] = nullptr; ba.bet[2] = nullptr; ba.dst[2] = nullptr;
  ba.sums[3] = nullptr; ba.gam[3] = nullptr; ba.bet[3] = nullptr; ba.dst[3] = nullptr;
  bnprep_kernel<<<2, 256, 0, stream>>>(ba, 128);

  // conv2 (PREBN): T1 -> T2
  conv_mfma_kernel<128, true, 0><<<dim3(2, 256, 2), 256, 0, stream>>>(
      T1a, wbf + woff[2], T2a, P_c1, S_c2, 128, SH1, 16384, SH1);
  ba.sums[0] = S_c2; ba.gam[0] = pp[14]; ba.bet[0] = pp[15]; ba.dst[0] = P_c2;
  ba.sums[1] = S_c2 + SSTR; ba.gam[1] = pp[20]; ba.bet[1] = pp[21]; ba.dst[1] = P_c2 + 512;
  bnprep_kernel<<<2, 256, 0, stream>>>(ba, 128);

  // finish1: O1 = relu(bn(T2) + Y0)
  finish_kernel<128, 1><<<dim3(1024, 2), 256, 0, stream>>>(
      T2a, P_c2, Y0A, nullptr, O1a, SH1, SH1, SH1);

  // conv3 quad: O1 -> {T3a,T5a,T3b,T5b} (128->256)
  conv_mfma_kernel<128, false, 1><<<dim3(4, 256, 4), 256, 0, stream>>>(
      O1a, wbf + woff[4], T3a, nullptr, S_q, 256, SH1, 32768, SH2);
  ba.sums[0] = S_q;            ba.gam[0] = pp[23]; ba.bet[0] = pp[24]; ba.dst[0] = P_c3;
  ba.sums[1] = S_q + SSTR;     ba.gam[1] = pp[29]; ba.bet[1] = pp[30]; ba.dst[1] = P_sc;
  ba.sums[2] = S_q + 2 * SSTR; ba.gam[2] = pp[32]; ba.bet[2] = pp[33]; ba.dst[2] = P_c3 + 512;
  ba.sums[3] = S_q + 3 * SSTR; ba.gam[3] = pp[38]; ba.bet[3] = pp[39]; ba.dst[3] = P_sc + 512;
  bnprep_kernel<<<4, 256, 0, stream>>>(ba, 256);

  // conv4 (PREBN): T3 -> T4 (256->256; T3 z-stride 8M shorts)
  conv_mfma_kernel<256, true, 0><<<dim3(4, 256, 2), 256, 0, stream>>>(
      T3a, wbf + woff[8], T4a, P_c3, S_c4, 256, (long)8 * M1, 65536, SH2);
  ba.sums[0] = S_c4; ba.gam[0] = pp[26]; ba.bet[0] = pp[27]; ba.dst[0] = P_c4;
  ba.sums[1] = S_c4 + SSTR; ba.gam[1] = pp[35]; ba.bet[1] = pp[36]; ba.dst[1] = P_c4 + 512;
  bnprep_kernel<<<2, 256, 0, stream>>>(ba, 256);

  // finish2: T3 = relu(bn(T4) + bn(T5))
  finish_kernel<256, 2><<<dim3(2048, 2), 256, 0, stream>>>(
      T4a, P_c4, T3a + SH2, P_sc, T3a, SH2, (long)8 * M1, (long)8 * M1);

  // conv6: T3 -> Fb (256->64)
  conv_mfma_kernel<256, false, 0><<<dim3(1, 256, 2), 256, 0, stream>>>(
      T3a, wbf + woff[10], Fba, nullptr, S_c6, 64, (long)8 * M1, 16384, (long)M1);
  ba.sums[0] = S_c6; ba.gam[0] = pp[41]; ba.bet[0] = pp[42]; ba.dst[0] = P_c6;
  ba.sums[1] = S_c6 + SSTR; ba.gam[1] = pp[44]; ba.bet[1] = pp[45]; ba.dst[1] = P_c6 + 512;
  bnprep_kernel<<<2, 256, 0, stream>>>(ba, 64);

  writeout_t_kernel<<<dim3(16, BATCH, 2), 256, 0, stream>>>(
      Fba, P_c6, (float*)d_out);
}

// Round 17
// 198.931 us; speedup vs baseline: 4.4285x; 1.0144x over previous
//
#include <hip/hip_runtime.h>
#include <hip/hip_bf16.h>
#include <cstddef>

static constexpr int BATCH = 16;
static constexpr int NCOPY = 16;
static constexpr int SSTR  = NCOPY * 512;   // floats per stat set

typedef __attribute__((ext_vector_type(8))) short bf16x8;
typedef __attribute__((ext_vector_type(4))) float f32x4;

__device__ __forceinline__ unsigned short f2bf(float f) {
  unsigned u = __float_as_uint(f);
  return (unsigned short)((u + 0x7fffu + ((u >> 16) & 1u)) >> 16);  // RNE
}

#define SEL4(dst, arr, idx)                                   \
  do {                                                        \
    if ((idx) == 0) dst = arr[0];                             \
    else if ((idx) == 1) dst = arr[1];                        \
    else if ((idx) == 2) dst = arr[2];                        \
    else dst = arr[3];                                        \
  } while (0)

__global__ void init_kernel(float* __restrict__ t, int n) {
  int i = blockIdx.x * 256 + threadIdx.x;
  if (i < n) t[i] = 0.f;
}

// ---- convert the 12 block-phase weight matrices to bf16 (layout [o][cin]) --
struct WcvtArgs { const float* p[12]; int sz[12]; int off[12]; };
__global__ __launch_bounds__(256)
void wcvt_kernel(WcvtArgs a, unsigned short* __restrict__ dst) {
  const int t = blockIdx.x;
  const float* src = a.p[t];
  unsigned short* d = dst + a.off[t];
  const int sz = a.sz[t];
  for (int i = blockIdx.y * 256 + threadIdx.x; i < sz; i += 16 * 256)
    d[i] = f2bf(src[i]);
}

// ---------------- q/k convs (all 4 in one launch) ---------------------------
struct QKArgs { const float* X[4]; const float* W[4]; const float* B[4];
                unsigned short* Y[4]; };
__global__ __launch_bounds__(256)
void conv_qk_all_kernel(QKArgs a) {
  __shared__ float wsT[64][4];
  const int tid = threadIdx.x;
  const int z = blockIdx.z;
  const int which = z >> 4;
  const int b = z & 15;
  const int o0 = blockIdx.x << 2;
  const int px = (blockIdx.y << 9) + (tid << 1);
  const float* W; const float* X; const float* bias; unsigned short* Y;
  SEL4(W, a.W, which); SEL4(X, a.X, which); SEL4(bias, a.B, which); SEL4(Y, a.Y, which);
  {
    int c = tid >> 2, k = tid & 3;
    wsT[c][k] = W[((o0 + k) << 6) + c];
  }
  __syncthreads();
  float acc[4][2] = {};
  const float* xb = X + ((size_t)b << 16) + px;
#pragma unroll 4
  for (int c = 0; c < 64; ++c) {
    float2 xv = *reinterpret_cast<const float2*>(xb + (c << 10));
    float4 w = *reinterpret_cast<const float4*>(wsT[c]);
    acc[0][0] = fmaf(w.x, xv.x, acc[0][0]); acc[0][1] = fmaf(w.x, xv.y, acc[0][1]);
    acc[1][0] = fmaf(w.y, xv.x, acc[1][0]); acc[1][1] = fmaf(w.y, xv.y, acc[1][1]);
    acc[2][0] = fmaf(w.z, xv.x, acc[2][0]); acc[2][1] = fmaf(w.z, xv.y, acc[2][1]);
    acc[3][0] = fmaf(w.w, xv.x, acc[3][0]); acc[3][1] = fmaf(w.w, xv.y, acc[3][1]);
  }
  float b0 = bias[o0], b1 = bias[o0 + 1], b2 = bias[o0 + 2], b3 = bias[o0 + 3];
  if (which < 2) {
    ushort4 v0, v1;
    v0.x = f2bf(acc[0][0] + b0); v0.y = f2bf(acc[1][0] + b1);
    v0.z = f2bf(acc[2][0] + b2); v0.w = f2bf(acc[3][0] + b3);
    v1.x = f2bf(acc[0][1] + b0); v1.y = f2bf(acc[1][1] + b1);
    v1.z = f2bf(acc[2][1] + b2); v1.w = f2bf(acc[3][1] + b3);
    unsigned short* yt = Y + ((size_t)b << 16) + ((size_t)px << 6) + o0;
    *reinterpret_cast<ushort4*>(yt) = v0;
    *reinterpret_cast<ushort4*>(yt + 64) = v1;
  } else {
    float bv[4] = {b0, b1, b2, b3};
#pragma unroll
    for (int k = 0; k < 4; ++k) {
      ushort2 v;
      v.x = f2bf(acc[k][0] + bv[k]); v.y = f2bf(acc[k][1] + bv[k]);
      *reinterpret_cast<ushort2*>(Y + ((size_t)b << 16) + ((size_t)(o0 + k) << 10) + px) = v;
    }
  }
}

// ---- MFMA fused PV ---------------------------------------------------------
__global__ __launch_bounds__(256)
void pv_mfma_kernel(const unsigned short* __restrict__ QAt,
                    const unsigned short* __restrict__ QBt,
                    const unsigned short* __restrict__ KBc,
                    float* __restrict__ PART, float* __restrict__ bsum) {
  __shared__ __align__(16) unsigned short Ai[4096];
  __shared__ __align__(16) unsigned short Bj[4096];
  __shared__ __align__(16) unsigned short Pl[4096];
  __shared__ float red[256];
  const int tid = threadIdx.x;
  const int lane = tid & 63, w = tid >> 6;
  const int g = lane >> 4, m = lane & 15;
  const int i0 = blockIdx.x << 6;
  const int jbase = blockIdx.y << 8;
  const int b = blockIdx.z;
  const size_t nb = (size_t)b << 16;

  {
    const unsigned short* src = QAt + nb + ((size_t)i0 << 6);
#pragma unroll
    for (int s = 0; s < 2; ++s) {
      int idx = tid + (s << 8);
      int n = idx >> 3, cc = idx & 7;
      bf16x8 v = *reinterpret_cast<const bf16x8*>(src + (n << 6) + ((cc ^ (n & 7)) << 3));
      *reinterpret_cast<bf16x8*>(Ai + (idx << 3)) = v;
    }
  }
  f32x4 accO[4];
#pragma unroll
  for (int n = 0; n < 4; ++n) accO[n] = (f32x4){0.f, 0.f, 0.f, 0.f};
  float psum = 0.f;

  for (int jt = 0; jt < 4; ++jt) {
    const int j0 = jbase + (jt << 6);
    __syncthreads();
    {
      const unsigned short* src = QBt + nb + ((size_t)j0 << 6);
#pragma unroll
      for (int s = 0; s < 2; ++s) {
        int idx = tid + (s << 8);
        int n = idx >> 3, cc = idx & 7;
        bf16x8 v = *reinterpret_cast<const bf16x8*>(src + (n << 6) + ((cc ^ (n & 7)) << 3));
        *reinterpret_cast<bf16x8*>(Bj + (idx << 3)) = v;
      }
    }
    __syncthreads();
    const int jrow = (w << 4) | m;
    bf16x8 a0 = *reinterpret_cast<const bf16x8*>(Bj + (jrow << 6) + ((g ^ (jrow & 7)) << 3));
    bf16x8 a1 = *reinterpret_cast<const bf16x8*>(Bj + (jrow << 6) + (((g + 4) ^ (jrow & 7)) << 3));
    f32x4 e[4];
#pragma unroll
    for (int n = 0; n < 4; ++n) {
      const int irow = (n << 4) | m;
      bf16x8 b0v = *reinterpret_cast<const bf16x8*>(Ai + (irow << 6) + ((g ^ (irow & 7)) << 3));
      bf16x8 b1v = *reinterpret_cast<const bf16x8*>(Ai + (irow << 6) + (((g + 4) ^ (irow & 7)) << 3));
      e[n] = (f32x4){0.f, 0.f, 0.f, 0.f};
      e[n] = __builtin_amdgcn_mfma_f32_16x16x32_bf16(a0, b0v, e[n], 0, 0, 0);
      e[n] = __builtin_amdgcn_mfma_f32_16x16x32_bf16(a1, b1v, e[n], 0, 0, 0);
    }
    const int j = (w << 4) | (g << 2);
#pragma unroll
    for (int n = 0; n < 4; ++n) {
      const int irow = (n << 4) | m;
      float p0 = __expf(-e[n][0]), p1 = __expf(-e[n][1]);
      float p2 = __expf(-e[n][2]), p3 = __expf(-e[n][3]);
      psum += (p0 + p1) + (p2 + p3);
      unsigned pk01 = (unsigned)f2bf(p0) | ((unsigned)f2bf(p1) << 16);
      unsigned pk23 = (unsigned)f2bf(p2) | ((unsigned)f2bf(p3) << 16);
      int base = irow << 6;
      int off0 = base + ((((j) >> 3) ^ (irow & 7)) << 3) + (j & 7);
      int off2 = base + ((((j + 2) >> 3) ^ (irow & 7)) << 3) + ((j + 2) & 7);
      *reinterpret_cast<unsigned*>(Pl + off0) = pk01;
      *reinterpret_cast<unsigned*>(Pl + off2) = pk23;
    }
    const int crow = (w << 4) | m;
    const unsigned short* kbp = KBc + nb + ((size_t)crow << 10) + j0 + (g << 3);
    bf16x8 ka0 = *reinterpret_cast<const bf16x8*>(kbp);
    bf16x8 ka1 = *reinterpret_cast<const bf16x8*>(kbp + 32);
    __syncthreads();
#pragma unroll
    for (int n = 0; n < 4; ++n) {
      const int irow = (n << 4) | m;
      bf16x8 p0 = *reinterpret_cast<const bf16x8*>(Pl + (irow << 6) + ((g ^ (irow & 7)) << 3));
      bf16x8 p1 = *reinterpret_cast<const bf16x8*>(Pl + (irow << 6) + (((g + 4) ^ (irow & 7)) << 3));
      accO[n] = __builtin_amdgcn_mfma_f32_16x16x32_bf16(ka0, p0, accO[n], 0, 0, 0);
      accO[n] = __builtin_amdgcn_mfma_f32_16x16x32_bf16(ka1, p1, accO[n], 0, 0, 0);
    }
  }
  float* OUT = PART + ((size_t)blockIdx.y << 20) + ((size_t)(b * 64) << 10);
#pragma unroll
  for (int n = 0; n < 4; ++n) {
    const int ig = i0 + (n << 4) + m;
    const int c = (w << 4) + (g << 2);
#pragma unroll
    for (int r = 0; r < 4; ++r)
      OUT[((size_t)(c + r) << 10) + ig] = accO[n][r];
  }
  red[tid] = psum; __syncthreads();
  for (int s = 128; s > 0; s >>= 1) {
    if (tid < s) red[tid] += red[tid + s];
    __syncthreads();
  }
  if (tid == 0) atomicAdd(bsum + b, red[0]);
}

// ---- MFMA fused PtV --------------------------------------------------------
__global__ __launch_bounds__(256)
void tpv_mfma_kernel(const unsigned short* __restrict__ QAt,
                     const unsigned short* __restrict__ QBt,
                     const unsigned short* __restrict__ KAc,
                     float* __restrict__ PART) {
  __shared__ __align__(16) unsigned short Bj[4096];
  __shared__ __align__(16) unsigned short Ai[4096];
  __shared__ __align__(16) unsigned short Pl[4096];
  const int tid = threadIdx.x;
  const int lane = tid & 63, w = tid >> 6;
  const int g = lane >> 4, m = lane & 15;
  const int j0 = blockIdx.x << 6;
  const int ibase = blockIdx.y << 8;
  const int b = blockIdx.z;
  const size_t nb = (size_t)b << 16;

  {
    const unsigned short* src = QBt + nb + ((size_t)j0 << 6);
#pragma unroll
    for (int s = 0; s < 2; ++s) {
      int idx = tid + (s << 8);
      int n = idx >> 3, cc = idx & 7;
      bf16x8 v = *reinterpret_cast<const bf16x8*>(src + (n << 6) + ((cc ^ (n & 7)) << 3));
      *reinterpret_cast<bf16x8*>(Bj + (idx << 3)) = v;
    }
  }
  f32x4 accO[4];
#pragma unroll
  for (int n = 0; n < 4; ++n) accO[n] = (f32x4){0.f, 0.f, 0.f, 0.f};

  for (int it = 0; it < 4; ++it) {
    const int i0 = ibase + (it << 6);
    __syncthreads();
    {
      const unsigned short* src = QAt + nb + ((size_t)i0 << 6);
#pragma unroll
      for (int s = 0; s < 2; ++s) {
        int idx = tid + (s << 8);
        int n = idx >> 3, cc = idx & 7;
        bf16x8 v = *reinterpret_cast<const bf16x8*>(src + (n << 6) + ((cc ^ (n & 7)) << 3));
        *reinterpret_cast<bf16x8*>(Ai + (idx << 3)) = v;
      }
    }
    __syncthreads();
    const int irow_a = (w << 4) | m;
    bf16x8 a0 = *reinterpret_cast<const bf16x8*>(Ai + (irow_a << 6) + ((g ^ (irow_a & 7)) << 3));
    bf16x8 a1 = *reinterpret_cast<const bf16x8*>(Ai + (irow_a << 6) + (((g + 4) ^ (irow_a & 7)) << 3));
    f32x4 e[4];
#pragma unroll
    for (int n = 0; n < 4; ++n) {
      const int jrow = (n << 4) | m;
      bf16x8 b0v = *reinterpret_cast<const bf16x8*>(Bj + (jrow << 6) + ((g ^ (jrow & 7)) << 3));
      bf16x8 b1v = *reinterpret_cast<const bf16x8*>(Bj + (jrow << 6) + (((g + 4) ^ (jrow & 7)) << 3));
      e[n] = (f32x4){0.f, 0.f, 0.f, 0.f};
      e[n] = __builtin_amdgcn_mfma_f32_16x16x32_bf16(a0, b0v, e[n], 0, 0, 0);
      e[n] = __builtin_amdgcn_mfma_f32_16x16x32_bf16(a1, b1v, e[n], 0, 0, 0);
    }
    const int i = (w << 4) | (g << 2);
#pragma unroll
    for (int n = 0; n < 4; ++n) {
      const int jrow = (n << 4) | m;
      float p0 = __expf(-e[n][0]), p1 = __expf(-e[n][1]);
      float p2 = __expf(-e[n][2]), p3 = __expf(-e[n][3]);
      unsigned pk01 = (unsigned)f2bf(p0) | ((unsigned)f2bf(p1) << 16);
      unsigned pk23 = (unsigned)f2bf(p2) | ((unsigned)f2bf(p3) << 16);
      int base = jrow << 6;
      int off0 = base + ((((i) >> 3) ^ (jrow & 7)) << 3) + (i & 7);
      int off2 = base + ((((i + 2) >> 3) ^ (jrow & 7)) << 3) + ((i + 2) & 7);
      *reinterpret_cast<unsigned*>(Pl + off0) = pk01;
      *reinterpret_cast<unsigned*>(Pl + off2) = pk23;
    }
    const int crow = (w << 4) | m;
    const unsigned short* kap = KAc + nb + ((size_t)crow << 10) + i0 + (g << 3);
    bf16x8 ka0 = *reinterpret_cast<const bf16x8*>(kap);
    bf16x8 ka1 = *reinterpret_cast<const bf16x8*>(kap + 32);
    __syncthreads();
#pragma unroll
    for (int n = 0; n < 4; ++n) {
      const int jrow = (n << 4) | m;
      bf16x8 p0 = *reinterpret_cast<const bf16x8*>(Pl + (jrow << 6) + ((g ^ (jrow & 7)) << 3));
      bf16x8 p1 = *reinterpret_cast<const bf16x8*>(Pl + (jrow << 6) + (((g + 4) ^ (jrow & 7)) << 3));
      accO[n] = __builtin_amdgcn_mfma_f32_16x16x32_bf16(ka0, p0, accO[n], 0, 0, 0);
      accO[n] = __builtin_amdgcn_mfma_f32_16x16x32_bf16(ka1, p1, accO[n], 0, 0, 0);
    }
  }
  float* OUT = PART + ((size_t)blockIdx.y << 20) + ((size_t)(b * 64) << 10);
#pragma unroll
  for (int n = 0; n < 4; ++n) {
    const int jg = j0 + (n << 4) + m;
    const int c = (w << 4) + (g << 2);
#pragma unroll
    for (int r = 0; r < 4; ++r)
      OUT[((size_t)(c + r) << 10) + jg] = accO[n][r];
  }
}

// ---- merge both streams ----------------------------------------------------
__global__ __launch_bounds__(256)
void merge_kernel(const float* __restrict__ PARTb, const float* __restrict__ XA,
                  const float* __restrict__ XB, unsigned short* __restrict__ Y0b,
                  const float* __restrict__ bsum) {
  __shared__ float ts[128][66];
  const int tid = threadIdx.x;
  const int n0 = blockIdx.x << 6;
  const int b = blockIdx.y;
  const int z = blockIdx.z;
  const float invS = 1.f / bsum[b];
  const size_t M1 = (size_t)1 << 20;
  const float* XR = z ? XB : XA;
  const float* PART = PARTb + (size_t)z * 4 * M1;
  unsigned short* Y0 = Y0b + (size_t)z * 2 * M1;
#pragma unroll
  for (int it = 0; it < 4; ++it) {
    int idx = it * 256 + tid;
    int c = idx >> 4, nq = (idx & 15) << 2;
    float4 v = *reinterpret_cast<const float4*>(XR + ((size_t)(b * 64 + c) << 10) + n0 + nq);
    ts[c][nq] = v.x; ts[c][nq + 1] = v.y; ts[c][nq + 2] = v.z; ts[c][nq + 3] = v.w;
  }
#pragma unroll
  for (int it = 0; it < 4; ++it) {
    int idx = it * 256 + tid;
    int c = idx >> 4, nq = (idx & 15) << 2;
    const float* p = PART + ((size_t)(b * 64 + c) << 10) + n0 + nq;
    float4 av = *reinterpret_cast<const float4*>(p);
    float4 b4 = *reinterpret_cast<const float4*>(p + M1);
    float4 c4 = *reinterpret_cast<const float4*>(p + 2 * M1);
    float4 d4 = *reinterpret_cast<const float4*>(p + 3 * M1);
    ts[64 + c][nq]     = ((av.x + b4.x) + (c4.x + d4.x)) * invS;
    ts[64 + c][nq + 1] = ((av.y + b4.y) + (c4.y + d4.y)) * invS;
    ts[64 + c][nq + 2] = ((av.z + b4.z) + (c4.z + d4.z)) * invS;
    ts[64 + c][nq + 3] = ((av.w + b4.w) + (c4.w + d4.w)) * invS;
  }
  __syncthreads();
  const int n = tid >> 2, c0 = (tid & 3) << 5;
  unsigned short* dst = Y0 + ((size_t)(b * 1024 + n0 + n) << 7) + c0;
#pragma unroll
  for (int q8 = 0; q8 < 4; ++q8) {
    const int cb = c0 + (q8 << 3);
    unsigned w0 = (unsigned)f2bf(ts[cb + 0][n]) | ((unsigned)f2bf(ts[cb + 1][n]) << 16);
    unsigned w1 = (unsigned)f2bf(ts[cb + 2][n]) | ((unsigned)f2bf(ts[cb + 3][n]) << 16);
    unsigned w2 = (unsigned)f2bf(ts[cb + 4][n]) | ((unsigned)f2bf(ts[cb + 5][n]) << 16);
    unsigned w3 = (unsigned)f2bf(ts[cb + 6][n]) | ((unsigned)f2bf(ts[cb + 7][n]) << 16);
    *reinterpret_cast<uint4*>(dst + (q8 << 3)) = make_uint4(w0, w1, w2, w3);
  }
}

// ---- gamma/beta pointer sets (per z, uniform SEL4) -------------------------
struct GBArgs { const float* g0[4]; const float* b0[4];
                const float* g1[4]; const float* b1[4]; };

// ---- MFMA conv v11: LDS-staged X tile with fused BN/residual epilogues -----
// SMODE: 0 plain copy; 1 relu(bn0(T)); 2 relu(bn0(T)+S); 3 relu(bn0(T)+bn1(S))
// Per-block bnprep fold is done inline from NCOPY-spread sums.
template<int CIN, int SMODE, int XDIV>
__global__ __launch_bounds__(256, 4)
void conv_mfma_kernel(const unsigned short* __restrict__ T0,
                      const unsigned short* __restrict__ S0,
                      const unsigned short* __restrict__ W0,
                      unsigned short* __restrict__ Yout0,
                      const float* __restrict__ sums0A, long s0str,
                      const float* __restrict__ sums1A, long s1str,
                      GBArgs gb,
                      float* __restrict__ outSums0,
                      int COUT, long tstr, long sstr, long wstr, long ystr) {
  constexpr int KS = CIN / 32;
  constexpr int ROWB = CIN * 2;
  constexpr int CPR = CIN / 8;
  __shared__ __align__(16) unsigned char Xs[64 * ROWB];
  __shared__ float scs[(SMODE >= 1) ? CIN : 1];
  __shared__ float shs[(SMODE >= 1) ? CIN : 1];
  __shared__ float sc2[(SMODE == 3) ? CIN : 1];
  __shared__ float sh2[(SMODE == 3) ? CIN : 1];
  const int tid = threadIdx.x;
  const int lane = tid & 63, w = tid >> 6;
  const int g = lane >> 4, m = lane & 15;
  const int z = blockIdx.z;
  const int zi = z >> XDIV;
  const int o0 = (blockIdx.x << 6) + (w << 4);
  const int nbase = blockIdx.y << 6;
  const unsigned short* Tin = T0 + (size_t)zi * tstr;
  const unsigned short* Sin = (SMODE >= 2) ? (S0 + (size_t)zi * sstr) : nullptr;
  const unsigned short* Wb  = W0 + (size_t)z * wstr;
  unsigned short* Yout      = Yout0 + (size_t)z * ystr;
  float* outSums            = outSums0 + (size_t)z * SSTR;
  if (SMODE >= 1) {
    const float* s0 = sums0A + (size_t)zi * s0str;
    const float* gg0; const float* bb0;
    SEL4(gg0, gb.g0, zi); SEL4(bb0, gb.b0, zi);
    const float invN = 1.f / 16384.f;
    for (int c = tid; c < CIN; c += 256) {
      float ss = 0.f, qq = 0.f;
#pragma unroll
      for (int p = 0; p < NCOPY; ++p) {
        ss += s0[p * 512 + c];
        qq += s0[p * 512 + 256 + c];
      }
      float mm = ss * invN;
      float vv = qq * invN - mm * mm;
      float s = gg0[c] * rsqrtf(vv + 1e-5f);
      scs[c] = s; shs[c] = bb0[c] - mm * s;
    }
    if (SMODE == 3) {
      const float* s1 = sums1A + (size_t)zi * s1str;
      const float* gg1; const float* bb1;
      SEL4(gg1, gb.g1, zi); SEL4(bb1, gb.b1, zi);
      for (int c = tid; c < CIN; c += 256) {
        float ss = 0.f, qq = 0.f;
#pragma unroll
        for (int p = 0; p < NCOPY; ++p) {
          ss += s1[p * 512 + c];
          qq += s1[p * 512 + 256 + c];
        }
        float mm = ss * invN;
        float vv = qq * invN - mm * mm;
        float s = gg1[c] * rsqrtf(vv + 1e-5f);
        sc2[c] = s; sh2[c] = bb1[c] - mm * s;
      }
    }
    __syncthreads();
  }
  // ---- stage tile: epilogue applied once, swizzled write -------------------
#pragma unroll
  for (int it = 0; it < (64 * CPR) / 256; ++it) {
    const int idx = it * 256 + tid;
    const int row = idx / CPR;
    const int cc = idx % CPR;
    bf16x8 v = *reinterpret_cast<const bf16x8*>(
        Tin + (size_t)(nbase + row) * CIN + cc * 8);
    if (SMODE >= 1) {
      bf16x8 sv;
      if (SMODE >= 2)
        sv = *reinterpret_cast<const bf16x8*>(
            Sin + (size_t)(nbase + row) * CIN + cc * 8);
      const int c0 = cc * 8;
#pragma unroll
      for (int j = 0; j < 8; ++j) {
        float x = __uint_as_float((unsigned)(unsigned short)v[j] << 16);
        x = fmaf(x, scs[c0 + j], shs[c0 + j]);
        if (SMODE == 2)
          x += __uint_as_float((unsigned)(unsigned short)sv[j] << 16);
        if (SMODE == 3) {
          float y = __uint_as_float((unsigned)(unsigned short)sv[j] << 16);
          x += fmaf(y, sc2[c0 + j], sh2[c0 + j]);
        }
        x = fmaxf(x, 0.f);
        v[j] = (short)f2bf(x);
      }
    }
    const int byte = (cc << 4) ^ ((row & 7) << 4);
    *reinterpret_cast<bf16x8*>(Xs + row * ROWB + byte) = v;
  }
  __syncthreads();
  // ---- W fragments in registers ----
  const unsigned short* Wr = Wb + (size_t)(o0 + m) * CIN + (g << 3);
  bf16x8 af[KS];
#pragma unroll
  for (int k = 0; k < KS; ++k) af[k] = *reinterpret_cast<const bf16x8*>(Wr + (k << 5));
  float sr[4] = {0.f, 0.f, 0.f, 0.f}, qr[4] = {0.f, 0.f, 0.f, 0.f};
#pragma unroll
  for (int nt = 0; nt < 4; ++nt) {
    const int row = (nt << 4) + m;
    const unsigned char* lrow = Xs + row * ROWB;
    const int swz = (row & 7) << 4;
    f32x4 acc = (f32x4){0.f, 0.f, 0.f, 0.f};
#pragma unroll
    for (int k = 0; k < KS; ++k) {
      const int byte = ((k << 6) + (g << 4)) ^ swz;
      bf16x8 bv = *reinterpret_cast<const bf16x8*>(lrow + byte);
      acc = __builtin_amdgcn_mfma_f32_16x16x32_bf16(af[k], bv, acc, 0, 0, 0);
    }
    ushort4 v;
    v.x = f2bf(acc[0]); v.y = f2bf(acc[1]);
    v.z = f2bf(acc[2]); v.w = f2bf(acc[3]);
    *reinterpret_cast<ushort4*>(Yout + (size_t)(nbase + row) * COUT + o0 + (g << 2)) = v;
#pragma unroll
    for (int r = 0; r < 4; ++r) {
      sr[r] += acc[r];
      qr[r] = fmaf(acc[r], acc[r], qr[r]);
    }
  }
#pragma unroll
  for (int r = 0; r < 4; ++r) {
    for (int off = 1; off < 16; off <<= 1) {
      sr[r] += __shfl_xor(sr[r], off);
      qr[r] += __shfl_xor(qr[r], off);
    }
  }
  if (m == 0) {
    float* dst = outSums + (blockIdx.y & (NCOPY - 1)) * 512;
#pragma unroll
    for (int r = 0; r < 4; ++r) {
      atomicAdd(&dst[o0 + (g << 2) + r], sr[r]);
      atomicAdd(&dst[256 + o0 + (g << 2) + r], qr[r]);
    }
  }
}

// ---- writeout: fold conv6 stats inline, bn, LDS transpose, f32 out ---------
__global__ __launch_bounds__(256)
void writeout_t_kernel(const unsigned short* __restrict__ F0,
                       const float* __restrict__ sumsA,
                       GBArgs gb,
                       float* __restrict__ out0) {
  __shared__ float ts[64][66];
  __shared__ float sc[64], sh[64];
  const int tid = threadIdx.x;
  const int z = blockIdx.z;
  const size_t M1 = (size_t)1 << 20;
  const unsigned short* F = F0 + (size_t)z * M1;
  float* outp = out0 + (size_t)z * M1;
  if (tid < 64) {
    const float* sums = sumsA + (size_t)z * SSTR;
    const float* gg; const float* bb;
    SEL4(gg, gb.g0, z); SEL4(bb, gb.b0, z);
    float s0 = 0.f, q0 = 0.f;
#pragma unroll
    for (int p = 0; p < NCOPY; ++p) {
      s0 += sums[p * 512 + tid];
      q0 += sums[p * 512 + 256 + tid];
    }
    const float invN = 1.f / 16384.f;
    float mm = s0 * invN;
    float vv = q0 * invN - mm * mm;
    float s = gg[tid] * rsqrtf(vv + 1e-5f);
    sc[tid] = s; sh[tid] = bb[tid] - mm * s;
  }
  __syncthreads();
  const int n0 = blockIdx.x << 6;
  const int b = blockIdx.y;
  {
    const int n = tid >> 2, c0 = (tid & 3) << 4;
    const unsigned short* Fr = F + ((size_t)(b * 1024 + n0 + n) << 6) + c0;
    uint4 v0 = *reinterpret_cast<const uint4*>(Fr);
    uint4 v1 = *reinterpret_cast<const uint4*>(Fr + 8);
    unsigned vw[8] = {v0.x, v0.y, v0.z, v0.w, v1.x, v1.y, v1.z, v1.w};
#pragma unroll
    for (int jw = 0; jw < 8; ++jw) {
      int c = c0 + jw * 2;
      float x0 = __uint_as_float((vw[jw] & 0xffffu) << 16);
      float x1 = __uint_as_float((vw[jw] >> 16) << 16);
      ts[c][n] = fmaf(x0, sc[c], sh[c]);
      ts[c + 1][n] = fmaf(x1, sc[c + 1], sh[c + 1]);
    }
  }
  __syncthreads();
  const int c = tid >> 2, nq = (tid & 3) << 4;
  float* orow = outp + ((size_t)(b * 64 + c) << 10) + n0 + nq;
#pragma unroll
  for (int q = 0; q < 4; ++q) {
    float4 ov;
    ov.x = ts[c][nq + q * 4 + 0]; ov.y = ts[c][nq + q * 4 + 1];
    ov.z = ts[c][nq + q * 4 + 2]; ov.w = ts[c][nq + q * 4 + 3];
    *reinterpret_cast<float4*>(orow + q * 4) = ov;
  }
}

// ============================ host side =====================================
extern "C" void kernel_launch(void* const* d_in, const int* in_sizes, int n_in,
                              void* d_out, int out_size, void* d_ws, size_t ws_size,
                              hipStream_t stream) {
  float* wsf = (float*)d_ws;
  const size_t M1 = (size_t)1 << 20;
  const size_t H1 = (size_t)1 << 19;

  unsigned short* QAt = (unsigned short*)wsf;
  unsigned short* QBt = (unsigned short*)(wsf + H1);
  unsigned short* KAc = (unsigned short*)(wsf + 2 * H1);
  unsigned short* KBc = (unsigned short*)(wsf + 3 * H1);
  float* PART1 = wsf + 2 * M1;                             // [2M,10M) both PARTs
  unsigned short* Y0A = (unsigned short*)(wsf + 10 * M1);  // Y0A,Y0B @1M-float stride
  unsigned short* T1a = (unsigned short*)(wsf + 12 * M1);
  unsigned short* T2a = (unsigned short*)(wsf + 14 * M1);
  unsigned short* T3a = (unsigned short*)(wsf + 18 * M1);  // T3a,T5a,T3b,T5b @2M-float stride
  unsigned short* T4a = (unsigned short*)(wsf + 26 * M1);  // T4a,T4b @2M-float stride
  unsigned short* Fba = (unsigned short*)(wsf + 30 * M1);  // Fba,Fbb @0.5M-float stride
  float* tail = wsf + 31 * M1;
  float* bsum = tail;
  float* stats = tail + 16;
  unsigned short* wbf = (unsigned short*)(stats + 12 * SSTR);

  const float* pp[46];
  for (int i = 0; i < 46 && i < n_in; ++i) pp[i] = (const float*)d_in[i];

  const int initN = 16 + 12 * SSTR;
  init_kernel<<<(initN + 255) / 256, 256, 0, stream>>>(tail, initN);

  // weight order: w11a,w11b,w12a,w12b,w21a,w2sa,w21b,w2sb,w22a,w22b,woa,wob
  const int widx[12] = {10, 16, 13, 19, 22, 28, 31, 37, 25, 34, 40, 43};
  WcvtArgs wa;
  int woff[12];
  {
    int run = 0;
    for (int i = 0; i < 12; ++i) {
      wa.p[i] = pp[widx[i]];
      wa.sz[i] = in_sizes[widx[i]];
      wa.off[i] = run; woff[i] = run;
      run += in_sizes[widx[i]];
    }
  }
  wcvt_kernel<<<dim3(12, 16), 256, 0, stream>>>(wa, wbf);

  QKArgs qk;
  qk.X[0] = pp[0]; qk.W[0] = pp[2]; qk.B[0] = pp[3]; qk.Y[0] = QAt;
  qk.X[1] = pp[1]; qk.W[1] = pp[4]; qk.B[1] = pp[5]; qk.Y[1] = QBt;
  qk.X[2] = pp[0]; qk.W[2] = pp[6]; qk.B[2] = pp[7]; qk.Y[2] = KAc;
  qk.X[3] = pp[1]; qk.W[3] = pp[8]; qk.B[3] = pp[9]; qk.Y[3] = KBc;
  conv_qk_all_kernel<<<dim3(16, 2, 64), 256, 0, stream>>>(qk);

  pv_mfma_kernel<<<dim3(16, 4, BATCH), 256, 0, stream>>>(QAt, QBt, KBc, PART1, bsum);
  tpv_mfma_kernel<<<dim3(16, 4, BATCH), 256, 0, stream>>>(QAt, QBt, KAc, PART1 + 4 * M1);
  merge_kernel<<<dim3(16, BATCH, 2), 256, 0, stream>>>(PART1, pp[0], pp[1], Y0A, bsum);

  float* S_c1 = stats;               // conv1 (2 z)
  float* S_c2 = stats + 2 * SSTR;    // conv2 (2 z)
  float* S_q  = stats + 4 * SSTR;    // quad (4 z)
  float* S_c4 = stats + 8 * SSTR;    // conv4 (2 z)
  float* S_c6 = stats + 10 * SSTR;   // conv6 (2 z)

  const long SH1 = (long)2 * M1;     // 1M-float stride in shorts
  const long SH2 = (long)4 * M1;     // 2M-float stride in shorts
  GBArgs gbE = {};
  GBArgs gb;

  // conv1 (SMODE0): Y0 -> T1
  conv_mfma_kernel<128, 0, 0><<<dim3(2, 256, 2), 256, 0, stream>>>(
      Y0A, nullptr, wbf + woff[0], T1a, nullptr, 0, nullptr, 0, gbE,
      S_c1, 128, SH1, 0, 16384, SH1);

  // conv2 (SMODE1: bn[conv1 stats, a1_s1/b1 params]): T1 -> T2
  gb = gbE;
  gb.g0[0] = pp[11]; gb.b0[0] = pp[12]; gb.g0[1] = pp[17]; gb.b0[1] = pp[18];
  conv_mfma_kernel<128, 1, 0><<<dim3(2, 256, 2), 256, 0, stream>>>(
      T1a, nullptr, wbf + woff[2], T2a, S_c1, SSTR, nullptr, 0, gb,
      S_c2, 128, SH1, 0, 16384, SH1);

  // quad (SMODE2: relu(bn(T2)+Y0)): -> {T3a,T5a,T3b,T5b}
  gb = gbE;
  gb.g0[0] = pp[14]; gb.b0[0] = pp[15]; gb.g0[1] = pp[20]; gb.b0[1] = pp[21];
  conv_mfma_kernel<128, 2, 1><<<dim3(4, 256, 4), 256, 0, stream>>>(
      T2a, Y0A, wbf + woff[4], T3a, S_c2, SSTR, nullptr, 0, gb,
      S_q, 256, SH1, SH1, 32768, SH2);

  // conv4 (SMODE1: bn[w21 stats (quad z0/z2), a2_s1/b1]): T3 -> T4
  gb = gbE;
  gb.g0[0] = pp[23]; gb.b0[0] = pp[24]; gb.g0[1] = pp[32]; gb.b0[1] = pp[33];
  conv_mfma_kernel<256, 1, 0><<<dim3(4, 256, 2), 256, 0, stream>>>(
      T3a, nullptr, wbf + woff[8], T4a, S_q, 2 * SSTR, nullptr, 0, gb,
      S_c4, 256, (long)8 * M1, 0, 65536, SH2);

  // conv6 (SMODE3: relu(bn(T4)+bn(T5))): -> Fb
  gb = gbE;
  gb.g0[0] = pp[26]; gb.b0[0] = pp[27]; gb.g0[1] = pp[35]; gb.b0[1] = pp[36];
  gb.g1[0] = pp[29]; gb.b1[0] = pp[30]; gb.g1[1] = pp[38]; gb.b1[1] = pp[39];
  conv_mfma_kernel<256, 3, 0><<<dim3(1, 256, 2), 256, 0, stream>>>(
      T4a, T3a + SH2 /*T5a*/, wbf + woff[10], Fba, S_c4, SSTR,
      S_q + SSTR, 2 * SSTR, gb,
      S_c6, 64, SH2, (long)8 * M1, 16384, (long)M1);

  // writeout (folds conv6 stats inline)
  gb = gbE;
  gb.g0[0] = pp[41]; gb.b0[0] = pp[42]; gb.g0[1] = pp[44]; gb.b0[1] = pp[45];
  writeout_t_kernel<<<dim3(16, BATCH, 2), 256, 0, stream>>>(
      Fba, S_c6, gb, (float*)d_out);
}

// Round 18
// 185.511 us; speedup vs baseline: 4.7489x; 1.0723x over previous
//
#include <hip/hip_runtime.h>
#include <hip/hip_bf16.h>
#include <cstddef>

static constexpr int BATCH = 16;
static constexpr int NCOPY = 16;
static constexpr int SSTR  = NCOPY * 512;   // floats per stat set

typedef __attribute__((ext_vector_type(8))) short bf16x8;
typedef __attribute__((ext_vector_type(4))) float f32x4;

__device__ __forceinline__ unsigned short f2bf(float f) {
  unsigned u = __float_as_uint(f);
  return (unsigned short)((u + 0x7fffu + ((u >> 16) & 1u)) >> 16);  // RNE
}

#define SEL4(dst, arr, idx)                                   \
  do {                                                        \
    if ((idx) == 0) dst = arr[0];                             \
    else if ((idx) == 1) dst = arr[1];                        \
    else if ((idx) == 2) dst = arr[2];                        \
    else dst = arr[3];                                        \
  } while (0)

__global__ void init_kernel(float* __restrict__ t, int n) {
  int i = blockIdx.x * 256 + threadIdx.x;
  if (i < n) t[i] = 0.f;
}

// ---- convert the 12 block-phase weight matrices to bf16 (layout [o][cin]) --
struct WcvtArgs { const float* p[12]; int sz[12]; int off[12]; };
__global__ __launch_bounds__(256)
void wcvt_kernel(WcvtArgs a, unsigned short* __restrict__ dst) {
  const int t = blockIdx.x;
  const float* src = a.p[t];
  unsigned short* d = dst + a.off[t];
  const int sz = a.sz[t];
  for (int i = blockIdx.y * 256 + threadIdx.x; i < sz; i += 16 * 256)
    d[i] = f2bf(src[i]);
}

// ---------------- q/k convs (all 4 in one launch) ---------------------------
struct QKArgs { const float* X[4]; const float* W[4]; const float* B[4];
                unsigned short* Y[4]; };
__global__ __launch_bounds__(256)
void conv_qk_all_kernel(QKArgs a) {
  __shared__ float wsT[64][4];
  const int tid = threadIdx.x;
  const int z = blockIdx.z;
  const int which = z >> 4;
  const int b = z & 15;
  const int o0 = blockIdx.x << 2;
  const int px = (blockIdx.y << 9) + (tid << 1);
  const float* W; const float* X; const float* bias; unsigned short* Y;
  SEL4(W, a.W, which); SEL4(X, a.X, which); SEL4(bias, a.B, which); SEL4(Y, a.Y, which);
  {
    int c = tid >> 2, k = tid & 3;
    wsT[c][k] = W[((o0 + k) << 6) + c];
  }
  __syncthreads();
  float acc[4][2] = {};
  const float* xb = X + ((size_t)b << 16) + px;
#pragma unroll 4
  for (int c = 0; c < 64; ++c) {
    float2 xv = *reinterpret_cast<const float2*>(xb + (c << 10));
    float4 w = *reinterpret_cast<const float4*>(wsT[c]);
    acc[0][0] = fmaf(w.x, xv.x, acc[0][0]); acc[0][1] = fmaf(w.x, xv.y, acc[0][1]);
    acc[1][0] = fmaf(w.y, xv.x, acc[1][0]); acc[1][1] = fmaf(w.y, xv.y, acc[1][1]);
    acc[2][0] = fmaf(w.z, xv.x, acc[2][0]); acc[2][1] = fmaf(w.z, xv.y, acc[2][1]);
    acc[3][0] = fmaf(w.w, xv.x, acc[3][0]); acc[3][1] = fmaf(w.w, xv.y, acc[3][1]);
  }
  float b0 = bias[o0], b1 = bias[o0 + 1], b2 = bias[o0 + 2], b3 = bias[o0 + 3];
  if (which < 2) {
    ushort4 v0, v1;
    v0.x = f2bf(acc[0][0] + b0); v0.y = f2bf(acc[1][0] + b1);
    v0.z = f2bf(acc[2][0] + b2); v0.w = f2bf(acc[3][0] + b3);
    v1.x = f2bf(acc[0][1] + b0); v1.y = f2bf(acc[1][1] + b1);
    v1.z = f2bf(acc[2][1] + b2); v1.w = f2bf(acc[3][1] + b3);
    unsigned short* yt = Y + ((size_t)b << 16) + ((size_t)px << 6) + o0;
    *reinterpret_cast<ushort4*>(yt) = v0;
    *reinterpret_cast<ushort4*>(yt + 64) = v1;
  } else {
    float bv[4] = {b0, b1, b2, b3};
#pragma unroll
    for (int k = 0; k < 4; ++k) {
      ushort2 v;
      v.x = f2bf(acc[k][0] + bv[k]); v.y = f2bf(acc[k][1] + bv[k]);
      *reinterpret_cast<ushort2*>(Y + ((size_t)b << 16) + ((size_t)(o0 + k) << 10) + px) = v;
    }
  }
}

// ---- combined MFMA attention: z<16 -> PV (batch z), z>=16 -> PtV (z-16) ----
// 2-way chunk split (blockIdx.y): PV partials at PART[y*1M], PtV at PART[2M + y*1M].
__global__ __launch_bounds__(256)
void attn_mfma_kernel(const unsigned short* __restrict__ QAt,
                      const unsigned short* __restrict__ QBt,
                      const unsigned short* __restrict__ KAc,
                      const unsigned short* __restrict__ KBc,
                      float* __restrict__ PART, float* __restrict__ bsum) {
  __shared__ __align__(16) unsigned short Ua[4096];  // persistent tile
  __shared__ __align__(16) unsigned short Vb[4096];  // streamed tile
  __shared__ __align__(16) unsigned short Pl[4096];  // P tile
  __shared__ float red[256];
  const int tid = threadIdx.x;
  const int lane = tid & 63, w = tid >> 6;
  const int g = lane >> 4, m = lane & 15;
  const int z = blockIdx.z;
  const bool isPV = (z < 16);
  const int b = z & 15;
  const size_t nb = (size_t)b << 16;
  const size_t M1 = (size_t)1 << 20;

  if (isPV) {
    const int i0 = blockIdx.x << 6;
    const int jbase = blockIdx.y << 9;   // 512 j per chunk
    {
      const unsigned short* src = QAt + nb + ((size_t)i0 << 6);
#pragma unroll
      for (int s = 0; s < 2; ++s) {
        int idx = tid + (s << 8);
        int n = idx >> 3, cc = idx & 7;
        bf16x8 v = *reinterpret_cast<const bf16x8*>(src + (n << 6) + ((cc ^ (n & 7)) << 3));
        *reinterpret_cast<bf16x8*>(Ua + (idx << 3)) = v;
      }
    }
    f32x4 accO[4];
#pragma unroll
    for (int n = 0; n < 4; ++n) accO[n] = (f32x4){0.f, 0.f, 0.f, 0.f};
    float psum = 0.f;
    for (int jt = 0; jt < 8; ++jt) {
      const int j0 = jbase + (jt << 6);
      __syncthreads();
      {
        const unsigned short* src = QBt + nb + ((size_t)j0 << 6);
#pragma unroll
        for (int s = 0; s < 2; ++s) {
          int idx = tid + (s << 8);
          int n = idx >> 3, cc = idx & 7;
          bf16x8 v = *reinterpret_cast<const bf16x8*>(src + (n << 6) + ((cc ^ (n & 7)) << 3));
          *reinterpret_cast<bf16x8*>(Vb + (idx << 3)) = v;
        }
      }
      __syncthreads();
      const int jrow = (w << 4) | m;
      bf16x8 a0 = *reinterpret_cast<const bf16x8*>(Vb + (jrow << 6) + ((g ^ (jrow & 7)) << 3));
      bf16x8 a1 = *reinterpret_cast<const bf16x8*>(Vb + (jrow << 6) + (((g + 4) ^ (jrow & 7)) << 3));
      f32x4 e[4];
#pragma unroll
      for (int n = 0; n < 4; ++n) {
        const int irow = (n << 4) | m;
        bf16x8 b0v = *reinterpret_cast<const bf16x8*>(Ua + (irow << 6) + ((g ^ (irow & 7)) << 3));
        bf16x8 b1v = *reinterpret_cast<const bf16x8*>(Ua + (irow << 6) + (((g + 4) ^ (irow & 7)) << 3));
        e[n] = (f32x4){0.f, 0.f, 0.f, 0.f};
        e[n] = __builtin_amdgcn_mfma_f32_16x16x32_bf16(a0, b0v, e[n], 0, 0, 0);
        e[n] = __builtin_amdgcn_mfma_f32_16x16x32_bf16(a1, b1v, e[n], 0, 0, 0);
      }
      const int j = (w << 4) | (g << 2);
#pragma unroll
      for (int n = 0; n < 4; ++n) {
        const int irow = (n << 4) | m;
        float p0 = __expf(-e[n][0]), p1 = __expf(-e[n][1]);
        float p2 = __expf(-e[n][2]), p3 = __expf(-e[n][3]);
        psum += (p0 + p1) + (p2 + p3);
        unsigned pk01 = (unsigned)f2bf(p0) | ((unsigned)f2bf(p1) << 16);
        unsigned pk23 = (unsigned)f2bf(p2) | ((unsigned)f2bf(p3) << 16);
        int base = irow << 6;
        int off0 = base + ((((j) >> 3) ^ (irow & 7)) << 3) + (j & 7);
        int off2 = base + ((((j + 2) >> 3) ^ (irow & 7)) << 3) + ((j + 2) & 7);
        *reinterpret_cast<unsigned*>(Pl + off0) = pk01;
        *reinterpret_cast<unsigned*>(Pl + off2) = pk23;
      }
      const int crow = (w << 4) | m;
      const unsigned short* kbp = KBc + nb + ((size_t)crow << 10) + j0 + (g << 3);
      bf16x8 ka0 = *reinterpret_cast<const bf16x8*>(kbp);
      bf16x8 ka1 = *reinterpret_cast<const bf16x8*>(kbp + 32);
      __syncthreads();
#pragma unroll
      for (int n = 0; n < 4; ++n) {
        const int irow = (n << 4) | m;
        bf16x8 p0 = *reinterpret_cast<const bf16x8*>(Pl + (irow << 6) + ((g ^ (irow & 7)) << 3));
        bf16x8 p1 = *reinterpret_cast<const bf16x8*>(Pl + (irow << 6) + (((g + 4) ^ (irow & 7)) << 3));
        accO[n] = __builtin_amdgcn_mfma_f32_16x16x32_bf16(ka0, p0, accO[n], 0, 0, 0);
        accO[n] = __builtin_amdgcn_mfma_f32_16x16x32_bf16(ka1, p1, accO[n], 0, 0, 0);
      }
    }
    float* OUT = PART + ((size_t)blockIdx.y * M1) + ((size_t)(b * 64) << 10);
#pragma unroll
    for (int n = 0; n < 4; ++n) {
      const int ig = i0 + (n << 4) + m;
      const int c = (w << 4) + (g << 2);
#pragma unroll
      for (int r = 0; r < 4; ++r)
        OUT[((size_t)(c + r) << 10) + ig] = accO[n][r];
    }
    red[tid] = psum; __syncthreads();
    for (int s = 128; s > 0; s >>= 1) {
      if (tid < s) red[tid] += red[tid + s];
      __syncthreads();
    }
    if (tid == 0) atomicAdd(bsum + b, red[0]);
  } else {
    const int j0 = blockIdx.x << 6;
    const int ibase = blockIdx.y << 9;
    {
      const unsigned short* src = QBt + nb + ((size_t)j0 << 6);
#pragma unroll
      for (int s = 0; s < 2; ++s) {
        int idx = tid + (s << 8);
        int n = idx >> 3, cc = idx & 7;
        bf16x8 v = *reinterpret_cast<const bf16x8*>(src + (n << 6) + ((cc ^ (n & 7)) << 3));
        *reinterpret_cast<bf16x8*>(Ua + (idx << 3)) = v;
      }
    }
    f32x4 accO[4];
#pragma unroll
    for (int n = 0; n < 4; ++n) accO[n] = (f32x4){0.f, 0.f, 0.f, 0.f};
    for (int it = 0; it < 8; ++it) {
      const int i0 = ibase + (it << 6);
      __syncthreads();
      {
        const unsigned short* src = QAt + nb + ((size_t)i0 << 6);
#pragma unroll
        for (int s = 0; s < 2; ++s) {
          int idx = tid + (s << 8);
          int n = idx >> 3, cc = idx & 7;
          bf16x8 v = *reinterpret_cast<const bf16x8*>(src + (n << 6) + ((cc ^ (n & 7)) << 3));
          *reinterpret_cast<bf16x8*>(Vb + (idx << 3)) = v;
        }
      }
      __syncthreads();
      const int irow_a = (w << 4) | m;
      bf16x8 a0 = *reinterpret_cast<const bf16x8*>(Vb + (irow_a << 6) + ((g ^ (irow_a & 7)) << 3));
      bf16x8 a1 = *reinterpret_cast<const bf16x8*>(Vb + (irow_a << 6) + (((g + 4) ^ (irow_a & 7)) << 3));
      f32x4 e[4];
#pragma unroll
      for (int n = 0; n < 4; ++n) {
        const int jrow = (n << 4) | m;
        bf16x8 b0v = *reinterpret_cast<const bf16x8*>(Ua + (jrow << 6) + ((g ^ (jrow & 7)) << 3));
        bf16x8 b1v = *reinterpret_cast<const bf16x8*>(Ua + (jrow << 6) + (((g + 4) ^ (jrow & 7)) << 3));
        e[n] = (f32x4){0.f, 0.f, 0.f, 0.f};
        e[n] = __builtin_amdgcn_mfma_f32_16x16x32_bf16(a0, b0v, e[n], 0, 0, 0);
        e[n] = __builtin_amdgcn_mfma_f32_16x16x32_bf16(a1, b1v, e[n], 0, 0, 0);
      }
      const int i = (w << 4) | (g << 2);
#pragma unroll
      for (int n = 0; n < 4; ++n) {
        const int jrow = (n << 4) | m;
        float p0 = __expf(-e[n][0]), p1 = __expf(-e[n][1]);
        float p2 = __expf(-e[n][2]), p3 = __expf(-e[n][3]);
        unsigned pk01 = (unsigned)f2bf(p0) | ((unsigned)f2bf(p1) << 16);
        unsigned pk23 = (unsigned)f2bf(p2) | ((unsigned)f2bf(p3) << 16);
        int base = jrow << 6;
        int off0 = base + ((((i) >> 3) ^ (jrow & 7)) << 3) + (i & 7);
        int off2 = base + ((((i + 2) >> 3) ^ (jrow & 7)) << 3) + ((i + 2) & 7);
        *reinterpret_cast<unsigned*>(Pl + off0) = pk01;
        *reinterpret_cast<unsigned*>(Pl + off2) = pk23;
      }
      const int crow = (w << 4) | m;
      const unsigned short* kap = KAc + nb + ((size_t)crow << 10) + i0 + (g << 3);
      bf16x8 ka0 = *reinterpret_cast<const bf16x8*>(kap);
      bf16x8 ka1 = *reinterpret_cast<const bf16x8*>(kap + 32);
      __syncthreads();
#pragma unroll
      for (int n = 0; n < 4; ++n) {
        const int jrow = (n << 4) | m;
        bf16x8 p0 = *reinterpret_cast<const bf16x8*>(Pl + (jrow << 6) + ((g ^ (jrow & 7)) << 3));
        bf16x8 p1 = *reinterpret_cast<const bf16x8*>(Pl + (jrow << 6) + (((g + 4) ^ (jrow & 7)) << 3));
        accO[n] = __builtin_amdgcn_mfma_f32_16x16x32_bf16(ka0, p0, accO[n], 0, 0, 0);
        accO[n] = __builtin_amdgcn_mfma_f32_16x16x32_bf16(ka1, p1, accO[n], 0, 0, 0);
      }
    }
    float* OUT = PART + 2 * M1 + ((size_t)blockIdx.y * M1) + ((size_t)(b * 64) << 10);
#pragma unroll
    for (int n = 0; n < 4; ++n) {
      const int jg = j0 + (n << 4) + m;
      const int c = (w << 4) + (g << 2);
#pragma unroll
      for (int r = 0; r < 4; ++r)
        OUT[((size_t)(c + r) << 10) + jg] = accO[n][r];
    }
  }
}

// ---- merge both streams (2 partials each) ----------------------------------
__global__ __launch_bounds__(256)
void merge_kernel(const float* __restrict__ PARTb, const float* __restrict__ XA,
                  const float* __restrict__ XB, unsigned short* __restrict__ Y0b,
                  const float* __restrict__ bsum) {
  __shared__ float ts[128][66];
  const int tid = threadIdx.x;
  const int n0 = blockIdx.x << 6;
  const int b = blockIdx.y;
  const int z = blockIdx.z;
  const float invS = 1.f / bsum[b];
  const size_t M1 = (size_t)1 << 20;
  const float* XR = z ? XB : XA;
  const float* PART = PARTb + (size_t)z * 2 * M1;
  unsigned short* Y0 = Y0b + (size_t)z * 2 * M1;
#pragma unroll
  for (int it = 0; it < 4; ++it) {
    int idx = it * 256 + tid;
    int c = idx >> 4, nq = (idx & 15) << 2;
    float4 v = *reinterpret_cast<const float4*>(XR + ((size_t)(b * 64 + c) << 10) + n0 + nq);
    ts[c][nq] = v.x; ts[c][nq + 1] = v.y; ts[c][nq + 2] = v.z; ts[c][nq + 3] = v.w;
  }
#pragma unroll
  for (int it = 0; it < 4; ++it) {
    int idx = it * 256 + tid;
    int c = idx >> 4, nq = (idx & 15) << 2;
    const float* p = PART + ((size_t)(b * 64 + c) << 10) + n0 + nq;
    float4 av = *reinterpret_cast<const float4*>(p);
    float4 b4 = *reinterpret_cast<const float4*>(p + M1);
    ts[64 + c][nq]     = (av.x + b4.x) * invS;
    ts[64 + c][nq + 1] = (av.y + b4.y) * invS;
    ts[64 + c][nq + 2] = (av.z + b4.z) * invS;
    ts[64 + c][nq + 3] = (av.w + b4.w) * invS;
  }
  __syncthreads();
  const int n = tid >> 2, c0 = (tid & 3) << 5;
  unsigned short* dst = Y0 + ((size_t)(b * 1024 + n0 + n) << 7) + c0;
#pragma unroll
  for (int q8 = 0; q8 < 4; ++q8) {
    const int cb = c0 + (q8 << 3);
    unsigned w0 = (unsigned)f2bf(ts[cb + 0][n]) | ((unsigned)f2bf(ts[cb + 1][n]) << 16);
    unsigned w1 = (unsigned)f2bf(ts[cb + 2][n]) | ((unsigned)f2bf(ts[cb + 3][n]) << 16);
    unsigned w2 = (unsigned)f2bf(ts[cb + 4][n]) | ((unsigned)f2bf(ts[cb + 5][n]) << 16);
    unsigned w3 = (unsigned)f2bf(ts[cb + 6][n]) | ((unsigned)f2bf(ts[cb + 7][n]) << 16);
    *reinterpret_cast<uint4*>(dst + (q8 << 3)) = make_uint4(w0, w1, w2, w3);
  }
}

// ---- gamma/beta pointer sets (per z, uniform SEL4) -------------------------
struct GBArgs { const float* g0[4]; const float* b0[4];
                const float* g1[4]; const float* b1[4]; };

// ---- MFMA conv v11: LDS-staged X tile with fused BN/residual epilogues -----
// SMODE: 0 plain copy; 1 relu(bn0(T)); 2 relu(bn0(T)+S); 3 relu(bn0(T)+bn1(S))
template<int CIN, int SMODE, int XDIV>
__global__ __launch_bounds__(256, 4)
void conv_mfma_kernel(const unsigned short* __restrict__ T0,
                      const unsigned short* __restrict__ S0,
                      const unsigned short* __restrict__ W0,
                      unsigned short* __restrict__ Yout0,
                      const float* __restrict__ sums0A, long s0str,
                      const float* __restrict__ sums1A, long s1str,
                      GBArgs gb,
                      float* __restrict__ outSums0,
                      int COUT, long tstr, long sstr, long wstr, long ystr) {
  constexpr int KS = CIN / 32;
  constexpr int ROWB = CIN * 2;
  constexpr int CPR = CIN / 8;
  __shared__ __align__(16) unsigned char Xs[64 * ROWB];
  __shared__ float scs[(SMODE >= 1) ? CIN : 1];
  __shared__ float shs[(SMODE >= 1) ? CIN : 1];
  __shared__ float sc2[(SMODE == 3) ? CIN : 1];
  __shared__ float sh2[(SMODE == 3) ? CIN : 1];
  const int tid = threadIdx.x;
  const int lane = tid & 63, w = tid >> 6;
  const int g = lane >> 4, m = lane & 15;
  const int z = blockIdx.z;
  const int zi = z >> XDIV;
  const int o0 = (blockIdx.x << 6) + (w << 4);
  const int nbase = blockIdx.y << 6;
  const unsigned short* Tin = T0 + (size_t)zi * tstr;
  const unsigned short* Sin = (SMODE >= 2) ? (S0 + (size_t)zi * sstr) : nullptr;
  const unsigned short* Wb  = W0 + (size_t)z * wstr;
  unsigned short* Yout      = Yout0 + (size_t)z * ystr;
  float* outSums            = outSums0 + (size_t)z * SSTR;
  if (SMODE >= 1) {
    const float* s0 = sums0A + (size_t)zi * s0str;
    const float* gg0; const float* bb0;
    SEL4(gg0, gb.g0, zi); SEL4(bb0, gb.b0, zi);
    const float invN = 1.f / 16384.f;
    for (int c = tid; c < CIN; c += 256) {
      float ss = 0.f, qq = 0.f;
#pragma unroll
      for (int p = 0; p < NCOPY; ++p) {
        ss += s0[p * 512 + c];
        qq += s0[p * 512 + 256 + c];
      }
      float mm = ss * invN;
      float vv = qq * invN - mm * mm;
      float s = gg0[c] * rsqrtf(vv + 1e-5f);
      scs[c] = s; shs[c] = bb0[c] - mm * s;
    }
    if (SMODE == 3) {
      const float* s1 = sums1A + (size_t)zi * s1str;
      const float* gg1; const float* bb1;
      SEL4(gg1, gb.g1, zi); SEL4(bb1, gb.b1, zi);
      for (int c = tid; c < CIN; c += 256) {
        float ss = 0.f, qq = 0.f;
#pragma unroll
        for (int p = 0; p < NCOPY; ++p) {
          ss += s1[p * 512 + c];
          qq += s1[p * 512 + 256 + c];
        }
        float mm = ss * invN;
        float vv = qq * invN - mm * mm;
        float s = gg1[c] * rsqrtf(vv + 1e-5f);
        sc2[c] = s; sh2[c] = bb1[c] - mm * s;
      }
    }
    __syncthreads();
  }
#pragma unroll
  for (int it = 0; it < (64 * CPR) / 256; ++it) {
    const int idx = it * 256 + tid;
    const int row = idx / CPR;
    const int cc = idx % CPR;
    bf16x8 v = *reinterpret_cast<const bf16x8*>(
        Tin + (size_t)(nbase + row) * CIN + cc * 8);
    if (SMODE >= 1) {
      bf16x8 sv;
      if (SMODE >= 2)
        sv = *reinterpret_cast<const bf16x8*>(
            Sin + (size_t)(nbase + row) * CIN + cc * 8);
      const int c0 = cc * 8;
#pragma unroll
      for (int j = 0; j < 8; ++j) {
        float x = __uint_as_float((unsigned)(unsigned short)v[j] << 16);
        x = fmaf(x, scs[c0 + j], shs[c0 + j]);
        if (SMODE == 2)
          x += __uint_as_float((unsigned)(unsigned short)sv[j] << 16);
        if (SMODE == 3) {
          float y = __uint_as_float((unsigned)(unsigned short)sv[j] << 16);
          x += fmaf(y, sc2[c0 + j], sh2[c0 + j]);
        }
        x = fmaxf(x, 0.f);
        v[j] = (short)f2bf(x);
      }
    }
    const int byte = (cc << 4) ^ ((row & 7) << 4);
    *reinterpret_cast<bf16x8*>(Xs + row * ROWB + byte) = v;
  }
  __syncthreads();
  const unsigned short* Wr = Wb + (size_t)(o0 + m) * CIN + (g << 3);
  bf16x8 af[KS];
#pragma unroll
  for (int k = 0; k < KS; ++k) af[k] = *reinterpret_cast<const bf16x8*>(Wr + (k << 5));
  float sr[4] = {0.f, 0.f, 0.f, 0.f}, qr[4] = {0.f, 0.f, 0.f, 0.f};
#pragma unroll
  for (int nt = 0; nt < 4; ++nt) {
    const int row = (nt << 4) + m;
    const unsigned char* lrow = Xs + row * ROWB;
    const int swz = (row & 7) << 4;
    f32x4 acc = (f32x4){0.f, 0.f, 0.f, 0.f};
#pragma unroll
    for (int k = 0; k < KS; ++k) {
      const int byte = ((k << 6) + (g << 4)) ^ swz;
      bf16x8 bv = *reinterpret_cast<const bf16x8*>(lrow + byte);
      acc = __builtin_amdgcn_mfma_f32_16x16x32_bf16(af[k], bv, acc, 0, 0, 0);
    }
    ushort4 v;
    v.x = f2bf(acc[0]); v.y = f2bf(acc[1]);
    v.z = f2bf(acc[2]); v.w = f2bf(acc[3]);
    *reinterpret_cast<ushort4*>(Yout + (size_t)(nbase + row) * COUT + o0 + (g << 2)) = v;
#pragma unroll
    for (int r = 0; r < 4; ++r) {
      sr[r] += acc[r];
      qr[r] = fmaf(acc[r], acc[r], qr[r]);
    }
  }
#pragma unroll
  for (int r = 0; r < 4; ++r) {
    for (int off = 1; off < 16; off <<= 1) {
      sr[r] += __shfl_xor(sr[r], off);
      qr[r] += __shfl_xor(qr[r], off);
    }
  }
  if (m == 0) {
    float* dst = outSums + (blockIdx.y & (NCOPY - 1)) * 512;
#pragma unroll
    for (int r = 0; r < 4; ++r) {
      atomicAdd(&dst[o0 + (g << 2) + r], sr[r]);
      atomicAdd(&dst[256 + o0 + (g << 2) + r], qr[r]);
    }
  }
}

// ---- writeout: fold conv6 stats inline, bn, LDS transpose, f32 out ---------
__global__ __launch_bounds__(256)
void writeout_t_kernel(const unsigned short* __restrict__ F0,
                       const float* __restrict__ sumsA,
                       GBArgs gb,
                       float* __restrict__ out0) {
  __shared__ float ts[64][66];
  __shared__ float sc[64], sh[64];
  const int tid = threadIdx.x;
  const int z = blockIdx.z;
  const size_t M1 = (size_t)1 << 20;
  const unsigned short* F = F0 + (size_t)z * M1;
  float* outp = out0 + (size_t)z * M1;
  if (tid < 64) {
    const float* sums = sumsA + (size_t)z * SSTR;
    const float* gg; const float* bb;
    SEL4(gg, gb.g0, z); SEL4(bb, gb.b0, z);
    float s0 = 0.f, q0 = 0.f;
#pragma unroll
    for (int p = 0; p < NCOPY; ++p) {
      s0 += sums[p * 512 + tid];
      q0 += sums[p * 512 + 256 + tid];
    }
    const float invN = 1.f / 16384.f;
    float mm = s0 * invN;
    float vv = q0 * invN - mm * mm;
    float s = gg[tid] * rsqrtf(vv + 1e-5f);
    sc[tid] = s; sh[tid] = bb[tid] - mm * s;
  }
  __syncthreads();
  const int n0 = blockIdx.x << 6;
  const int b = blockIdx.y;
  {
    const int n = tid >> 2, c0 = (tid & 3) << 4;
    const unsigned short* Fr = F + ((size_t)(b * 1024 + n0 + n) << 6) + c0;
    uint4 v0 = *reinterpret_cast<const uint4*>(Fr);
    uint4 v1 = *reinterpret_cast<const uint4*>(Fr + 8);
    unsigned vw[8] = {v0.x, v0.y, v0.z, v0.w, v1.x, v1.y, v1.z, v1.w};
#pragma unroll
    for (int jw = 0; jw < 8; ++jw) {
      int c = c0 + jw * 2;
      float x0 = __uint_as_float((vw[jw] & 0xffffu) << 16);
      float x1 = __uint_as_float((vw[jw] >> 16) << 16);
      ts[c][n] = fmaf(x0, sc[c], sh[c]);
      ts[c + 1][n] = fmaf(x1, sc[c + 1], sh[c + 1]);
    }
  }
  __syncthreads();
  const int c = tid >> 2, nq = (tid & 3) << 4;
  float* orow = outp + ((size_t)(b * 64 + c) << 10) + n0 + nq;
#pragma unroll
  for (int q = 0; q < 4; ++q) {
    float4 ov;
    ov.x = ts[c][nq + q * 4 + 0]; ov.y = ts[c][nq + q * 4 + 1];
    ov.z = ts[c][nq + q * 4 + 2]; ov.w = ts[c][nq + q * 4 + 3];
    *reinterpret_cast<float4*>(orow + q * 4) = ov;
  }
}

// ============================ host side =====================================
extern "C" void kernel_launch(void* const* d_in, const int* in_sizes, int n_in,
                              void* d_out, int out_size, void* d_ws, size_t ws_size,
                              hipStream_t stream) {
  float* wsf = (float*)d_ws;
  const size_t M1 = (size_t)1 << 20;
  const size_t H1 = (size_t)1 << 19;

  unsigned short* QAt = (unsigned short*)wsf;
  unsigned short* QBt = (unsigned short*)(wsf + H1);
  unsigned short* KAc = (unsigned short*)(wsf + 2 * H1);
  unsigned short* KBc = (unsigned short*)(wsf + 3 * H1);
  float* PART1 = wsf + 2 * M1;                             // [2M,6M): pv 2 + tpv 2
  unsigned short* Y0A = (unsigned short*)(wsf + 10 * M1);  // Y0A,Y0B @1M-float stride
  unsigned short* T1a = (unsigned short*)(wsf + 12 * M1);
  unsigned short* T2a = (unsigned short*)(wsf + 14 * M1);
  unsigned short* T3a = (unsigned short*)(wsf + 18 * M1);  // T3a,T5a,T3b,T5b @2M-float stride
  unsigned short* T4a = (unsigned short*)(wsf + 26 * M1);  // T4a,T4b @2M-float stride
  unsigned short* Fba = (unsigned short*)(wsf + 30 * M1);  // Fba,Fbb @0.5M-float stride
  float* tail = wsf + 31 * M1;
  float* bsum = tail;
  float* stats = tail + 16;
  unsigned short* wbf = (unsigned short*)(stats + 12 * SSTR);

  const float* pp[46];
  for (int i = 0; i < 46 && i < n_in; ++i) pp[i] = (const float*)d_in[i];

  const int initN = 16 + 12 * SSTR;
  init_kernel<<<(initN + 255) / 256, 256, 0, stream>>>(tail, initN);

  // weight order: w11a,w11b,w12a,w12b,w21a,w2sa,w21b,w2sb,w22a,w22b,woa,wob
  const int widx[12] = {10, 16, 13, 19, 22, 28, 31, 37, 25, 34, 40, 43};
  WcvtArgs wa;
  int woff[12];
  {
    int run = 0;
    for (int i = 0; i < 12; ++i) {
      wa.p[i] = pp[widx[i]];
      wa.sz[i] = in_sizes[widx[i]];
      wa.off[i] = run; woff[i] = run;
      run += in_sizes[widx[i]];
    }
  }
  wcvt_kernel<<<dim3(12, 16), 256, 0, stream>>>(wa, wbf);

  QKArgs qk;
  qk.X[0] = pp[0]; qk.W[0] = pp[2]; qk.B[0] = pp[3]; qk.Y[0] = QAt;
  qk.X[1] = pp[1]; qk.W[1] = pp[4]; qk.B[1] = pp[5]; qk.Y[1] = QBt;
  qk.X[2] = pp[0]; qk.W[2] = pp[6]; qk.B[2] = pp[7]; qk.Y[2] = KAc;
  qk.X[3] = pp[1]; qk.W[3] = pp[8]; qk.B[3] = pp[9]; qk.Y[3] = KBc;
  conv_qk_all_kernel<<<dim3(16, 2, 64), 256, 0, stream>>>(qk);

  attn_mfma_kernel<<<dim3(16, 2, 32), 256, 0, stream>>>(
      QAt, QBt, KAc, KBc, PART1, bsum);
  merge_kernel<<<dim3(16, BATCH, 2), 256, 0, stream>>>(PART1, pp[0], pp[1], Y0A, bsum);

  float* S_c1 = stats;               // conv1 (2 z)
  float* S_c2 = stats + 2 * SSTR;    // conv2 (2 z)
  float* S_q  = stats + 4 * SSTR;    // quad (4 z)
  float* S_c4 = stats + 8 * SSTR;    // conv4 (2 z)
  float* S_c6 = stats + 10 * SSTR;   // conv6 (2 z)

  const long SH1 = (long)2 * M1;     // 1M-float stride in shorts
  const long SH2 = (long)4 * M1;     // 2M-float stride in shorts
  GBArgs gbE = {};
  GBArgs gb;

  // conv1 (SMODE0): Y0 -> T1
  conv_mfma_kernel<128, 0, 0><<<dim3(2, 256, 2), 256, 0, stream>>>(
      Y0A, nullptr, wbf + woff[0], T1a, nullptr, 0, nullptr, 0, gbE,
      S_c1, 128, SH1, 0, 16384, SH1);

  // conv2 (SMODE1: bn[conv1 stats, a1_s1/b1 params]): T1 -> T2
  gb = gbE;
  gb.g0[0] = pp[11]; gb.b0[0] = pp[12]; gb.g0[1] = pp[17]; gb.b0[1] = pp[18];
  conv_mfma_kernel<128, 1, 0><<<dim3(2, 256, 2), 256, 0, stream>>>(
      T1a, nullptr, wbf + woff[2], T2a, S_c1, SSTR, nullptr, 0, gb,
      S_c2, 128, SH1, 0, 16384, SH1);

  // quad (SMODE2: relu(bn(T2)+Y0)): -> {T3a,T5a,T3b,T5b}
  gb = gbE;
  gb.g0[0] = pp[14]; gb.b0[0] = pp[15]; gb.g0[1] = pp[20]; gb.b0[1] = pp[21];
  conv_mfma_kernel<128, 2, 1><<<dim3(4, 256, 4), 256, 0, stream>>>(
      T2a, Y0A, wbf + woff[4], T3a, S_c2, SSTR, nullptr, 0, gb,
      S_q, 256, SH1, SH1, 32768, SH2);

  // conv4 (SMODE1: bn[w21 stats (quad z0/z2), a2_s1/b1]): T3 -> T4
  gb = gbE;
  gb.g0[0] = pp[23]; gb.b0[0] = pp[24]; gb.g0[1] = pp[32]; gb.b0[1] = pp[33];
  conv_mfma_kernel<256, 1, 0><<<dim3(4, 256, 2), 256, 0, stream>>>(
      T3a, nullptr, wbf + woff[8], T4a, S_q, 2 * SSTR, nullptr, 0, gb,
      S_c4, 256, (long)8 * M1, 0, 65536, SH2);

  // conv6 (SMODE3: relu(bn(T4)+bn(T5))): -> Fb
  gb = gbE;
  gb.g0[0] = pp[26]; gb.b0[0] = pp[27]; gb.g0[1] = pp[35]; gb.b0[1] = pp[36];
  gb.g1[0] = pp[29]; gb.b1[0] = pp[30]; gb.g1[1] = pp[38]; gb.b1[1] = pp[39];
  conv_mfma_kernel<256, 3, 0><<<dim3(1, 256, 2), 256, 0, stream>>>(
      T4a, T3a + SH2 /*T5a*/, wbf + woff[10], Fba, S_c4, SSTR,
      S_q + SSTR, 2 * SSTR, gb,
      S_c6, 64, SH2, (long)8 * M1, 16384, (long)M1);

  // writeout (folds conv6 stats inline)
  gb = gbE;
  gb.g0[0] = pp[41]; gb.b0[0] = pp[42]; gb.g0[1] = pp[44]; gb.b0[1] = pp[45];
  writeout_t_kernel<<<dim3(16, BATCH, 2), 256, 0, stream>>>(
      Fba, S_c6, gb, (float*)d_out);
}

// Round 19
// 166.779 us; speedup vs baseline: 5.2822x; 1.1123x over previous
//
#include <hip/hip_runtime.h>
#include <hip/hip_bf16.h>
#include <cstddef>

static constexpr int BATCH = 16;
static constexpr int NCOPY = 16;
static constexpr int SSTR  = NCOPY * 512;   // floats per stat set

typedef __attribute__((ext_vector_type(8))) short bf16x8;
typedef __attribute__((ext_vector_type(4))) float f32x4;

__device__ __forceinline__ unsigned short f2bf(float f) {
  unsigned u = __float_as_uint(f);
  return (unsigned short)((u + 0x7fffu + ((u >> 16) & 1u)) >> 16);  // RNE
}

#define SEL4(dst, arr, idx)                                   \
  do {                                                        \
    if ((idx) == 0) dst = arr[0];                             \
    else if ((idx) == 1) dst = arr[1];                        \
    else if ((idx) == 2) dst = arr[2];                        \
    else dst = arr[3];                                        \
  } while (0)

__global__ void init_kernel(float* __restrict__ t, int n) {
  int i = blockIdx.x * 256 + threadIdx.x;
  if (i < n) t[i] = 0.f;
}

// ---- convert the 12 block-phase weight matrices to bf16 (layout [o][cin]) --
struct WcvtArgs { const float* p[12]; int sz[12]; int off[12]; };
__global__ __launch_bounds__(256)
void wcvt_kernel(WcvtArgs a, unsigned short* __restrict__ dst) {
  const int t = blockIdx.x;
  const float* src = a.p[t];
  unsigned short* d = dst + a.off[t];
  const int sz = a.sz[t];
  for (int i = blockIdx.y * 256 + threadIdx.x; i < sz; i += 16 * 256)
    d[i] = f2bf(src[i]);
}

// ---------------- q/k convs (all 4 in one launch) ---------------------------
struct QKArgs { const float* X[4]; const float* W[4]; const float* B[4];
                unsigned short* Y[4]; };
__global__ __launch_bounds__(256)
void conv_qk_all_kernel(QKArgs a) {
  __shared__ float wsT[64][4];
  const int tid = threadIdx.x;
  const int z = blockIdx.z;
  const int which = z >> 4;
  const int b = z & 15;
  const int o0 = blockIdx.x << 2;
  const int px = (blockIdx.y << 9) + (tid << 1);
  const float* W; const float* X; const float* bias; unsigned short* Y;
  SEL4(W, a.W, which); SEL4(X, a.X, which); SEL4(bias, a.B, which); SEL4(Y, a.Y, which);
  {
    int c = tid >> 2, k = tid & 3;
    wsT[c][k] = W[((o0 + k) << 6) + c];
  }
  __syncthreads();
  float acc[4][2] = {};
  const float* xb = X + ((size_t)b << 16) + px;
#pragma unroll 4
  for (int c = 0; c < 64; ++c) {
    float2 xv = *reinterpret_cast<const float2*>(xb + (c << 10));
    float4 w = *reinterpret_cast<const float4*>(wsT[c]);
    acc[0][0] = fmaf(w.x, xv.x, acc[0][0]); acc[0][1] = fmaf(w.x, xv.y, acc[0][1]);
    acc[1][0] = fmaf(w.y, xv.x, acc[1][0]); acc[1][1] = fmaf(w.y, xv.y, acc[1][1]);
    acc[2][0] = fmaf(w.z, xv.x, acc[2][0]); acc[2][1] = fmaf(w.z, xv.y, acc[2][1]);
    acc[3][0] = fmaf(w.w, xv.x, acc[3][0]); acc[3][1] = fmaf(w.w, xv.y, acc[3][1]);
  }
  float b0 = bias[o0], b1 = bias[o0 + 1], b2 = bias[o0 + 2], b3 = bias[o0 + 3];
  if (which < 2) {
    ushort4 v0, v1;
    v0.x = f2bf(acc[0][0] + b0); v0.y = f2bf(acc[1][0] + b1);
    v0.z = f2bf(acc[2][0] + b2); v0.w = f2bf(acc[3][0] + b3);
    v1.x = f2bf(acc[0][1] + b0); v1.y = f2bf(acc[1][1] + b1);
    v1.z = f2bf(acc[2][1] + b2); v1.w = f2bf(acc[3][1] + b3);
    unsigned short* yt = Y + ((size_t)b << 16) + ((size_t)px << 6) + o0;
    *reinterpret_cast<ushort4*>(yt) = v0;
    *reinterpret_cast<ushort4*>(yt + 64) = v1;
  } else {
    float bv[4] = {b0, b1, b2, b3};
#pragma unroll
    for (int k = 0; k < 4; ++k) {
      ushort2 v;
      v.x = f2bf(acc[k][0] + bv[k]); v.y = f2bf(acc[k][1] + bv[k]);
      *reinterpret_cast<ushort2*>(Y + ((size_t)b << 16) + ((size_t)(o0 + k) << 10) + px) = v;
    }
  }
}

// ---- combined MFMA attention: z<16 -> PV (batch z), z>=16 -> PtV (z-16) ----
__global__ __launch_bounds__(256)
void attn_mfma_kernel(const unsigned short* __restrict__ QAt,
                      const unsigned short* __restrict__ QBt,
                      const unsigned short* __restrict__ KAc,
                      const unsigned short* __restrict__ KBc,
                      float* __restrict__ PART, float* __restrict__ bsum) {
  __shared__ __align__(16) unsigned short Ua[4096];
  __shared__ __align__(16) unsigned short Vb[4096];
  __shared__ __align__(16) unsigned short Pl[4096];
  __shared__ float red[256];
  const int tid = threadIdx.x;
  const int lane = tid & 63, w = tid >> 6;
  const int g = lane >> 4, m = lane & 15;
  const int z = blockIdx.z;
  const bool isPV = (z < 16);
  const int b = z & 15;
  const size_t nb = (size_t)b << 16;
  const size_t M1 = (size_t)1 << 20;

  if (isPV) {
    const int i0 = blockIdx.x << 6;
    const int jbase = blockIdx.y << 9;
    {
      const unsigned short* src = QAt + nb + ((size_t)i0 << 6);
#pragma unroll
      for (int s = 0; s < 2; ++s) {
        int idx = tid + (s << 8);
        int n = idx >> 3, cc = idx & 7;
        bf16x8 v = *reinterpret_cast<const bf16x8*>(src + (n << 6) + ((cc ^ (n & 7)) << 3));
        *reinterpret_cast<bf16x8*>(Ua + (idx << 3)) = v;
      }
    }
    f32x4 accO[4];
#pragma unroll
    for (int n = 0; n < 4; ++n) accO[n] = (f32x4){0.f, 0.f, 0.f, 0.f};
    float psum = 0.f;
    for (int jt = 0; jt < 8; ++jt) {
      const int j0 = jbase + (jt << 6);
      __syncthreads();
      {
        const unsigned short* src = QBt + nb + ((size_t)j0 << 6);
#pragma unroll
        for (int s = 0; s < 2; ++s) {
          int idx = tid + (s << 8);
          int n = idx >> 3, cc = idx & 7;
          bf16x8 v = *reinterpret_cast<const bf16x8*>(src + (n << 6) + ((cc ^ (n & 7)) << 3));
          *reinterpret_cast<bf16x8*>(Vb + (idx << 3)) = v;
        }
      }
      __syncthreads();
      const int jrow = (w << 4) | m;
      bf16x8 a0 = *reinterpret_cast<const bf16x8*>(Vb + (jrow << 6) + ((g ^ (jrow & 7)) << 3));
      bf16x8 a1 = *reinterpret_cast<const bf16x8*>(Vb + (jrow << 6) + (((g + 4) ^ (jrow & 7)) << 3));
      f32x4 e[4];
#pragma unroll
      for (int n = 0; n < 4; ++n) {
        const int irow = (n << 4) | m;
        bf16x8 b0v = *reinterpret_cast<const bf16x8*>(Ua + (irow << 6) + ((g ^ (irow & 7)) << 3));
        bf16x8 b1v = *reinterpret_cast<const bf16x8*>(Ua + (irow << 6) + (((g + 4) ^ (irow & 7)) << 3));
        e[n] = (f32x4){0.f, 0.f, 0.f, 0.f};
        e[n] = __builtin_amdgcn_mfma_f32_16x16x32_bf16(a0, b0v, e[n], 0, 0, 0);
        e[n] = __builtin_amdgcn_mfma_f32_16x16x32_bf16(a1, b1v, e[n], 0, 0, 0);
      }
      const int j = (w << 4) | (g << 2);
#pragma unroll
      for (int n = 0; n < 4; ++n) {
        const int irow = (n << 4) | m;
        float p0 = __expf(-e[n][0]), p1 = __expf(-e[n][1]);
        float p2 = __expf(-e[n][2]), p3 = __expf(-e[n][3]);
        psum += (p0 + p1) + (p2 + p3);
        unsigned pk01 = (unsigned)f2bf(p0) | ((unsigned)f2bf(p1) << 16);
        unsigned pk23 = (unsigned)f2bf(p2) | ((unsigned)f2bf(p3) << 16);
        int base = irow << 6;
        int off0 = base + ((((j) >> 3) ^ (irow & 7)) << 3) + (j & 7);
        int off2 = base + ((((j + 2) >> 3) ^ (irow & 7)) << 3) + ((j + 2) & 7);
        *reinterpret_cast<unsigned*>(Pl + off0) = pk01;
        *reinterpret_cast<unsigned*>(Pl + off2) = pk23;
      }
      const int crow = (w << 4) | m;
      const unsigned short* kbp = KBc + nb + ((size_t)crow << 10) + j0 + (g << 3);
      bf16x8 ka0 = *reinterpret_cast<const bf16x8*>(kbp);
      bf16x8 ka1 = *reinterpret_cast<const bf16x8*>(kbp + 32);
      __syncthreads();
#pragma unroll
      for (int n = 0; n < 4; ++n) {
        const int irow = (n << 4) | m;
        bf16x8 p0 = *reinterpret_cast<const bf16x8*>(Pl + (irow << 6) + ((g ^ (irow & 7)) << 3));
        bf16x8 p1 = *reinterpret_cast<const bf16x8*>(Pl + (irow << 6) + (((g + 4) ^ (irow & 7)) << 3));
        accO[n] = __builtin_amdgcn_mfma_f32_16x16x32_bf16(ka0, p0, accO[n], 0, 0, 0);
        accO[n] = __builtin_amdgcn_mfma_f32_16x16x32_bf16(ka1, p1, accO[n], 0, 0, 0);
      }
    }
    float* OUT = PART + ((size_t)blockIdx.y * M1) + ((size_t)(b * 64) << 10);
#pragma unroll
    for (int n = 0; n < 4; ++n) {
      const int ig = i0 + (n << 4) + m;
      const int c = (w << 4) + (g << 2);
#pragma unroll
      for (int r = 0; r < 4; ++r)
        OUT[((size_t)(c + r) << 10) + ig] = accO[n][r];
    }
    red[tid] = psum; __syncthreads();
    for (int s = 128; s > 0; s >>= 1) {
      if (tid < s) red[tid] += red[tid + s];
      __syncthreads();
    }
    if (tid == 0) atomicAdd(bsum + b, red[0]);
  } else {
    const int j0 = blockIdx.x << 6;
    const int ibase = blockIdx.y << 9;
    {
      const unsigned short* src = QBt + nb + ((size_t)j0 << 6);
#pragma unroll
      for (int s = 0; s < 2; ++s) {
        int idx = tid + (s << 8);
        int n = idx >> 3, cc = idx & 7;
        bf16x8 v = *reinterpret_cast<const bf16x8*>(src + (n << 6) + ((cc ^ (n & 7)) << 3));
        *reinterpret_cast<bf16x8*>(Ua + (idx << 3)) = v;
      }
    }
    f32x4 accO[4];
#pragma unroll
    for (int n = 0; n < 4; ++n) accO[n] = (f32x4){0.f, 0.f, 0.f, 0.f};
    for (int it = 0; it < 8; ++it) {
      const int i0 = ibase + (it << 6);
      __syncthreads();
      {
        const unsigned short* src = QAt + nb + ((size_t)i0 << 6);
#pragma unroll
        for (int s = 0; s < 2; ++s) {
          int idx = tid + (s << 8);
          int n = idx >> 3, cc = idx & 7;
          bf16x8 v = *reinterpret_cast<const bf16x8*>(src + (n << 6) + ((cc ^ (n & 7)) << 3));
          *reinterpret_cast<bf16x8*>(Vb + (idx << 3)) = v;
        }
      }
      __syncthreads();
      const int irow_a = (w << 4) | m;
      bf16x8 a0 = *reinterpret_cast<const bf16x8*>(Vb + (irow_a << 6) + ((g ^ (irow_a & 7)) << 3));
      bf16x8 a1 = *reinterpret_cast<const bf16x8*>(Vb + (irow_a << 6) + (((g + 4) ^ (irow_a & 7)) << 3));
      f32x4 e[4];
#pragma unroll
      for (int n = 0; n < 4; ++n) {
        const int jrow = (n << 4) | m;
        bf16x8 b0v = *reinterpret_cast<const bf16x8*>(Ua + (jrow << 6) + ((g ^ (jrow & 7)) << 3));
        bf16x8 b1v = *reinterpret_cast<const bf16x8*>(Ua + (jrow << 6) + (((g + 4) ^ (jrow & 7)) << 3));
        e[n] = (f32x4){0.f, 0.f, 0.f, 0.f};
        e[n] = __builtin_amdgcn_mfma_f32_16x16x32_bf16(a0, b0v, e[n], 0, 0, 0);
        e[n] = __builtin_amdgcn_mfma_f32_16x16x32_bf16(a1, b1v, e[n], 0, 0, 0);
      }
      const int i = (w << 4) | (g << 2);
#pragma unroll
      for (int n = 0; n < 4; ++n) {
        const int jrow = (n << 4) | m;
        float p0 = __expf(-e[n][0]), p1 = __expf(-e[n][1]);
        float p2 = __expf(-e[n][2]), p3 = __expf(-e[n][3]);
        unsigned pk01 = (unsigned)f2bf(p0) | ((unsigned)f2bf(p1) << 16);
        unsigned pk23 = (unsigned)f2bf(p2) | ((unsigned)f2bf(p3) << 16);
        int base = jrow << 6;
        int off0 = base + ((((i) >> 3) ^ (jrow & 7)) << 3) + (i & 7);
        int off2 = base + ((((i + 2) >> 3) ^ (jrow & 7)) << 3) + ((i + 2) & 7);
        *reinterpret_cast<unsigned*>(Pl + off0) = pk01;
        *reinterpret_cast<unsigned*>(Pl + off2) = pk23;
      }
      const int crow = (w << 4) | m;
      const unsigned short* kap = KAc + nb + ((size_t)crow << 10) + i0 + (g << 3);
      bf16x8 ka0 = *reinterpret_cast<const bf16x8*>(kap);
      bf16x8 ka1 = *reinterpret_cast<const bf16x8*>(kap + 32);
      __syncthreads();
#pragma unroll
      for (int n = 0; n < 4; ++n) {
        const int jrow = (n << 4) | m;
        bf16x8 p0 = *reinterpret_cast<const bf16x8*>(Pl + (jrow << 6) + ((g ^ (jrow & 7)) << 3));
        bf16x8 p1 = *reinterpret_cast<const bf16x8*>(Pl + (jrow << 6) + (((g + 4) ^ (jrow & 7)) << 3));
        accO[n] = __builtin_amdgcn_mfma_f32_16x16x32_bf16(ka0, p0, accO[n], 0, 0, 0);
        accO[n] = __builtin_amdgcn_mfma_f32_16x16x32_bf16(ka1, p1, accO[n], 0, 0, 0);
      }
    }
    float* OUT = PART + 2 * M1 + ((size_t)blockIdx.y * M1) + ((size_t)(b * 64) << 10);
#pragma unroll
    for (int n = 0; n < 4; ++n) {
      const int jg = j0 + (n << 4) + m;
      const int c = (w << 4) + (g << 2);
#pragma unroll
      for (int r = 0; r < 4; ++r)
        OUT[((size_t)(c + r) << 10) + jg] = accO[n][r];
    }
  }
}

// ---- merge both streams (2 partials each) ----------------------------------
__global__ __launch_bounds__(256)
void merge_kernel(const float* __restrict__ PARTb, const float* __restrict__ XA,
                  const float* __restrict__ XB, unsigned short* __restrict__ Y0b,
                  const float* __restrict__ bsum) {
  __shared__ float ts[128][66];
  const int tid = threadIdx.x;
  const int n0 = blockIdx.x << 6;
  const int b = blockIdx.y;
  const int z = blockIdx.z;
  const float invS = 1.f / bsum[b];
  const size_t M1 = (size_t)1 << 20;
  const float* XR = z ? XB : XA;
  const float* PART = PARTb + (size_t)z * 2 * M1;
  unsigned short* Y0 = Y0b + (size_t)z * 2 * M1;
#pragma unroll
  for (int it = 0; it < 4; ++it) {
    int idx = it * 256 + tid;
    int c = idx >> 4, nq = (idx & 15) << 2;
    float4 v = *reinterpret_cast<const float4*>(XR + ((size_t)(b * 64 + c) << 10) + n0 + nq);
    ts[c][nq] = v.x; ts[c][nq + 1] = v.y; ts[c][nq + 2] = v.z; ts[c][nq + 3] = v.w;
  }
#pragma unroll
  for (int it = 0; it < 4; ++it) {
    int idx = it * 256 + tid;
    int c = idx >> 4, nq = (idx & 15) << 2;
    const float* p = PART + ((size_t)(b * 64 + c) << 10) + n0 + nq;
    float4 av = *reinterpret_cast<const float4*>(p);
    float4 b4 = *reinterpret_cast<const float4*>(p + M1);
    ts[64 + c][nq]     = (av.x + b4.x) * invS;
    ts[64 + c][nq + 1] = (av.y + b4.y) * invS;
    ts[64 + c][nq + 2] = (av.z + b4.z) * invS;
    ts[64 + c][nq + 3] = (av.w + b4.w) * invS;
  }
  __syncthreads();
  const int n = tid >> 2, c0 = (tid & 3) << 5;
  unsigned short* dst = Y0 + ((size_t)(b * 1024 + n0 + n) << 7) + c0;
#pragma unroll
  for (int q8 = 0; q8 < 4; ++q8) {
    const int cb = c0 + (q8 << 3);
    unsigned w0 = (unsigned)f2bf(ts[cb + 0][n]) | ((unsigned)f2bf(ts[cb + 1][n]) << 16);
    unsigned w1 = (unsigned)f2bf(ts[cb + 2][n]) | ((unsigned)f2bf(ts[cb + 3][n]) << 16);
    unsigned w2 = (unsigned)f2bf(ts[cb + 4][n]) | ((unsigned)f2bf(ts[cb + 5][n]) << 16);
    unsigned w3 = (unsigned)f2bf(ts[cb + 6][n]) | ((unsigned)f2bf(ts[cb + 7][n]) << 16);
    *reinterpret_cast<uint4*>(dst + (q8 << 3)) = make_uint4(w0, w1, w2, w3);
  }
}

// ---- gamma/beta pointer sets (per z, uniform SEL4) -------------------------
struct GBArgs { const float* g0[4]; const float* b0[4];
                const float* g1[4]; const float* b1[4]; };

// ---- MFMA conv v12: LDS-staged tile, OC output groups per wave -------------
// SMODE: 0 plain copy; 1 relu(bn0(T)); 2 relu(bn0(T)+S); 3 relu(bn0(T)+bn1(S))
template<int CIN, int OC, int SMODE, int XDIV>
__global__ __launch_bounds__(256, 4)
void conv_mfma_kernel(const unsigned short* __restrict__ T0,
                      const unsigned short* __restrict__ S0,
                      const unsigned short* __restrict__ W0,
                      unsigned short* __restrict__ Yout0,
                      const float* __restrict__ sums0A, long s0str,
                      const float* __restrict__ sums1A, long s1str,
                      GBArgs gb,
                      float* __restrict__ outSums0,
                      int COUT, long tstr, long sstr, long wstr, long ystr) {
  constexpr int KS = CIN / 32;
  constexpr int ROWB = CIN * 2;
  constexpr int CPR = CIN / 8;
  __shared__ __align__(16) unsigned char Xs[64 * ROWB];
  __shared__ float scs[(SMODE >= 1) ? CIN : 1];
  __shared__ float shs[(SMODE >= 1) ? CIN : 1];
  __shared__ float sc2[(SMODE == 3) ? CIN : 1];
  __shared__ float sh2[(SMODE == 3) ? CIN : 1];
  const int tid = threadIdx.x;
  const int lane = tid & 63, w = tid >> 6;
  const int g = lane >> 4, m = lane & 15;
  const int z = blockIdx.z;
  const int zi = z >> XDIV;
  const int obase = blockIdx.x * (OC << 6) + (w << 4);
  const int nbase = blockIdx.y << 6;
  const unsigned short* Tin = T0 + (size_t)zi * tstr;
  const unsigned short* Sin = (SMODE >= 2) ? (S0 + (size_t)zi * sstr) : nullptr;
  const unsigned short* Wb  = W0 + (size_t)z * wstr;
  unsigned short* Yout      = Yout0 + (size_t)z * ystr;
  float* outSums            = outSums0 + (size_t)z * SSTR;
  if (SMODE >= 1) {
    const float* s0 = sums0A + (size_t)zi * s0str;
    const float* gg0; const float* bb0;
    SEL4(gg0, gb.g0, zi); SEL4(bb0, gb.b0, zi);
    const float invN = 1.f / 16384.f;
    for (int c = tid; c < CIN; c += 256) {
      float ss = 0.f, qq = 0.f;
#pragma unroll
      for (int p = 0; p < NCOPY; ++p) {
        ss += s0[p * 512 + c];
        qq += s0[p * 512 + 256 + c];
      }
      float mm = ss * invN;
      float vv = qq * invN - mm * mm;
      float s = gg0[c] * rsqrtf(vv + 1e-5f);
      scs[c] = s; shs[c] = bb0[c] - mm * s;
    }
    if (SMODE == 3) {
      const float* s1 = sums1A + (size_t)zi * s1str;
      const float* gg1; const float* bb1;
      SEL4(gg1, gb.g1, zi); SEL4(bb1, gb.b1, zi);
      for (int c = tid; c < CIN; c += 256) {
        float ss = 0.f, qq = 0.f;
#pragma unroll
        for (int p = 0; p < NCOPY; ++p) {
          ss += s1[p * 512 + c];
          qq += s1[p * 512 + 256 + c];
        }
        float mm = ss * invN;
        float vv = qq * invN - mm * mm;
        float s = gg1[c] * rsqrtf(vv + 1e-5f);
        sc2[c] = s; sh2[c] = bb1[c] - mm * s;
      }
    }
    __syncthreads();
  }
#pragma unroll
  for (int it = 0; it < (64 * CPR) / 256; ++it) {
    const int idx = it * 256 + tid;
    const int row = idx / CPR;
    const int cc = idx % CPR;
    bf16x8 v = *reinterpret_cast<const bf16x8*>(
        Tin + (size_t)(nbase + row) * CIN + cc * 8);
    if (SMODE >= 1) {
      bf16x8 sv;
      if (SMODE >= 2)
        sv = *reinterpret_cast<const bf16x8*>(
            Sin + (size_t)(nbase + row) * CIN + cc * 8);
      const int c0 = cc * 8;
#pragma unroll
      for (int j = 0; j < 8; ++j) {
        float x = __uint_as_float((unsigned)(unsigned short)v[j] << 16);
        x = fmaf(x, scs[c0 + j], shs[c0 + j]);
        if (SMODE == 2)
          x += __uint_as_float((unsigned)(unsigned short)sv[j] << 16);
        if (SMODE == 3) {
          float y = __uint_as_float((unsigned)(unsigned short)sv[j] << 16);
          x += fmaf(y, sc2[c0 + j], sh2[c0 + j]);
        }
        x = fmaxf(x, 0.f);
        v[j] = (short)f2bf(x);
      }
    }
    const int byte = (cc << 4) ^ ((row & 7) << 4);
    *reinterpret_cast<bf16x8*>(Xs + row * ROWB + byte) = v;
  }
  __syncthreads();
  // ---- W fragments for OC output groups ----
  bf16x8 af[KS][OC];
#pragma unroll
  for (int oc = 0; oc < OC; ++oc) {
    const unsigned short* Wr = Wb + (size_t)(obase + (oc << 6) + m) * CIN + (g << 3);
#pragma unroll
    for (int k = 0; k < KS; ++k)
      af[k][oc] = *reinterpret_cast<const bf16x8*>(Wr + (k << 5));
  }
  float sr[OC][4], qr[OC][4];
#pragma unroll
  for (int oc = 0; oc < OC; ++oc)
#pragma unroll
    for (int r = 0; r < 4; ++r) { sr[oc][r] = 0.f; qr[oc][r] = 0.f; }
#pragma unroll
  for (int nt = 0; nt < 4; ++nt) {
    const int row = (nt << 4) + m;
    const unsigned char* lrow = Xs + row * ROWB;
    const int swz = (row & 7) << 4;
    f32x4 acc[OC];
#pragma unroll
    for (int oc = 0; oc < OC; ++oc) acc[oc] = (f32x4){0.f, 0.f, 0.f, 0.f};
#pragma unroll
    for (int k = 0; k < KS; ++k) {
      const int byte = ((k << 6) + (g << 4)) ^ swz;
      bf16x8 bv = *reinterpret_cast<const bf16x8*>(lrow + byte);
#pragma unroll
      for (int oc = 0; oc < OC; ++oc)
        acc[oc] = __builtin_amdgcn_mfma_f32_16x16x32_bf16(af[k][oc], bv, acc[oc], 0, 0, 0);
    }
#pragma unroll
    for (int oc = 0; oc < OC; ++oc) {
      ushort4 v;
      v.x = f2bf(acc[oc][0]); v.y = f2bf(acc[oc][1]);
      v.z = f2bf(acc[oc][2]); v.w = f2bf(acc[oc][3]);
      *reinterpret_cast<ushort4*>(
          Yout + (size_t)(nbase + row) * COUT + obase + (oc << 6) + (g << 2)) = v;
#pragma unroll
      for (int r = 0; r < 4; ++r) {
        sr[oc][r] += acc[oc][r];
        qr[oc][r] = fmaf(acc[oc][r], acc[oc][r], qr[oc][r]);
      }
    }
  }
#pragma unroll
  for (int oc = 0; oc < OC; ++oc)
#pragma unroll
    for (int r = 0; r < 4; ++r) {
      for (int off = 1; off < 16; off <<= 1) {
        sr[oc][r] += __shfl_xor(sr[oc][r], off);
        qr[oc][r] += __shfl_xor(qr[oc][r], off);
      }
    }
  if (m == 0) {
    float* dst = outSums + (blockIdx.y & (NCOPY - 1)) * 512;
#pragma unroll
    for (int oc = 0; oc < OC; ++oc)
#pragma unroll
      for (int r = 0; r < 4; ++r) {
        atomicAdd(&dst[obase + (oc << 6) + (g << 2) + r], sr[oc][r]);
        atomicAdd(&dst[256 + obase + (oc << 6) + (g << 2) + r], qr[oc][r]);
      }
  }
}

// ---- writeout: fold conv6 stats inline, bn, LDS transpose, f32 out ---------
__global__ __launch_bounds__(256)
void writeout_t_kernel(const unsigned short* __restrict__ F0,
                       const float* __restrict__ sumsA,
                       GBArgs gb,
                       float* __restrict__ out0) {
  __shared__ float ts[64][66];
  __shared__ float sc[64], sh[64];
  const int tid = threadIdx.x;
  const int z = blockIdx.z;
  const size_t M1 = (size_t)1 << 20;
  const unsigned short* F = F0 + (size_t)z * M1;
  float* outp = out0 + (size_t)z * M1;
  if (tid < 64) {
    const float* sums = sumsA + (size_t)z * SSTR;
    const float* gg; const float* bb;
    SEL4(gg, gb.g0, z); SEL4(bb, gb.b0, z);
    float s0 = 0.f, q0 = 0.f;
#pragma unroll
    for (int p = 0; p < NCOPY; ++p) {
      s0 += sums[p * 512 + tid];
      q0 += sums[p * 512 + 256 + tid];
    }
    const float invN = 1.f / 16384.f;
    float mm = s0 * invN;
    float vv = q0 * invN - mm * mm;
    float s = gg[tid] * rsqrtf(vv + 1e-5f);
    sc[tid] = s; sh[tid] = bb[tid] - mm * s;
  }
  __syncthreads();
  const int n0 = blockIdx.x << 6;
  const int b = blockIdx.y;
  {
    const int n = tid >> 2, c0 = (tid & 3) << 4;
    const unsigned short* Fr = F + ((size_t)(b * 1024 + n0 + n) << 6) + c0;
    uint4 v0 = *reinterpret_cast<const uint4*>(Fr);
    uint4 v1 = *reinterpret_cast<const uint4*>(Fr + 8);
    unsigned vw[8] = {v0.x, v0.y, v0.z, v0.w, v1.x, v1.y, v1.z, v1.w};
#pragma unroll
    for (int jw = 0; jw < 8; ++jw) {
      int c = c0 + jw * 2;
      float x0 = __uint_as_float((vw[jw] & 0xffffu) << 16);
      float x1 = __uint_as_float((vw[jw] >> 16) << 16);
      ts[c][n] = fmaf(x0, sc[c], sh[c]);
      ts[c + 1][n] = fmaf(x1, sc[c + 1], sh[c + 1]);
    }
  }
  __syncthreads();
  const int c = tid >> 2, nq = (tid & 3) << 4;
  float* orow = outp + ((size_t)(b * 64 + c) << 10) + n0 + nq;
#pragma unroll
  for (int q = 0; q < 4; ++q) {
    float4 ov;
    ov.x = ts[c][nq + q * 4 + 0]; ov.y = ts[c][nq + q * 4 + 1];
    ov.z = ts[c][nq + q * 4 + 2]; ov.w = ts[c][nq + q * 4 + 3];
    *reinterpret_cast<float4*>(orow + q * 4) = ov;
  }
}

// ============================ host side =====================================
extern "C" void kernel_launch(void* const* d_in, const int* in_sizes, int n_in,
                              void* d_out, int out_size, void* d_ws, size_t ws_size,
                              hipStream_t stream) {
  float* wsf = (float*)d_ws;
  const size_t M1 = (size_t)1 << 20;
  const size_t H1 = (size_t)1 << 19;

  unsigned short* QAt = (unsigned short*)wsf;
  unsigned short* QBt = (unsigned short*)(wsf + H1);
  unsigned short* KAc = (unsigned short*)(wsf + 2 * H1);
  unsigned short* KBc = (unsigned short*)(wsf + 3 * H1);
  float* PART1 = wsf + 2 * M1;                             // [2M,6M): pv 2 + tpv 2
  unsigned short* Y0A = (unsigned short*)(wsf + 10 * M1);  // Y0A,Y0B @1M-float stride
  unsigned short* T1a = (unsigned short*)(wsf + 12 * M1);
  unsigned short* T2a = (unsigned short*)(wsf + 14 * M1);
  unsigned short* T3a = (unsigned short*)(wsf + 18 * M1);  // T3a,T5a,T3b,T5b @2M-float stride
  unsigned short* T4a = (unsigned short*)(wsf + 26 * M1);  // T4a,T4b @2M-float stride
  unsigned short* Fba = (unsigned short*)(wsf + 30 * M1);  // Fba,Fbb @0.5M-float stride
  float* tail = wsf + 31 * M1;
  float* bsum = tail;
  float* stats = tail + 16;
  unsigned short* wbf = (unsigned short*)(stats + 12 * SSTR);

  const float* pp[46];
  for (int i = 0; i < 46 && i < n_in; ++i) pp[i] = (const float*)d_in[i];

  const int initN = 16 + 12 * SSTR;
  init_kernel<<<(initN + 255) / 256, 256, 0, stream>>>(tail, initN);

  // weight order: w11a,w11b,w12a,w12b,w21a,w2sa,w21b,w2sb,w22a,w22b,woa,wob
  const int widx[12] = {10, 16, 13, 19, 22, 28, 31, 37, 25, 34, 40, 43};
  WcvtArgs wa;
  int woff[12];
  {
    int run = 0;
    for (int i = 0; i < 12; ++i) {
      wa.p[i] = pp[widx[i]];
      wa.sz[i] = in_sizes[widx[i]];
      wa.off[i] = run; woff[i] = run;
      run += in_sizes[widx[i]];
    }
  }
  wcvt_kernel<<<dim3(12, 16), 256, 0, stream>>>(wa, wbf);

  QKArgs qk;
  qk.X[0] = pp[0]; qk.W[0] = pp[2]; qk.B[0] = pp[3]; qk.Y[0] = QAt;
  qk.X[1] = pp[1]; qk.W[1] = pp[4]; qk.B[1] = pp[5]; qk.Y[1] = QBt;
  qk.X[2] = pp[0]; qk.W[2] = pp[6]; qk.B[2] = pp[7]; qk.Y[2] = KAc;
  qk.X[3] = pp[1]; qk.W[3] = pp[8]; qk.B[3] = pp[9]; qk.Y[3] = KBc;
  conv_qk_all_kernel<<<dim3(16, 2, 64), 256, 0, stream>>>(qk);

  attn_mfma_kernel<<<dim3(16, 2, 32), 256, 0, stream>>>(
      QAt, QBt, KAc, KBc, PART1, bsum);
  merge_kernel<<<dim3(16, BATCH, 2), 256, 0, stream>>>(PART1, pp[0], pp[1], Y0A, bsum);

  float* S_c1 = stats;               // conv1 (2 z)
  float* S_c2 = stats + 2 * SSTR;    // conv2 (2 z)
  float* S_q  = stats + 4 * SSTR;    // quad (4 z)
  float* S_c4 = stats + 8 * SSTR;    // conv4 (2 z)
  float* S_c6 = stats + 10 * SSTR;   // conv6 (2 z)

  const long SH1 = (long)2 * M1;     // 1M-float stride in shorts
  const long SH2 = (long)4 * M1;     // 2M-float stride in shorts
  GBArgs gbE = {};
  GBArgs gb;

  // conv1 (SMODE0, OC=2): Y0 -> T1
  conv_mfma_kernel<128, 2, 0, 0><<<dim3(1, 256, 2), 256, 0, stream>>>(
      Y0A, nullptr, wbf + woff[0], T1a, nullptr, 0, nullptr, 0, gbE,
      S_c1, 128, SH1, 0, 16384, SH1);

  // conv2 (SMODE1, OC=2): T1 -> T2
  gb = gbE;
  gb.g0[0] = pp[11]; gb.b0[0] = pp[12]; gb.g0[1] = pp[17]; gb.b0[1] = pp[18];
  conv_mfma_kernel<128, 2, 1, 0><<<dim3(1, 256, 2), 256, 0, stream>>>(
      T1a, nullptr, wbf + woff[2], T2a, S_c1, SSTR, nullptr, 0, gb,
      S_c2, 128, SH1, 0, 16384, SH1);

  // quad (SMODE2, OC=2): relu(bn(T2)+Y0) -> {T3a,T5a,T3b,T5b}
  gb = gbE;
  gb.g0[0] = pp[14]; gb.b0[0] = pp[15]; gb.g0[1] = pp[20]; gb.b0[1] = pp[21];
  conv_mfma_kernel<128, 2, 2, 1><<<dim3(2, 256, 4), 256, 0, stream>>>(
      T2a, Y0A, wbf + woff[4], T3a, S_c2, SSTR, nullptr, 0, gb,
      S_q, 256, SH1, SH1, 32768, SH2);

  // conv4 (SMODE1, OC=2): T3 -> T4
  gb = gbE;
  gb.g0[0] = pp[23]; gb.b0[0] = pp[24]; gb.g0[1] = pp[32]; gb.b0[1] = pp[33];
  conv_mfma_kernel<256, 2, 1, 0><<<dim3(2, 256, 2), 256, 0, stream>>>(
      T3a, nullptr, wbf + woff[8], T4a, S_q, 2 * SSTR, nullptr, 0, gb,
      S_c4, 256, (long)8 * M1, 0, 65536, SH2);

  // conv6 (SMODE3, OC=1): relu(bn(T4)+bn(T5)) -> Fb
  gb = gbE;
  gb.g0[0] = pp[26]; gb.b0[0] = pp[27]; gb.g0[1] = pp[35]; gb.b0[1] = pp[36];
  gb.g1[0] = pp[29]; gb.b1[0] = pp[30]; gb.g1[1] = pp[38]; gb.b1[1] = pp[39];
  conv_mfma_kernel<256, 1, 3, 0><<<dim3(1, 256, 2), 256, 0, stream>>>(
      T4a, T3a + SH2 /*T5a*/, wbf + woff[10], Fba, S_c4, SSTR,
      S_q + SSTR, 2 * SSTR, gb,
      S_c6, 64, SH2, (long)8 * M1, 16384, (long)M1);

  // writeout (folds conv6 stats inline)
  gb = gbE;
  gb.g0[0] = pp[41]; gb.b0[0] = pp[42]; gb.g0[1] = pp[44]; gb.b0[1] = pp[45];
  writeout_t_kernel<<<dim3(16, BATCH, 2), 256, 0, stream>>>(
      Fba, S_c6, gb, (float*)d_out);
}